// Round 10
// baseline (622.927 us; speedup 1.0000x reference)
//
#include <hip/hip_runtime.h>
#include <hip/hip_bf16.h>
#include <hip/hip_fp16.h>
#include <math.h>

#define Bq 2
#define Cq 64
#define Hq 192
#define Wq 192
#define HWq (Hq*Wq)            // 36864
#define Nq ((size_t)Bq*Cq*HWq) // 4718592

typedef __attribute__((ext_vector_type(8))) _Float16 f16x8;
typedef __attribute__((ext_vector_type(4))) float f32x4;

__device__ inline unsigned short h2us(__half h) {
  union { __half h; unsigned short u; } v; v.h = h; return v.u;
}

// ---------------------------------------------------------------------------
// Small prep (1 block)
// ---------------------------------------------------------------------------
__global__ __launch_bounds__(256) void prep_small_kernel(
    const float* hc1_w, const float* hc1_b, const float* hc2_w, const float* hc2_b,
    const float* hc3_w, const float* hc3_b,
    const float* vc1_w, const float* vc1_b, const float* vc2_w, const float* vc2_b,
    const float* vc3_w, const float* vc3_b,
    const float* h_off_w, const float* h_off_b, const float* h_bn_g, const float* h_bn_b,
    const float* h_bn_m, const float* h_bn_v,
    const float* v_off_w, const float* v_off_b, const float* v_bn_g, const float* v_bn_b,
    const float* v_bn_m, const float* v_bn_v,
    const float* last_w, const float* last_g, const float* last_b, const float* last_m,
    const float* last_v,
    float* wEffH, float* bEffH, float* wEffV, float* bEffV,
    float* wOffH, float* bOffH, float* wOffV, float* bOffV,
    float* lwT, float* lbO)
{
  int t = threadIdx.x;
  if (t < 128) {
    int ch = t & 63;
    bool ish = t < 64;
    const float* w1 = (ish ? hc1_w : vc1_w) + ch*9;
    const float* w2 = (ish ? hc2_w : vc2_w) + ch*7;
    const float* w3 = (ish ? hc3_w : vc3_w) + ch*5;
    float t15[15];
    for (int s = 0; s < 15; s++) {
      float a = 0.f;
      for (int j = 0; j < 9; j++) { int k2 = s - j; if (k2 >= 0 && k2 < 7) a += w1[j]*w2[k2]; }
      t15[s] = a;
    }
    float* we = (ish ? wEffH : wEffV) + ch*19;
    for (int s = 0; s < 19; s++) {
      float a = 0.f;
      for (int j = 0; j < 15; j++) { int k3 = s - j; if (k3 >= 0 && k3 < 5) a += t15[j]*w3[k3]; }
      we[s] = a;
    }
    float S2 = 0.f, S3 = 0.f;
    for (int j = 0; j < 7; j++) S2 += w2[j];
    for (int j = 0; j < 5; j++) S3 += w3[j];
    float b1 = (ish ? hc1_b : vc1_b)[ch];
    float b2 = (ish ? hc2_b : vc2_b)[ch];
    float b3 = (ish ? hc3_b : vc3_b)[ch];
    (ish ? bEffH : bEffV)[ch] = b1*S2*S3 + b2*S3 + b3;
  }
  for (int idx = t; idx < 9*64*7; idx += 256) {
    int tap = idx / 448; int rem = idx % 448; int i = rem / 7; int m = rem % 7;
    float invh = h_bn_g[m] / sqrtf(h_bn_v[m] + 1e-5f);
    wOffH[(tap*64 + i)*8 + m] = h_off_w[(m*64 + i)*9 + tap] * invh;
    float invv = v_bn_g[7+m] / sqrtf(v_bn_v[7+m] + 1e-5f);
    wOffV[(tap*64 + i)*8 + m] = v_off_w[((7+m)*64 + i)*9 + tap] * invv;
  }
  if (t < 7) {
    float invh = h_bn_g[t] / sqrtf(h_bn_v[t] + 1e-5f);
    bOffH[t] = h_off_b[t]*invh + h_bn_b[t] - h_bn_m[t]*invh;
    float invv = v_bn_g[7+t] / sqrtf(v_bn_v[7+t] + 1e-5f);
    bOffV[t] = v_off_b[7+t]*invv + v_bn_b[7+t] - v_bn_m[7+t]*invv;
  }
  for (int idx = t; idx < 4096; idx += 256) {
    int o = idx % 64; int i = idx / 64;
    float inv = last_g[o] / sqrtf(last_v[o] + 1e-3f);
    lwT[i*64 + o] = last_w[o*64 + i] * inv;
  }
  if (t < 64) {
    float inv = last_g[t] / sqrtf(last_v[t] + 1e-3f);
    lbO[t] = last_b[t] - last_m[t]*inv;
  }
}

// ---------------------------------------------------------------------------
// Border prep (impulse-response composed clipped 19-tap weights)
// ---------------------------------------------------------------------------
__global__ __launch_bounds__(256) void prep_border_kernel(
    const float* hc1_w, const float* hc1_b, const float* hc2_w, const float* hc2_b,
    const float* hc3_w, const float* hc3_b,
    const float* vc1_w, const float* vc1_b, const float* vc2_w, const float* vc2_b,
    const float* vc3_w, const float* vc3_b,
    float* wB)
{
  int tid = blockIdx.x*256 + threadIdx.x;
  if (tid >= 2*64*18) return;
  int cls = tid % 18;
  int ch  = (tid / 18) % 64;
  int br  = tid / (18*64);
  int c = (cls < 9) ? cls : cls + 174;
  const float* w1 = (br==0 ? hc1_w : vc1_w) + ch*9;
  const float* w2 = (br==0 ? hc2_w : vc2_w) + ch*7;
  const float* w3 = (br==0 ? hc3_w : vc3_w) + ch*5;
  float b1 = (br==0 ? hc1_b : vc1_b)[ch];
  float b2 = (br==0 ? hc2_b : vc2_b)[ch];
  float b3 = (br==0 ? hc3_b : vc3_b)[ch];
  float* dst = wB + ((size_t)(br*64 + ch)*18 + cls)*20;
  for (int cse = 0; cse < 20; cse++) {
    bool basis = (cse < 19);
    int fd = c + cse - 9;
    float B1 = basis ? 0.f : b1, B2 = basis ? 0.f : b2, B3 = basis ? 0.f : b3;
    float o3 = B3;
    for (int m = 0; m < 5; m++) {
      int d = c + m - 2;
      if (d < 0 || d >= Wq) continue;
      float o2 = B2;
      for (int k = 0; k < 7; k++) {
        int e = d + k - 3;
        if (e < 0 || e >= Wq) continue;
        float o1 = B1;
        if (basis) {
          int tp = fd - e + 4;
          if (tp >= 0 && tp < 9 && fd >= 0 && fd < Wq) o1 += w1[tp];
        }
        o2 += o1 * w2[k];
      }
      o3 += o2 * w3[m];
    }
    dst[cse] = o3;
  }
}

// ---------------------------------------------------------------------------
// Big prep: dsc weights -> f16 hi/lo MFMA pack [tap][kc][hl][oc][32]
//           + w_first f16 hi/lo pack for conv7.
// ---------------------------------------------------------------------------
__global__ __launch_bounds__(256) void prep_big_kernel(
    const float* __restrict__ w_first,
    const float* __restrict__ h_dsc_w, const float* __restrict__ v_dsc_w,
    unsigned short* __restrict__ wtpH, unsigned short* __restrict__ wtpV,
    unsigned short* __restrict__ wpack)
{
  int tid = blockIdx.x*256 + threadIdx.x;
  int nthr = gridDim.x*256;
  for (int idx = tid; idx < 7*2*2*64*32; idx += nthr) {
    int ch32 = idx & 31;
    int oc   = (idx >> 5) & 63;
    int hl   = (idx >> 11) & 1;
    int kc   = (idx >> 12) & 1;
    int tap  = idx >> 13;
    int i = kc*32 + ch32;
    float vh = h_dsc_w[oc*448 + i*7 + tap];
    float vv = v_dsc_w[oc*448 + i*7 + tap];
    _Float16 hh = (_Float16)vh;
    _Float16 hv = (_Float16)vv;
    unsigned short uh, uv;
    if (!hl) { uh = *(unsigned short*)&hh; uv = *(unsigned short*)&hv; }
    else {
      _Float16 lh = (_Float16)(vh - (float)hh);
      _Float16 lv = (_Float16)(vv - (float)hv);
      uh = *(unsigned short*)&lh; uv = *(unsigned short*)&lv;
    }
    wtpH[idx] = uh; wtpV[idx] = uv;
  }
  for (int e = tid; e < 2*49*2*64*32; e += nthr) {
    int ch  = e & 31;
    int oc  = (e >> 5) & 63;
    int hl  = (e >> 11) & 1;
    int rest = e >> 12;
    int tap = rest % 49;
    int h   = rest / 49;
    float wv = w_first[((size_t)oc*64 + h*32 + ch)*49 + tap];
    __half hh = __float2half(wv);
    unsigned short us;
    if (!hl) us = h2us(hh);
    else { float rr = wv - __half2float(hh); us = h2us(__float2half(rr)); }
    wpack[e] = us;
  }
}

// ---------------------------------------------------------------------------
// x (NCHW f32) -> xpack single f16: [b][r][c][64] (8 granules of 8 ch)
// ---------------------------------------------------------------------------
__global__ __launch_bounds__(192) void tof16_pack_kernel(const float* __restrict__ x,
                                                         unsigned short* __restrict__ xpack)
{
  __shared__ unsigned int s[192*64];
  int r = blockIdx.x, b = blockIdx.y;
  int t = threadIdx.x;
  for (int ch = 0; ch < 64; ch++) {
    float v = x[((size_t)(b*64+ch)*Hq + r)*Wq + t];
    _Float16 hh = (_Float16)v;
    s[t*64 + (ch ^ (t & 31))] = (unsigned int)*(unsigned short*)&hh;
  }
  __syncthreads();
  unsigned short* dst = xpack + ((size_t)b*Hq + r)*Wq*64;
  for (int i = 0; i < 8; i++) {
    int gidx = i*192 + t;                // 1536 granules of 16B
    int c = gidx >> 3, g = gidx & 7;
    unsigned short tmp[8];
#pragma unroll
    for (int j = 0; j < 8; j++) {
      int ch = g*8 + j;
      tmp[j] = (unsigned short)s[c*64 + (ch ^ (c & 31))];
    }
    uint4 v;
    v.x = (unsigned int)tmp[0] | ((unsigned int)tmp[1] << 16);
    v.y = (unsigned int)tmp[2] | ((unsigned int)tmp[3] << 16);
    v.z = (unsigned int)tmp[4] | ((unsigned int)tmp[5] << 16);
    v.w = (unsigned int)tmp[6] | ((unsigned int)tmp[7] << 16);
    *(uint4*)(dst + (size_t)gidx*8) = v;
  }
}

// ---------------------------------------------------------------------------
// feat (NCHW f32) -> fpack PLANE-MAJOR: [b][sub(16)][px][8ch] f16 hi/lo
// ---------------------------------------------------------------------------
__global__ __launch_bounds__(192) void fpack_kernel(const float* __restrict__ in,
                                                    unsigned short* __restrict__ pack)
{
  __shared__ unsigned int s[192*64];
  int r = blockIdx.x, b = blockIdx.y;
  int t = threadIdx.x;
  for (int ch = 0; ch < 64; ch++) {
    float v = in[((size_t)(b*64+ch)*Hq + r)*Wq + t];
    __half hh = __float2half(v);
    float rr = v - __half2float(hh);
    __half hl = __float2half(rr);
    unsigned int pk = (unsigned int)h2us(hh) | ((unsigned int)h2us(hl) << 16);
    s[t*64 + (ch ^ (t & 31))] = pk;
  }
  __syncthreads();
#pragma unroll
  for (int sub = 0; sub < 16; sub++) {
    int hl = sub >> 3, g8 = sub & 7;
    unsigned short tmp[8];
#pragma unroll
    for (int j = 0; j < 8; j++) {
      int ch = g8*8 + j;
      unsigned int u = s[t*64 + (ch ^ (t & 31))];
      tmp[j] = hl ? (unsigned short)(u >> 16) : (unsigned short)(u & 0xffff);
    }
    uint4 v;
    v.x = (unsigned int)tmp[0] | ((unsigned int)tmp[1] << 16);
    v.y = (unsigned int)tmp[2] | ((unsigned int)tmp[3] << 16);
    v.z = (unsigned int)tmp[4] | ((unsigned int)tmp[5] << 16);
    v.w = (unsigned int)tmp[6] | ((unsigned int)tmp[7] << 16);
    *(uint4*)(pack + (((size_t)b*16 + sub)*HWq + r*Wq + t)*8) = v;
  }
}

// ---------------------------------------------------------------------------
// 7x7 conv via MFMA, 2-pass (x single f16, w hi/lo exact), B staged in LDS
// per 2-tap group so all waves share one L2 fetch per block.
// Block: 192 thr = 3 waves; wave = 1 output row x 48 cols; 64 oc.
// Grid 4x64x2 = 512 blocks (2/CU). LDS: A 31.1 KB + B 16 KB = 47.5 KB.
// ---------------------------------------------------------------------------
__global__ __launch_bounds__(192) void conv7_mfma_kernel(
    const unsigned short* __restrict__ xpack,   // [b][r][c][64] f16
    const unsigned short* __restrict__ wpack,   // [h][tap][hl][oc][32] f16
    float* __restrict__ out)
{
  __shared__ __align__(16) unsigned short sA[9*54*32];   // 31104 B
  __shared__ __align__(16) unsigned short sB[2*2*64*32]; // 16384 B
  int ct = blockIdx.x;          // 0..3
  int rt = blockIdx.y;          // 0..63
  int b  = blockIdx.z;
  int r0 = rt*3, c0 = ct*48;
  int t = threadIdx.x;
  int w = t >> 6;
  int l = t & 63;
  int l15 = l & 15, lg = l >> 4;

  f32x4 acc[3][4];
#pragma unroll
  for (int i = 0; i < 3; i++)
#pragma unroll
    for (int j = 0; j < 4; j++) acc[i][j] = (f32x4){0.f,0.f,0.f,0.f};

  for (int h = 0; h < 2; h++) {
    __syncthreads();            // prev half's sA/sB readers done
    // ---- stage A: 9 rows x 54 cols x 4 granules (32 ch of this half) ------
    for (int idx = t; idx < 9*54*4; idx += 192) {
      int g = idx & 3, pix = idx >> 2;
      int row = pix / 54, col = pix % 54;
      int gr = r0 - 3 + row, gc = c0 - 3 + col;
      uint4 v = {0u,0u,0u,0u};
      if (gr >= 0 && gr < Hq && gc >= 0 && gc < Wq)
        v = *(const uint4*)(xpack + (((size_t)b*Hq + gr)*Wq + gc)*64 + (h*4 + g)*8);
      ((uint4*)sA)[(row*54 + col)*4 + (g ^ ((col >> 1) & 3))] = v;
    }
    for (int tg = 0; tg < 25; tg++) {
      int ntap = (tg < 24) ? 2 : 1;
      __syncthreads();          // sB readers done (and sA staged, for tg==0)
      // ---- stage B group: linear-coalesced copy, swizzled granule dest ----
      {
        const uint4* src = (const uint4*)(wpack + ((size_t)(h*49 + tg*2))*4096);
        for (int idx = t; idx < ntap*512; idx += 192) {
          int tp = idx >> 9, rem = idx & 511;
          int hl2 = rem >> 8, oc = (rem >> 2) & 63, lg2 = rem & 3;
          ((uint4*)sB)[tp*512 + hl2*256 + oc*4 + (lg2 ^ ((oc >> 1) & 3))] = src[idx];
        }
      }
      __syncthreads();
      for (int tp = 0; tp < ntap; tp++) {
        int tap = tg*2 + tp;
        int dy = tap / 7, dx = tap % 7;
        f16x8 bh[4], bl[4];
#pragma unroll
        for (int tb = 0; tb < 4; tb++) {
          int oc = tb*16 + l15;
          bh[tb] = *(const f16x8*)((const uint4*)sB + tp*512 +       oc*4 + (lg ^ ((oc >> 1) & 3)));
          bl[tb] = *(const f16x8*)((const uint4*)sB + tp*512 + 256 + oc*4 + (lg ^ ((oc >> 1) & 3)));
        }
        int arow = w + dy;
        f16x8 a[3];
#pragma unroll
        for (int ta = 0; ta < 3; ta++) {
          int col = ta*16 + l15 + dx;
          a[ta] = *(const f16x8*)((const uint4*)sA + (arow*54 + col)*4 + (lg ^ ((col >> 1) & 3)));
        }
#pragma unroll
        for (int ta = 0; ta < 3; ta++)
#pragma unroll
          for (int tb = 0; tb < 4; tb++) {
            acc[ta][tb] = __builtin_amdgcn_mfma_f32_16x16x32_f16(a[ta], bh[tb], acc[ta][tb], 0, 0, 0);
            acc[ta][tb] = __builtin_amdgcn_mfma_f32_16x16x32_f16(a[ta], bl[tb], acc[ta][tb], 0, 0, 0);
          }
      }
    }
  }
#pragma unroll
  for (int tb = 0; tb < 4; tb++) {
    int oc = tb*16 + l15;
    float* dst = out + ((size_t)(b*64 + oc)*Hq + (r0 + w))*Wq + c0;
#pragma unroll
    for (int ta = 0; ta < 3; ta++) {
      f32x4 v = acc[ta][tb];
      *(float4*)(dst + ta*16 + lg*4) = make_float4(v[0], v[1], v[2], v[3]);
    }
  }
}

// ---------------------------------------------------------------------------
// Separable 7x7 avg pool
// ---------------------------------------------------------------------------
__global__ __launch_bounds__(256) void pool_row_kernel(const float* __restrict__ in, float* __restrict__ out)
{
  int idx = blockIdx.x*256 + threadIdx.x;
  int c = idx % Wq;
  int base = idx - c;
  float s = 0.f;
#pragma unroll
  for (int dc = -3; dc <= 3; dc++) {
    int cc = c + dc;
    if (cc >= 0 && cc < Wq) s += in[base + cc];
  }
  out[idx] = s;
}

__global__ __launch_bounds__(256) void pool_col_kernel(const float* __restrict__ in, float* __restrict__ out)
{
  int idx = blockIdx.x*256 + threadIdx.x;
  int c = idx % Wq;
  int r = (idx / Wq) % Hq;
  int plane = idx / HWq;
  float s = 0.f;
#pragma unroll
  for (int dr = -3; dr <= 3; dr++) {
    int rr = r + dr;
    if (rr >= 0 && rr < Hq) s += in[(size_t)plane*HWq + rr*Wq + c];
  }
  out[idx] = s * (1.f/49.f);
}

// ---------------------------------------------------------------------------
// Depthwise chain: uniform 19-tap, class-selected weights
// ---------------------------------------------------------------------------
__global__ __launch_bounds__(256) void dw_h_kernel(const float* __restrict__ x1,
                                                   const float* __restrict__ wEff,
                                                   const float* __restrict__ bEff,
                                                   const float* __restrict__ wB,
                                                   float* __restrict__ out)
{
  __shared__ float sW[19][20];
  int b = blockIdx.z, ch = blockIdx.y;
  int t = threadIdx.x;
  for (int i = t; i < 380; i += 256) {
    int row = i / 20, jj = i % 20;
    float v;
    if (row < 18) v = wB[((size_t)ch*18 + row)*20 + jj];
    else v = (jj < 19) ? wEff[ch*19 + jj] : bEff[ch];
    sW[row][jj] = v;
  }
  __syncthreads();
  int p = blockIdx.x*256 + t;
  int r = p / Wq, c = p % Wq;
  const float* src = x1 + (size_t)(b*Cq + ch)*HWq + r*Wq;
  int row = (c < 9) ? c : ((c >= Wq-9) ? (c - 174) : 18);
  float s = sW[row][19];
#pragma unroll
  for (int j = 0; j < 19; j++) {
    int idx = min(max(c + j - 9, 0), Wq-1);
    s += src[idx] * sW[row][j];
  }
  out[(size_t)(b*Cq + ch)*HWq + p] = s;
}

__global__ __launch_bounds__(256) void dw_v_kernel(const float* __restrict__ x1,
                                                   const float* __restrict__ wEff,
                                                   const float* __restrict__ bEff,
                                                   const float* __restrict__ wB,
                                                   float* __restrict__ out)
{
  __shared__ float sW[19][20];
  int b = blockIdx.z, ch = blockIdx.y;
  int t = threadIdx.x;
  for (int i = t; i < 380; i += 256) {
    int row = i / 20, jj = i % 20;
    float v;
    if (row < 18) v = wB[((size_t)ch*18 + row)*20 + jj];
    else v = (jj < 19) ? wEff[ch*19 + jj] : bEff[ch];
    sW[row][jj] = v;
  }
  __syncthreads();
  int p = blockIdx.x*256 + t;
  int r = p / Wq, c = p % Wq;
  const float* src = x1 + (size_t)(b*Cq + ch)*HWq + c;
  int row = (r < 9) ? r : ((r >= Hq-9) ? (r - 174) : 18);
  float s = sW[row][19];
#pragma unroll
  for (int j = 0; j < 19; j++) {
    int idx = min(max(r + j - 9, 0), Hq-1);
    s += src[idx*Wq] * sW[row][j];
  }
  out[(size_t)(b*Cq + ch)*HWq + p] = s;
}

// ---------------------------------------------------------------------------
// Offset conv + tanh + cum, reading plane-major fpack (coalesced)
// ---------------------------------------------------------------------------
__global__ __launch_bounds__(256) void off_cum_kernel(const unsigned short* __restrict__ fp,
                                                      const float* __restrict__ wOff,
                                                      const float* __restrict__ bOff,
                                                      float* __restrict__ cum)
{
  const size_t HW8 = (size_t)HWq*8;
  int b = blockIdx.y;
  int p = blockIdx.x*256 + threadIdx.x;
  int r = p / Wq, c = p % Wq;
  float tv[7];
#pragma unroll
  for (int m = 0; m < 7; m++) tv[m] = bOff[m];
  const unsigned short* fb = fp + (size_t)b*HWq*128;
  for (int tap = 0; tap < 9; tap++) {
    int dy = tap/3 - 1, dx = tap%3 - 1;
    int rr = r + dy, cc = c + dx;
    if (rr < 0 || rr >= Hq || cc < 0 || cc >= Wq) continue;
    const unsigned short* p0 = fb + ((size_t)rr*Wq + cc)*8;
    const float* wp = wOff + tap*512;
    for (int g = 0; g < 8; g++) {
      f16x8 hv = *(const f16x8*)(p0 + (size_t)g*HW8);
      f16x8 lv = *(const f16x8*)(p0 + (size_t)(8 + g)*HW8);
#pragma unroll
      for (int e = 0; e < 8; e++) {
        float fv = (float)hv[e] + (float)lv[e];
        const float* wr = wp + (g*8 + e)*8;
#pragma unroll
        for (int m = 0; m < 7; m++) tv[m] += fv * wr[m];
      }
    }
  }
#pragma unroll
  for (int m = 0; m < 7; m++) tv[m] = tanhf(tv[m]);
  float c0 = tv[0], c1 = tv[1] + tv[2], c2 = tv[2], c3 = 0.f;
  float c4 = tv[4], c5 = tv[4] + tv[5], c6 = tv[6];
  size_t bb = (size_t)b*7*HWq + p;
  cum[bb + 0*HWq] = c0; cum[bb + 1*HWq] = c1; cum[bb + 2*HWq] = c2;
  cum[bb + 3*HWq] = c3; cum[bb + 4*HWq] = c4; cum[bb + 5*HWq] = c5;
  cum[bb + 6*HWq] = c6;
}

// ---------------------------------------------------------------------------
// Deformable sample + einsum via MFMA (f16 hi/lo 3-pass).
// Plane-major fpack reads + XCD-banded block swizzle.
// ---------------------------------------------------------------------------
template<int MORPH>
__global__ __launch_bounds__(128) void einsum_mfma_kernel(
    const unsigned short* __restrict__ fp,   // fpack [b][sub16][px][8]
    const float* __restrict__ cum,
    const unsigned short* __restrict__ wtp,  // [tap][kc][hl][oc][32] f16
    const float* __restrict__ dsc_b,
    float* __restrict__ out)                 // NCHW f32
{
  __shared__ __align__(16) unsigned short sA[2*64*128];  // 32 KB
  const size_t HW8 = (size_t)HWq*8;
  int bid = blockIdx.x;                   // 0..575
  int swz = (bid & 7)*72 + (bid >> 3);    // XCD-contiguous bands (576 = 8*72)
  int b   = swz / 288;
  int blk = swz % 288;
  int t = threadIdx.x;
  int w = t >> 6, l = t & 63;
  int l15 = l & 15, lg = l >> 4;
  int p = blk*128 + w*64 + l;
  int r = p / Wq, c = p % Wq;

  f32x4 acc[4][4];
#pragma unroll
  for (int i = 0; i < 4; i++)
#pragma unroll
    for (int j = 0; j < 4; j++) acc[i][j] = (f32x4){0.f,0.f,0.f,0.f};

  const unsigned short* fb = fp + (size_t)b*HWq*128;
  unsigned short* myrow = sA + (size_t)(w*64 + l)*128;

  for (int k = 0; k < 7; k++) {
    bool oob;
    const unsigned short *p0, *p1;
    float w0, w1;
    if (MORPH == 0) {
      int xi = c + k - 3;
      oob = (xi < 0 || xi >= Wq);
      if (!oob) {
        float y = (float)r + cum[((size_t)(b*7 + k))*HWq + p];
        float y0 = floorf(y);
        int y0q = (int)y0;
        int y0i = min(max(y0q, 0), Hq-1);
        int y1i = min(max(y0q + 1, 0), Hq-1);
        float y0f = fminf(fmaxf(y0, 0.f), (float)Hq);
        float y1f = fminf(fmaxf(y0 + 1.f, 0.f), (float)Hq);
        w0 = y1f - y; w1 = y - y0f;
        p0 = fb + ((size_t)y0i*Wq + xi)*8;
        p1 = fb + ((size_t)y1i*Wq + xi)*8;
      }
    } else {
      int yi = r + k - 3;
      oob = (yi < 0 || yi >= Hq);
      if (!oob) {
        float xf = (float)c + cum[((size_t)(b*7 + k))*HWq + p];
        float x0 = floorf(xf);
        int x0q = (int)x0;
        int x0i = min(max(x0q, 0), Wq-1);
        int x1i = min(max(x0q + 1, 0), Wq-1);
        float x0f = fminf(fmaxf(x0, 0.f), (float)Wq);
        float x1f = fminf(fmaxf(x0 + 1.f, 0.f), (float)Wq);
        w0 = x1f - xf; w1 = xf - x0f;
        p0 = fb + ((size_t)yi*Wq + x0i)*8;
        p1 = fb + ((size_t)yi*Wq + x1i)*8;
      }
    }
    if (oob) {
      uint4 z = {0u,0u,0u,0u};
#pragma unroll
      for (int j = 0; j < 16; j++) ((uint4*)myrow)[j] = z;
    } else {
#pragma unroll
      for (int g = 0; g < 8; g++) {
        f16x8 a0h = *(const f16x8*)(p0 + (size_t)g*HW8);
        f16x8 a0l = *(const f16x8*)(p0 + (size_t)(8 + g)*HW8);
        f16x8 a1h = *(const f16x8*)(p1 + (size_t)g*HW8);
        f16x8 a1l = *(const f16x8*)(p1 + (size_t)(8 + g)*HW8);
        f16x8 sh, sl;
#pragma unroll
        for (int e = 0; e < 8; e++) {
          float v = w0*((float)a0h[e] + (float)a0l[e]) + w1*((float)a1h[e] + (float)a1l[e]);
          _Float16 vh = (_Float16)v;
          sh[e] = vh;
          sl[e] = (_Float16)(v - (float)vh);
        }
        *(f16x8*)(myrow + (size_t)(g ^ l15)*8)       = sh;
        *(f16x8*)(myrow + (size_t)((8 + g) ^ l15)*8) = sl;
      }
    }
    __syncthreads();
#pragma unroll
    for (int kc = 0; kc < 2; kc++) {
      const unsigned short* wbase = wtp + (size_t)((k*2 + kc)*2)*2048;
      f16x8 bh[4], bl[4];
#pragma unroll
      for (int tb = 0; tb < 4; tb++) {
        bh[tb] = *(const f16x8*)(wbase + (tb*16 + l15)*32 + lg*8);
        bl[tb] = *(const f16x8*)(wbase + 2048 + (tb*16 + l15)*32 + lg*8);
      }
      f16x8 ah[4], al[4];
#pragma unroll
      for (int ta = 0; ta < 4; ta++) {
        const unsigned short* rbase = sA + (size_t)(w*64 + ta*16 + l15)*128;
        ah[ta] = *(const f16x8*)(rbase + (size_t)((kc*4 + lg) ^ l15)*8);
        al[ta] = *(const f16x8*)(rbase + (size_t)((8 + kc*4 + lg) ^ l15)*8);
      }
#pragma unroll
      for (int ta = 0; ta < 4; ta++)
#pragma unroll
        for (int tb = 0; tb < 4; tb++) {
          acc[ta][tb] = __builtin_amdgcn_mfma_f32_16x16x32_f16(ah[ta], bh[tb], acc[ta][tb], 0, 0, 0);
          acc[ta][tb] = __builtin_amdgcn_mfma_f32_16x16x32_f16(ah[ta], bl[tb], acc[ta][tb], 0, 0, 0);
          acc[ta][tb] = __builtin_amdgcn_mfma_f32_16x16x32_f16(al[ta], bh[tb], acc[ta][tb], 0, 0, 0);
        }
    }
    __syncthreads();
  }
  int pbase = blk*128 + w*64;
#pragma unroll
  for (int tb = 0; tb < 4; tb++) {
    int oc = tb*16 + l15;
    float bias = dsc_b[oc];
    float* dst = out + (size_t)(b*64 + oc)*HWq + pbase;
#pragma unroll
    for (int ta = 0; ta < 4; ta++) {
      f32x4 v = acc[ta][tb];
      *(float4*)(dst + ta*16 + lg*4) = make_float4(v[0]+bias, v[1]+bias, v[2]+bias, v[3]+bias);
    }
  }
}

// ---------------------------------------------------------------------------
// GroupNorm stats + finalize + combine + final 1x1 + SiLU
// ---------------------------------------------------------------------------
__global__ __launch_bounds__(256) void gnstats_kernel(const float* __restrict__ h_ds,
                                                      const float* __restrict__ v_ds,
                                                      float* __restrict__ stats)
{
  int plane = blockIdx.x;
  int buf = plane >> 7;
  int rem = plane & 127;
  const float* src = (buf ? v_ds : h_ds) + (size_t)rem*HWq;
  float s = 0.f, s2 = 0.f;
  for (int i = threadIdx.x; i < HWq; i += 256) {
    float v = src[i];
    s += v; s2 += v*v;
  }
  __shared__ float red[2][4];
  for (int off = 32; off; off >>= 1) {
    s  += __shfl_down(s, off);
    s2 += __shfl_down(s2, off);
  }
  if ((threadIdx.x & 63) == 0) { red[0][threadIdx.x >> 6] = s; red[1][threadIdx.x >> 6] = s2; }
  __syncthreads();
  if (threadIdx.x == 0) {
    s  = red[0][0] + red[0][1] + red[0][2] + red[0][3];
    s2 = red[1][0] + red[1][1] + red[1][2] + red[1][3];
    stats[plane*2 + 0] = s;
    stats[plane*2 + 1] = s2;
  }
}

__global__ __launch_bounds__(256) void gnfinal_kernel(const float* __restrict__ stats,
                                                      const float* __restrict__ h_gn_g, const float* __restrict__ h_gn_b,
                                                      const float* __restrict__ v_gn_g, const float* __restrict__ v_gn_b,
                                                      float* __restrict__ gnAB)
{
  int t = threadIdx.x;
  int buf = t >> 7, ch = t & 63;
  int base = t & ~3;
  float sum = 0.f, ss = 0.f;
#pragma unroll
  for (int q = 0; q < 4; q++) { sum += stats[(base+q)*2]; ss += stats[(base+q)*2 + 1]; }
  const float n = 4.f * HWq;
  float mean = sum / n;
  float var = ss / n - mean*mean;
  float gg = (buf ? v_gn_g : h_gn_g)[ch];
  float bb = (buf ? v_gn_b : h_gn_b)[ch];
  float A = gg / sqrtf(var + 1e-5f);
  gnAB[t*2 + 0] = A;
  gnAB[t*2 + 1] = bb - mean*A;
}

__global__ __launch_bounds__(256) void combine_kernel(const float* __restrict__ h_ds,
                                                      const float* __restrict__ v_ds,
                                                      const float* __restrict__ x1,
                                                      const float* __restrict__ gnAB,
                                                      float* __restrict__ comb)
{
  size_t idx = (size_t)blockIdx.x*256 + threadIdx.x;
  int plane = (int)(idx / HWq);
  int ih = plane*2;
  int iv = (128 + plane)*2;
  float hv = h_ds[idx]*gnAB[ih] + gnAB[ih+1]; hv = fmaxf(hv, 0.f);
  float vv = v_ds[idx]*gnAB[iv] + gnAB[iv+1]; vv = fmaxf(vv, 0.f);
  comb[idx] = hv + vv + x1[idx];
}

__global__ __launch_bounds__(256) void final_kernel(const float* __restrict__ comb,
                                                    const float* __restrict__ lwT,
                                                    const float* __restrict__ lbO,
                                                    float* __restrict__ out)
{
  int b = blockIdx.y;
  int p = blockIdx.x*256 + threadIdx.x;
  const float* cb = comb + (size_t)b*Cq*HWq + p;
  float acc[64];
#pragma unroll
  for (int o = 0; o < 64; o++) acc[o] = 0.f;
  for (int i = 0; i < 64; i++) {
    float cv = cb[(size_t)i*HWq];
    const float* wr = lwT + i*64;
#pragma unroll
    for (int o = 0; o < 64; o++) acc[o] += cv * wr[o];
  }
  float* dst = out + (size_t)b*Cq*HWq + p;
#pragma unroll
  for (int o = 0; o < 64; o++) {
    float yv = acc[o] + lbO[o];
    dst[(size_t)o*HWq] = yv / (1.f + expf(-yv));
  }
}

// ---------------------------------------------------------------------------
extern "C" void kernel_launch(void* const* d_in, const int* in_sizes, int n_in,
                              void* d_out, int out_size, void* d_ws, size_t ws_size,
                              hipStream_t stream)
{
  const float* x       = (const float*)d_in[0];
  const float* w_first = (const float*)d_in[1];
  float* ws = (float*)d_ws;

  float* bufA = ws;            // conv7 out -> hfeat -> h-einsum-out
  float* bufB = ws + Nq;       // rowsum -> vfeat -> v-einsum-out
  float* x1   = ws + 2*Nq;
  float* h_ds = ws + 3*Nq;     // xpack -> fpackH -> comb
  float* v_ds = ws + 4*Nq;     // fpackV
  size_t off = 5*Nq;
  float* hcum  = ws + off; off += (size_t)Bq*7*HWq;
  float* vcum  = ws + off; off += (size_t)Bq*7*HWq;
  float* wEffH = ws + off; off += 64*19;
  float* bEffH = ws + off; off += 64;
  float* wEffV = ws + off; off += 64*19;
  float* bEffV = ws + off; off += 64;
  float* wtH   = ws + off; off += 64*64*7;   // holds wtpH f16 pack
  float* wtV   = ws + off; off += 64*64*7;   // holds wtpV f16 pack
  float* wOffH = ws + off; off += 9*64*8;
  float* bOffH = ws + off; off += 8;
  float* wOffV = ws + off; off += 9*64*8;
  float* bOffV = ws + off; off += 8;
  float* lwT   = ws + off; off += 64*64;
  float* lbO   = ws + off; off += 64;
  float* stats = ws + off; off += 512;
  float* gnAB  = ws + off; off += 512;
  float* wB    = ws + off; off += 2*64*18*20;
  unsigned short* wpack = (unsigned short*)(ws + off); off += 2*49*2*64*32/2 + 16;
  unsigned short* xpack  = (unsigned short*)h_ds;
  unsigned short* fpackH = (unsigned short*)h_ds;
  unsigned short* fpackV = (unsigned short*)v_ds;
  unsigned short* wtpH = (unsigned short*)wtH;
  unsigned short* wtpV = (unsigned short*)wtV;

  prep_small_kernel<<<dim3(1), dim3(256), 0, stream>>>(
      (const float*)d_in[2],  (const float*)d_in[3],  (const float*)d_in[4],  (const float*)d_in[5],
      (const float*)d_in[6],  (const float*)d_in[7],
      (const float*)d_in[8],  (const float*)d_in[9],  (const float*)d_in[10], (const float*)d_in[11],
      (const float*)d_in[12], (const float*)d_in[13],
      (const float*)d_in[14], (const float*)d_in[15], (const float*)d_in[16], (const float*)d_in[17],
      (const float*)d_in[18], (const float*)d_in[19],
      (const float*)d_in[24], (const float*)d_in[25], (const float*)d_in[26], (const float*)d_in[27],
      (const float*)d_in[28], (const float*)d_in[29],
      (const float*)d_in[34], (const float*)d_in[35], (const float*)d_in[36], (const float*)d_in[37],
      (const float*)d_in[38],
      wEffH, bEffH, wEffV, bEffV, wOffH, bOffH, wOffV, bOffV, lwT, lbO);

  prep_border_kernel<<<dim3(9), dim3(256), 0, stream>>>(
      (const float*)d_in[2],  (const float*)d_in[3],  (const float*)d_in[4],  (const float*)d_in[5],
      (const float*)d_in[6],  (const float*)d_in[7],
      (const float*)d_in[8],  (const float*)d_in[9],  (const float*)d_in[10], (const float*)d_in[11],
      (const float*)d_in[12], (const float*)d_in[13], wB);

  prep_big_kernel<<<dim3(64), dim3(256), 0, stream>>>(
      w_first, (const float*)d_in[20], (const float*)d_in[30], wtpH, wtpV, wpack);

  tof16_pack_kernel<<<dim3(Hq, Bq), dim3(192), 0, stream>>>(x, xpack);
  conv7_mfma_kernel<<<dim3(4, 64, 2), dim3(192), 0, stream>>>(xpack, wpack, bufA);

  pool_row_kernel<<<dim3(18432), dim3(256), 0, stream>>>(bufA, bufB);
  pool_col_kernel<<<dim3(18432), dim3(256), 0, stream>>>(bufB, x1);

  dw_h_kernel<<<dim3(144, 64, 2), dim3(256), 0, stream>>>(x1, wEffH, bEffH, wB, bufA);
  dw_v_kernel<<<dim3(144, 64, 2), dim3(256), 0, stream>>>(x1, wEffV, bEffV, wB + 64*18*20, bufB);

  fpack_kernel<<<dim3(Hq, Bq), dim3(192), 0, stream>>>(bufA, fpackH);
  fpack_kernel<<<dim3(Hq, Bq), dim3(192), 0, stream>>>(bufB, fpackV);

  off_cum_kernel<<<dim3(144, 2), dim3(256), 0, stream>>>(fpackH, wOffH, bOffH, hcum);
  off_cum_kernel<<<dim3(144, 2), dim3(256), 0, stream>>>(fpackV, wOffV, bOffV, vcum);

  einsum_mfma_kernel<0><<<dim3(576), dim3(128), 0, stream>>>(fpackH, hcum, wtpH, (const float*)d_in[21], bufA);
  einsum_mfma_kernel<1><<<dim3(576), dim3(128), 0, stream>>>(fpackV, vcum, wtpV, (const float*)d_in[31], bufB);

  gnstats_kernel<<<dim3(256), dim3(256), 0, stream>>>(bufA, bufB, stats);
  gnfinal_kernel<<<dim3(1), dim3(256), 0, stream>>>(stats,
      (const float*)d_in[22], (const float*)d_in[23],
      (const float*)d_in[32], (const float*)d_in[33], gnAB);

  combine_kernel<<<dim3(18432), dim3(256), 0, stream>>>(bufA, bufB, x1, gnAB, h_ds);
  final_kernel<<<dim3(144, 2), dim3(256), 0, stream>>>(h_ds, lwT, lbO, (float*)d_out);
}

// Round 11
// 594.561 us; speedup vs baseline: 1.0477x; 1.0477x over previous
//
#include <hip/hip_runtime.h>
#include <hip/hip_bf16.h>
#include <hip/hip_fp16.h>
#include <math.h>

#define Bq 2
#define Cq 64
#define Hq 192
#define Wq 192
#define HWq (Hq*Wq)            // 36864
#define Nq ((size_t)Bq*Cq*HWq) // 4718592

typedef __attribute__((ext_vector_type(8))) _Float16 f16x8;
typedef __attribute__((ext_vector_type(4))) float f32x4;

__device__ inline unsigned short h2us(__half h) {
  union { __half h; unsigned short u; } v; v.h = h; return v.u;
}

// ---------------------------------------------------------------------------
// Small prep (1 block)
// ---------------------------------------------------------------------------
__global__ __launch_bounds__(256) void prep_small_kernel(
    const float* hc1_w, const float* hc1_b, const float* hc2_w, const float* hc2_b,
    const float* hc3_w, const float* hc3_b,
    const float* vc1_w, const float* vc1_b, const float* vc2_w, const float* vc2_b,
    const float* vc3_w, const float* vc3_b,
    const float* h_off_w, const float* h_off_b, const float* h_bn_g, const float* h_bn_b,
    const float* h_bn_m, const float* h_bn_v,
    const float* v_off_w, const float* v_off_b, const float* v_bn_g, const float* v_bn_b,
    const float* v_bn_m, const float* v_bn_v,
    const float* last_w, const float* last_g, const float* last_b, const float* last_m,
    const float* last_v,
    float* wEffH, float* bEffH, float* wEffV, float* bEffV,
    float* wOffH, float* bOffH, float* wOffV, float* bOffV,
    float* lwT, float* lbO)
{
  int t = threadIdx.x;
  if (t < 128) {
    int ch = t & 63;
    bool ish = t < 64;
    const float* w1 = (ish ? hc1_w : vc1_w) + ch*9;
    const float* w2 = (ish ? hc2_w : vc2_w) + ch*7;
    const float* w3 = (ish ? hc3_w : vc3_w) + ch*5;
    float t15[15];
    for (int s = 0; s < 15; s++) {
      float a = 0.f;
      for (int j = 0; j < 9; j++) { int k2 = s - j; if (k2 >= 0 && k2 < 7) a += w1[j]*w2[k2]; }
      t15[s] = a;
    }
    float* we = (ish ? wEffH : wEffV) + ch*19;
    for (int s = 0; s < 19; s++) {
      float a = 0.f;
      for (int j = 0; j < 15; j++) { int k3 = s - j; if (k3 >= 0 && k3 < 5) a += t15[j]*w3[k3]; }
      we[s] = a;
    }
    float S2 = 0.f, S3 = 0.f;
    for (int j = 0; j < 7; j++) S2 += w2[j];
    for (int j = 0; j < 5; j++) S3 += w3[j];
    float b1 = (ish ? hc1_b : vc1_b)[ch];
    float b2 = (ish ? hc2_b : vc2_b)[ch];
    float b3 = (ish ? hc3_b : vc3_b)[ch];
    (ish ? bEffH : bEffV)[ch] = b1*S2*S3 + b2*S3 + b3;
  }
  for (int idx = t; idx < 9*64*7; idx += 256) {
    int tap = idx / 448; int rem = idx % 448; int i = rem / 7; int m = rem % 7;
    float invh = h_bn_g[m] / sqrtf(h_bn_v[m] + 1e-5f);
    wOffH[(tap*64 + i)*8 + m] = h_off_w[(m*64 + i)*9 + tap] * invh;
    float invv = v_bn_g[7+m] / sqrtf(v_bn_v[7+m] + 1e-5f);
    wOffV[(tap*64 + i)*8 + m] = v_off_w[((7+m)*64 + i)*9 + tap] * invv;
  }
  if (t < 7) {
    float invh = h_bn_g[t] / sqrtf(h_bn_v[t] + 1e-5f);
    bOffH[t] = h_off_b[t]*invh + h_bn_b[t] - h_bn_m[t]*invh;
    float invv = v_bn_g[7+t] / sqrtf(v_bn_v[7+t] + 1e-5f);
    bOffV[t] = v_off_b[7+t]*invv + v_bn_b[7+t] - v_bn_m[7+t]*invv;
  }
  for (int idx = t; idx < 4096; idx += 256) {
    int o = idx % 64; int i = idx / 64;
    float inv = last_g[o] / sqrtf(last_v[o] + 1e-3f);
    lwT[i*64 + o] = last_w[o*64 + i] * inv;
  }
  if (t < 64) {
    float inv = last_g[t] / sqrtf(last_v[t] + 1e-3f);
    lbO[t] = last_b[t] - last_m[t]*inv;
  }
}

// ---------------------------------------------------------------------------
// Border prep (impulse-response composed clipped 19-tap weights)
// ---------------------------------------------------------------------------
__global__ __launch_bounds__(256) void prep_border_kernel(
    const float* hc1_w, const float* hc1_b, const float* hc2_w, const float* hc2_b,
    const float* hc3_w, const float* hc3_b,
    const float* vc1_w, const float* vc1_b, const float* vc2_w, const float* vc2_b,
    const float* vc3_w, const float* vc3_b,
    float* wB)
{
  int tid = blockIdx.x*256 + threadIdx.x;
  if (tid >= 2*64*18) return;
  int cls = tid % 18;
  int ch  = (tid / 18) % 64;
  int br  = tid / (18*64);
  int c = (cls < 9) ? cls : cls + 174;
  const float* w1 = (br==0 ? hc1_w : vc1_w) + ch*9;
  const float* w2 = (br==0 ? hc2_w : vc2_w) + ch*7;
  const float* w3 = (br==0 ? hc3_w : vc3_w) + ch*5;
  float b1 = (br==0 ? hc1_b : vc1_b)[ch];
  float b2 = (br==0 ? hc2_b : vc2_b)[ch];
  float b3 = (br==0 ? hc3_b : vc3_b)[ch];
  float* dst = wB + ((size_t)(br*64 + ch)*18 + cls)*20;
  for (int cse = 0; cse < 20; cse++) {
    bool basis = (cse < 19);
    int fd = c + cse - 9;
    float B1 = basis ? 0.f : b1, B2 = basis ? 0.f : b2, B3 = basis ? 0.f : b3;
    float o3 = B3;
    for (int m = 0; m < 5; m++) {
      int d = c + m - 2;
      if (d < 0 || d >= Wq) continue;
      float o2 = B2;
      for (int k = 0; k < 7; k++) {
        int e = d + k - 3;
        if (e < 0 || e >= Wq) continue;
        float o1 = B1;
        if (basis) {
          int tp = fd - e + 4;
          if (tp >= 0 && tp < 9 && fd >= 0 && fd < Wq) o1 += w1[tp];
        }
        o2 += o1 * w2[k];
      }
      o3 += o2 * w3[m];
    }
    dst[cse] = o3;
  }
}

// ---------------------------------------------------------------------------
// Big prep: dsc weights -> f16 hi/lo MFMA pack [tap][kc][hl][oc][32]
//           + w_first f16 hi/lo pack for conv7.
// ---------------------------------------------------------------------------
__global__ __launch_bounds__(256) void prep_big_kernel(
    const float* __restrict__ w_first,
    const float* __restrict__ h_dsc_w, const float* __restrict__ v_dsc_w,
    unsigned short* __restrict__ wtpH, unsigned short* __restrict__ wtpV,
    unsigned short* __restrict__ wpack)
{
  int tid = blockIdx.x*256 + threadIdx.x;
  int nthr = gridDim.x*256;
  for (int idx = tid; idx < 7*2*2*64*32; idx += nthr) {
    int ch32 = idx & 31;
    int oc   = (idx >> 5) & 63;
    int hl   = (idx >> 11) & 1;
    int kc   = (idx >> 12) & 1;
    int tap  = idx >> 13;
    int i = kc*32 + ch32;
    float vh = h_dsc_w[oc*448 + i*7 + tap];
    float vv = v_dsc_w[oc*448 + i*7 + tap];
    _Float16 hh = (_Float16)vh;
    _Float16 hv = (_Float16)vv;
    unsigned short uh, uv;
    if (!hl) { uh = *(unsigned short*)&hh; uv = *(unsigned short*)&hv; }
    else {
      _Float16 lh = (_Float16)(vh - (float)hh);
      _Float16 lv = (_Float16)(vv - (float)hv);
      uh = *(unsigned short*)&lh; uv = *(unsigned short*)&lv;
    }
    wtpH[idx] = uh; wtpV[idx] = uv;
  }
  for (int e = tid; e < 2*49*2*64*32; e += nthr) {
    int ch  = e & 31;
    int oc  = (e >> 5) & 63;
    int hl  = (e >> 11) & 1;
    int rest = e >> 12;
    int tap = rest % 49;
    int h   = rest / 49;
    float wv = w_first[((size_t)oc*64 + h*32 + ch)*49 + tap];
    __half hh = __float2half(wv);
    unsigned short us;
    if (!hl) us = h2us(hh);
    else { float rr = wv - __half2float(hh); us = h2us(__float2half(rr)); }
    wpack[e] = us;
  }
}

// ---------------------------------------------------------------------------
// x (NCHW f32) -> xpack single f16: [b][r][c][64] (8 granules of 8 ch)
// ---------------------------------------------------------------------------
__global__ __launch_bounds__(192) void tof16_pack_kernel(const float* __restrict__ x,
                                                         unsigned short* __restrict__ xpack)
{
  __shared__ unsigned int s[192*64];
  int r = blockIdx.x, b = blockIdx.y;
  int t = threadIdx.x;
  for (int ch = 0; ch < 64; ch++) {
    float v = x[((size_t)(b*64+ch)*Hq + r)*Wq + t];
    _Float16 hh = (_Float16)v;
    s[t*64 + (ch ^ (t & 31))] = (unsigned int)*(unsigned short*)&hh;
  }
  __syncthreads();
  unsigned short* dst = xpack + ((size_t)b*Hq + r)*Wq*64;
  for (int i = 0; i < 8; i++) {
    int gidx = i*192 + t;                // 1536 granules of 16B
    int c = gidx >> 3, g = gidx & 7;
    unsigned short tmp[8];
#pragma unroll
    for (int j = 0; j < 8; j++) {
      int ch = g*8 + j;
      tmp[j] = (unsigned short)s[c*64 + (ch ^ (c & 31))];
    }
    uint4 v;
    v.x = (unsigned int)tmp[0] | ((unsigned int)tmp[1] << 16);
    v.y = (unsigned int)tmp[2] | ((unsigned int)tmp[3] << 16);
    v.z = (unsigned int)tmp[4] | ((unsigned int)tmp[5] << 16);
    v.w = (unsigned int)tmp[6] | ((unsigned int)tmp[7] << 16);
    *(uint4*)(dst + (size_t)gidx*8) = v;
  }
}

// ---------------------------------------------------------------------------
// feat (NCHW f32) -> fpack PLANE-MAJOR: [b][sub(16)][px][8ch] f16 hi/lo
// ---------------------------------------------------------------------------
__global__ __launch_bounds__(192) void fpack_kernel(const float* __restrict__ in,
                                                    unsigned short* __restrict__ pack)
{
  __shared__ unsigned int s[192*64];
  int r = blockIdx.x, b = blockIdx.y;
  int t = threadIdx.x;
  for (int ch = 0; ch < 64; ch++) {
    float v = in[((size_t)(b*64+ch)*Hq + r)*Wq + t];
    __half hh = __float2half(v);
    float rr = v - __half2float(hh);
    __half hl = __float2half(rr);
    unsigned int pk = (unsigned int)h2us(hh) | ((unsigned int)h2us(hl) << 16);
    s[t*64 + (ch ^ (t & 31))] = pk;
  }
  __syncthreads();
#pragma unroll
  for (int sub = 0; sub < 16; sub++) {
    int hl = sub >> 3, g8 = sub & 7;
    unsigned short tmp[8];
#pragma unroll
    for (int j = 0; j < 8; j++) {
      int ch = g8*8 + j;
      unsigned int u = s[t*64 + (ch ^ (t & 31))];
      tmp[j] = hl ? (unsigned short)(u >> 16) : (unsigned short)(u & 0xffff);
    }
    uint4 v;
    v.x = (unsigned int)tmp[0] | ((unsigned int)tmp[1] << 16);
    v.y = (unsigned int)tmp[2] | ((unsigned int)tmp[3] << 16);
    v.z = (unsigned int)tmp[4] | ((unsigned int)tmp[5] << 16);
    v.w = (unsigned int)tmp[6] | ((unsigned int)tmp[7] << 16);
    *(uint4*)(pack + (((size_t)b*16 + sub)*HWq + r*Wq + t)*8) = v;
  }
}

// ---------------------------------------------------------------------------
// 7x7 conv via MFMA, 2-pass (x single f16, w hi/lo exact).
// R8 structure: B DIRECT from global (L2), barrier-free 49-tap inner loop,
// 4 barriers/block total. Geometry: 2 rows x 48 cols per block, 2 waves.
// Grid 4x96x2 = 768 blocks = 3/CU (9 waves/CU), LDS 27.6 KB.
// ---------------------------------------------------------------------------
__global__ __launch_bounds__(128) void conv7_mfma_kernel(
    const unsigned short* __restrict__ xpack,   // [b][r][c][64] f16
    const unsigned short* __restrict__ wpack,   // [h][tap][hl][oc][32] f16
    float* __restrict__ out)
{
  __shared__ __align__(16) unsigned short sA[8*54*32];   // 27648 B
  int ct = blockIdx.x;          // 0..3
  int rt = blockIdx.y;          // 0..95
  int b  = blockIdx.z;
  int r0 = rt*2, c0 = ct*48;
  int t = threadIdx.x;
  int w = t >> 6;               // wave -> output row offset (0..1)
  int l = t & 63;
  int l15 = l & 15, lg = l >> 4;

  f32x4 acc[3][4];
#pragma unroll
  for (int i = 0; i < 3; i++)
#pragma unroll
    for (int j = 0; j < 4; j++) acc[i][j] = (f32x4){0.f,0.f,0.f,0.f};

  for (int h = 0; h < 2; h++) {
    __syncthreads();            // prev half's sA readers done
    // ---- stage A: 8 rows x 54 cols x 4 granules (32 ch of this half) ------
    for (int idx = t; idx < 8*54*4; idx += 128) {
      int g = idx & 3, pix = idx >> 2;
      int row = pix / 54, col = pix % 54;
      int gr = r0 - 3 + row, gc = c0 - 3 + col;
      uint4 v = {0u,0u,0u,0u};
      if (gr >= 0 && gr < Hq && gc >= 0 && gc < Wq)
        v = *(const uint4*)(xpack + (((size_t)b*Hq + gr)*Wq + gc)*64 + (h*4 + g)*8);
      ((uint4*)sA)[(row*54 + col)*4 + (g ^ ((col >> 1) & 3))] = v;
    }
    __syncthreads();
    const unsigned short* wb = wpack + (size_t)h*49*4096;
    for (int tap = 0; tap < 49; tap++) {
      int dy = tap / 7, dx = tap % 7;
      f16x8 bh[4], bl[4];
#pragma unroll
      for (int tb = 0; tb < 4; tb++) {
        bh[tb] = *(const f16x8*)(wb + (size_t)tap*4096 + (tb*16 + l15)*32 + lg*8);
        bl[tb] = *(const f16x8*)(wb + (size_t)tap*4096 + 2048 + (tb*16 + l15)*32 + lg*8);
      }
      int arow = w + dy;        // 0..7
      f16x8 a[3];
#pragma unroll
      for (int ta = 0; ta < 3; ta++) {
        int col = ta*16 + l15 + dx;
        a[ta] = *(const f16x8*)((const uint4*)sA + (arow*54 + col)*4 + (lg ^ ((col >> 1) & 3)));
      }
#pragma unroll
      for (int ta = 0; ta < 3; ta++)
#pragma unroll
        for (int tb = 0; tb < 4; tb++) {
          acc[ta][tb] = __builtin_amdgcn_mfma_f32_16x16x32_f16(a[ta], bh[tb], acc[ta][tb], 0, 0, 0);
          acc[ta][tb] = __builtin_amdgcn_mfma_f32_16x16x32_f16(a[ta], bl[tb], acc[ta][tb], 0, 0, 0);
        }
    }
  }
#pragma unroll
  for (int tb = 0; tb < 4; tb++) {
    int oc = tb*16 + l15;
    float* dst = out + ((size_t)(b*64 + oc)*Hq + (r0 + w))*Wq + c0;
#pragma unroll
    for (int ta = 0; ta < 3; ta++) {
      f32x4 v = acc[ta][tb];
      *(float4*)(dst + ta*16 + lg*4) = make_float4(v[0], v[1], v[2], v[3]);
    }
  }
}

// ---------------------------------------------------------------------------
// Separable 7x7 avg pool
// ---------------------------------------------------------------------------
__global__ __launch_bounds__(256) void pool_row_kernel(const float* __restrict__ in, float* __restrict__ out)
{
  int idx = blockIdx.x*256 + threadIdx.x;
  int c = idx % Wq;
  int base = idx - c;
  float s = 0.f;
#pragma unroll
  for (int dc = -3; dc <= 3; dc++) {
    int cc = c + dc;
    if (cc >= 0 && cc < Wq) s += in[base + cc];
  }
  out[idx] = s;
}

__global__ __launch_bounds__(256) void pool_col_kernel(const float* __restrict__ in, float* __restrict__ out)
{
  int idx = blockIdx.x*256 + threadIdx.x;
  int c = idx % Wq;
  int r = (idx / Wq) % Hq;
  int plane = idx / HWq;
  float s = 0.f;
#pragma unroll
  for (int dr = -3; dr <= 3; dr++) {
    int rr = r + dr;
    if (rr >= 0 && rr < Hq) s += in[(size_t)plane*HWq + rr*Wq + c];
  }
  out[idx] = s * (1.f/49.f);
}

// ---------------------------------------------------------------------------
// Depthwise chain: uniform 19-tap, class-selected weights
// ---------------------------------------------------------------------------
__global__ __launch_bounds__(256) void dw_h_kernel(const float* __restrict__ x1,
                                                   const float* __restrict__ wEff,
                                                   const float* __restrict__ bEff,
                                                   const float* __restrict__ wB,
                                                   float* __restrict__ out)
{
  __shared__ float sW[19][20];
  int b = blockIdx.z, ch = blockIdx.y;
  int t = threadIdx.x;
  for (int i = t; i < 380; i += 256) {
    int row = i / 20, jj = i % 20;
    float v;
    if (row < 18) v = wB[((size_t)ch*18 + row)*20 + jj];
    else v = (jj < 19) ? wEff[ch*19 + jj] : bEff[ch];
    sW[row][jj] = v;
  }
  __syncthreads();
  int p = blockIdx.x*256 + t;
  int r = p / Wq, c = p % Wq;
  const float* src = x1 + (size_t)(b*Cq + ch)*HWq + r*Wq;
  int row = (c < 9) ? c : ((c >= Wq-9) ? (c - 174) : 18);
  float s = sW[row][19];
#pragma unroll
  for (int j = 0; j < 19; j++) {
    int idx = min(max(c + j - 9, 0), Wq-1);
    s += src[idx] * sW[row][j];
  }
  out[(size_t)(b*Cq + ch)*HWq + p] = s;
}

__global__ __launch_bounds__(256) void dw_v_kernel(const float* __restrict__ x1,
                                                   const float* __restrict__ wEff,
                                                   const float* __restrict__ bEff,
                                                   const float* __restrict__ wB,
                                                   float* __restrict__ out)
{
  __shared__ float sW[19][20];
  int b = blockIdx.z, ch = blockIdx.y;
  int t = threadIdx.x;
  for (int i = t; i < 380; i += 256) {
    int row = i / 20, jj = i % 20;
    float v;
    if (row < 18) v = wB[((size_t)ch*18 + row)*20 + jj];
    else v = (jj < 19) ? wEff[ch*19 + jj] : bEff[ch];
    sW[row][jj] = v;
  }
  __syncthreads();
  int p = blockIdx.x*256 + t;
  int r = p / Wq, c = p % Wq;
  const float* src = x1 + (size_t)(b*Cq + ch)*HWq + c;
  int row = (r < 9) ? r : ((r >= Hq-9) ? (r - 174) : 18);
  float s = sW[row][19];
#pragma unroll
  for (int j = 0; j < 19; j++) {
    int idx = min(max(r + j - 9, 0), Hq-1);
    s += src[idx*Wq] * sW[row][j];
  }
  out[(size_t)(b*Cq + ch)*HWq + p] = s;
}

// ---------------------------------------------------------------------------
// Offset conv + tanh + cum, reading plane-major fpack (coalesced)
// ---------------------------------------------------------------------------
__global__ __launch_bounds__(256) void off_cum_kernel(const unsigned short* __restrict__ fp,
                                                      const float* __restrict__ wOff,
                                                      const float* __restrict__ bOff,
                                                      float* __restrict__ cum)
{
  const size_t HW8 = (size_t)HWq*8;
  int b = blockIdx.y;
  int p = blockIdx.x*256 + threadIdx.x;
  int r = p / Wq, c = p % Wq;
  float tv[7];
#pragma unroll
  for (int m = 0; m < 7; m++) tv[m] = bOff[m];
  const unsigned short* fb = fp + (size_t)b*HWq*128;
  for (int tap = 0; tap < 9; tap++) {
    int dy = tap/3 - 1, dx = tap%3 - 1;
    int rr = r + dy, cc = c + dx;
    if (rr < 0 || rr >= Hq || cc < 0 || cc >= Wq) continue;
    const unsigned short* p0 = fb + ((size_t)rr*Wq + cc)*8;
    const float* wp = wOff + tap*512;
    for (int g = 0; g < 8; g++) {
      f16x8 hv = *(const f16x8*)(p0 + (size_t)g*HW8);
      f16x8 lv = *(const f16x8*)(p0 + (size_t)(8 + g)*HW8);
#pragma unroll
      for (int e = 0; e < 8; e++) {
        float fv = (float)hv[e] + (float)lv[e];
        const float* wr = wp + (g*8 + e)*8;
#pragma unroll
        for (int m = 0; m < 7; m++) tv[m] += fv * wr[m];
      }
    }
  }
#pragma unroll
  for (int m = 0; m < 7; m++) tv[m] = tanhf(tv[m]);
  float c0 = tv[0], c1 = tv[1] + tv[2], c2 = tv[2], c3 = 0.f;
  float c4 = tv[4], c5 = tv[4] + tv[5], c6 = tv[6];
  size_t bb = (size_t)b*7*HWq + p;
  cum[bb + 0*HWq] = c0; cum[bb + 1*HWq] = c1; cum[bb + 2*HWq] = c2;
  cum[bb + 3*HWq] = c3; cum[bb + 4*HWq] = c4; cum[bb + 5*HWq] = c5;
  cum[bb + 6*HWq] = c6;
}

// ---------------------------------------------------------------------------
// Deformable sample + einsum via MFMA (f16 hi/lo 3-pass).
// Plane-major fpack reads + XCD-banded block swizzle.
// ---------------------------------------------------------------------------
template<int MORPH>
__global__ __launch_bounds__(128) void einsum_mfma_kernel(
    const unsigned short* __restrict__ fp,   // fpack [b][sub16][px][8]
    const float* __restrict__ cum,
    const unsigned short* __restrict__ wtp,  // [tap][kc][hl][oc][32] f16
    const float* __restrict__ dsc_b,
    float* __restrict__ out)                 // NCHW f32
{
  __shared__ __align__(16) unsigned short sA[2*64*128];  // 32 KB
  const size_t HW8 = (size_t)HWq*8;
  int bid = blockIdx.x;                   // 0..575
  int swz = (bid & 7)*72 + (bid >> 3);    // XCD-contiguous bands (576 = 8*72)
  int b   = swz / 288;
  int blk = swz % 288;
  int t = threadIdx.x;
  int w = t >> 6, l = t & 63;
  int l15 = l & 15, lg = l >> 4;
  int p = blk*128 + w*64 + l;
  int r = p / Wq, c = p % Wq;

  f32x4 acc[4][4];
#pragma unroll
  for (int i = 0; i < 4; i++)
#pragma unroll
    for (int j = 0; j < 4; j++) acc[i][j] = (f32x4){0.f,0.f,0.f,0.f};

  const unsigned short* fb = fp + (size_t)b*HWq*128;
  unsigned short* myrow = sA + (size_t)(w*64 + l)*128;

  for (int k = 0; k < 7; k++) {
    bool oob;
    const unsigned short *p0, *p1;
    float w0, w1;
    if (MORPH == 0) {
      int xi = c + k - 3;
      oob = (xi < 0 || xi >= Wq);
      if (!oob) {
        float y = (float)r + cum[((size_t)(b*7 + k))*HWq + p];
        float y0 = floorf(y);
        int y0q = (int)y0;
        int y0i = min(max(y0q, 0), Hq-1);
        int y1i = min(max(y0q + 1, 0), Hq-1);
        float y0f = fminf(fmaxf(y0, 0.f), (float)Hq);
        float y1f = fminf(fmaxf(y0 + 1.f, 0.f), (float)Hq);
        w0 = y1f - y; w1 = y - y0f;
        p0 = fb + ((size_t)y0i*Wq + xi)*8;
        p1 = fb + ((size_t)y1i*Wq + xi)*8;
      }
    } else {
      int yi = r + k - 3;
      oob = (yi < 0 || yi >= Hq);
      if (!oob) {
        float xf = (float)c + cum[((size_t)(b*7 + k))*HWq + p];
        float x0 = floorf(xf);
        int x0q = (int)x0;
        int x0i = min(max(x0q, 0), Wq-1);
        int x1i = min(max(x0q + 1, 0), Wq-1);
        float x0f = fminf(fmaxf(x0, 0.f), (float)Wq);
        float x1f = fminf(fmaxf(x0 + 1.f, 0.f), (float)Wq);
        w0 = x1f - xf; w1 = xf - x0f;
        p0 = fb + ((size_t)yi*Wq + x0i)*8;
        p1 = fb + ((size_t)yi*Wq + x1i)*8;
      }
    }
    if (oob) {
      uint4 z = {0u,0u,0u,0u};
#pragma unroll
      for (int j = 0; j < 16; j++) ((uint4*)myrow)[j] = z;
    } else {
#pragma unroll
      for (int g = 0; g < 8; g++) {
        f16x8 a0h = *(const f16x8*)(p0 + (size_t)g*HW8);
        f16x8 a0l = *(const f16x8*)(p0 + (size_t)(8 + g)*HW8);
        f16x8 a1h = *(const f16x8*)(p1 + (size_t)g*HW8);
        f16x8 a1l = *(const f16x8*)(p1 + (size_t)(8 + g)*HW8);
        f16x8 sh, sl;
#pragma unroll
        for (int e = 0; e < 8; e++) {
          float v = w0*((float)a0h[e] + (float)a0l[e]) + w1*((float)a1h[e] + (float)a1l[e]);
          _Float16 vh = (_Float16)v;
          sh[e] = vh;
          sl[e] = (_Float16)(v - (float)vh);
        }
        *(f16x8*)(myrow + (size_t)(g ^ l15)*8)       = sh;
        *(f16x8*)(myrow + (size_t)((8 + g) ^ l15)*8) = sl;
      }
    }
    __syncthreads();
#pragma unroll
    for (int kc = 0; kc < 2; kc++) {
      const unsigned short* wbase = wtp + (size_t)((k*2 + kc)*2)*2048;
      f16x8 bh[4], bl[4];
#pragma unroll
      for (int tb = 0; tb < 4; tb++) {
        bh[tb] = *(const f16x8*)(wbase + (tb*16 + l15)*32 + lg*8);
        bl[tb] = *(const f16x8*)(wbase + 2048 + (tb*16 + l15)*32 + lg*8);
      }
      f16x8 ah[4], al[4];
#pragma unroll
      for (int ta = 0; ta < 4; ta++) {
        const unsigned short* rbase = sA + (size_t)(w*64 + ta*16 + l15)*128;
        ah[ta] = *(const f16x8*)(rbase + (size_t)((kc*4 + lg) ^ l15)*8);
        al[ta] = *(const f16x8*)(rbase + (size_t)((8 + kc*4 + lg) ^ l15)*8);
      }
#pragma unroll
      for (int ta = 0; ta < 4; ta++)
#pragma unroll
        for (int tb = 0; tb < 4; tb++) {
          acc[ta][tb] = __builtin_amdgcn_mfma_f32_16x16x32_f16(ah[ta], bh[tb], acc[ta][tb], 0, 0, 0);
          acc[ta][tb] = __builtin_amdgcn_mfma_f32_16x16x32_f16(ah[ta], bl[tb], acc[ta][tb], 0, 0, 0);
          acc[ta][tb] = __builtin_amdgcn_mfma_f32_16x16x32_f16(al[ta], bh[tb], acc[ta][tb], 0, 0, 0);
        }
    }
    __syncthreads();
  }
  int pbase = blk*128 + w*64;
#pragma unroll
  for (int tb = 0; tb < 4; tb++) {
    int oc = tb*16 + l15;
    float bias = dsc_b[oc];
    float* dst = out + (size_t)(b*64 + oc)*HWq + pbase;
#pragma unroll
    for (int ta = 0; ta < 4; ta++) {
      f32x4 v = acc[ta][tb];
      *(float4*)(dst + ta*16 + lg*4) = make_float4(v[0]+bias, v[1]+bias, v[2]+bias, v[3]+bias);
    }
  }
}

// ---------------------------------------------------------------------------
// GroupNorm stats + finalize + combine + final 1x1 + SiLU
// ---------------------------------------------------------------------------
__global__ __launch_bounds__(256) void gnstats_kernel(const float* __restrict__ h_ds,
                                                      const float* __restrict__ v_ds,
                                                      float* __restrict__ stats)
{
  int plane = blockIdx.x;
  int buf = plane >> 7;
  int rem = plane & 127;
  const float* src = (buf ? v_ds : h_ds) + (size_t)rem*HWq;
  float s = 0.f, s2 = 0.f;
  for (int i = threadIdx.x; i < HWq; i += 256) {
    float v = src[i];
    s += v; s2 += v*v;
  }
  __shared__ float red[2][4];
  for (int off = 32; off; off >>= 1) {
    s  += __shfl_down(s, off);
    s2 += __shfl_down(s2, off);
  }
  if ((threadIdx.x & 63) == 0) { red[0][threadIdx.x >> 6] = s; red[1][threadIdx.x >> 6] = s2; }
  __syncthreads();
  if (threadIdx.x == 0) {
    s  = red[0][0] + red[0][1] + red[0][2] + red[0][3];
    s2 = red[1][0] + red[1][1] + red[1][2] + red[1][3];
    stats[plane*2 + 0] = s;
    stats[plane*2 + 1] = s2;
  }
}

__global__ __launch_bounds__(256) void gnfinal_kernel(const float* __restrict__ stats,
                                                      const float* __restrict__ h_gn_g, const float* __restrict__ h_gn_b,
                                                      const float* __restrict__ v_gn_g, const float* __restrict__ v_gn_b,
                                                      float* __restrict__ gnAB)
{
  int t = threadIdx.x;
  int buf = t >> 7, ch = t & 63;
  int base = t & ~3;
  float sum = 0.f, ss = 0.f;
#pragma unroll
  for (int q = 0; q < 4; q++) { sum += stats[(base+q)*2]; ss += stats[(base+q)*2 + 1]; }
  const float n = 4.f * HWq;
  float mean = sum / n;
  float var = ss / n - mean*mean;
  float gg = (buf ? v_gn_g : h_gn_g)[ch];
  float bb = (buf ? v_gn_b : h_gn_b)[ch];
  float A = gg / sqrtf(var + 1e-5f);
  gnAB[t*2 + 0] = A;
  gnAB[t*2 + 1] = bb - mean*A;
}

__global__ __launch_bounds__(256) void combine_kernel(const float* __restrict__ h_ds,
                                                      const float* __restrict__ v_ds,
                                                      const float* __restrict__ x1,
                                                      const float* __restrict__ gnAB,
                                                      float* __restrict__ comb)
{
  size_t idx = (size_t)blockIdx.x*256 + threadIdx.x;
  int plane = (int)(idx / HWq);
  int ih = plane*2;
  int iv = (128 + plane)*2;
  float hv = h_ds[idx]*gnAB[ih] + gnAB[ih+1]; hv = fmaxf(hv, 0.f);
  float vv = v_ds[idx]*gnAB[iv] + gnAB[iv+1]; vv = fmaxf(vv, 0.f);
  comb[idx] = hv + vv + x1[idx];
}

__global__ __launch_bounds__(256) void final_kernel(const float* __restrict__ comb,
                                                    const float* __restrict__ lwT,
                                                    const float* __restrict__ lbO,
                                                    float* __restrict__ out)
{
  int b = blockIdx.y;
  int p = blockIdx.x*256 + threadIdx.x;
  const float* cb = comb + (size_t)b*Cq*HWq + p;
  float acc[64];
#pragma unroll
  for (int o = 0; o < 64; o++) acc[o] = 0.f;
  for (int i = 0; i < 64; i++) {
    float cv = cb[(size_t)i*HWq];
    const float* wr = lwT + i*64;
#pragma unroll
    for (int o = 0; o < 64; o++) acc[o] += cv * wr[o];
  }
  float* dst = out + (size_t)b*Cq*HWq + p;
#pragma unroll
  for (int o = 0; o < 64; o++) {
    float yv = acc[o] + lbO[o];
    dst[(size_t)o*HWq] = yv / (1.f + expf(-yv));
  }
}

// ---------------------------------------------------------------------------
extern "C" void kernel_launch(void* const* d_in, const int* in_sizes, int n_in,
                              void* d_out, int out_size, void* d_ws, size_t ws_size,
                              hipStream_t stream)
{
  const float* x       = (const float*)d_in[0];
  const float* w_first = (const float*)d_in[1];
  float* ws = (float*)d_ws;

  float* bufA = ws;            // conv7 out -> hfeat -> h-einsum-out
  float* bufB = ws + Nq;       // rowsum -> vfeat -> v-einsum-out
  float* x1   = ws + 2*Nq;
  float* h_ds = ws + 3*Nq;     // xpack -> fpackH -> comb
  float* v_ds = ws + 4*Nq;     // fpackV
  size_t off = 5*Nq;
  float* hcum  = ws + off; off += (size_t)Bq*7*HWq;
  float* vcum  = ws + off; off += (size_t)Bq*7*HWq;
  float* wEffH = ws + off; off += 64*19;
  float* bEffH = ws + off; off += 64;
  float* wEffV = ws + off; off += 64*19;
  float* bEffV = ws + off; off += 64;
  float* wtH   = ws + off; off += 64*64*7;   // holds wtpH f16 pack
  float* wtV   = ws + off; off += 64*64*7;   // holds wtpV f16 pack
  float* wOffH = ws + off; off += 9*64*8;
  float* bOffH = ws + off; off += 8;
  float* wOffV = ws + off; off += 9*64*8;
  float* bOffV = ws + off; off += 8;
  float* lwT   = ws + off; off += 64*64;
  float* lbO   = ws + off; off += 64;
  float* stats = ws + off; off += 512;
  float* gnAB  = ws + off; off += 512;
  float* wB    = ws + off; off += 2*64*18*20;
  unsigned short* wpack = (unsigned short*)(ws + off); off += 2*49*2*64*32/2 + 16;
  unsigned short* xpack  = (unsigned short*)h_ds;
  unsigned short* fpackH = (unsigned short*)h_ds;
  unsigned short* fpackV = (unsigned short*)v_ds;
  unsigned short* wtpH = (unsigned short*)wtH;
  unsigned short* wtpV = (unsigned short*)wtV;

  prep_small_kernel<<<dim3(1), dim3(256), 0, stream>>>(
      (const float*)d_in[2],  (const float*)d_in[3],  (const float*)d_in[4],  (const float*)d_in[5],
      (const float*)d_in[6],  (const float*)d_in[7],
      (const float*)d_in[8],  (const float*)d_in[9],  (const float*)d_in[10], (const float*)d_in[11],
      (const float*)d_in[12], (const float*)d_in[13],
      (const float*)d_in[14], (const float*)d_in[15], (const float*)d_in[16], (const float*)d_in[17],
      (const float*)d_in[18], (const float*)d_in[19],
      (const float*)d_in[24], (const float*)d_in[25], (const float*)d_in[26], (const float*)d_in[27],
      (const float*)d_in[28], (const float*)d_in[29],
      (const float*)d_in[34], (const float*)d_in[35], (const float*)d_in[36], (const float*)d_in[37],
      (const float*)d_in[38],
      wEffH, bEffH, wEffV, bEffV, wOffH, bOffH, wOffV, bOffV, lwT, lbO);

  prep_border_kernel<<<dim3(9), dim3(256), 0, stream>>>(
      (const float*)d_in[2],  (const float*)d_in[3],  (const float*)d_in[4],  (const float*)d_in[5],
      (const float*)d_in[6],  (const float*)d_in[7],
      (const float*)d_in[8],  (const float*)d_in[9],  (const float*)d_in[10], (const float*)d_in[11],
      (const float*)d_in[12], (const float*)d_in[13], wB);

  prep_big_kernel<<<dim3(64), dim3(256), 0, stream>>>(
      w_first, (const float*)d_in[20], (const float*)d_in[30], wtpH, wtpV, wpack);

  tof16_pack_kernel<<<dim3(Hq, Bq), dim3(192), 0, stream>>>(x, xpack);
  conv7_mfma_kernel<<<dim3(4, 96, 2), dim3(128), 0, stream>>>(xpack, wpack, bufA);

  pool_row_kernel<<<dim3(18432), dim3(256), 0, stream>>>(bufA, bufB);
  pool_col_kernel<<<dim3(18432), dim3(256), 0, stream>>>(bufB, x1);

  dw_h_kernel<<<dim3(144, 64, 2), dim3(256), 0, stream>>>(x1, wEffH, bEffH, wB, bufA);
  dw_v_kernel<<<dim3(144, 64, 2), dim3(256), 0, stream>>>(x1, wEffV, bEffV, wB + 64*18*20, bufB);

  fpack_kernel<<<dim3(Hq, Bq), dim3(192), 0, stream>>>(bufA, fpackH);
  fpack_kernel<<<dim3(Hq, Bq), dim3(192), 0, stream>>>(bufB, fpackV);

  off_cum_kernel<<<dim3(144, 2), dim3(256), 0, stream>>>(fpackH, wOffH, bOffH, hcum);
  off_cum_kernel<<<dim3(144, 2), dim3(256), 0, stream>>>(fpackV, wOffV, bOffV, vcum);

  einsum_mfma_kernel<0><<<dim3(576), dim3(128), 0, stream>>>(fpackH, hcum, wtpH, (const float*)d_in[21], bufA);
  einsum_mfma_kernel<1><<<dim3(576), dim3(128), 0, stream>>>(fpackV, vcum, wtpV, (const float*)d_in[31], bufB);

  gnstats_kernel<<<dim3(256), dim3(256), 0, stream>>>(bufA, bufB, stats);
  gnfinal_kernel<<<dim3(1), dim3(256), 0, stream>>>(stats,
      (const float*)d_in[22], (const float*)d_in[23],
      (const float*)d_in[32], (const float*)d_in[33], gnAB);

  combine_kernel<<<dim3(18432), dim3(256), 0, stream>>>(bufA, bufB, x1, gnAB, h_ds);
  final_kernel<<<dim3(144, 2), dim3(256), 0, stream>>>(h_ds, lwT, lbO, (float*)d_out);
}

// Round 12
// 585.746 us; speedup vs baseline: 1.0635x; 1.0150x over previous
//
#include <hip/hip_runtime.h>
#include <hip/hip_bf16.h>
#include <hip/hip_fp16.h>
#include <math.h>

#define Bq 2
#define Cq 64
#define Hq 192
#define Wq 192
#define HWq (Hq*Wq)            // 36864
#define Nq ((size_t)Bq*Cq*HWq) // 4718592

typedef __attribute__((ext_vector_type(8))) _Float16 f16x8;
typedef __attribute__((ext_vector_type(4))) float f32x4;

__device__ inline unsigned short h2us(__half h) {
  union { __half h; unsigned short u; } v; v.h = h; return v.u;
}

// ---------------------------------------------------------------------------
// Small prep (1 block)
// ---------------------------------------------------------------------------
__global__ __launch_bounds__(256) void prep_small_kernel(
    const float* hc1_w, const float* hc1_b, const float* hc2_w, const float* hc2_b,
    const float* hc3_w, const float* hc3_b,
    const float* vc1_w, const float* vc1_b, const float* vc2_w, const float* vc2_b,
    const float* vc3_w, const float* vc3_b,
    const float* h_off_w, const float* h_off_b, const float* h_bn_g, const float* h_bn_b,
    const float* h_bn_m, const float* h_bn_v,
    const float* v_off_w, const float* v_off_b, const float* v_bn_g, const float* v_bn_b,
    const float* v_bn_m, const float* v_bn_v,
    const float* last_w, const float* last_g, const float* last_b, const float* last_m,
    const float* last_v,
    float* wEffH, float* bEffH, float* wEffV, float* bEffV,
    float* wOffH, float* bOffH, float* wOffV, float* bOffV,
    float* lwT, float* lbO)
{
  int t = threadIdx.x;
  if (t < 128) {
    int ch = t & 63;
    bool ish = t < 64;
    const float* w1 = (ish ? hc1_w : vc1_w) + ch*9;
    const float* w2 = (ish ? hc2_w : vc2_w) + ch*7;
    const float* w3 = (ish ? hc3_w : vc3_w) + ch*5;
    float t15[15];
    for (int s = 0; s < 15; s++) {
      float a = 0.f;
      for (int j = 0; j < 9; j++) { int k2 = s - j; if (k2 >= 0 && k2 < 7) a += w1[j]*w2[k2]; }
      t15[s] = a;
    }
    float* we = (ish ? wEffH : wEffV) + ch*19;
    for (int s = 0; s < 19; s++) {
      float a = 0.f;
      for (int j = 0; j < 15; j++) { int k3 = s - j; if (k3 >= 0 && k3 < 5) a += t15[j]*w3[k3]; }
      we[s] = a;
    }
    float S2 = 0.f, S3 = 0.f;
    for (int j = 0; j < 7; j++) S2 += w2[j];
    for (int j = 0; j < 5; j++) S3 += w3[j];
    float b1 = (ish ? hc1_b : vc1_b)[ch];
    float b2 = (ish ? hc2_b : vc2_b)[ch];
    float b3 = (ish ? hc3_b : vc3_b)[ch];
    (ish ? bEffH : bEffV)[ch] = b1*S2*S3 + b2*S3 + b3;
  }
  for (int idx = t; idx < 9*64*7; idx += 256) {
    int tap = idx / 448; int rem = idx % 448; int i = rem / 7; int m = rem % 7;
    float invh = h_bn_g[m] / sqrtf(h_bn_v[m] + 1e-5f);
    wOffH[(tap*64 + i)*8 + m] = h_off_w[(m*64 + i)*9 + tap] * invh;
    float invv = v_bn_g[7+m] / sqrtf(v_bn_v[7+m] + 1e-5f);
    wOffV[(tap*64 + i)*8 + m] = v_off_w[((7+m)*64 + i)*9 + tap] * invv;
  }
  if (t < 7) {
    float invh = h_bn_g[t] / sqrtf(h_bn_v[t] + 1e-5f);
    bOffH[t] = h_off_b[t]*invh + h_bn_b[t] - h_bn_m[t]*invh;
    float invv = v_bn_g[7+t] / sqrtf(v_bn_v[7+t] + 1e-5f);
    bOffV[t] = v_off_b[7+t]*invv + v_bn_b[7+t] - v_bn_m[7+t]*invv;
  }
  for (int idx = t; idx < 4096; idx += 256) {
    int o = idx % 64; int i = idx / 64;
    float inv = last_g[o] / sqrtf(last_v[o] + 1e-3f);
    lwT[i*64 + o] = last_w[o*64 + i] * inv;
  }
  if (t < 64) {
    float inv = last_g[t] / sqrtf(last_v[t] + 1e-3f);
    lbO[t] = last_b[t] - last_m[t]*inv;
  }
}

// ---------------------------------------------------------------------------
// Border prep (impulse-response composed clipped 19-tap weights)
// ---------------------------------------------------------------------------
__global__ __launch_bounds__(256) void prep_border_kernel(
    const float* hc1_w, const float* hc1_b, const float* hc2_w, const float* hc2_b,
    const float* hc3_w, const float* hc3_b,
    const float* vc1_w, const float* vc1_b, const float* vc2_w, const float* vc2_b,
    const float* vc3_w, const float* vc3_b,
    float* wB)
{
  int tid = blockIdx.x*256 + threadIdx.x;
  if (tid >= 2*64*18) return;
  int cls = tid % 18;
  int ch  = (tid / 18) % 64;
  int br  = tid / (18*64);
  int c = (cls < 9) ? cls : cls + 174;
  const float* w1 = (br==0 ? hc1_w : vc1_w) + ch*9;
  const float* w2 = (br==0 ? hc2_w : vc2_w) + ch*7;
  const float* w3 = (br==0 ? hc3_w : vc3_w) + ch*5;
  float b1 = (br==0 ? hc1_b : vc1_b)[ch];
  float b2 = (br==0 ? hc2_b : vc2_b)[ch];
  float b3 = (br==0 ? hc3_b : vc3_b)[ch];
  float* dst = wB + ((size_t)(br*64 + ch)*18 + cls)*20;
  for (int cse = 0; cse < 20; cse++) {
    bool basis = (cse < 19);
    int fd = c + cse - 9;
    float B1 = basis ? 0.f : b1, B2 = basis ? 0.f : b2, B3 = basis ? 0.f : b3;
    float o3 = B3;
    for (int m = 0; m < 5; m++) {
      int d = c + m - 2;
      if (d < 0 || d >= Wq) continue;
      float o2 = B2;
      for (int k = 0; k < 7; k++) {
        int e = d + k - 3;
        if (e < 0 || e >= Wq) continue;
        float o1 = B1;
        if (basis) {
          int tp = fd - e + 4;
          if (tp >= 0 && tp < 9 && fd >= 0 && fd < Wq) o1 += w1[tp];
        }
        o2 += o1 * w2[k];
      }
      o3 += o2 * w3[m];
    }
    dst[cse] = o3;
  }
}

// ---------------------------------------------------------------------------
// Big prep: dsc weights -> f16 hi/lo MFMA pack [tap][kc][hl][oc][32]
//           + w_first f16 hi/lo pack for conv7.
// ---------------------------------------------------------------------------
__global__ __launch_bounds__(256) void prep_big_kernel(
    const float* __restrict__ w_first,
    const float* __restrict__ h_dsc_w, const float* __restrict__ v_dsc_w,
    unsigned short* __restrict__ wtpH, unsigned short* __restrict__ wtpV,
    unsigned short* __restrict__ wpack)
{
  int tid = blockIdx.x*256 + threadIdx.x;
  int nthr = gridDim.x*256;
  for (int idx = tid; idx < 7*2*2*64*32; idx += nthr) {
    int ch32 = idx & 31;
    int oc   = (idx >> 5) & 63;
    int hl   = (idx >> 11) & 1;
    int kc   = (idx >> 12) & 1;
    int tap  = idx >> 13;
    int i = kc*32 + ch32;
    float vh = h_dsc_w[oc*448 + i*7 + tap];
    float vv = v_dsc_w[oc*448 + i*7 + tap];
    _Float16 hh = (_Float16)vh;
    _Float16 hv = (_Float16)vv;
    unsigned short uh, uv;
    if (!hl) { uh = *(unsigned short*)&hh; uv = *(unsigned short*)&hv; }
    else {
      _Float16 lh = (_Float16)(vh - (float)hh);
      _Float16 lv = (_Float16)(vv - (float)hv);
      uh = *(unsigned short*)&lh; uv = *(unsigned short*)&lv;
    }
    wtpH[idx] = uh; wtpV[idx] = uv;
  }
  for (int e = tid; e < 2*49*2*64*32; e += nthr) {
    int ch  = e & 31;
    int oc  = (e >> 5) & 63;
    int hl  = (e >> 11) & 1;
    int rest = e >> 12;
    int tap = rest % 49;
    int h   = rest / 49;
    float wv = w_first[((size_t)oc*64 + h*32 + ch)*49 + tap];
    __half hh = __float2half(wv);
    unsigned short us;
    if (!hl) us = h2us(hh);
    else { float rr = wv - __half2float(hh); us = h2us(__float2half(rr)); }
    wpack[e] = us;
  }
}

// ---------------------------------------------------------------------------
// x (NCHW f32) -> xpack single f16: [b][r][c][64] (8 granules of 8 ch)
// ---------------------------------------------------------------------------
__global__ __launch_bounds__(192) void tof16_pack_kernel(const float* __restrict__ x,
                                                         unsigned short* __restrict__ xpack)
{
  __shared__ unsigned int s[192*64];
  int r = blockIdx.x, b = blockIdx.y;
  int t = threadIdx.x;
  for (int ch = 0; ch < 64; ch++) {
    float v = x[((size_t)(b*64+ch)*Hq + r)*Wq + t];
    _Float16 hh = (_Float16)v;
    s[t*64 + (ch ^ (t & 31))] = (unsigned int)*(unsigned short*)&hh;
  }
  __syncthreads();
  unsigned short* dst = xpack + ((size_t)b*Hq + r)*Wq*64;
  for (int i = 0; i < 8; i++) {
    int gidx = i*192 + t;                // 1536 granules of 16B
    int c = gidx >> 3, g = gidx & 7;
    unsigned short tmp[8];
#pragma unroll
    for (int j = 0; j < 8; j++) {
      int ch = g*8 + j;
      tmp[j] = (unsigned short)s[c*64 + (ch ^ (c & 31))];
    }
    uint4 v;
    v.x = (unsigned int)tmp[0] | ((unsigned int)tmp[1] << 16);
    v.y = (unsigned int)tmp[2] | ((unsigned int)tmp[3] << 16);
    v.z = (unsigned int)tmp[4] | ((unsigned int)tmp[5] << 16);
    v.w = (unsigned int)tmp[6] | ((unsigned int)tmp[7] << 16);
    *(uint4*)(dst + (size_t)gidx*8) = v;
  }
}

// ---------------------------------------------------------------------------
// 7x7 conv via MFMA, 2-pass (x single f16, w hi/lo exact).
// B direct from global (L2), barrier-free 49-tap inner loop.
// Block = 1 wave (64 thr), covers 2 rows x 48 cols -> 6 A-frags,
// 48 MFMA per 8KB B-fetch. Grid 4x96x2 = 768 blocks, LDS 27.6 KB (5/CU).
// ---------------------------------------------------------------------------
__global__ __launch_bounds__(64) void conv7_mfma_kernel(
    const unsigned short* __restrict__ xpack,   // [b][r][c][64] f16
    const unsigned short* __restrict__ wpack,   // [h][tap][hl][oc][32] f16
    float* __restrict__ out)
{
  __shared__ __align__(16) unsigned short sA[8*54*32];   // 27648 B
  int ct = blockIdx.x;          // 0..3
  int rt = blockIdx.y;          // 0..95
  int b  = blockIdx.z;
  int r0 = rt*2, c0 = ct*48;
  int l = threadIdx.x;
  int l15 = l & 15, lg = l >> 4;

  f32x4 acc[2][3][4];
#pragma unroll
  for (int i = 0; i < 2; i++)
#pragma unroll
    for (int j = 0; j < 3; j++)
#pragma unroll
      for (int q = 0; q < 4; q++) acc[i][j][q] = (f32x4){0.f,0.f,0.f,0.f};

  for (int h = 0; h < 2; h++) {
    __syncthreads();            // prev half's sA readers done
    for (int idx = l; idx < 8*54*4; idx += 64) {
      int g = idx & 3, pix = idx >> 2;
      int row = pix / 54, col = pix % 54;
      int gr = r0 - 3 + row, gc = c0 - 3 + col;
      uint4 v = {0u,0u,0u,0u};
      if (gr >= 0 && gr < Hq && gc >= 0 && gc < Wq)
        v = *(const uint4*)(xpack + (((size_t)b*Hq + gr)*Wq + gc)*64 + (h*4 + g)*8);
      ((uint4*)sA)[(row*54 + col)*4 + (g ^ ((col >> 1) & 3))] = v;
    }
    __syncthreads();
    const unsigned short* wb = wpack + (size_t)h*49*4096;
    for (int tap = 0; tap < 49; tap++) {
      int dy = tap / 7, dx = tap % 7;
      f16x8 bh[4], bl[4];
#pragma unroll
      for (int tb = 0; tb < 4; tb++) {
        bh[tb] = *(const f16x8*)(wb + (size_t)tap*4096 + (tb*16 + l15)*32 + lg*8);
        bl[tb] = *(const f16x8*)(wb + (size_t)tap*4096 + 2048 + (tb*16 + l15)*32 + lg*8);
      }
#pragma unroll
      for (int rw = 0; rw < 2; rw++) {
        int arow = rw + dy;     // 0..7
        f16x8 a[3];
#pragma unroll
        for (int tc = 0; tc < 3; tc++) {
          int col = tc*16 + l15 + dx;
          a[tc] = *(const f16x8*)((const uint4*)sA + (arow*54 + col)*4 + (lg ^ ((col >> 1) & 3)));
        }
#pragma unroll
        for (int tc = 0; tc < 3; tc++)
#pragma unroll
          for (int tb = 0; tb < 4; tb++) {
            acc[rw][tc][tb] = __builtin_amdgcn_mfma_f32_16x16x32_f16(a[tc], bh[tb], acc[rw][tc][tb], 0, 0, 0);
            acc[rw][tc][tb] = __builtin_amdgcn_mfma_f32_16x16x32_f16(a[tc], bl[tb], acc[rw][tc][tb], 0, 0, 0);
          }
      }
    }
  }
#pragma unroll
  for (int tb = 0; tb < 4; tb++) {
    int oc = tb*16 + l15;
#pragma unroll
    for (int rw = 0; rw < 2; rw++) {
      float* dst = out + ((size_t)(b*64 + oc)*Hq + (r0 + rw))*Wq + c0;
#pragma unroll
      for (int tc = 0; tc < 3; tc++) {
        f32x4 v = acc[rw][tc][tb];
        *(float4*)(dst + tc*16 + lg*4) = make_float4(v[0], v[1], v[2], v[3]);
      }
    }
  }
}

// ---------------------------------------------------------------------------
// Separable 7x7 avg pool
// ---------------------------------------------------------------------------
__global__ __launch_bounds__(256) void pool_row_kernel(const float* __restrict__ in, float* __restrict__ out)
{
  int idx = blockIdx.x*256 + threadIdx.x;
  int c = idx % Wq;
  int base = idx - c;
  float s = 0.f;
#pragma unroll
  for (int dc = -3; dc <= 3; dc++) {
    int cc = c + dc;
    if (cc >= 0 && cc < Wq) s += in[base + cc];
  }
  out[idx] = s;
}

__global__ __launch_bounds__(256) void pool_col_kernel(const float* __restrict__ in, float* __restrict__ out)
{
  int idx = blockIdx.x*256 + threadIdx.x;
  int c = idx % Wq;
  int r = (idx / Wq) % Hq;
  int plane = idx / HWq;
  float s = 0.f;
#pragma unroll
  for (int dr = -3; dr <= 3; dr++) {
    int rr = r + dr;
    if (rr >= 0 && rr < Hq) s += in[(size_t)plane*HWq + rr*Wq + c];
  }
  out[idx] = s * (1.f/49.f);
}

// ---------------------------------------------------------------------------
// FUSED depthwise 19-tap + f16 hi/lo plane-major pack.
// Thread = 8 channels x 1 pixel; writes one hi-granule + one lo-granule.
// Grid (144, 8, 2): px-block, g8, b.
// ---------------------------------------------------------------------------
__global__ __launch_bounds__(256) void dwf_h_kernel(const float* __restrict__ x1,
                                                    const float* __restrict__ wEff,
                                                    const float* __restrict__ bEff,
                                                    const float* __restrict__ wB,
                                                    unsigned short* __restrict__ pack)
{
  __shared__ float sW[8][19][20];
  int b = blockIdx.z, g8 = blockIdx.y;
  int t = threadIdx.x;
  int chb = g8*8;
  for (int i = t; i < 8*380; i += 256) {
    int ch8 = i / 380; int rem = i % 380;
    int row = rem / 20, jj = rem % 20;
    int ch = chb + ch8;
    float v;
    if (row < 18) v = wB[((size_t)ch*18 + row)*20 + jj];
    else v = (jj < 19) ? wEff[ch*19 + jj] : bEff[ch];
    sW[ch8][row][jj] = v;
  }
  __syncthreads();
  int p = blockIdx.x*256 + t;
  int r = p / Wq, c = p % Wq;
  int row = (c < 9) ? c : ((c >= Wq-9) ? (c - 174) : 18);
  float vals[8];
#pragma unroll
  for (int ch8 = 0; ch8 < 8; ch8++) {
    const float* src = x1 + (size_t)(b*Cq + chb + ch8)*HWq + r*Wq;
    float s = sW[ch8][row][19];
#pragma unroll
    for (int j = 0; j < 19; j++) {
      int idx = min(max(c + j - 9, 0), Wq-1);
      s += src[idx] * sW[ch8][row][j];
    }
    vals[ch8] = s;
  }
  unsigned int hi[4], lo[4];
#pragma unroll
  for (int q = 0; q < 4; q++) {
    __half h0 = __float2half(vals[2*q]);
    __half h1 = __float2half(vals[2*q+1]);
    __half l0 = __float2half(vals[2*q]   - __half2float(h0));
    __half l1 = __float2half(vals[2*q+1] - __half2float(h1));
    hi[q] = (unsigned int)h2us(h0) | ((unsigned int)h2us(h1) << 16);
    lo[q] = (unsigned int)h2us(l0) | ((unsigned int)h2us(l1) << 16);
  }
  *(uint4*)(pack + (((size_t)b*16 + g8)*HWq + p)*8)     = make_uint4(hi[0], hi[1], hi[2], hi[3]);
  *(uint4*)(pack + (((size_t)b*16 + 8 + g8)*HWq + p)*8) = make_uint4(lo[0], lo[1], lo[2], lo[3]);
}

__global__ __launch_bounds__(256) void dwf_v_kernel(const float* __restrict__ x1,
                                                    const float* __restrict__ wEff,
                                                    const float* __restrict__ bEff,
                                                    const float* __restrict__ wB,
                                                    unsigned short* __restrict__ pack)
{
  __shared__ float sW[8][19][20];
  int b = blockIdx.z, g8 = blockIdx.y;
  int t = threadIdx.x;
  int chb = g8*8;
  for (int i = t; i < 8*380; i += 256) {
    int ch8 = i / 380; int rem = i % 380;
    int row = rem / 20, jj = rem % 20;
    int ch = chb + ch8;
    float v;
    if (row < 18) v = wB[((size_t)ch*18 + row)*20 + jj];
    else v = (jj < 19) ? wEff[ch*19 + jj] : bEff[ch];
    sW[ch8][row][jj] = v;
  }
  __syncthreads();
  int p = blockIdx.x*256 + t;
  int r = p / Wq, c = p % Wq;
  int row = (r < 9) ? r : ((r >= Hq-9) ? (r - 174) : 18);
  float vals[8];
#pragma unroll
  for (int ch8 = 0; ch8 < 8; ch8++) {
    const float* src = x1 + (size_t)(b*Cq + chb + ch8)*HWq + c;
    float s = sW[ch8][row][19];
#pragma unroll
    for (int j = 0; j < 19; j++) {
      int idx = min(max(r + j - 9, 0), Hq-1);
      s += src[idx*Wq] * sW[ch8][row][j];
    }
    vals[ch8] = s;
  }
  unsigned int hi[4], lo[4];
#pragma unroll
  for (int q = 0; q < 4; q++) {
    __half h0 = __float2half(vals[2*q]);
    __half h1 = __float2half(vals[2*q+1]);
    __half l0 = __float2half(vals[2*q]   - __half2float(h0));
    __half l1 = __float2half(vals[2*q+1] - __half2float(h1));
    hi[q] = (unsigned int)h2us(h0) | ((unsigned int)h2us(h1) << 16);
    lo[q] = (unsigned int)h2us(l0) | ((unsigned int)h2us(l1) << 16);
  }
  *(uint4*)(pack + (((size_t)b*16 + g8)*HWq + p)*8)     = make_uint4(hi[0], hi[1], hi[2], hi[3]);
  *(uint4*)(pack + (((size_t)b*16 + 8 + g8)*HWq + p)*8) = make_uint4(lo[0], lo[1], lo[2], lo[3]);
}

// ---------------------------------------------------------------------------
// Offset conv + tanh + cum, reading plane-major fpack (coalesced)
// ---------------------------------------------------------------------------
__global__ __launch_bounds__(256) void off_cum_kernel(const unsigned short* __restrict__ fp,
                                                      const float* __restrict__ wOff,
                                                      const float* __restrict__ bOff,
                                                      float* __restrict__ cum)
{
  const size_t HW8 = (size_t)HWq*8;
  int b = blockIdx.y;
  int p = blockIdx.x*256 + threadIdx.x;
  int r = p / Wq, c = p % Wq;
  float tv[7];
#pragma unroll
  for (int m = 0; m < 7; m++) tv[m] = bOff[m];
  const unsigned short* fb = fp + (size_t)b*HWq*128;
  for (int tap = 0; tap < 9; tap++) {
    int dy = tap/3 - 1, dx = tap%3 - 1;
    int rr = r + dy, cc = c + dx;
    if (rr < 0 || rr >= Hq || cc < 0 || cc >= Wq) continue;
    const unsigned short* p0 = fb + ((size_t)rr*Wq + cc)*8;
    const float* wp = wOff + tap*512;
    for (int g = 0; g < 8; g++) {
      f16x8 hv = *(const f16x8*)(p0 + (size_t)g*HW8);
      f16x8 lv = *(const f16x8*)(p0 + (size_t)(8 + g)*HW8);
#pragma unroll
      for (int e = 0; e < 8; e++) {
        float fv = (float)hv[e] + (float)lv[e];
        const float* wr = wp + (g*8 + e)*8;
#pragma unroll
        for (int m = 0; m < 7; m++) tv[m] += fv * wr[m];
      }
    }
  }
#pragma unroll
  for (int m = 0; m < 7; m++) tv[m] = tanhf(tv[m]);
  float c0 = tv[0], c1 = tv[1] + tv[2], c2 = tv[2], c3 = 0.f;
  float c4 = tv[4], c5 = tv[4] + tv[5], c6 = tv[6];
  size_t bb = (size_t)b*7*HWq + p;
  cum[bb + 0*HWq] = c0; cum[bb + 1*HWq] = c1; cum[bb + 2*HWq] = c2;
  cum[bb + 3*HWq] = c3; cum[bb + 4*HWq] = c4; cum[bb + 5*HWq] = c5;
  cum[bb + 6*HWq] = c6;
}

// ---------------------------------------------------------------------------
// Deformable sample + einsum via MFMA (f16 hi/lo 3-pass).
// Plane-major fpack reads + XCD-banded block swizzle.
// ---------------------------------------------------------------------------
template<int MORPH>
__global__ __launch_bounds__(128) void einsum_mfma_kernel(
    const unsigned short* __restrict__ fp,   // fpack [b][sub16][px][8]
    const float* __restrict__ cum,
    const unsigned short* __restrict__ wtp,  // [tap][kc][hl][oc][32] f16
    const float* __restrict__ dsc_b,
    float* __restrict__ out)                 // NCHW f32
{
  __shared__ __align__(16) unsigned short sA[2*64*128];  // 32 KB
  const size_t HW8 = (size_t)HWq*8;
  int bid = blockIdx.x;                   // 0..575
  int swz = (bid & 7)*72 + (bid >> 3);    // XCD-contiguous bands (576 = 8*72)
  int b   = swz / 288;
  int blk = swz % 288;
  int t = threadIdx.x;
  int w = t >> 6, l = t & 63;
  int l15 = l & 15, lg = l >> 4;
  int p = blk*128 + w*64 + l;
  int r = p / Wq, c = p % Wq;

  f32x4 acc[4][4];
#pragma unroll
  for (int i = 0; i < 4; i++)
#pragma unroll
    for (int j = 0; j < 4; j++) acc[i][j] = (f32x4){0.f,0.f,0.f,0.f};

  const unsigned short* fb = fp + (size_t)b*HWq*128;
  unsigned short* myrow = sA + (size_t)(w*64 + l)*128;

  for (int k = 0; k < 7; k++) {
    bool oob;
    const unsigned short *p0, *p1;
    float w0, w1;
    if (MORPH == 0) {
      int xi = c + k - 3;
      oob = (xi < 0 || xi >= Wq);
      if (!oob) {
        float y = (float)r + cum[((size_t)(b*7 + k))*HWq + p];
        float y0 = floorf(y);
        int y0q = (int)y0;
        int y0i = min(max(y0q, 0), Hq-1);
        int y1i = min(max(y0q + 1, 0), Hq-1);
        float y0f = fminf(fmaxf(y0, 0.f), (float)Hq);
        float y1f = fminf(fmaxf(y0 + 1.f, 0.f), (float)Hq);
        w0 = y1f - y; w1 = y - y0f;
        p0 = fb + ((size_t)y0i*Wq + xi)*8;
        p1 = fb + ((size_t)y1i*Wq + xi)*8;
      }
    } else {
      int yi = r + k - 3;
      oob = (yi < 0 || yi >= Hq);
      if (!oob) {
        float xf = (float)c + cum[((size_t)(b*7 + k))*HWq + p];
        float x0 = floorf(xf);
        int x0q = (int)x0;
        int x0i = min(max(x0q, 0), Wq-1);
        int x1i = min(max(x0q + 1, 0), Wq-1);
        float x0f = fminf(fmaxf(x0, 0.f), (float)Wq);
        float x1f = fminf(fmaxf(x0 + 1.f, 0.f), (float)Wq);
        w0 = x1f - xf; w1 = xf - x0f;
        p0 = fb + ((size_t)yi*Wq + x0i)*8;
        p1 = fb + ((size_t)yi*Wq + x1i)*8;
      }
    }
    if (oob) {
      uint4 z = {0u,0u,0u,0u};
#pragma unroll
      for (int j = 0; j < 16; j++) ((uint4*)myrow)[j] = z;
    } else {
#pragma unroll
      for (int g = 0; g < 8; g++) {
        f16x8 a0h = *(const f16x8*)(p0 + (size_t)g*HW8);
        f16x8 a0l = *(const f16x8*)(p0 + (size_t)(8 + g)*HW8);
        f16x8 a1h = *(const f16x8*)(p1 + (size_t)g*HW8);
        f16x8 a1l = *(const f16x8*)(p1 + (size_t)(8 + g)*HW8);
        f16x8 sh, sl;
#pragma unroll
        for (int e = 0; e < 8; e++) {
          float v = w0*((float)a0h[e] + (float)a0l[e]) + w1*((float)a1h[e] + (float)a1l[e]);
          _Float16 vh = (_Float16)v;
          sh[e] = vh;
          sl[e] = (_Float16)(v - (float)vh);
        }
        *(f16x8*)(myrow + (size_t)(g ^ l15)*8)       = sh;
        *(f16x8*)(myrow + (size_t)((8 + g) ^ l15)*8) = sl;
      }
    }
    __syncthreads();
#pragma unroll
    for (int kc = 0; kc < 2; kc++) {
      const unsigned short* wbase = wtp + (size_t)((k*2 + kc)*2)*2048;
      f16x8 bh[4], bl[4];
#pragma unroll
      for (int tb = 0; tb < 4; tb++) {
        bh[tb] = *(const f16x8*)(wbase + (tb*16 + l15)*32 + lg*8);
        bl[tb] = *(const f16x8*)(wbase + 2048 + (tb*16 + l15)*32 + lg*8);
      }
      f16x8 ah[4], al[4];
#pragma unroll
      for (int ta = 0; ta < 4; ta++) {
        const unsigned short* rbase = sA + (size_t)(w*64 + ta*16 + l15)*128;
        ah[ta] = *(const f16x8*)(rbase + (size_t)((kc*4 + lg) ^ l15)*8);
        al[ta] = *(const f16x8*)(rbase + (size_t)((8 + kc*4 + lg) ^ l15)*8);
      }
#pragma unroll
      for (int ta = 0; ta < 4; ta++)
#pragma unroll
        for (int tb = 0; tb < 4; tb++) {
          acc[ta][tb] = __builtin_amdgcn_mfma_f32_16x16x32_f16(ah[ta], bh[tb], acc[ta][tb], 0, 0, 0);
          acc[ta][tb] = __builtin_amdgcn_mfma_f32_16x16x32_f16(ah[ta], bl[tb], acc[ta][tb], 0, 0, 0);
          acc[ta][tb] = __builtin_amdgcn_mfma_f32_16x16x32_f16(al[ta], bh[tb], acc[ta][tb], 0, 0, 0);
        }
    }
    __syncthreads();
  }
  int pbase = blk*128 + w*64;
#pragma unroll
  for (int tb = 0; tb < 4; tb++) {
    int oc = tb*16 + l15;
    float bias = dsc_b[oc];
    float* dst = out + (size_t)(b*64 + oc)*HWq + pbase;
#pragma unroll
    for (int ta = 0; ta < 4; ta++) {
      f32x4 v = acc[ta][tb];
      *(float4*)(dst + ta*16 + lg*4) = make_float4(v[0]+bias, v[1]+bias, v[2]+bias, v[3]+bias);
    }
  }
}

// ---------------------------------------------------------------------------
// GroupNorm stats + finalize
// ---------------------------------------------------------------------------
__global__ __launch_bounds__(256) void gnstats_kernel(const float* __restrict__ h_ds,
                                                      const float* __restrict__ v_ds,
                                                      float* __restrict__ stats)
{
  int plane = blockIdx.x;
  int buf = plane >> 7;
  int rem = plane & 127;
  const float* src = (buf ? v_ds : h_ds) + (size_t)rem*HWq;
  float s = 0.f, s2 = 0.f;
  for (int i = threadIdx.x; i < HWq; i += 256) {
    float v = src[i];
    s += v; s2 += v*v;
  }
  __shared__ float red[2][4];
  for (int off = 32; off; off >>= 1) {
    s  += __shfl_down(s, off);
    s2 += __shfl_down(s2, off);
  }
  if ((threadIdx.x & 63) == 0) { red[0][threadIdx.x >> 6] = s; red[1][threadIdx.x >> 6] = s2; }
  __syncthreads();
  if (threadIdx.x == 0) {
    s  = red[0][0] + red[0][1] + red[0][2] + red[0][3];
    s2 = red[1][0] + red[1][1] + red[1][2] + red[1][3];
    stats[plane*2 + 0] = s;
    stats[plane*2 + 1] = s2;
  }
}

__global__ __launch_bounds__(256) void gnfinal_kernel(const float* __restrict__ stats,
                                                      const float* __restrict__ h_gn_g, const float* __restrict__ h_gn_b,
                                                      const float* __restrict__ v_gn_g, const float* __restrict__ v_gn_b,
                                                      float* __restrict__ gnAB)
{
  int t = threadIdx.x;
  int buf = t >> 7, ch = t & 63;
  int base = t & ~3;
  float sum = 0.f, ss = 0.f;
#pragma unroll
  for (int q = 0; q < 4; q++) { sum += stats[(base+q)*2]; ss += stats[(base+q)*2 + 1]; }
  const float n = 4.f * HWq;
  float mean = sum / n;
  float var = ss / n - mean*mean;
  float gg = (buf ? v_gn_g : h_gn_g)[ch];
  float bb = (buf ? v_gn_b : h_gn_b)[ch];
  float A = gg / sqrtf(var + 1e-5f);
  gnAB[t*2 + 0] = A;
  gnAB[t*2 + 1] = bb - mean*A;
}

// ---------------------------------------------------------------------------
// FUSED: comb = relu(GN(h)) + relu(GN(v)) + x1 inline, then 1x1 conv + SiLU
// ---------------------------------------------------------------------------
__global__ __launch_bounds__(256) void final2_kernel(const float* __restrict__ hbuf,
                                                     const float* __restrict__ vbuf,
                                                     const float* __restrict__ x1,
                                                     const float* __restrict__ gnAB,
                                                     const float* __restrict__ lwT,
                                                     const float* __restrict__ lbO,
                                                     float* __restrict__ out)
{
  int b = blockIdx.y;
  int p = blockIdx.x*256 + threadIdx.x;
  float acc[64];
#pragma unroll
  for (int o = 0; o < 64; o++) acc[o] = 0.f;
  for (int i = 0; i < 64; i++) {
    size_t off = (size_t)(b*64 + i)*HWq + p;
    int plane = b*64 + i;
    int ih = plane*2;
    int iv = (128 + plane)*2;
    float hv = fmaxf(hbuf[off]*gnAB[ih] + gnAB[ih+1], 0.f);
    float vv = fmaxf(vbuf[off]*gnAB[iv] + gnAB[iv+1], 0.f);
    float cv = hv + vv + x1[off];
    const float* wr = lwT + i*64;
#pragma unroll
    for (int o = 0; o < 64; o++) acc[o] += cv * wr[o];
  }
  float* dst = out + (size_t)b*Cq*HWq + p;
#pragma unroll
  for (int o = 0; o < 64; o++) {
    float yv = acc[o] + lbO[o];
    dst[(size_t)o*HWq] = yv / (1.f + expf(-yv));
  }
}

// ---------------------------------------------------------------------------
extern "C" void kernel_launch(void* const* d_in, const int* in_sizes, int n_in,
                              void* d_out, int out_size, void* d_ws, size_t ws_size,
                              hipStream_t stream)
{
  const float* x       = (const float*)d_in[0];
  const float* w_first = (const float*)d_in[1];
  float* ws = (float*)d_ws;

  float* bufA = ws;            // conv7 out -> h-einsum-out
  float* bufB = ws + Nq;       // rowsum tmp -> v-einsum-out
  float* x1   = ws + 2*Nq;
  float* h_ds = ws + 3*Nq;     // xpack -> fpackH
  float* v_ds = ws + 4*Nq;     // fpackV
  size_t off = 5*Nq;
  float* hcum  = ws + off; off += (size_t)Bq*7*HWq;
  float* vcum  = ws + off; off += (size_t)Bq*7*HWq;
  float* wEffH = ws + off; off += 64*19;
  float* bEffH = ws + off; off += 64;
  float* wEffV = ws + off; off += 64*19;
  float* bEffV = ws + off; off += 64;
  float* wtH   = ws + off; off += 64*64*7;   // holds wtpH f16 pack
  float* wtV   = ws + off; off += 64*64*7;   // holds wtpV f16 pack
  float* wOffH = ws + off; off += 9*64*8;
  float* bOffH = ws + off; off += 8;
  float* wOffV = ws + off; off += 9*64*8;
  float* bOffV = ws + off; off += 8;
  float* lwT   = ws + off; off += 64*64;
  float* lbO   = ws + off; off += 64;
  float* stats = ws + off; off += 512;
  float* gnAB  = ws + off; off += 512;
  float* wB    = ws + off; off += 2*64*18*20;
  unsigned short* wpack = (unsigned short*)(ws + off); off += 2*49*2*64*32/2 + 16;
  unsigned short* xpack  = (unsigned short*)h_ds;
  unsigned short* fpackH = (unsigned short*)h_ds;
  unsigned short* fpackV = (unsigned short*)v_ds;
  unsigned short* wtpH = (unsigned short*)wtH;
  unsigned short* wtpV = (unsigned short*)wtV;

  prep_small_kernel<<<dim3(1), dim3(256), 0, stream>>>(
      (const float*)d_in[2],  (const float*)d_in[3],  (const float*)d_in[4],  (const float*)d_in[5],
      (const float*)d_in[6],  (const float*)d_in[7],
      (const float*)d_in[8],  (const float*)d_in[9],  (const float*)d_in[10], (const float*)d_in[11],
      (const float*)d_in[12], (const float*)d_in[13],
      (const float*)d_in[14], (const float*)d_in[15], (const float*)d_in[16], (const float*)d_in[17],
      (const float*)d_in[18], (const float*)d_in[19],
      (const float*)d_in[24], (const float*)d_in[25], (const float*)d_in[26], (const float*)d_in[27],
      (const float*)d_in[28], (const float*)d_in[29],
      (const float*)d_in[34], (const float*)d_in[35], (const float*)d_in[36], (const float*)d_in[37],
      (const float*)d_in[38],
      wEffH, bEffH, wEffV, bEffV, wOffH, bOffH, wOffV, bOffV, lwT, lbO);

  prep_border_kernel<<<dim3(9), dim3(256), 0, stream>>>(
      (const float*)d_in[2],  (const float*)d_in[3],  (const float*)d_in[4],  (const float*)d_in[5],
      (const float*)d_in[6],  (const float*)d_in[7],
      (const float*)d_in[8],  (const float*)d_in[9],  (const float*)d_in[10], (const float*)d_in[11],
      (const float*)d_in[12], (const float*)d_in[13], wB);

  prep_big_kernel<<<dim3(64), dim3(256), 0, stream>>>(
      w_first, (const float*)d_in[20], (const float*)d_in[30], wtpH, wtpV, wpack);

  tof16_pack_kernel<<<dim3(Hq, Bq), dim3(192), 0, stream>>>(x, xpack);
  conv7_mfma_kernel<<<dim3(4, 96, 2), dim3(64), 0, stream>>>(xpack, wpack, bufA);

  pool_row_kernel<<<dim3(18432), dim3(256), 0, stream>>>(bufA, bufB);
  pool_col_kernel<<<dim3(18432), dim3(256), 0, stream>>>(bufB, x1);

  dwf_h_kernel<<<dim3(144, 8, 2), dim3(256), 0, stream>>>(x1, wEffH, bEffH, wB, fpackH);
  dwf_v_kernel<<<dim3(144, 8, 2), dim3(256), 0, stream>>>(x1, wEffV, bEffV, wB + 64*18*20, fpackV);

  off_cum_kernel<<<dim3(144, 2), dim3(256), 0, stream>>>(fpackH, wOffH, bOffH, hcum);
  off_cum_kernel<<<dim3(144, 2), dim3(256), 0, stream>>>(fpackV, wOffV, bOffV, vcum);

  einsum_mfma_kernel<0><<<dim3(576), dim3(128), 0, stream>>>(fpackH, hcum, wtpH, (const float*)d_in[21], bufA);
  einsum_mfma_kernel<1><<<dim3(576), dim3(128), 0, stream>>>(fpackV, vcum, wtpV, (const float*)d_in[31], bufB);

  gnstats_kernel<<<dim3(256), dim3(256), 0, stream>>>(bufA, bufB, stats);
  gnfinal_kernel<<<dim3(1), dim3(256), 0, stream>>>(stats,
      (const float*)d_in[22], (const float*)d_in[23],
      (const float*)d_in[32], (const float*)d_in[33], gnAB);

  final2_kernel<<<dim3(144, 2), dim3(256), 0, stream>>>(bufA, bufB, x1, gnAB, lwT, lbO, (float*)d_out);
}

// Round 13
// 556.906 us; speedup vs baseline: 1.1185x; 1.0518x over previous
//
#include <hip/hip_runtime.h>
#include <hip/hip_bf16.h>
#include <hip/hip_fp16.h>
#include <math.h>

#define Bq 2
#define Cq 64
#define Hq 192
#define Wq 192
#define HWq (Hq*Wq)            // 36864
#define Nq ((size_t)Bq*Cq*HWq) // 4718592

typedef __attribute__((ext_vector_type(8))) _Float16 f16x8;
typedef __attribute__((ext_vector_type(4))) float f32x4;

__device__ inline unsigned short h2us(__half h) {
  union { __half h; unsigned short u; } v; v.h = h; return v.u;
}

// ---------------------------------------------------------------------------
// Small prep (1 block)
// ---------------------------------------------------------------------------
__global__ __launch_bounds__(256) void prep_small_kernel(
    const float* hc1_w, const float* hc1_b, const float* hc2_w, const float* hc2_b,
    const float* hc3_w, const float* hc3_b,
    const float* vc1_w, const float* vc1_b, const float* vc2_w, const float* vc2_b,
    const float* vc3_w, const float* vc3_b,
    const float* h_off_w, const float* h_off_b, const float* h_bn_g, const float* h_bn_b,
    const float* h_bn_m, const float* h_bn_v,
    const float* v_off_w, const float* v_off_b, const float* v_bn_g, const float* v_bn_b,
    const float* v_bn_m, const float* v_bn_v,
    const float* last_w, const float* last_g, const float* last_b, const float* last_m,
    const float* last_v,
    float* wEffH, float* bEffH, float* wEffV, float* bEffV,
    float* wOffH, float* bOffH, float* wOffV, float* bOffV,
    float* lwT, float* lbO)
{
  int t = threadIdx.x;
  if (t < 128) {
    int ch = t & 63;
    bool ish = t < 64;
    const float* w1 = (ish ? hc1_w : vc1_w) + ch*9;
    const float* w2 = (ish ? hc2_w : vc2_w) + ch*7;
    const float* w3 = (ish ? hc3_w : vc3_w) + ch*5;
    float t15[15];
    for (int s = 0; s < 15; s++) {
      float a = 0.f;
      for (int j = 0; j < 9; j++) { int k2 = s - j; if (k2 >= 0 && k2 < 7) a += w1[j]*w2[k2]; }
      t15[s] = a;
    }
    float* we = (ish ? wEffH : wEffV) + ch*19;
    for (int s = 0; s < 19; s++) {
      float a = 0.f;
      for (int j = 0; j < 15; j++) { int k3 = s - j; if (k3 >= 0 && k3 < 5) a += t15[j]*w3[k3]; }
      we[s] = a;
    }
    float S2 = 0.f, S3 = 0.f;
    for (int j = 0; j < 7; j++) S2 += w2[j];
    for (int j = 0; j < 5; j++) S3 += w3[j];
    float b1 = (ish ? hc1_b : vc1_b)[ch];
    float b2 = (ish ? hc2_b : vc2_b)[ch];
    float b3 = (ish ? hc3_b : vc3_b)[ch];
    (ish ? bEffH : bEffV)[ch] = b1*S2*S3 + b2*S3 + b3;
  }
  for (int idx = t; idx < 9*64*7; idx += 256) {
    int tap = idx / 448; int rem = idx % 448; int i = rem / 7; int m = rem % 7;
    float invh = h_bn_g[m] / sqrtf(h_bn_v[m] + 1e-5f);
    wOffH[(tap*64 + i)*8 + m] = h_off_w[(m*64 + i)*9 + tap] * invh;
    float invv = v_bn_g[7+m] / sqrtf(v_bn_v[7+m] + 1e-5f);
    wOffV[(tap*64 + i)*8 + m] = v_off_w[((7+m)*64 + i)*9 + tap] * invv;
  }
  if (t < 7) {
    float invh = h_bn_g[t] / sqrtf(h_bn_v[t] + 1e-5f);
    bOffH[t] = h_off_b[t]*invh + h_bn_b[t] - h_bn_m[t]*invh;
    float invv = v_bn_g[7+t] / sqrtf(v_bn_v[7+t] + 1e-5f);
    bOffV[t] = v_off_b[7+t]*invv + v_bn_b[7+t] - v_bn_m[7+t]*invv;
  }
  for (int idx = t; idx < 4096; idx += 256) {
    int o = idx % 64; int i = idx / 64;
    float inv = last_g[o] / sqrtf(last_v[o] + 1e-3f);
    lwT[i*64 + o] = last_w[o*64 + i] * inv;
  }
  if (t < 64) {
    float inv = last_g[t] / sqrtf(last_v[t] + 1e-3f);
    lbO[t] = last_b[t] - last_m[t]*inv;
  }
}

// ---------------------------------------------------------------------------
// Border prep (impulse-response composed clipped 19-tap weights)
// ---------------------------------------------------------------------------
__global__ __launch_bounds__(256) void prep_border_kernel(
    const float* hc1_w, const float* hc1_b, const float* hc2_w, const float* hc2_b,
    const float* hc3_w, const float* hc3_b,
    const float* vc1_w, const float* vc1_b, const float* vc2_w, const float* vc2_b,
    const float* vc3_w, const float* vc3_b,
    float* wB)
{
  int tid = blockIdx.x*256 + threadIdx.x;
  if (tid >= 2*64*18) return;
  int cls = tid % 18;
  int ch  = (tid / 18) % 64;
  int br  = tid / (18*64);
  int c = (cls < 9) ? cls : cls + 174;
  const float* w1 = (br==0 ? hc1_w : vc1_w) + ch*9;
  const float* w2 = (br==0 ? hc2_w : vc2_w) + ch*7;
  const float* w3 = (br==0 ? hc3_w : vc3_w) + ch*5;
  float b1 = (br==0 ? hc1_b : vc1_b)[ch];
  float b2 = (br==0 ? hc2_b : vc2_b)[ch];
  float b3 = (br==0 ? hc3_b : vc3_b)[ch];
  float* dst = wB + ((size_t)(br*64 + ch)*18 + cls)*20;
  for (int cse = 0; cse < 20; cse++) {
    bool basis = (cse < 19);
    int fd = c + cse - 9;
    float B1 = basis ? 0.f : b1, B2 = basis ? 0.f : b2, B3 = basis ? 0.f : b3;
    float o3 = B3;
    for (int m = 0; m < 5; m++) {
      int d = c + m - 2;
      if (d < 0 || d >= Wq) continue;
      float o2 = B2;
      for (int k = 0; k < 7; k++) {
        int e = d + k - 3;
        if (e < 0 || e >= Wq) continue;
        float o1 = B1;
        if (basis) {
          int tp = fd - e + 4;
          if (tp >= 0 && tp < 9 && fd >= 0 && fd < Wq) o1 += w1[tp];
        }
        o2 += o1 * w2[k];
      }
      o3 += o2 * w3[m];
    }
    dst[cse] = o3;
  }
}

// ---------------------------------------------------------------------------
// Big prep: dsc weights -> f16 hi/lo MFMA pack [tap][kc][hl][oc][32]
//           + w_first f16 hi/lo pack for conv7.
// ---------------------------------------------------------------------------
__global__ __launch_bounds__(256) void prep_big_kernel(
    const float* __restrict__ w_first,
    const float* __restrict__ h_dsc_w, const float* __restrict__ v_dsc_w,
    unsigned short* __restrict__ wtpH, unsigned short* __restrict__ wtpV,
    unsigned short* __restrict__ wpack)
{
  int tid = blockIdx.x*256 + threadIdx.x;
  int nthr = gridDim.x*256;
  for (int idx = tid; idx < 7*2*2*64*32; idx += nthr) {
    int ch32 = idx & 31;
    int oc   = (idx >> 5) & 63;
    int hl   = (idx >> 11) & 1;
    int kc   = (idx >> 12) & 1;
    int tap  = idx >> 13;
    int i = kc*32 + ch32;
    float vh = h_dsc_w[oc*448 + i*7 + tap];
    float vv = v_dsc_w[oc*448 + i*7 + tap];
    _Float16 hh = (_Float16)vh;
    _Float16 hv = (_Float16)vv;
    unsigned short uh, uv;
    if (!hl) { uh = *(unsigned short*)&hh; uv = *(unsigned short*)&hv; }
    else {
      _Float16 lh = (_Float16)(vh - (float)hh);
      _Float16 lv = (_Float16)(vv - (float)hv);
      uh = *(unsigned short*)&lh; uv = *(unsigned short*)&lv;
    }
    wtpH[idx] = uh; wtpV[idx] = uv;
  }
  for (int e = tid; e < 2*49*2*64*32; e += nthr) {
    int ch  = e & 31;
    int oc  = (e >> 5) & 63;
    int hl  = (e >> 11) & 1;
    int rest = e >> 12;
    int tap = rest % 49;
    int h   = rest / 49;
    float wv = w_first[((size_t)oc*64 + h*32 + ch)*49 + tap];
    __half hh = __float2half(wv);
    unsigned short us;
    if (!hl) us = h2us(hh);
    else { float rr = wv - __half2float(hh); us = h2us(__float2half(rr)); }
    wpack[e] = us;
  }
}

// ---------------------------------------------------------------------------
// x (NCHW f32) -> xpack single f16: [b][r][c][64] (8 granules of 8 ch)
// ---------------------------------------------------------------------------
__global__ __launch_bounds__(192) void tof16_pack_kernel(const float* __restrict__ x,
                                                         unsigned short* __restrict__ xpack)
{
  __shared__ unsigned int s[192*64];
  int r = blockIdx.x, b = blockIdx.y;
  int t = threadIdx.x;
  for (int ch = 0; ch < 64; ch++) {
    float v = x[((size_t)(b*64+ch)*Hq + r)*Wq + t];
    _Float16 hh = (_Float16)v;
    s[t*64 + (ch ^ (t & 31))] = (unsigned int)*(unsigned short*)&hh;
  }
  __syncthreads();
  unsigned short* dst = xpack + ((size_t)b*Hq + r)*Wq*64;
  for (int i = 0; i < 8; i++) {
    int gidx = i*192 + t;                // 1536 granules of 16B
    int c = gidx >> 3, g = gidx & 7;
    unsigned short tmp[8];
#pragma unroll
    for (int j = 0; j < 8; j++) {
      int ch = g*8 + j;
      tmp[j] = (unsigned short)s[c*64 + (ch ^ (c & 31))];
    }
    uint4 v;
    v.x = (unsigned int)tmp[0] | ((unsigned int)tmp[1] << 16);
    v.y = (unsigned int)tmp[2] | ((unsigned int)tmp[3] << 16);
    v.z = (unsigned int)tmp[4] | ((unsigned int)tmp[5] << 16);
    v.w = (unsigned int)tmp[6] | ((unsigned int)tmp[7] << 16);
    *(uint4*)(dst + (size_t)gidx*8) = v;
  }
}

// ---------------------------------------------------------------------------
// 7x7 conv via MFMA, 2-pass (x single f16, w hi/lo exact).
// Block = 2 waves split by OC-HALF (wave w owns oc w*32..w*32+31):
// per-wave B-fetch 4KB/tap (disjoint), 24 MFMA/tap, acc 48 VGPR.
// #pragma unroll 7 on the tap loop gives the scheduler a 7-tap window
// of independent B-loads to hoist (software pipelining).
// Tile 2 rows x 48 cols, grid 4x96x2 = 768 blocks, LDS 27.6 KB.
// ---------------------------------------------------------------------------
__global__ __launch_bounds__(128) void conv7_mfma_kernel(
    const unsigned short* __restrict__ xpack,   // [b][r][c][64] f16
    const unsigned short* __restrict__ wpack,   // [h][tap][hl][oc][32] f16
    float* __restrict__ out)
{
  __shared__ __align__(16) unsigned short sA[8*54*32];   // 27648 B
  int ct = blockIdx.x;          // 0..3
  int rt = blockIdx.y;          // 0..95
  int b  = blockIdx.z;
  int r0 = rt*2, c0 = ct*48;
  int t = threadIdx.x;
  int wv = t >> 6;              // wave -> oc half
  int l  = t & 63;
  int l15 = l & 15, lg = l >> 4;
  int ocb = wv*32;

  f32x4 acc[2][3][2];           // [row][col-tile][oc-tile-in-half]
#pragma unroll
  for (int i = 0; i < 2; i++)
#pragma unroll
    for (int j = 0; j < 3; j++)
#pragma unroll
      for (int q = 0; q < 2; q++) acc[i][j][q] = (f32x4){0.f,0.f,0.f,0.f};

  for (int h = 0; h < 2; h++) {
    __syncthreads();            // prev half's sA readers done
    for (int idx = t; idx < 8*54*4; idx += 128) {
      int g = idx & 3, pix = idx >> 2;
      int row = pix / 54, col = pix % 54;
      int gr = r0 - 3 + row, gc = c0 - 3 + col;
      uint4 v = {0u,0u,0u,0u};
      if (gr >= 0 && gr < Hq && gc >= 0 && gc < Wq)
        v = *(const uint4*)(xpack + (((size_t)b*Hq + gr)*Wq + gc)*64 + (h*4 + g)*8);
      ((uint4*)sA)[(row*54 + col)*4 + (g ^ ((col >> 1) & 3))] = v;
    }
    __syncthreads();
    const unsigned short* wb = wpack + (size_t)h*49*4096;
#pragma unroll 7
    for (int tap = 0; tap < 49; tap++) {
      int dy = tap / 7, dx = tap % 7;
      f16x8 bh[2], bl[2];
#pragma unroll
      for (int tbL = 0; tbL < 2; tbL++) {
        int oc = ocb + tbL*16 + l15;
        bh[tbL] = *(const f16x8*)(wb + (size_t)tap*4096 +        oc*32 + lg*8);
        bl[tbL] = *(const f16x8*)(wb + (size_t)tap*4096 + 2048 + oc*32 + lg*8);
      }
#pragma unroll
      for (int rw = 0; rw < 2; rw++) {
        int arow = rw + dy;     // 0..7
        f16x8 a[3];
#pragma unroll
        for (int tc = 0; tc < 3; tc++) {
          int col = tc*16 + l15 + dx;
          a[tc] = *(const f16x8*)((const uint4*)sA + (arow*54 + col)*4 + (lg ^ ((col >> 1) & 3)));
        }
#pragma unroll
        for (int tc = 0; tc < 3; tc++)
#pragma unroll
          for (int tbL = 0; tbL < 2; tbL++) {
            acc[rw][tc][tbL] = __builtin_amdgcn_mfma_f32_16x16x32_f16(a[tc], bh[tbL], acc[rw][tc][tbL], 0, 0, 0);
            acc[rw][tc][tbL] = __builtin_amdgcn_mfma_f32_16x16x32_f16(a[tc], bl[tbL], acc[rw][tc][tbL], 0, 0, 0);
          }
      }
    }
  }
#pragma unroll
  for (int tbL = 0; tbL < 2; tbL++) {
    int oc = ocb + tbL*16 + l15;
#pragma unroll
    for (int rw = 0; rw < 2; rw++) {
      float* dst = out + ((size_t)(b*64 + oc)*Hq + (r0 + rw))*Wq + c0;
#pragma unroll
      for (int tc = 0; tc < 3; tc++) {
        f32x4 v = acc[rw][tc][tbL];
        *(float4*)(dst + tc*16 + lg*4) = make_float4(v[0], v[1], v[2], v[3]);
      }
    }
  }
}

// ---------------------------------------------------------------------------
// Separable 7x7 avg pool
// ---------------------------------------------------------------------------
__global__ __launch_bounds__(256) void pool_row_kernel(const float* __restrict__ in, float* __restrict__ out)
{
  int idx = blockIdx.x*256 + threadIdx.x;
  int c = idx % Wq;
  int base = idx - c;
  float s = 0.f;
#pragma unroll
  for (int dc = -3; dc <= 3; dc++) {
    int cc = c + dc;
    if (cc >= 0 && cc < Wq) s += in[base + cc];
  }
  out[idx] = s;
}

__global__ __launch_bounds__(256) void pool_col_kernel(const float* __restrict__ in, float* __restrict__ out)
{
  int idx = blockIdx.x*256 + threadIdx.x;
  int c = idx % Wq;
  int r = (idx / Wq) % Hq;
  int plane = idx / HWq;
  float s = 0.f;
#pragma unroll
  for (int dr = -3; dr <= 3; dr++) {
    int rr = r + dr;
    if (rr >= 0 && rr < Hq) s += in[(size_t)plane*HWq + rr*Wq + c];
  }
  out[idx] = s * (1.f/49.f);
}

// ---------------------------------------------------------------------------
// FUSED depthwise 19-tap + f16 hi/lo plane-major pack.
// Thread = 8 channels x 1 pixel; writes one hi-granule + one lo-granule.
// Grid (144, 8, 2): px-block, g8, b.
// ---------------------------------------------------------------------------
__global__ __launch_bounds__(256) void dwf_h_kernel(const float* __restrict__ x1,
                                                    const float* __restrict__ wEff,
                                                    const float* __restrict__ bEff,
                                                    const float* __restrict__ wB,
                                                    unsigned short* __restrict__ pack)
{
  __shared__ float sW[8][19][20];
  int b = blockIdx.z, g8 = blockIdx.y;
  int t = threadIdx.x;
  int chb = g8*8;
  for (int i = t; i < 8*380; i += 256) {
    int ch8 = i / 380; int rem = i % 380;
    int row = rem / 20, jj = rem % 20;
    int ch = chb + ch8;
    float v;
    if (row < 18) v = wB[((size_t)ch*18 + row)*20 + jj];
    else v = (jj < 19) ? wEff[ch*19 + jj] : bEff[ch];
    sW[ch8][row][jj] = v;
  }
  __syncthreads();
  int p = blockIdx.x*256 + t;
  int r = p / Wq, c = p % Wq;
  int row = (c < 9) ? c : ((c >= Wq-9) ? (c - 174) : 18);
  float vals[8];
#pragma unroll
  for (int ch8 = 0; ch8 < 8; ch8++) {
    const float* src = x1 + (size_t)(b*Cq + chb + ch8)*HWq + r*Wq;
    float s = sW[ch8][row][19];
#pragma unroll
    for (int j = 0; j < 19; j++) {
      int idx = min(max(c + j - 9, 0), Wq-1);
      s += src[idx] * sW[ch8][row][j];
    }
    vals[ch8] = s;
  }
  unsigned int hi[4], lo[4];
#pragma unroll
  for (int q = 0; q < 4; q++) {
    __half h0 = __float2half(vals[2*q]);
    __half h1 = __float2half(vals[2*q+1]);
    __half l0 = __float2half(vals[2*q]   - __half2float(h0));
    __half l1 = __float2half(vals[2*q+1] - __half2float(h1));
    hi[q] = (unsigned int)h2us(h0) | ((unsigned int)h2us(h1) << 16);
    lo[q] = (unsigned int)h2us(l0) | ((unsigned int)h2us(l1) << 16);
  }
  *(uint4*)(pack + (((size_t)b*16 + g8)*HWq + p)*8)     = make_uint4(hi[0], hi[1], hi[2], hi[3]);
  *(uint4*)(pack + (((size_t)b*16 + 8 + g8)*HWq + p)*8) = make_uint4(lo[0], lo[1], lo[2], lo[3]);
}

__global__ __launch_bounds__(256) void dwf_v_kernel(const float* __restrict__ x1,
                                                    const float* __restrict__ wEff,
                                                    const float* __restrict__ bEff,
                                                    const float* __restrict__ wB,
                                                    unsigned short* __restrict__ pack)
{
  __shared__ float sW[8][19][20];
  int b = blockIdx.z, g8 = blockIdx.y;
  int t = threadIdx.x;
  int chb = g8*8;
  for (int i = t; i < 8*380; i += 256) {
    int ch8 = i / 380; int rem = i % 380;
    int row = rem / 20, jj = rem % 20;
    int ch = chb + ch8;
    float v;
    if (row < 18) v = wB[((size_t)ch*18 + row)*20 + jj];
    else v = (jj < 19) ? wEff[ch*19 + jj] : bEff[ch];
    sW[ch8][row][jj] = v;
  }
  __syncthreads();
  int p = blockIdx.x*256 + t;
  int r = p / Wq, c = p % Wq;
  int row = (r < 9) ? r : ((r >= Hq-9) ? (r - 174) : 18);
  float vals[8];
#pragma unroll
  for (int ch8 = 0; ch8 < 8; ch8++) {
    const float* src = x1 + (size_t)(b*Cq + chb + ch8)*HWq + c;
    float s = sW[ch8][row][19];
#pragma unroll
    for (int j = 0; j < 19; j++) {
      int idx = min(max(r + j - 9, 0), Hq-1);
      s += src[idx*Wq] * sW[ch8][row][j];
    }
    vals[ch8] = s;
  }
  unsigned int hi[4], lo[4];
#pragma unroll
  for (int q = 0; q < 4; q++) {
    __half h0 = __float2half(vals[2*q]);
    __half h1 = __float2half(vals[2*q+1]);
    __half l0 = __float2half(vals[2*q]   - __half2float(h0));
    __half l1 = __float2half(vals[2*q+1] - __half2float(h1));
    hi[q] = (unsigned int)h2us(h0) | ((unsigned int)h2us(h1) << 16);
    lo[q] = (unsigned int)h2us(l0) | ((unsigned int)h2us(l1) << 16);
  }
  *(uint4*)(pack + (((size_t)b*16 + g8)*HWq + p)*8)     = make_uint4(hi[0], hi[1], hi[2], hi[3]);
  *(uint4*)(pack + (((size_t)b*16 + 8 + g8)*HWq + p)*8) = make_uint4(lo[0], lo[1], lo[2], lo[3]);
}

// ---------------------------------------------------------------------------
// Offset conv + tanh + cum, reading plane-major fpack (coalesced)
// ---------------------------------------------------------------------------
__global__ __launch_bounds__(256) void off_cum_kernel(const unsigned short* __restrict__ fp,
                                                      const float* __restrict__ wOff,
                                                      const float* __restrict__ bOff,
                                                      float* __restrict__ cum)
{
  const size_t HW8 = (size_t)HWq*8;
  int b = blockIdx.y;
  int p = blockIdx.x*256 + threadIdx.x;
  int r = p / Wq, c = p % Wq;
  float tv[7];
#pragma unroll
  for (int m = 0; m < 7; m++) tv[m] = bOff[m];
  const unsigned short* fb = fp + (size_t)b*HWq*128;
  for (int tap = 0; tap < 9; tap++) {
    int dy = tap/3 - 1, dx = tap%3 - 1;
    int rr = r + dy, cc = c + dx;
    if (rr < 0 || rr >= Hq || cc < 0 || cc >= Wq) continue;
    const unsigned short* p0 = fb + ((size_t)rr*Wq + cc)*8;
    const float* wp = wOff + tap*512;
    for (int g = 0; g < 8; g++) {
      f16x8 hv = *(const f16x8*)(p0 + (size_t)g*HW8);
      f16x8 lv = *(const f16x8*)(p0 + (size_t)(8 + g)*HW8);
#pragma unroll
      for (int e = 0; e < 8; e++) {
        float fv = (float)hv[e] + (float)lv[e];
        const float* wr = wp + (g*8 + e)*8;
#pragma unroll
        for (int m = 0; m < 7; m++) tv[m] += fv * wr[m];
      }
    }
  }
#pragma unroll
  for (int m = 0; m < 7; m++) tv[m] = tanhf(tv[m]);
  float c0 = tv[0], c1 = tv[1] + tv[2], c2 = tv[2], c3 = 0.f;
  float c4 = tv[4], c5 = tv[4] + tv[5], c6 = tv[6];
  size_t bb = (size_t)b*7*HWq + p;
  cum[bb + 0*HWq] = c0; cum[bb + 1*HWq] = c1; cum[bb + 2*HWq] = c2;
  cum[bb + 3*HWq] = c3; cum[bb + 4*HWq] = c4; cum[bb + 5*HWq] = c5;
  cum[bb + 6*HWq] = c6;
}

// ---------------------------------------------------------------------------
// Deformable sample + einsum via MFMA (f16 hi/lo 3-pass).
// Plane-major fpack reads + XCD-banded block swizzle.
// ---------------------------------------------------------------------------
template<int MORPH>
__global__ __launch_bounds__(128) void einsum_mfma_kernel(
    const unsigned short* __restrict__ fp,   // fpack [b][sub16][px][8]
    const float* __restrict__ cum,
    const unsigned short* __restrict__ wtp,  // [tap][kc][hl][oc][32] f16
    const float* __restrict__ dsc_b,
    float* __restrict__ out)                 // NCHW f32
{
  __shared__ __align__(16) unsigned short sA[2*64*128];  // 32 KB
  const size_t HW8 = (size_t)HWq*8;
  int bid = blockIdx.x;                   // 0..575
  int swz = (bid & 7)*72 + (bid >> 3);    // XCD-contiguous bands (576 = 8*72)
  int b   = swz / 288;
  int blk = swz % 288;
  int t = threadIdx.x;
  int w = t >> 6, l = t & 63;
  int l15 = l & 15, lg = l >> 4;
  int p = blk*128 + w*64 + l;
  int r = p / Wq, c = p % Wq;

  f32x4 acc[4][4];
#pragma unroll
  for (int i = 0; i < 4; i++)
#pragma unroll
    for (int j = 0; j < 4; j++) acc[i][j] = (f32x4){0.f,0.f,0.f,0.f};

  const unsigned short* fb = fp + (size_t)b*HWq*128;
  unsigned short* myrow = sA + (size_t)(w*64 + l)*128;

  for (int k = 0; k < 7; k++) {
    bool oob;
    const unsigned short *p0, *p1;
    float w0, w1;
    if (MORPH == 0) {
      int xi = c + k - 3;
      oob = (xi < 0 || xi >= Wq);
      if (!oob) {
        float y = (float)r + cum[((size_t)(b*7 + k))*HWq + p];
        float y0 = floorf(y);
        int y0q = (int)y0;
        int y0i = min(max(y0q, 0), Hq-1);
        int y1i = min(max(y0q + 1, 0), Hq-1);
        float y0f = fminf(fmaxf(y0, 0.f), (float)Hq);
        float y1f = fminf(fmaxf(y0 + 1.f, 0.f), (float)Hq);
        w0 = y1f - y; w1 = y - y0f;
        p0 = fb + ((size_t)y0i*Wq + xi)*8;
        p1 = fb + ((size_t)y1i*Wq + xi)*8;
      }
    } else {
      int yi = r + k - 3;
      oob = (yi < 0 || yi >= Hq);
      if (!oob) {
        float xf = (float)c + cum[((size_t)(b*7 + k))*HWq + p];
        float x0 = floorf(xf);
        int x0q = (int)x0;
        int x0i = min(max(x0q, 0), Wq-1);
        int x1i = min(max(x0q + 1, 0), Wq-1);
        float x0f = fminf(fmaxf(x0, 0.f), (float)Wq);
        float x1f = fminf(fmaxf(x0 + 1.f, 0.f), (float)Wq);
        w0 = x1f - xf; w1 = xf - x0f;
        p0 = fb + ((size_t)yi*Wq + x0i)*8;
        p1 = fb + ((size_t)yi*Wq + x1i)*8;
      }
    }
    if (oob) {
      uint4 z = {0u,0u,0u,0u};
#pragma unroll
      for (int j = 0; j < 16; j++) ((uint4*)myrow)[j] = z;
    } else {
#pragma unroll
      for (int g = 0; g < 8; g++) {
        f16x8 a0h = *(const f16x8*)(p0 + (size_t)g*HW8);
        f16x8 a0l = *(const f16x8*)(p0 + (size_t)(8 + g)*HW8);
        f16x8 a1h = *(const f16x8*)(p1 + (size_t)g*HW8);
        f16x8 a1l = *(const f16x8*)(p1 + (size_t)(8 + g)*HW8);
        f16x8 sh, sl;
#pragma unroll
        for (int e = 0; e < 8; e++) {
          float v = w0*((float)a0h[e] + (float)a0l[e]) + w1*((float)a1h[e] + (float)a1l[e]);
          _Float16 vh = (_Float16)v;
          sh[e] = vh;
          sl[e] = (_Float16)(v - (float)vh);
        }
        *(f16x8*)(myrow + (size_t)(g ^ l15)*8)       = sh;
        *(f16x8*)(myrow + (size_t)((8 + g) ^ l15)*8) = sl;
      }
    }
    __syncthreads();
#pragma unroll
    for (int kc = 0; kc < 2; kc++) {
      const unsigned short* wbase = wtp + (size_t)((k*2 + kc)*2)*2048;
      f16x8 bh[4], bl[4];
#pragma unroll
      for (int tb = 0; tb < 4; tb++) {
        bh[tb] = *(const f16x8*)(wbase + (tb*16 + l15)*32 + lg*8);
        bl[tb] = *(const f16x8*)(wbase + 2048 + (tb*16 + l15)*32 + lg*8);
      }
      f16x8 ah[4], al[4];
#pragma unroll
      for (int ta = 0; ta < 4; ta++) {
        const unsigned short* rbase = sA + (size_t)(w*64 + ta*16 + l15)*128;
        ah[ta] = *(const f16x8*)(rbase + (size_t)((kc*4 + lg) ^ l15)*8);
        al[ta] = *(const f16x8*)(rbase + (size_t)((8 + kc*4 + lg) ^ l15)*8);
      }
#pragma unroll
      for (int ta = 0; ta < 4; ta++)
#pragma unroll
        for (int tb = 0; tb < 4; tb++) {
          acc[ta][tb] = __builtin_amdgcn_mfma_f32_16x16x32_f16(ah[ta], bh[tb], acc[ta][tb], 0, 0, 0);
          acc[ta][tb] = __builtin_amdgcn_mfma_f32_16x16x32_f16(ah[ta], bl[tb], acc[ta][tb], 0, 0, 0);
          acc[ta][tb] = __builtin_amdgcn_mfma_f32_16x16x32_f16(al[ta], bh[tb], acc[ta][tb], 0, 0, 0);
        }
    }
    __syncthreads();
  }
  int pbase = blk*128 + w*64;
#pragma unroll
  for (int tb = 0; tb < 4; tb++) {
    int oc = tb*16 + l15;
    float bias = dsc_b[oc];
    float* dst = out + (size_t)(b*64 + oc)*HWq + pbase;
#pragma unroll
    for (int ta = 0; ta < 4; ta++) {
      f32x4 v = acc[ta][tb];
      *(float4*)(dst + ta*16 + lg*4) = make_float4(v[0]+bias, v[1]+bias, v[2]+bias, v[3]+bias);
    }
  }
}

// ---------------------------------------------------------------------------
// GroupNorm stats + finalize
// ---------------------------------------------------------------------------
__global__ __launch_bounds__(256) void gnstats_kernel(const float* __restrict__ h_ds,
                                                      const float* __restrict__ v_ds,
                                                      float* __restrict__ stats)
{
  int plane = blockIdx.x;
  int buf = plane >> 7;
  int rem = plane & 127;
  const float* src = (buf ? v_ds : h_ds) + (size_t)rem*HWq;
  float s = 0.f, s2 = 0.f;
  for (int i = threadIdx.x; i < HWq; i += 256) {
    float v = src[i];
    s += v; s2 += v*v;
  }
  __shared__ float red[2][4];
  for (int off = 32; off; off >>= 1) {
    s  += __shfl_down(s, off);
    s2 += __shfl_down(s2, off);
  }
  if ((threadIdx.x & 63) == 0) { red[0][threadIdx.x >> 6] = s; red[1][threadIdx.x >> 6] = s2; }
  __syncthreads();
  if (threadIdx.x == 0) {
    s  = red[0][0] + red[0][1] + red[0][2] + red[0][3];
    s2 = red[1][0] + red[1][1] + red[1][2] + red[1][3];
    stats[plane*2 + 0] = s;
    stats[plane*2 + 1] = s2;
  }
}

__global__ __launch_bounds__(256) void gnfinal_kernel(const float* __restrict__ stats,
                                                      const float* __restrict__ h_gn_g, const float* __restrict__ h_gn_b,
                                                      const float* __restrict__ v_gn_g, const float* __restrict__ v_gn_b,
                                                      float* __restrict__ gnAB)
{
  int t = threadIdx.x;
  int buf = t >> 7, ch = t & 63;
  int base = t & ~3;
  float sum = 0.f, ss = 0.f;
#pragma unroll
  for (int q = 0; q < 4; q++) { sum += stats[(base+q)*2]; ss += stats[(base+q)*2 + 1]; }
  const float n = 4.f * HWq;
  float mean = sum / n;
  float var = ss / n - mean*mean;
  float gg = (buf ? v_gn_g : h_gn_g)[ch];
  float bb = (buf ? v_gn_b : h_gn_b)[ch];
  float A = gg / sqrtf(var + 1e-5f);
  gnAB[t*2 + 0] = A;
  gnAB[t*2 + 1] = bb - mean*A;
}

// ---------------------------------------------------------------------------
// FUSED: comb = relu(GN(h)) + relu(GN(v)) + x1 inline, then 1x1 conv + SiLU
// ---------------------------------------------------------------------------
__global__ __launch_bounds__(256) void final2_kernel(const float* __restrict__ hbuf,
                                                     const float* __restrict__ vbuf,
                                                     const float* __restrict__ x1,
                                                     const float* __restrict__ gnAB,
                                                     const float* __restrict__ lwT,
                                                     const float* __restrict__ lbO,
                                                     float* __restrict__ out)
{
  int b = blockIdx.y;
  int p = blockIdx.x*256 + threadIdx.x;
  float acc[64];
#pragma unroll
  for (int o = 0; o < 64; o++) acc[o] = 0.f;
  for (int i = 0; i < 64; i++) {
    size_t off = (size_t)(b*64 + i)*HWq + p;
    int plane = b*64 + i;
    int ih = plane*2;
    int iv = (128 + plane)*2;
    float hv = fmaxf(hbuf[off]*gnAB[ih] + gnAB[ih+1], 0.f);
    float vv = fmaxf(vbuf[off]*gnAB[iv] + gnAB[iv+1], 0.f);
    float cv = hv + vv + x1[off];
    const float* wr = lwT + i*64;
#pragma unroll
    for (int o = 0; o < 64; o++) acc[o] += cv * wr[o];
  }
  float* dst = out + (size_t)b*Cq*HWq + p;
#pragma unroll
  for (int o = 0; o < 64; o++) {
    float yv = acc[o] + lbO[o];
    dst[(size_t)o*HWq] = yv / (1.f + expf(-yv));
  }
}

// ---------------------------------------------------------------------------
extern "C" void kernel_launch(void* const* d_in, const int* in_sizes, int n_in,
                              void* d_out, int out_size, void* d_ws, size_t ws_size,
                              hipStream_t stream)
{
  const float* x       = (const float*)d_in[0];
  const float* w_first = (const float*)d_in[1];
  float* ws = (float*)d_ws;

  float* bufA = ws;            // conv7 out -> h-einsum-out
  float* bufB = ws + Nq;       // rowsum tmp -> v-einsum-out
  float* x1   = ws + 2*Nq;
  float* h_ds = ws + 3*Nq;     // xpack -> fpackH
  float* v_ds = ws + 4*Nq;     // fpackV
  size_t off = 5*Nq;
  float* hcum  = ws + off; off += (size_t)Bq*7*HWq;
  float* vcum  = ws + off; off += (size_t)Bq*7*HWq;
  float* wEffH = ws + off; off += 64*19;
  float* bEffH = ws + off; off += 64;
  float* wEffV = ws + off; off += 64*19;
  float* bEffV = ws + off; off += 64;
  float* wtH   = ws + off; off += 64*64*7;   // holds wtpH f16 pack
  float* wtV   = ws + off; off += 64*64*7;   // holds wtpV f16 pack
  float* wOffH = ws + off; off += 9*64*8;
  float* bOffH = ws + off; off += 8;
  float* wOffV = ws + off; off += 9*64*8;
  float* bOffV = ws + off; off += 8;
  float* lwT   = ws + off; off += 64*64;
  float* lbO   = ws + off; off += 64;
  float* stats = ws + off; off += 512;
  float* gnAB  = ws + off; off += 512;
  float* wB    = ws + off; off += 2*64*18*20;
  unsigned short* wpack = (unsigned short*)(ws + off); off += 2*49*2*64*32/2 + 16;
  unsigned short* xpack  = (unsigned short*)h_ds;
  unsigned short* fpackH = (unsigned short*)h_ds;
  unsigned short* fpackV = (unsigned short*)v_ds;
  unsigned short* wtpH = (unsigned short*)wtH;
  unsigned short* wtpV = (unsigned short*)wtV;

  prep_small_kernel<<<dim3(1), dim3(256), 0, stream>>>(
      (const float*)d_in[2],  (const float*)d_in[3],  (const float*)d_in[4],  (const float*)d_in[5],
      (const float*)d_in[6],  (const float*)d_in[7],
      (const float*)d_in[8],  (const float*)d_in[9],  (const float*)d_in[10], (const float*)d_in[11],
      (const float*)d_in[12], (const float*)d_in[13],
      (const float*)d_in[14], (const float*)d_in[15], (const float*)d_in[16], (const float*)d_in[17],
      (const float*)d_in[18], (const float*)d_in[19],
      (const float*)d_in[24], (const float*)d_in[25], (const float*)d_in[26], (const float*)d_in[27],
      (const float*)d_in[28], (const float*)d_in[29],
      (const float*)d_in[34], (const float*)d_in[35], (const float*)d_in[36], (const float*)d_in[37],
      (const float*)d_in[38],
      wEffH, bEffH, wEffV, bEffV, wOffH, bOffH, wOffV, bOffV, lwT, lbO);

  prep_border_kernel<<<dim3(9), dim3(256), 0, stream>>>(
      (const float*)d_in[2],  (const float*)d_in[3],  (const float*)d_in[4],  (const float*)d_in[5],
      (const float*)d_in[6],  (const float*)d_in[7],
      (const float*)d_in[8],  (const float*)d_in[9],  (const float*)d_in[10], (const float*)d_in[11],
      (const float*)d_in[12], (const float*)d_in[13], wB);

  prep_big_kernel<<<dim3(64), dim3(256), 0, stream>>>(
      w_first, (const float*)d_in[20], (const float*)d_in[30], wtpH, wtpV, wpack);

  tof16_pack_kernel<<<dim3(Hq, Bq), dim3(192), 0, stream>>>(x, xpack);
  conv7_mfma_kernel<<<dim3(4, 96, 2), dim3(128), 0, stream>>>(xpack, wpack, bufA);

  pool_row_kernel<<<dim3(18432), dim3(256), 0, stream>>>(bufA, bufB);
  pool_col_kernel<<<dim3(18432), dim3(256), 0, stream>>>(bufB, x1);

  dwf_h_kernel<<<dim3(144, 8, 2), dim3(256), 0, stream>>>(x1, wEffH, bEffH, wB, fpackH);
  dwf_v_kernel<<<dim3(144, 8, 2), dim3(256), 0, stream>>>(x1, wEffV, bEffV, wB + 64*18*20, fpackV);

  off_cum_kernel<<<dim3(144, 2), dim3(256), 0, stream>>>(fpackH, wOffH, bOffH, hcum);
  off_cum_kernel<<<dim3(144, 2), dim3(256), 0, stream>>>(fpackV, wOffV, bOffV, vcum);

  einsum_mfma_kernel<0><<<dim3(576), dim3(128), 0, stream>>>(fpackH, hcum, wtpH, (const float*)d_in[21], bufA);
  einsum_mfma_kernel<1><<<dim3(576), dim3(128), 0, stream>>>(fpackV, vcum, wtpV, (const float*)d_in[31], bufB);

  gnstats_kernel<<<dim3(256), dim3(256), 0, stream>>>(bufA, bufB, stats);
  gnfinal_kernel<<<dim3(1), dim3(256), 0, stream>>>(stats,
      (const float*)d_in[22], (const float*)d_in[23],
      (const float*)d_in[32], (const float*)d_in[33], gnAB);

  final2_kernel<<<dim3(144, 2), dim3(256), 0, stream>>>(bufA, bufB, x1, gnAB, lwT, lbO, (float*)d_out);
}

// Round 14
// 497.993 us; speedup vs baseline: 1.2509x; 1.1183x over previous
//
#include <hip/hip_runtime.h>
#include <hip/hip_bf16.h>
#include <hip/hip_fp16.h>
#include <math.h>

#define Bq 2
#define Cq 64
#define Hq 192
#define Wq 192
#define HWq (Hq*Wq)            // 36864
#define Nq ((size_t)Bq*Cq*HWq) // 4718592

typedef __attribute__((ext_vector_type(8))) _Float16 f16x8;
typedef __attribute__((ext_vector_type(4))) float f32x4;

__device__ inline unsigned short h2us(__half h) {
  union { __half h; unsigned short u; } v; v.h = h; return v.u;
}

// ---------------------------------------------------------------------------
// Small prep (1 block) — composition loops fully unrolled over REGISTER
// weight arrays (no dependent global-load chains).
// ---------------------------------------------------------------------------
__global__ __launch_bounds__(256) void prep_small_kernel(
    const float* hc1_w, const float* hc1_b, const float* hc2_w, const float* hc2_b,
    const float* hc3_w, const float* hc3_b,
    const float* vc1_w, const float* vc1_b, const float* vc2_w, const float* vc2_b,
    const float* vc3_w, const float* vc3_b,
    const float* h_off_w, const float* h_off_b, const float* h_bn_g, const float* h_bn_b,
    const float* h_bn_m, const float* h_bn_v,
    const float* v_off_w, const float* v_off_b, const float* v_bn_g, const float* v_bn_b,
    const float* v_bn_m, const float* v_bn_v,
    const float* last_w, const float* last_g, const float* last_b, const float* last_m,
    const float* last_v,
    float* wEffH, float* bEffH, float* wEffV, float* bEffV,
    float* wOffH, float* bOffH, float* wOffV, float* bOffV,
    float* lwT, float* lbO)
{
  int t = threadIdx.x;
  if (t < 128) {
    int ch = t & 63;
    bool ish = t < 64;
    const float* w1p = (ish ? hc1_w : vc1_w) + ch*9;
    const float* w2p = (ish ? hc2_w : vc2_w) + ch*7;
    const float* w3p = (ish ? hc3_w : vc3_w) + ch*5;
    float w1r[9], w2r[7], w3r[5];
#pragma unroll
    for (int j = 0; j < 9; j++) w1r[j] = w1p[j];
#pragma unroll
    for (int k = 0; k < 7; k++) w2r[k] = w2p[k];
#pragma unroll
    for (int m = 0; m < 5; m++) w3r[m] = w3p[m];
    float t15[15];
#pragma unroll
    for (int s = 0; s < 15; s++) {
      float a = 0.f;
#pragma unroll
      for (int j = 0; j < 9; j++) { int k2 = s - j; if (k2 >= 0 && k2 < 7) a += w1r[j]*w2r[k2]; }
      t15[s] = a;
    }
    float* we = (ish ? wEffH : wEffV) + ch*19;
#pragma unroll
    for (int s = 0; s < 19; s++) {
      float a = 0.f;
#pragma unroll
      for (int j = 0; j < 15; j++) { int k3 = s - j; if (k3 >= 0 && k3 < 5) a += t15[j]*w3r[k3]; }
      we[s] = a;
    }
    float S2 = 0.f, S3 = 0.f;
#pragma unroll
    for (int j = 0; j < 7; j++) S2 += w2r[j];
#pragma unroll
    for (int j = 0; j < 5; j++) S3 += w3r[j];
    float b1 = (ish ? hc1_b : vc1_b)[ch];
    float b2 = (ish ? hc2_b : vc2_b)[ch];
    float b3 = (ish ? hc3_b : vc3_b)[ch];
    (ish ? bEffH : bEffV)[ch] = b1*S2*S3 + b2*S3 + b3;
  }
  for (int idx = t; idx < 9*64*7; idx += 256) {
    int tap = idx / 448; int rem = idx % 448; int i = rem / 7; int m = rem % 7;
    float invh = h_bn_g[m] / sqrtf(h_bn_v[m] + 1e-5f);
    wOffH[(tap*64 + i)*8 + m] = h_off_w[(m*64 + i)*9 + tap] * invh;
    float invv = v_bn_g[7+m] / sqrtf(v_bn_v[7+m] + 1e-5f);
    wOffV[(tap*64 + i)*8 + m] = v_off_w[((7+m)*64 + i)*9 + tap] * invv;
  }
  if (t < 7) {
    float invh = h_bn_g[t] / sqrtf(h_bn_v[t] + 1e-5f);
    bOffH[t] = h_off_b[t]*invh + h_bn_b[t] - h_bn_m[t]*invh;
    float invv = v_bn_g[7+t] / sqrtf(v_bn_v[7+t] + 1e-5f);
    bOffV[t] = v_off_b[7+t]*invv + v_bn_b[7+t] - v_bn_m[7+t]*invv;
  }
  for (int idx = t; idx < 4096; idx += 256) {
    int o = idx % 64; int i = idx / 64;
    float inv = last_g[o] / sqrtf(last_v[o] + 1e-3f);
    lwT[i*64 + o] = last_w[o*64 + i] * inv;
  }
  if (t < 64) {
    float inv = last_g[t] / sqrtf(last_v[t] + 1e-3f);
    lbO[t] = last_b[t] - last_m[t]*inv;
  }
}

// ---------------------------------------------------------------------------
// Border prep — algebraic form dst[s] = Σ_{m+k+j=s} [bounds]·w3[m]w2[k]w1[j],
// fully unrolled so all indices are compile-time: weights live in registers,
// acc[19] lives in registers. Eliminates the 700-deep dependent-load chain.
// ---------------------------------------------------------------------------
__global__ __launch_bounds__(256) void prep_border_kernel(
    const float* hc1_w, const float* hc1_b, const float* hc2_w, const float* hc2_b,
    const float* hc3_w, const float* hc3_b,
    const float* vc1_w, const float* vc1_b, const float* vc2_w, const float* vc2_b,
    const float* vc3_w, const float* vc3_b,
    float* wB)
{
  int tid = blockIdx.x*256 + threadIdx.x;
  if (tid >= 2*64*18) return;
  int cls = tid % 18;
  int ch  = (tid / 18) % 64;
  int br  = tid / (18*64);
  int c = (cls < 9) ? cls : cls + 174;
  const float* w1p = (br==0 ? hc1_w : vc1_w) + ch*9;
  const float* w2p = (br==0 ? hc2_w : vc2_w) + ch*7;
  const float* w3p = (br==0 ? hc3_w : vc3_w) + ch*5;
  float b1 = (br==0 ? hc1_b : vc1_b)[ch];
  float b2 = (br==0 ? hc2_b : vc2_b)[ch];
  float b3 = (br==0 ? hc3_b : vc3_b)[ch];
  float w1r[9], w2r[7], w3r[5];
#pragma unroll
  for (int j = 0; j < 9; j++) w1r[j] = w1p[j];
#pragma unroll
  for (int k = 0; k < 7; k++) w2r[k] = w2p[k];
#pragma unroll
  for (int m = 0; m < 5; m++) w3r[m] = w3p[m];

  float acc[19];
#pragma unroll
  for (int s = 0; s < 19; s++) acc[s] = 0.f;
  float bacc = b3;
#pragma unroll
  for (int m = 0; m < 5; m++) {
    int d = c + m - 2;
    bool dok = (d >= 0 && d < Wq);
    float s2b = b2;
#pragma unroll
    for (int k = 0; k < 7; k++) {
      int e = d + k - 3;
      bool eok = (e >= 0 && e < Wq);
      if (eok) s2b += w2r[k] * b1;
      float wmk = w3r[m] * w2r[k];
#pragma unroll
      for (int j = 0; j < 9; j++) {
        int fd = e + j - 4;
        bool fok = (fd >= 0 && fd < Wq);
        float contrib = (dok && eok && fok) ? wmk * w1r[j] : 0.f;
        acc[m + k + j] += contrib;
      }
    }
    if (dok) bacc += w3r[m] * s2b;
  }
  float* dst = wB + ((size_t)(br*64 + ch)*18 + cls)*20;
#pragma unroll
  for (int s = 0; s < 19; s++) dst[s] = acc[s];
  dst[19] = bacc;
}

// ---------------------------------------------------------------------------
// Big prep: dsc weights -> f16 hi/lo MFMA pack [tap][kc][hl][oc][32]
//           + w_first f16 hi/lo pack for conv7.
// ---------------------------------------------------------------------------
__global__ __launch_bounds__(256) void prep_big_kernel(
    const float* __restrict__ w_first,
    const float* __restrict__ h_dsc_w, const float* __restrict__ v_dsc_w,
    unsigned short* __restrict__ wtpH, unsigned short* __restrict__ wtpV,
    unsigned short* __restrict__ wpack)
{
  int tid = blockIdx.x*256 + threadIdx.x;
  int nthr = gridDim.x*256;
  for (int idx = tid; idx < 7*2*2*64*32; idx += nthr) {
    int ch32 = idx & 31;
    int oc   = (idx >> 5) & 63;
    int hl   = (idx >> 11) & 1;
    int kc   = (idx >> 12) & 1;
    int tap  = idx >> 13;
    int i = kc*32 + ch32;
    float vh = h_dsc_w[oc*448 + i*7 + tap];
    float vv = v_dsc_w[oc*448 + i*7 + tap];
    _Float16 hh = (_Float16)vh;
    _Float16 hv = (_Float16)vv;
    unsigned short uh, uv;
    if (!hl) { uh = *(unsigned short*)&hh; uv = *(unsigned short*)&hv; }
    else {
      _Float16 lh = (_Float16)(vh - (float)hh);
      _Float16 lv = (_Float16)(vv - (float)hv);
      uh = *(unsigned short*)&lh; uv = *(unsigned short*)&lv;
    }
    wtpH[idx] = uh; wtpV[idx] = uv;
  }
  for (int e = tid; e < 2*49*2*64*32; e += nthr) {
    int ch  = e & 31;
    int oc  = (e >> 5) & 63;
    int hl  = (e >> 11) & 1;
    int rest = e >> 12;
    int tap = rest % 49;
    int h   = rest / 49;
    float wv = w_first[((size_t)oc*64 + h*32 + ch)*49 + tap];
    __half hh = __float2half(wv);
    unsigned short us;
    if (!hl) us = h2us(hh);
    else { float rr = wv - __half2float(hh); us = h2us(__float2half(rr)); }
    wpack[e] = us;
  }
}

// ---------------------------------------------------------------------------
// x (NCHW f32) -> xpack single f16: [b][r][c][64] (8 granules of 8 ch)
// ---------------------------------------------------------------------------
__global__ __launch_bounds__(192) void tof16_pack_kernel(const float* __restrict__ x,
                                                         unsigned short* __restrict__ xpack)
{
  __shared__ unsigned int s[192*64];
  int r = blockIdx.x, b = blockIdx.y;
  int t = threadIdx.x;
  for (int ch = 0; ch < 64; ch++) {
    float v = x[((size_t)(b*64+ch)*Hq + r)*Wq + t];
    _Float16 hh = (_Float16)v;
    s[t*64 + (ch ^ (t & 31))] = (unsigned int)*(unsigned short*)&hh;
  }
  __syncthreads();
  unsigned short* dst = xpack + ((size_t)b*Hq + r)*Wq*64;
  for (int i = 0; i < 8; i++) {
    int gidx = i*192 + t;                // 1536 granules of 16B
    int c = gidx >> 3, g = gidx & 7;
    unsigned short tmp[8];
#pragma unroll
    for (int j = 0; j < 8; j++) {
      int ch = g*8 + j;
      tmp[j] = (unsigned short)s[c*64 + (ch ^ (c & 31))];
    }
    uint4 v;
    v.x = (unsigned int)tmp[0] | ((unsigned int)tmp[1] << 16);
    v.y = (unsigned int)tmp[2] | ((unsigned int)tmp[3] << 16);
    v.z = (unsigned int)tmp[4] | ((unsigned int)tmp[5] << 16);
    v.w = (unsigned int)tmp[6] | ((unsigned int)tmp[7] << 16);
    *(uint4*)(dst + (size_t)gidx*8) = v;
  }
}

// ---------------------------------------------------------------------------
// 7x7 conv via MFMA, 2-pass (x single f16, w hi/lo exact).
// Block = 2 waves split by OC-HALF; per-wave B-fetch 4KB/tap, 24 MFMA/tap.
// #pragma unroll 7 on the tap loop for compiler software pipelining.
// Tile 2 rows x 48 cols, grid 4x96x2 = 768 blocks, LDS 27.6 KB.
// ---------------------------------------------------------------------------
__global__ __launch_bounds__(128) void conv7_mfma_kernel(
    const unsigned short* __restrict__ xpack,   // [b][r][c][64] f16
    const unsigned short* __restrict__ wpack,   // [h][tap][hl][oc][32] f16
    float* __restrict__ out)
{
  __shared__ __align__(16) unsigned short sA[8*54*32];   // 27648 B
  int ct = blockIdx.x;          // 0..3
  int rt = blockIdx.y;          // 0..95
  int b  = blockIdx.z;
  int r0 = rt*2, c0 = ct*48;
  int t = threadIdx.x;
  int wv = t >> 6;              // wave -> oc half
  int l  = t & 63;
  int l15 = l & 15, lg = l >> 4;
  int ocb = wv*32;

  f32x4 acc[2][3][2];           // [row][col-tile][oc-tile-in-half]
#pragma unroll
  for (int i = 0; i < 2; i++)
#pragma unroll
    for (int j = 0; j < 3; j++)
#pragma unroll
      for (int q = 0; q < 2; q++) acc[i][j][q] = (f32x4){0.f,0.f,0.f,0.f};

  for (int h = 0; h < 2; h++) {
    __syncthreads();            // prev half's sA readers done
    for (int idx = t; idx < 8*54*4; idx += 128) {
      int g = idx & 3, pix = idx >> 2;
      int row = pix / 54, col = pix % 54;
      int gr = r0 - 3 + row, gc = c0 - 3 + col;
      uint4 v = {0u,0u,0u,0u};
      if (gr >= 0 && gr < Hq && gc >= 0 && gc < Wq)
        v = *(const uint4*)(xpack + (((size_t)b*Hq + gr)*Wq + gc)*64 + (h*4 + g)*8);
      ((uint4*)sA)[(row*54 + col)*4 + (g ^ ((col >> 1) & 3))] = v;
    }
    __syncthreads();
    const unsigned short* wb = wpack + (size_t)h*49*4096;
#pragma unroll 7
    for (int tap = 0; tap < 49; tap++) {
      int dy = tap / 7, dx = tap % 7;
      f16x8 bh[2], bl[2];
#pragma unroll
      for (int tbL = 0; tbL < 2; tbL++) {
        int oc = ocb + tbL*16 + l15;
        bh[tbL] = *(const f16x8*)(wb + (size_t)tap*4096 +        oc*32 + lg*8);
        bl[tbL] = *(const f16x8*)(wb + (size_t)tap*4096 + 2048 + oc*32 + lg*8);
      }
#pragma unroll
      for (int rw = 0; rw < 2; rw++) {
        int arow = rw + dy;     // 0..7
        f16x8 a[3];
#pragma unroll
        for (int tc = 0; tc < 3; tc++) {
          int col = tc*16 + l15 + dx;
          a[tc] = *(const f16x8*)((const uint4*)sA + (arow*54 + col)*4 + (lg ^ ((col >> 1) & 3)));
        }
#pragma unroll
        for (int tc = 0; tc < 3; tc++)
#pragma unroll
          for (int tbL = 0; tbL < 2; tbL++) {
            acc[rw][tc][tbL] = __builtin_amdgcn_mfma_f32_16x16x32_f16(a[tc], bh[tbL], acc[rw][tc][tbL], 0, 0, 0);
            acc[rw][tc][tbL] = __builtin_amdgcn_mfma_f32_16x16x32_f16(a[tc], bl[tbL], acc[rw][tc][tbL], 0, 0, 0);
          }
      }
    }
  }
#pragma unroll
  for (int tbL = 0; tbL < 2; tbL++) {
    int oc = ocb + tbL*16 + l15;
#pragma unroll
    for (int rw = 0; rw < 2; rw++) {
      float* dst = out + ((size_t)(b*64 + oc)*Hq + (r0 + rw))*Wq + c0;
#pragma unroll
      for (int tc = 0; tc < 3; tc++) {
        f32x4 v = acc[rw][tc][tbL];
        *(float4*)(dst + tc*16 + lg*4) = make_float4(v[0], v[1], v[2], v[3]);
      }
    }
  }
}

// ---------------------------------------------------------------------------
// Separable 7x7 avg pool
// ---------------------------------------------------------------------------
__global__ __launch_bounds__(256) void pool_row_kernel(const float* __restrict__ in, float* __restrict__ out)
{
  int idx = blockIdx.x*256 + threadIdx.x;
  int c = idx % Wq;
  int base = idx - c;
  float s = 0.f;
#pragma unroll
  for (int dc = -3; dc <= 3; dc++) {
    int cc = c + dc;
    if (cc >= 0 && cc < Wq) s += in[base + cc];
  }
  out[idx] = s;
}

__global__ __launch_bounds__(256) void pool_col_kernel(const float* __restrict__ in, float* __restrict__ out)
{
  int idx = blockIdx.x*256 + threadIdx.x;
  int c = idx % Wq;
  int r = (idx / Wq) % Hq;
  int plane = idx / HWq;
  float s = 0.f;
#pragma unroll
  for (int dr = -3; dr <= 3; dr++) {
    int rr = r + dr;
    if (rr >= 0 && rr < Hq) s += in[(size_t)plane*HWq + rr*Wq + c];
  }
  out[idx] = s * (1.f/49.f);
}

// ---------------------------------------------------------------------------
// FUSED depthwise 19-tap + f16 hi/lo plane-major pack.
// ---------------------------------------------------------------------------
__global__ __launch_bounds__(256) void dwf_h_kernel(const float* __restrict__ x1,
                                                    const float* __restrict__ wEff,
                                                    const float* __restrict__ bEff,
                                                    const float* __restrict__ wB,
                                                    unsigned short* __restrict__ pack)
{
  __shared__ float sW[8][19][20];
  int b = blockIdx.z, g8 = blockIdx.y;
  int t = threadIdx.x;
  int chb = g8*8;
  for (int i = t; i < 8*380; i += 256) {
    int ch8 = i / 380; int rem = i % 380;
    int row = rem / 20, jj = rem % 20;
    int ch = chb + ch8;
    float v;
    if (row < 18) v = wB[((size_t)ch*18 + row)*20 + jj];
    else v = (jj < 19) ? wEff[ch*19 + jj] : bEff[ch];
    sW[ch8][row][jj] = v;
  }
  __syncthreads();
  int p = blockIdx.x*256 + t;
  int r = p / Wq, c = p % Wq;
  int row = (c < 9) ? c : ((c >= Wq-9) ? (c - 174) : 18);
  float vals[8];
#pragma unroll
  for (int ch8 = 0; ch8 < 8; ch8++) {
    const float* src = x1 + (size_t)(b*Cq + chb + ch8)*HWq + r*Wq;
    float s = sW[ch8][row][19];
#pragma unroll
    for (int j = 0; j < 19; j++) {
      int idx = min(max(c + j - 9, 0), Wq-1);
      s += src[idx] * sW[ch8][row][j];
    }
    vals[ch8] = s;
  }
  unsigned int hi[4], lo[4];
#pragma unroll
  for (int q = 0; q < 4; q++) {
    __half h0 = __float2half(vals[2*q]);
    __half h1 = __float2half(vals[2*q+1]);
    __half l0 = __float2half(vals[2*q]   - __half2float(h0));
    __half l1 = __float2half(vals[2*q+1] - __half2float(h1));
    hi[q] = (unsigned int)h2us(h0) | ((unsigned int)h2us(h1) << 16);
    lo[q] = (unsigned int)h2us(l0) | ((unsigned int)h2us(l1) << 16);
  }
  *(uint4*)(pack + (((size_t)b*16 + g8)*HWq + p)*8)     = make_uint4(hi[0], hi[1], hi[2], hi[3]);
  *(uint4*)(pack + (((size_t)b*16 + 8 + g8)*HWq + p)*8) = make_uint4(lo[0], lo[1], lo[2], lo[3]);
}

__global__ __launch_bounds__(256) void dwf_v_kernel(const float* __restrict__ x1,
                                                    const float* __restrict__ wEff,
                                                    const float* __restrict__ bEff,
                                                    const float* __restrict__ wB,
                                                    unsigned short* __restrict__ pack)
{
  __shared__ float sW[8][19][20];
  int b = blockIdx.z, g8 = blockIdx.y;
  int t = threadIdx.x;
  int chb = g8*8;
  for (int i = t; i < 8*380; i += 256) {
    int ch8 = i / 380; int rem = i % 380;
    int row = rem / 20, jj = rem % 20;
    int ch = chb + ch8;
    float v;
    if (row < 18) v = wB[((size_t)ch*18 + row)*20 + jj];
    else v = (jj < 19) ? wEff[ch*19 + jj] : bEff[ch];
    sW[ch8][row][jj] = v;
  }
  __syncthreads();
  int p = blockIdx.x*256 + t;
  int r = p / Wq, c = p % Wq;
  int row = (r < 9) ? r : ((r >= Hq-9) ? (r - 174) : 18);
  float vals[8];
#pragma unroll
  for (int ch8 = 0; ch8 < 8; ch8++) {
    const float* src = x1 + (size_t)(b*Cq + chb + ch8)*HWq + c;
    float s = sW[ch8][row][19];
#pragma unroll
    for (int j = 0; j < 19; j++) {
      int idx = min(max(r + j - 9, 0), Hq-1);
      s += src[idx*Wq] * sW[ch8][row][j];
    }
    vals[ch8] = s;
  }
  unsigned int hi[4], lo[4];
#pragma unroll
  for (int q = 0; q < 4; q++) {
    __half h0 = __float2half(vals[2*q]);
    __half h1 = __float2half(vals[2*q+1]);
    __half l0 = __float2half(vals[2*q]   - __half2float(h0));
    __half l1 = __float2half(vals[2*q+1] - __half2float(h1));
    hi[q] = (unsigned int)h2us(h0) | ((unsigned int)h2us(h1) << 16);
    lo[q] = (unsigned int)h2us(l0) | ((unsigned int)h2us(l1) << 16);
  }
  *(uint4*)(pack + (((size_t)b*16 + g8)*HWq + p)*8)     = make_uint4(hi[0], hi[1], hi[2], hi[3]);
  *(uint4*)(pack + (((size_t)b*16 + 8 + g8)*HWq + p)*8) = make_uint4(lo[0], lo[1], lo[2], lo[3]);
}

// ---------------------------------------------------------------------------
// Offset conv + tanh + cum, reading plane-major fpack (coalesced)
// ---------------------------------------------------------------------------
__global__ __launch_bounds__(256) void off_cum_kernel(const unsigned short* __restrict__ fp,
                                                      const float* __restrict__ wOff,
                                                      const float* __restrict__ bOff,
                                                      float* __restrict__ cum)
{
  const size_t HW8 = (size_t)HWq*8;
  int b = blockIdx.y;
  int p = blockIdx.x*256 + threadIdx.x;
  int r = p / Wq, c = p % Wq;
  float tv[7];
#pragma unroll
  for (int m = 0; m < 7; m++) tv[m] = bOff[m];
  const unsigned short* fb = fp + (size_t)b*HWq*128;
  for (int tap = 0; tap < 9; tap++) {
    int dy = tap/3 - 1, dx = tap%3 - 1;
    int rr = r + dy, cc = c + dx;
    if (rr < 0 || rr >= Hq || cc < 0 || cc >= Wq) continue;
    const unsigned short* p0 = fb + ((size_t)rr*Wq + cc)*8;
    const float* wp = wOff + tap*512;
    for (int g = 0; g < 8; g++) {
      f16x8 hv = *(const f16x8*)(p0 + (size_t)g*HW8);
      f16x8 lv = *(const f16x8*)(p0 + (size_t)(8 + g)*HW8);
#pragma unroll
      for (int e = 0; e < 8; e++) {
        float fv = (float)hv[e] + (float)lv[e];
        const float* wr = wp + (g*8 + e)*8;
#pragma unroll
        for (int m = 0; m < 7; m++) tv[m] += fv * wr[m];
      }
    }
  }
#pragma unroll
  for (int m = 0; m < 7; m++) tv[m] = tanhf(tv[m]);
  float c0 = tv[0], c1 = tv[1] + tv[2], c2 = tv[2], c3 = 0.f;
  float c4 = tv[4], c5 = tv[4] + tv[5], c6 = tv[6];
  size_t bb = (size_t)b*7*HWq + p;
  cum[bb + 0*HWq] = c0; cum[bb + 1*HWq] = c1; cum[bb + 2*HWq] = c2;
  cum[bb + 3*HWq] = c3; cum[bb + 4*HWq] = c4; cum[bb + 5*HWq] = c5;
  cum[bb + 6*HWq] = c6;
}

// ---------------------------------------------------------------------------
// Deformable sample + einsum via MFMA (f16 hi/lo 3-pass).
// Plane-major fpack reads + XCD-banded block swizzle.
// ---------------------------------------------------------------------------
template<int MORPH>
__global__ __launch_bounds__(128) void einsum_mfma_kernel(
    const unsigned short* __restrict__ fp,   // fpack [b][sub16][px][8]
    const float* __restrict__ cum,
    const unsigned short* __restrict__ wtp,  // [tap][kc][hl][oc][32] f16
    const float* __restrict__ dsc_b,
    float* __restrict__ out)                 // NCHW f32
{
  __shared__ __align__(16) unsigned short sA[2*64*128];  // 32 KB
  const size_t HW8 = (size_t)HWq*8;
  int bid = blockIdx.x;                   // 0..575
  int swz = (bid & 7)*72 + (bid >> 3);    // XCD-contiguous bands (576 = 8*72)
  int b   = swz / 288;
  int blk = swz % 288;
  int t = threadIdx.x;
  int w = t >> 6, l = t & 63;
  int l15 = l & 15, lg = l >> 4;
  int p = blk*128 + w*64 + l;
  int r = p / Wq, c = p % Wq;

  f32x4 acc[4][4];
#pragma unroll
  for (int i = 0; i < 4; i++)
#pragma unroll
    for (int j = 0; j < 4; j++) acc[i][j] = (f32x4){0.f,0.f,0.f,0.f};

  const unsigned short* fb = fp + (size_t)b*HWq*128;
  unsigned short* myrow = sA + (size_t)(w*64 + l)*128;

  for (int k = 0; k < 7; k++) {
    bool oob;
    const unsigned short *p0, *p1;
    float w0, w1;
    if (MORPH == 0) {
      int xi = c + k - 3;
      oob = (xi < 0 || xi >= Wq);
      if (!oob) {
        float y = (float)r + cum[((size_t)(b*7 + k))*HWq + p];
        float y0 = floorf(y);
        int y0q = (int)y0;
        int y0i = min(max(y0q, 0), Hq-1);
        int y1i = min(max(y0q + 1, 0), Hq-1);
        float y0f = fminf(fmaxf(y0, 0.f), (float)Hq);
        float y1f = fminf(fmaxf(y0 + 1.f, 0.f), (float)Hq);
        w0 = y1f - y; w1 = y - y0f;
        p0 = fb + ((size_t)y0i*Wq + xi)*8;
        p1 = fb + ((size_t)y1i*Wq + xi)*8;
      }
    } else {
      int yi = r + k - 3;
      oob = (yi < 0 || yi >= Hq);
      if (!oob) {
        float xf = (float)c + cum[((size_t)(b*7 + k))*HWq + p];
        float x0 = floorf(xf);
        int x0q = (int)x0;
        int x0i = min(max(x0q, 0), Wq-1);
        int x1i = min(max(x0q + 1, 0), Wq-1);
        float x0f = fminf(fmaxf(x0, 0.f), (float)Wq);
        float x1f = fminf(fmaxf(x0 + 1.f, 0.f), (float)Wq);
        w0 = x1f - xf; w1 = xf - x0f;
        p0 = fb + ((size_t)yi*Wq + x0i)*8;
        p1 = fb + ((size_t)yi*Wq + x1i)*8;
      }
    }
    if (oob) {
      uint4 z = {0u,0u,0u,0u};
#pragma unroll
      for (int j = 0; j < 16; j++) ((uint4*)myrow)[j] = z;
    } else {
#pragma unroll
      for (int g = 0; g < 8; g++) {
        f16x8 a0h = *(const f16x8*)(p0 + (size_t)g*HW8);
        f16x8 a0l = *(const f16x8*)(p0 + (size_t)(8 + g)*HW8);
        f16x8 a1h = *(const f16x8*)(p1 + (size_t)g*HW8);
        f16x8 a1l = *(const f16x8*)(p1 + (size_t)(8 + g)*HW8);
        f16x8 sh, sl;
#pragma unroll
        for (int e = 0; e < 8; e++) {
          float v = w0*((float)a0h[e] + (float)a0l[e]) + w1*((float)a1h[e] + (float)a1l[e]);
          _Float16 vh = (_Float16)v;
          sh[e] = vh;
          sl[e] = (_Float16)(v - (float)vh);
        }
        *(f16x8*)(myrow + (size_t)(g ^ l15)*8)       = sh;
        *(f16x8*)(myrow + (size_t)((8 + g) ^ l15)*8) = sl;
      }
    }
    __syncthreads();
#pragma unroll
    for (int kc = 0; kc < 2; kc++) {
      const unsigned short* wbase = wtp + (size_t)((k*2 + kc)*2)*2048;
      f16x8 bh[4], bl[4];
#pragma unroll
      for (int tb = 0; tb < 4; tb++) {
        bh[tb] = *(const f16x8*)(wbase + (tb*16 + l15)*32 + lg*8);
        bl[tb] = *(const f16x8*)(wbase + 2048 + (tb*16 + l15)*32 + lg*8);
      }
      f16x8 ah[4], al[4];
#pragma unroll
      for (int ta = 0; ta < 4; ta++) {
        const unsigned short* rbase = sA + (size_t)(w*64 + ta*16 + l15)*128;
        ah[ta] = *(const f16x8*)(rbase + (size_t)((kc*4 + lg) ^ l15)*8);
        al[ta] = *(const f16x8*)(rbase + (size_t)((8 + kc*4 + lg) ^ l15)*8);
      }
#pragma unroll
      for (int ta = 0; ta < 4; ta++)
#pragma unroll
        for (int tb = 0; tb < 4; tb++) {
          acc[ta][tb] = __builtin_amdgcn_mfma_f32_16x16x32_f16(ah[ta], bh[tb], acc[ta][tb], 0, 0, 0);
          acc[ta][tb] = __builtin_amdgcn_mfma_f32_16x16x32_f16(ah[ta], bl[tb], acc[ta][tb], 0, 0, 0);
          acc[ta][tb] = __builtin_amdgcn_mfma_f32_16x16x32_f16(al[ta], bh[tb], acc[ta][tb], 0, 0, 0);
        }
    }
    __syncthreads();
  }
  int pbase = blk*128 + w*64;
#pragma unroll
  for (int tb = 0; tb < 4; tb++) {
    int oc = tb*16 + l15;
    float bias = dsc_b[oc];
    float* dst = out + (size_t)(b*64 + oc)*HWq + pbase;
#pragma unroll
    for (int ta = 0; ta < 4; ta++) {
      f32x4 v = acc[ta][tb];
      *(float4*)(dst + ta*16 + lg*4) = make_float4(v[0]+bias, v[1]+bias, v[2]+bias, v[3]+bias);
    }
  }
}

// ---------------------------------------------------------------------------
// GroupNorm stats + finalize
// ---------------------------------------------------------------------------
__global__ __launch_bounds__(256) void gnstats_kernel(const float* __restrict__ h_ds,
                                                      const float* __restrict__ v_ds,
                                                      float* __restrict__ stats)
{
  int plane = blockIdx.x;
  int buf = plane >> 7;
  int rem = plane & 127;
  const float* src = (buf ? v_ds : h_ds) + (size_t)rem*HWq;
  float s = 0.f, s2 = 0.f;
  for (int i = threadIdx.x; i < HWq; i += 256) {
    float v = src[i];
    s += v; s2 += v*v;
  }
  __shared__ float red[2][4];
  for (int off = 32; off; off >>= 1) {
    s  += __shfl_down(s, off);
    s2 += __shfl_down(s2, off);
  }
  if ((threadIdx.x & 63) == 0) { red[0][threadIdx.x >> 6] = s; red[1][threadIdx.x >> 6] = s2; }
  __syncthreads();
  if (threadIdx.x == 0) {
    s  = red[0][0] + red[0][1] + red[0][2] + red[0][3];
    s2 = red[1][0] + red[1][1] + red[1][2] + red[1][3];
    stats[plane*2 + 0] = s;
    stats[plane*2 + 1] = s2;
  }
}

__global__ __launch_bounds__(256) void gnfinal_kernel(const float* __restrict__ stats,
                                                      const float* __restrict__ h_gn_g, const float* __restrict__ h_gn_b,
                                                      const float* __restrict__ v_gn_g, const float* __restrict__ v_gn_b,
                                                      float* __restrict__ gnAB)
{
  int t = threadIdx.x;
  int buf = t >> 7, ch = t & 63;
  int base = t & ~3;
  float sum = 0.f, ss = 0.f;
#pragma unroll
  for (int q = 0; q < 4; q++) { sum += stats[(base+q)*2]; ss += stats[(base+q)*2 + 1]; }
  const float n = 4.f * HWq;
  float mean = sum / n;
  float var = ss / n - mean*mean;
  float gg = (buf ? v_gn_g : h_gn_g)[ch];
  float bb = (buf ? v_gn_b : h_gn_b)[ch];
  float A = gg / sqrtf(var + 1e-5f);
  gnAB[t*2 + 0] = A;
  gnAB[t*2 + 1] = bb - mean*A;
}

// ---------------------------------------------------------------------------
// FUSED: comb = relu(GN(h)) + relu(GN(v)) + x1 inline, then 1x1 conv + SiLU
// ---------------------------------------------------------------------------
__global__ __launch_bounds__(256) void final2_kernel(const float* __restrict__ hbuf,
                                                     const float* __restrict__ vbuf,
                                                     const float* __restrict__ x1,
                                                     const float* __restrict__ gnAB,
                                                     const float* __restrict__ lwT,
                                                     const float* __restrict__ lbO,
                                                     float* __restrict__ out)
{
  int b = blockIdx.y;
  int p = blockIdx.x*256 + threadIdx.x;
  float acc[64];
#pragma unroll
  for (int o = 0; o < 64; o++) acc[o] = 0.f;
  for (int i = 0; i < 64; i++) {
    size_t off = (size_t)(b*64 + i)*HWq + p;
    int plane = b*64 + i;
    int ih = plane*2;
    int iv = (128 + plane)*2;
    float hv = fmaxf(hbuf[off]*gnAB[ih] + gnAB[ih+1], 0.f);
    float vv = fmaxf(vbuf[off]*gnAB[iv] + gnAB[iv+1], 0.f);
    float cv = hv + vv + x1[off];
    const float* wr = lwT + i*64;
#pragma unroll
    for (int o = 0; o < 64; o++) acc[o] += cv * wr[o];
  }
  float* dst = out + (size_t)b*Cq*HWq + p;
#pragma unroll
  for (int o = 0; o < 64; o++) {
    float yv = acc[o] + lbO[o];
    dst[(size_t)o*HWq] = yv / (1.f + expf(-yv));
  }
}

// ---------------------------------------------------------------------------
extern "C" void kernel_launch(void* const* d_in, const int* in_sizes, int n_in,
                              void* d_out, int out_size, void* d_ws, size_t ws_size,
                              hipStream_t stream)
{
  const float* x       = (const float*)d_in[0];
  const float* w_first = (const float*)d_in[1];
  float* ws = (float*)d_ws;

  float* bufA = ws;            // conv7 out -> h-einsum-out
  float* bufB = ws + Nq;       // rowsum tmp -> v-einsum-out
  float* x1   = ws + 2*Nq;
  float* h_ds = ws + 3*Nq;     // xpack -> fpackH
  float* v_ds = ws + 4*Nq;     // fpackV
  size_t off = 5*Nq;
  float* hcum  = ws + off; off += (size_t)Bq*7*HWq;
  float* vcum  = ws + off; off += (size_t)Bq*7*HWq;
  float* wEffH = ws + off; off += 64*19;
  float* bEffH = ws + off; off += 64;
  float* wEffV = ws + off; off += 64*19;
  float* bEffV = ws + off; off += 64;
  float* wtH   = ws + off; off += 64*64*7;   // holds wtpH f16 pack
  float* wtV   = ws + off; off += 64*64*7;   // holds wtpV f16 pack
  float* wOffH = ws + off; off += 9*64*8;
  float* bOffH = ws + off; off += 8;
  float* wOffV = ws + off; off += 9*64*8;
  float* bOffV = ws + off; off += 8;
  float* lwT   = ws + off; off += 64*64;
  float* lbO   = ws + off; off += 64;
  float* stats = ws + off; off += 512;
  float* gnAB  = ws + off; off += 512;
  float* wB    = ws + off; off += 2*64*18*20;
  unsigned short* wpack = (unsigned short*)(ws + off); off += 2*49*2*64*32/2 + 16;
  unsigned short* xpack  = (unsigned short*)h_ds;
  unsigned short* fpackH = (unsigned short*)h_ds;
  unsigned short* fpackV = (unsigned short*)v_ds;
  unsigned short* wtpH = (unsigned short*)wtH;
  unsigned short* wtpV = (unsigned short*)wtV;

  prep_small_kernel<<<dim3(1), dim3(256), 0, stream>>>(
      (const float*)d_in[2],  (const float*)d_in[3],  (const float*)d_in[4],  (const float*)d_in[5],
      (const float*)d_in[6],  (const float*)d_in[7],
      (const float*)d_in[8],  (const float*)d_in[9],  (const float*)d_in[10], (const float*)d_in[11],
      (const float*)d_in[12], (const float*)d_in[13],
      (const float*)d_in[14], (const float*)d_in[15], (const float*)d_in[16], (const float*)d_in[17],
      (const float*)d_in[18], (const float*)d_in[19],
      (const float*)d_in[24], (const float*)d_in[25], (const float*)d_in[26], (const float*)d_in[27],
      (const float*)d_in[28], (const float*)d_in[29],
      (const float*)d_in[34], (const float*)d_in[35], (const float*)d_in[36], (const float*)d_in[37],
      (const float*)d_in[38],
      wEffH, bEffH, wEffV, bEffV, wOffH, bOffH, wOffV, bOffV, lwT, lbO);

  prep_border_kernel<<<dim3(9), dim3(256), 0, stream>>>(
      (const float*)d_in[2],  (const float*)d_in[3],  (const float*)d_in[4],  (const float*)d_in[5],
      (const float*)d_in[6],  (const float*)d_in[7],
      (const float*)d_in[8],  (const float*)d_in[9],  (const float*)d_in[10], (const float*)d_in[11],
      (const float*)d_in[12], (const float*)d_in[13], wB);

  prep_big_kernel<<<dim3(64), dim3(256), 0, stream>>>(
      w_first, (const float*)d_in[20], (const float*)d_in[30], wtpH, wtpV, wpack);

  tof16_pack_kernel<<<dim3(Hq, Bq), dim3(192), 0, stream>>>(x, xpack);
  conv7_mfma_kernel<<<dim3(4, 96, 2), dim3(128), 0, stream>>>(xpack, wpack, bufA);

  pool_row_kernel<<<dim3(18432), dim3(256), 0, stream>>>(bufA, bufB);
  pool_col_kernel<<<dim3(18432), dim3(256), 0, stream>>>(bufB, x1);

  dwf_h_kernel<<<dim3(144, 8, 2), dim3(256), 0, stream>>>(x1, wEffH, bEffH, wB, fpackH);
  dwf_v_kernel<<<dim3(144, 8, 2), dim3(256), 0, stream>>>(x1, wEffV, bEffV, wB + 64*18*20, fpackV);

  off_cum_kernel<<<dim3(144, 2), dim3(256), 0, stream>>>(fpackH, wOffH, bOffH, hcum);
  off_cum_kernel<<<dim3(144, 2), dim3(256), 0, stream>>>(fpackV, wOffV, bOffV, vcum);

  einsum_mfma_kernel<0><<<dim3(576), dim3(128), 0, stream>>>(fpackH, hcum, wtpH, (const float*)d_in[21], bufA);
  einsum_mfma_kernel<1><<<dim3(576), dim3(128), 0, stream>>>(fpackV, vcum, wtpV, (const float*)d_in[31], bufB);

  gnstats_kernel<<<dim3(256), dim3(256), 0, stream>>>(bufA, bufB, stats);
  gnfinal_kernel<<<dim3(1), dim3(256), 0, stream>>>(stats,
      (const float*)d_in[22], (const float*)d_in[23],
      (const float*)d_in[32], (const float*)d_in[33], gnAB);

  final2_kernel<<<dim3(144, 2), dim3(256), 0, stream>>>(bufA, bufB, x1, gnAB, lwT, lbO, (float*)d_out);
}

// Round 16
// 458.964 us; speedup vs baseline: 1.3572x; 1.0850x over previous
//
#include <hip/hip_runtime.h>
#include <hip/hip_bf16.h>
#include <hip/hip_fp16.h>
#include <math.h>

#define Bq 2
#define Cq 64
#define Hq 192
#define Wq 192
#define HWq (Hq*Wq)            // 36864
#define Nq ((size_t)Bq*Cq*HWq) // 4718592

typedef __attribute__((ext_vector_type(8))) _Float16 f16x8;
typedef __attribute__((ext_vector_type(4))) float f32x4;

__device__ inline unsigned short h2us(__half h) {
  union { __half h; unsigned short u; } v; v.h = h; return v.u;
}

// ---------------------------------------------------------------------------
// Small prep (1 block) — register-unrolled composition
// ---------------------------------------------------------------------------
__global__ __launch_bounds__(256) void prep_small_kernel(
    const float* hc1_w, const float* hc1_b, const float* hc2_w, const float* hc2_b,
    const float* hc3_w, const float* hc3_b,
    const float* vc1_w, const float* vc1_b, const float* vc2_w, const float* vc2_b,
    const float* vc3_w, const float* vc3_b,
    const float* h_off_w, const float* h_off_b, const float* h_bn_g, const float* h_bn_b,
    const float* h_bn_m, const float* h_bn_v,
    const float* v_off_w, const float* v_off_b, const float* v_bn_g, const float* v_bn_b,
    const float* v_bn_m, const float* v_bn_v,
    const float* last_w, const float* last_g, const float* last_b, const float* last_m,
    const float* last_v,
    float* wEffH, float* bEffH, float* wEffV, float* bEffV,
    float* wOffH, float* bOffH, float* wOffV, float* bOffV,
    float* lwT, float* lbO)
{
  int t = threadIdx.x;
  if (t < 128) {
    int ch = t & 63;
    bool ish = t < 64;
    const float* w1p = (ish ? hc1_w : vc1_w) + ch*9;
    const float* w2p = (ish ? hc2_w : vc2_w) + ch*7;
    const float* w3p = (ish ? hc3_w : vc3_w) + ch*5;
    float w1r[9], w2r[7], w3r[5];
#pragma unroll
    for (int j = 0; j < 9; j++) w1r[j] = w1p[j];
#pragma unroll
    for (int k = 0; k < 7; k++) w2r[k] = w2p[k];
#pragma unroll
    for (int m = 0; m < 5; m++) w3r[m] = w3p[m];
    float t15[15];
#pragma unroll
    for (int s = 0; s < 15; s++) {
      float a = 0.f;
#pragma unroll
      for (int j = 0; j < 9; j++) { int k2 = s - j; if (k2 >= 0 && k2 < 7) a += w1r[j]*w2r[k2]; }
      t15[s] = a;
    }
    float* we = (ish ? wEffH : wEffV) + ch*19;
#pragma unroll
    for (int s = 0; s < 19; s++) {
      float a = 0.f;
#pragma unroll
      for (int j = 0; j < 15; j++) { int k3 = s - j; if (k3 >= 0 && k3 < 5) a += t15[j]*w3r[k3]; }
      we[s] = a;
    }
    float S2 = 0.f, S3 = 0.f;
#pragma unroll
    for (int j = 0; j < 7; j++) S2 += w2r[j];
#pragma unroll
    for (int j = 0; j < 5; j++) S3 += w3r[j];
    float b1 = (ish ? hc1_b : vc1_b)[ch];
    float b2 = (ish ? hc2_b : vc2_b)[ch];
    float b3 = (ish ? hc3_b : vc3_b)[ch];
    (ish ? bEffH : bEffV)[ch] = b1*S2*S3 + b2*S3 + b3;
  }
  for (int idx = t; idx < 9*64*7; idx += 256) {
    int tap = idx / 448; int rem = idx % 448; int i = rem / 7; int m = rem % 7;
    float invh = h_bn_g[m] / sqrtf(h_bn_v[m] + 1e-5f);
    wOffH[(tap*64 + i)*8 + m] = h_off_w[(m*64 + i)*9 + tap] * invh;
    float invv = v_bn_g[7+m] / sqrtf(v_bn_v[7+m] + 1e-5f);
    wOffV[(tap*64 + i)*8 + m] = v_off_w[((7+m)*64 + i)*9 + tap] * invv;
  }
  if (t < 7) {
    float invh = h_bn_g[t] / sqrtf(h_bn_v[t] + 1e-5f);
    bOffH[t] = h_off_b[t]*invh + h_bn_b[t] - h_bn_m[t]*invh;
    float invv = v_bn_g[7+t] / sqrtf(v_bn_v[7+t] + 1e-5f);
    bOffV[t] = v_off_b[7+t]*invv + v_bn_b[7+t] - v_bn_m[7+t]*invv;
  }
  for (int idx = t; idx < 4096; idx += 256) {
    int o = idx % 64; int i = idx / 64;
    float inv = last_g[o] / sqrtf(last_v[o] + 1e-3f);
    lwT[i*64 + o] = last_w[o*64 + i] * inv;
  }
  if (t < 64) {
    float inv = last_g[t] / sqrtf(last_v[t] + 1e-3f);
    lbO[t] = last_b[t] - last_m[t]*inv;
  }
}

// ---------------------------------------------------------------------------
// Border prep — fully unrolled, registers only
// ---------------------------------------------------------------------------
__global__ __launch_bounds__(256) void prep_border_kernel(
    const float* hc1_w, const float* hc1_b, const float* hc2_w, const float* hc2_b,
    const float* hc3_w, const float* hc3_b,
    const float* vc1_w, const float* vc1_b, const float* vc2_w, const float* vc2_b,
    const float* vc3_w, const float* vc3_b,
    float* wB)
{
  int tid = blockIdx.x*256 + threadIdx.x;
  if (tid >= 2*64*18) return;
  int cls = tid % 18;
  int ch  = (tid / 18) % 64;
  int br  = tid / (18*64);
  int c = (cls < 9) ? cls : cls + 174;
  const float* w1p = (br==0 ? hc1_w : vc1_w) + ch*9;
  const float* w2p = (br==0 ? hc2_w : vc2_w) + ch*7;
  const float* w3p = (br==0 ? hc3_w : vc3_w) + ch*5;
  float b1 = (br==0 ? hc1_b : vc1_b)[ch];
  float b2 = (br==0 ? hc2_b : vc2_b)[ch];
  float b3 = (br==0 ? hc3_b : vc3_b)[ch];
  float w1r[9], w2r[7], w3r[5];
#pragma unroll
  for (int j = 0; j < 9; j++) w1r[j] = w1p[j];
#pragma unroll
  for (int k = 0; k < 7; k++) w2r[k] = w2p[k];
#pragma unroll
  for (int m = 0; m < 5; m++) w3r[m] = w3p[m];

  float acc[19];
#pragma unroll
  for (int s = 0; s < 19; s++) acc[s] = 0.f;
  float bacc = b3;
#pragma unroll
  for (int m = 0; m < 5; m++) {
    int d = c + m - 2;
    bool dok = (d >= 0 && d < Wq);
    float s2b = b2;
#pragma unroll
    for (int k = 0; k < 7; k++) {
      int e = d + k - 3;
      bool eok = (e >= 0 && e < Wq);
      if (eok) s2b += w2r[k] * b1;
      float wmk = w3r[m] * w2r[k];
#pragma unroll
      for (int j = 0; j < 9; j++) {
        int fd = e + j - 4;
        bool fok = (fd >= 0 && fd < Wq);
        float contrib = (dok && eok && fok) ? wmk * w1r[j] : 0.f;
        acc[m + k + j] += contrib;
      }
    }
    if (dok) bacc += w3r[m] * s2b;
  }
  float* dst = wB + ((size_t)(br*64 + ch)*18 + cls)*20;
#pragma unroll
  for (int s = 0; s < 19; s++) dst[s] = acc[s];
  dst[19] = bacc;
}

// ---------------------------------------------------------------------------
// Big prep: dsc weights -> f16 hi/lo MFMA pack [tap][kc][hl][oc][32]
//           + w_first f16 hi/lo pack for conv7 [h][tap][hl][oc][32].
// ---------------------------------------------------------------------------
__global__ __launch_bounds__(256) void prep_big_kernel(
    const float* __restrict__ w_first,
    const float* __restrict__ h_dsc_w, const float* __restrict__ v_dsc_w,
    unsigned short* __restrict__ wtpH, unsigned short* __restrict__ wtpV,
    unsigned short* __restrict__ wpack)
{
  int tid = blockIdx.x*256 + threadIdx.x;
  int nthr = gridDim.x*256;
  for (int idx = tid; idx < 7*2*2*64*32; idx += nthr) {
    int ch32 = idx & 31;
    int oc   = (idx >> 5) & 63;
    int hl   = (idx >> 11) & 1;
    int kc   = (idx >> 12) & 1;
    int tap  = idx >> 13;
    int i = kc*32 + ch32;
    float vh = h_dsc_w[oc*448 + i*7 + tap];
    float vv = v_dsc_w[oc*448 + i*7 + tap];
    _Float16 hh = (_Float16)vh;
    _Float16 hv = (_Float16)vv;
    unsigned short uh, uv;
    if (!hl) { uh = *(unsigned short*)&hh; uv = *(unsigned short*)&hv; }
    else {
      _Float16 lh = (_Float16)(vh - (float)hh);
      _Float16 lv = (_Float16)(vv - (float)hv);
      uh = *(unsigned short*)&lh; uv = *(unsigned short*)&lv;
    }
    wtpH[idx] = uh; wtpV[idx] = uv;
  }
  for (int e = tid; e < 2*49*2*64*32; e += nthr) {
    int ch  = e & 31;
    int oc  = (e >> 5) & 63;
    int hl  = (e >> 11) & 1;
    int rest = e >> 12;
    int tap = rest % 49;
    int h   = rest / 49;
    float wv = w_first[((size_t)oc*64 + h*32 + ch)*49 + tap];
    __half hh = __float2half(wv);
    unsigned short us;
    if (!hl) us = h2us(hh);
    else { float rr = wv - __half2float(hh); us = h2us(__float2half(rr)); }
    wpack[e] = us;
  }
}

// ---------------------------------------------------------------------------
// x (NCHW f32) -> xpack single f16: [b][r][c][64]
// ---------------------------------------------------------------------------
__global__ __launch_bounds__(192) void tof16_pack_kernel(const float* __restrict__ x,
                                                         unsigned short* __restrict__ xpack)
{
  __shared__ unsigned int s[192*64];
  int r = blockIdx.x, b = blockIdx.y;
  int t = threadIdx.x;
  for (int ch = 0; ch < 64; ch++) {
    float v = x[((size_t)(b*64+ch)*Hq + r)*Wq + t];
    _Float16 hh = (_Float16)v;
    s[t*64 + (ch ^ (t & 31))] = (unsigned int)*(unsigned short*)&hh;
  }
  __syncthreads();
  unsigned short* dst = xpack + ((size_t)b*Hq + r)*Wq*64;
  for (int i = 0; i < 8; i++) {
    int gidx = i*192 + t;
    int c = gidx >> 3, g = gidx & 7;
    unsigned short tmp[8];
#pragma unroll
    for (int j = 0; j < 8; j++) {
      int ch = g*8 + j;
      tmp[j] = (unsigned short)s[c*64 + (ch ^ (c & 31))];
    }
    uint4 v;
    v.x = (unsigned int)tmp[0] | ((unsigned int)tmp[1] << 16);
    v.y = (unsigned int)tmp[2] | ((unsigned int)tmp[3] << 16);
    v.z = (unsigned int)tmp[4] | ((unsigned int)tmp[5] << 16);
    v.w = (unsigned int)tmp[6] | ((unsigned int)tmp[7] << 16);
    *(uint4*)(dst + (size_t)gidx*8) = v;
  }
}

// ---------------------------------------------------------------------------
// 7x7 conv via MFMA, 2-pass (x single f16, w hi/lo exact) — R14 validated.
// ---------------------------------------------------------------------------
__global__ __launch_bounds__(128) void conv7_mfma_kernel(
    const unsigned short* __restrict__ xpack,   // [b][r][c][64] f16
    const unsigned short* __restrict__ wpack,   // [h][tap][hl][oc][32] f16
    float* __restrict__ out)
{
  __shared__ __align__(16) unsigned short sA[8*54*32];   // 27648 B
  int ct = blockIdx.x;          // 0..3
  int rt = blockIdx.y;          // 0..95
  int b  = blockIdx.z;
  int r0 = rt*2, c0 = ct*48;
  int t = threadIdx.x;
  int wv = t >> 6;              // wave -> oc half
  int l  = t & 63;
  int l15 = l & 15, lg = l >> 4;
  int ocb = wv*32;

  f32x4 acc[2][3][2];
#pragma unroll
  for (int i = 0; i < 2; i++)
#pragma unroll
    for (int j = 0; j < 3; j++)
#pragma unroll
      for (int q = 0; q < 2; q++) acc[i][j][q] = (f32x4){0.f,0.f,0.f,0.f};

  for (int h = 0; h < 2; h++) {
    __syncthreads();
    for (int idx = t; idx < 8*54*4; idx += 128) {
      int g = idx & 3, pix = idx >> 2;
      int row = pix / 54, col = pix % 54;
      int gr = r0 - 3 + row, gc = c0 - 3 + col;
      uint4 v = {0u,0u,0u,0u};
      if (gr >= 0 && gr < Hq && gc >= 0 && gc < Wq)
        v = *(const uint4*)(xpack + (((size_t)b*Hq + gr)*Wq + gc)*64 + (h*4 + g)*8);
      ((uint4*)sA)[(row*54 + col)*4 + (g ^ ((col >> 1) & 3))] = v;
    }
    __syncthreads();
    const unsigned short* wb = wpack + (size_t)h*49*4096;
#pragma unroll 7
    for (int tap = 0; tap < 49; tap++) {
      int dy = tap / 7, dx = tap % 7;
      f16x8 bh[2], bl[2];
#pragma unroll
      for (int tbL = 0; tbL < 2; tbL++) {
        int oc = ocb + tbL*16 + l15;
        bh[tbL] = *(const f16x8*)(wb + (size_t)tap*4096 +        oc*32 + lg*8);
        bl[tbL] = *(const f16x8*)(wb + (size_t)tap*4096 + 2048 + oc*32 + lg*8);
      }
#pragma unroll
      for (int rw = 0; rw < 2; rw++) {
        int arow = rw + dy;
        f16x8 a[3];
#pragma unroll
        for (int tc = 0; tc < 3; tc++) {
          int col = tc*16 + l15 + dx;
          a[tc] = *(const f16x8*)((const uint4*)sA + (arow*54 + col)*4 + (lg ^ ((col >> 1) & 3)));
        }
#pragma unroll
        for (int tc = 0; tc < 3; tc++)
#pragma unroll
          for (int tbL = 0; tbL < 2; tbL++) {
            acc[rw][tc][tbL] = __builtin_amdgcn_mfma_f32_16x16x32_f16(a[tc], bh[tbL], acc[rw][tc][tbL], 0, 0, 0);
            acc[rw][tc][tbL] = __builtin_amdgcn_mfma_f32_16x16x32_f16(a[tc], bl[tbL], acc[rw][tc][tbL], 0, 0, 0);
          }
      }
    }
  }
#pragma unroll
  for (int tbL = 0; tbL < 2; tbL++) {
    int oc = ocb + tbL*16 + l15;
#pragma unroll
    for (int rw = 0; rw < 2; rw++) {
      float* dst = out + ((size_t)(b*64 + oc)*Hq + (r0 + rw))*Wq + c0;
#pragma unroll
      for (int tc = 0; tc < 3; tc++) {
        f32x4 v = acc[rw][tc][tbL];
        *(float4*)(dst + tc*16 + lg*4) = make_float4(v[0], v[1], v[2], v[3]);
      }
    }
  }
}

// ---------------------------------------------------------------------------
// FUSED separable 7x7 avg pool: one kernel, LDS-staged.
// Block = 32 output rows x 192 cols of one plane. Grid (6, 128).
// raw rows (zero-padded) -> column(row-dim) sums -> row(col-dim) sums /49.
// ---------------------------------------------------------------------------
__global__ __launch_bounds__(256) void pool_fused_kernel(const float* __restrict__ in,
                                                         float* __restrict__ out)
{
  __shared__ float raw[38][192];   // 29184 B
  __shared__ float cs[32][192];    // 24576 B
  int rt = blockIdx.x;             // 0..5
  int plane = blockIdx.y;          // 0..127
  int r0 = rt*32;
  int t = threadIdx.x;
  const float* src = in + (size_t)plane*HWq;
  for (int idx = t; idx < 38*192; idx += 256) {
    int lr = idx / 192, c = idx % 192;
    int gr = r0 - 3 + lr;
    raw[lr][c] = (gr >= 0 && gr < Hq) ? src[gr*Wq + c] : 0.f;
  }
  __syncthreads();
  for (int idx = t; idx < 32*192; idx += 256) {
    int lr = idx / 192, c = idx % 192;
    float s = 0.f;
#pragma unroll
    for (int dr = 0; dr < 7; dr++) s += raw[lr + dr][c];
    cs[lr][c] = s;
  }
  __syncthreads();
  float* dst = out + (size_t)plane*HWq + r0*Wq;
  for (int idx = t; idx < 32*192; idx += 256) {
    int lr = idx / 192, c = idx % 192;
    float s = 0.f;
#pragma unroll
    for (int dc = -3; dc <= 3; dc++) {
      int cc = c + dc;
      if (cc >= 0 && cc < Wq) s += cs[lr][cc];
    }
    dst[idx] = s * (1.f/49.f);
  }
}

// ---------------------------------------------------------------------------
// FUSED depthwise 19-tap + f16 hi/lo plane-major pack.
// ---------------------------------------------------------------------------
__global__ __launch_bounds__(256) void dwf_h_kernel(const float* __restrict__ x1,
                                                    const float* __restrict__ wEff,
                                                    const float* __restrict__ bEff,
                                                    const float* __restrict__ wB,
                                                    unsigned short* __restrict__ pack)
{
  __shared__ float sW[8][19][20];
  int b = blockIdx.z, g8 = blockIdx.y;
  int t = threadIdx.x;
  int chb = g8*8;
  for (int i = t; i < 8*380; i += 256) {
    int ch8 = i / 380; int rem = i % 380;
    int row = rem / 20, jj = rem % 20;
    int ch = chb + ch8;
    float v;
    if (row < 18) v = wB[((size_t)ch*18 + row)*20 + jj];
    else v = (jj < 19) ? wEff[ch*19 + jj] : bEff[ch];
    sW[ch8][row][jj] = v;
  }
  __syncthreads();
  int p = blockIdx.x*256 + t;
  int r = p / Wq, c = p % Wq;
  int row = (c < 9) ? c : ((c >= Wq-9) ? (c - 174) : 18);
  float vals[8];
#pragma unroll
  for (int ch8 = 0; ch8 < 8; ch8++) {
    const float* src = x1 + (size_t)(b*Cq + chb + ch8)*HWq + r*Wq;
    float s = sW[ch8][row][19];
#pragma unroll
    for (int j = 0; j < 19; j++) {
      int idx = min(max(c + j - 9, 0), Wq-1);
      s += src[idx] * sW[ch8][row][j];
    }
    vals[ch8] = s;
  }
  unsigned int hi[4], lo[4];
#pragma unroll
  for (int q = 0; q < 4; q++) {
    __half h0 = __float2half(vals[2*q]);
    __half h1 = __float2half(vals[2*q+1]);
    __half l0 = __float2half(vals[2*q]   - __half2float(h0));
    __half l1 = __float2half(vals[2*q+1] - __half2float(h1));
    hi[q] = (unsigned int)h2us(h0) | ((unsigned int)h2us(h1) << 16);
    lo[q] = (unsigned int)h2us(l0) | ((unsigned int)h2us(l1) << 16);
  }
  *(uint4*)(pack + (((size_t)b*16 + g8)*HWq + p)*8)     = make_uint4(hi[0], hi[1], hi[2], hi[3]);
  *(uint4*)(pack + (((size_t)b*16 + 8 + g8)*HWq + p)*8) = make_uint4(lo[0], lo[1], lo[2], lo[3]);
}

__global__ __launch_bounds__(256) void dwf_v_kernel(const float* __restrict__ x1,
                                                    const float* __restrict__ wEff,
                                                    const float* __restrict__ bEff,
                                                    const float* __restrict__ wB,
                                                    unsigned short* __restrict__ pack)
{
  __shared__ float sW[8][19][20];
  int b = blockIdx.z, g8 = blockIdx.y;
  int t = threadIdx.x;
  int chb = g8*8;
  for (int i = t; i < 8*380; i += 256) {
    int ch8 = i / 380; int rem = i % 380;
    int row = rem / 20, jj = rem % 20;
    int ch = chb + ch8;
    float v;
    if (row < 18) v = wB[((size_t)ch*18 + row)*20 + jj];
    else v = (jj < 19) ? wEff[ch*19 + jj] : bEff[ch];
    sW[ch8][row][jj] = v;
  }
  __syncthreads();
  int p = blockIdx.x*256 + t;
  int r = p / Wq, c = p % Wq;
  int row = (r < 9) ? r : ((r >= Hq-9) ? (r - 174) : 18);
  float vals[8];
#pragma unroll
  for (int ch8 = 0; ch8 < 8; ch8++) {
    const float* src = x1 + (size_t)(b*Cq + chb + ch8)*HWq + c;
    float s = sW[ch8][row][19];
#pragma unroll
    for (int j = 0; j < 19; j++) {
      int idx = min(max(r + j - 9, 0), Hq-1);
      s += src[idx*Wq] * sW[ch8][row][j];
    }
    vals[ch8] = s;
  }
  unsigned int hi[4], lo[4];
#pragma unroll
  for (int q = 0; q < 4; q++) {
    __half h0 = __float2half(vals[2*q]);
    __half h1 = __float2half(vals[2*q+1]);
    __half l0 = __float2half(vals[2*q]   - __half2float(h0));
    __half l1 = __float2half(vals[2*q+1] - __half2float(h1));
    hi[q] = (unsigned int)h2us(h0) | ((unsigned int)h2us(h1) << 16);
    lo[q] = (unsigned int)h2us(l0) | ((unsigned int)h2us(l1) << 16);
  }
  *(uint4*)(pack + (((size_t)b*16 + g8)*HWq + p)*8)     = make_uint4(hi[0], hi[1], hi[2], hi[3]);
  *(uint4*)(pack + (((size_t)b*16 + 8 + g8)*HWq + p)*8) = make_uint4(lo[0], lo[1], lo[2], lo[3]);
}

// ---------------------------------------------------------------------------
// Offset conv + tanh + cum, reading plane-major fpack (coalesced)
// ---------------------------------------------------------------------------
__global__ __launch_bounds__(256) void off_cum_kernel(const unsigned short* __restrict__ fp,
                                                      const float* __restrict__ wOff,
                                                      const float* __restrict__ bOff,
                                                      float* __restrict__ cum)
{
  const size_t HW8 = (size_t)HWq*8;
  int b = blockIdx.y;
  int p = blockIdx.x*256 + threadIdx.x;
  int r = p / Wq, c = p % Wq;
  float tv[7];
#pragma unroll
  for (int m = 0; m < 7; m++) tv[m] = bOff[m];
  const unsigned short* fb = fp + (size_t)b*HWq*128;
  for (int tap = 0; tap < 9; tap++) {
    int dy = tap/3 - 1, dx = tap%3 - 1;
    int rr = r + dy, cc = c + dx;
    if (rr < 0 || rr >= Hq || cc < 0 || cc >= Wq) continue;
    const unsigned short* p0 = fb + ((size_t)rr*Wq + cc)*8;
    const float* wp = wOff + tap*512;
    for (int g = 0; g < 8; g++) {
      f16x8 hv = *(const f16x8*)(p0 + (size_t)g*HW8);
      f16x8 lv = *(const f16x8*)(p0 + (size_t)(8 + g)*HW8);
#pragma unroll
      for (int e = 0; e < 8; e++) {
        float fv = (float)hv[e] + (float)lv[e];
        const float* wr = wp + (g*8 + e)*8;
#pragma unroll
        for (int m = 0; m < 7; m++) tv[m] += fv * wr[m];
      }
    }
  }
#pragma unroll
  for (int m = 0; m < 7; m++) tv[m] = tanhf(tv[m]);
  float c0 = tv[0], c1 = tv[1] + tv[2], c2 = tv[2], c3 = 0.f;
  float c4 = tv[4], c5 = tv[4] + tv[5], c6 = tv[6];
  size_t bb = (size_t)b*7*HWq + p;
  cum[bb + 0*HWq] = c0; cum[bb + 1*HWq] = c1; cum[bb + 2*HWq] = c2;
  cum[bb + 3*HWq] = c3; cum[bb + 4*HWq] = c4; cum[bb + 5*HWq] = c5;
  cum[bb + 6*HWq] = c6;
}

// ---------------------------------------------------------------------------
// Deformable sample + einsum via MFMA (f16 hi/lo 3-pass) — R14 validated.
// ---------------------------------------------------------------------------
template<int MORPH>
__global__ __launch_bounds__(128) void einsum_mfma_kernel(
    const unsigned short* __restrict__ fp,   // fpack [b][sub16][px][8]
    const float* __restrict__ cum,
    const unsigned short* __restrict__ wtp,  // [tap][kc][hl][oc][32] f16
    const float* __restrict__ dsc_b,
    float* __restrict__ out)                 // NCHW f32
{
  __shared__ __align__(16) unsigned short sA[2*64*128];  // 32 KB
  const size_t HW8 = (size_t)HWq*8;
  int bid = blockIdx.x;
  int swz = (bid & 7)*72 + (bid >> 3);
  int b   = swz / 288;
  int blk = swz % 288;
  int t = threadIdx.x;
  int w = t >> 6, l = t & 63;
  int l15 = l & 15, lg = l >> 4;
  int p = blk*128 + w*64 + l;
  int r = p / Wq, c = p % Wq;

  f32x4 acc[4][4];
#pragma unroll
  for (int i = 0; i < 4; i++)
#pragma unroll
    for (int j = 0; j < 4; j++) acc[i][j] = (f32x4){0.f,0.f,0.f,0.f};

  const unsigned short* fb = fp + (size_t)b*HWq*128;
  unsigned short* myrow = sA + (size_t)(w*64 + l)*128;

  for (int k = 0; k < 7; k++) {
    bool oob;
    const unsigned short *p0, *p1;
    float w0, w1;
    if (MORPH == 0) {
      int xi = c + k - 3;
      oob = (xi < 0 || xi >= Wq);
      if (!oob) {
        float y = (float)r + cum[((size_t)(b*7 + k))*HWq + p];
        float y0 = floorf(y);
        int y0q = (int)y0;
        int y0i = min(max(y0q, 0), Hq-1);
        int y1i = min(max(y0q + 1, 0), Hq-1);
        float y0f = fminf(fmaxf(y0, 0.f), (float)Hq);
        float y1f = fminf(fmaxf(y0 + 1.f, 0.f), (float)Hq);
        w0 = y1f - y; w1 = y - y0f;
        p0 = fb + ((size_t)y0i*Wq + xi)*8;
        p1 = fb + ((size_t)y1i*Wq + xi)*8;
      }
    } else {
      int yi = r + k - 3;
      oob = (yi < 0 || yi >= Hq);
      if (!oob) {
        float xf = (float)c + cum[((size_t)(b*7 + k))*HWq + p];
        float x0 = floorf(xf);
        int x0q = (int)x0;
        int x0i = min(max(x0q, 0), Wq-1);
        int x1i = min(max(x0q + 1, 0), Wq-1);
        float x0f = fminf(fmaxf(x0, 0.f), (float)Wq);
        float x1f = fminf(fmaxf(x0 + 1.f, 0.f), (float)Wq);
        w0 = x1f - xf; w1 = xf - x0f;
        p0 = fb + ((size_t)yi*Wq + x0i)*8;
        p1 = fb + ((size_t)yi*Wq + x1i)*8;
      }
    }
    if (oob) {
      uint4 z = {0u,0u,0u,0u};
#pragma unroll
      for (int j = 0; j < 16; j++) ((uint4*)myrow)[j] = z;
    } else {
#pragma unroll
      for (int g = 0; g < 8; g++) {
        f16x8 a0h = *(const f16x8*)(p0 + (size_t)g*HW8);
        f16x8 a0l = *(const f16x8*)(p0 + (size_t)(8 + g)*HW8);
        f16x8 a1h = *(const f16x8*)(p1 + (size_t)g*HW8);
        f16x8 a1l = *(const f16x8*)(p1 + (size_t)(8 + g)*HW8);
        f16x8 sh, sl;
#pragma unroll
        for (int e = 0; e < 8; e++) {
          float v = w0*((float)a0h[e] + (float)a0l[e]) + w1*((float)a1h[e] + (float)a1l[e]);
          _Float16 vh = (_Float16)v;
          sh[e] = vh;
          sl[e] = (_Float16)(v - (float)vh);
        }
        *(f16x8*)(myrow + (size_t)(g ^ l15)*8)       = sh;
        *(f16x8*)(myrow + (size_t)((8 + g) ^ l15)*8) = sl;
      }
    }
    __syncthreads();
#pragma unroll
    for (int kc = 0; kc < 2; kc++) {
      const unsigned short* wbase = wtp + (size_t)((k*2 + kc)*2)*2048;
      f16x8 bh[4], bl[4];
#pragma unroll
      for (int tb = 0; tb < 4; tb++) {
        bh[tb] = *(const f16x8*)(wbase + (tb*16 + l15)*32 + lg*8);
        bl[tb] = *(const f16x8*)(wbase + 2048 + (tb*16 + l15)*32 + lg*8);
      }
      f16x8 ah[4], al[4];
#pragma unroll
      for (int ta = 0; ta < 4; ta++) {
        const unsigned short* rbase = sA + (size_t)(w*64 + ta*16 + l15)*128;
        ah[ta] = *(const f16x8*)(rbase + (size_t)((kc*4 + lg) ^ l15)*8);
        al[ta] = *(const f16x8*)(rbase + (size_t)((8 + kc*4 + lg) ^ l15)*8);
      }
#pragma unroll
      for (int ta = 0; ta < 4; ta++)
#pragma unroll
        for (int tb = 0; tb < 4; tb++) {
          acc[ta][tb] = __builtin_amdgcn_mfma_f32_16x16x32_f16(ah[ta], bh[tb], acc[ta][tb], 0, 0, 0);
          acc[ta][tb] = __builtin_amdgcn_mfma_f32_16x16x32_f16(ah[ta], bl[tb], acc[ta][tb], 0, 0, 0);
          acc[ta][tb] = __builtin_amdgcn_mfma_f32_16x16x32_f16(al[ta], bh[tb], acc[ta][tb], 0, 0, 0);
        }
    }
    __syncthreads();
  }
  int pbase = blk*128 + w*64;
#pragma unroll
  for (int tb = 0; tb < 4; tb++) {
    int oc = tb*16 + l15;
    float bias = dsc_b[oc];
    float* dst = out + (size_t)(b*64 + oc)*HWq + pbase;
#pragma unroll
    for (int ta = 0; ta < 4; ta++) {
      f32x4 v = acc[ta][tb];
      *(float4*)(dst + ta*16 + lg*4) = make_float4(v[0]+bias, v[1]+bias, v[2]+bias, v[3]+bias);
    }
  }
}

// ---------------------------------------------------------------------------
// GroupNorm stats + finalize
// ---------------------------------------------------------------------------
__global__ __launch_bounds__(256) void gnstats_kernel(const float* __restrict__ h_ds,
                                                      const float* __restrict__ v_ds,
                                                      float* __restrict__ stats)
{
  int plane = blockIdx.x;
  int buf = plane >> 7;
  int rem = plane & 127;
  const float* src = (buf ? v_ds : h_ds) + (size_t)rem*HWq;
  float s = 0.f, s2 = 0.f;
  for (int i = threadIdx.x; i < HWq; i += 256) {
    float v = src[i];
    s += v; s2 += v*v;
  }
  __shared__ float red[2][4];
  for (int off = 32; off; off >>= 1) {
    s  += __shfl_down(s, off);
    s2 += __shfl_down(s2, off);
  }
  if ((threadIdx.x & 63) == 0) { red[0][threadIdx.x >> 6] = s; red[1][threadIdx.x >> 6] = s2; }
  __syncthreads();
  if (threadIdx.x == 0) {
    s  = red[0][0] + red[0][1] + red[0][2] + red[0][3];
    s2 = red[1][0] + red[1][1] + red[1][2] + red[1][3];
    stats[plane*2 + 0] = s;
    stats[plane*2 + 1] = s2;
  }
}

__global__ __launch_bounds__(256) void gnfinal_kernel(const float* __restrict__ stats,
                                                      const float* __restrict__ h_gn_g, const float* __restrict__ h_gn_b,
                                                      const float* __restrict__ v_gn_g, const float* __restrict__ v_gn_b,
                                                      float* __restrict__ gnAB)
{
  int t = threadIdx.x;
  int buf = t >> 7, ch = t & 63;
  int base = t & ~3;
  float sum = 0.f, ss = 0.f;
#pragma unroll
  for (int q = 0; q < 4; q++) { sum += stats[(base+q)*2]; ss += stats[(base+q)*2 + 1]; }
  const float n = 4.f * HWq;
  float mean = sum / n;
  float var = ss / n - mean*mean;
  float gg = (buf ? v_gn_g : h_gn_g)[ch];
  float bb = (buf ? v_gn_b : h_gn_b)[ch];
  float A = gg / sqrtf(var + 1e-5f);
  gnAB[t*2 + 0] = A;
  gnAB[t*2 + 1] = bb - mean*A;
}

// ---------------------------------------------------------------------------
// FUSED: comb = relu(GN(h)) + relu(GN(v)) + x1 inline, then 1x1 conv + SiLU
// ---------------------------------------------------------------------------
__global__ __launch_bounds__(256) void final2_kernel(const float* __restrict__ hbuf,
                                                     const float* __restrict__ vbuf,
                                                     const float* __restrict__ x1,
                                                     const float* __restrict__ gnAB,
                                                     const float* __restrict__ lwT,
                                                     const float* __restrict__ lbO,
                                                     float* __restrict__ out)
{
  int b = blockIdx.y;
  int p = blockIdx.x*256 + threadIdx.x;
  float acc[64];
#pragma unroll
  for (int o = 0; o < 64; o++) acc[o] = 0.f;
  for (int i = 0; i < 64; i++) {
    size_t off = (size_t)(b*64 + i)*HWq + p;
    int plane = b*64 + i;
    int ih = plane*2;
    int iv = (128 + plane)*2;
    float hv = fmaxf(hbuf[off]*gnAB[ih] + gnAB[ih+1], 0.f);
    float vv = fmaxf(vbuf[off]*gnAB[iv] + gnAB[iv+1], 0.f);
    float cv = hv + vv + x1[off];
    const float* wr = lwT + i*64;
#pragma unroll
    for (int o = 0; o < 64; o++) acc[o] += cv * wr[o];
  }
  float* dst = out + (size_t)b*Cq*HWq + p;
#pragma unroll
  for (int o = 0; o < 64; o++) {
    float yv = acc[o] + lbO[o];
    dst[(size_t)o*HWq] = yv / (1.f + expf(-yv));
  }
}

// ---------------------------------------------------------------------------
extern "C" void kernel_launch(void* const* d_in, const int* in_sizes, int n_in,
                              void* d_out, int out_size, void* d_ws, size_t ws_size,
                              hipStream_t stream)
{
  const float* x       = (const float*)d_in[0];
  const float* w_first = (const float*)d_in[1];
  float* ws = (float*)d_ws;

  float* bufA = ws;            // conv7 out -> h-einsum-out
  float* bufB = ws + Nq;       // v-einsum-out
  float* x1   = ws + 2*Nq;
  float* h_ds = ws + 3*Nq;     // xpack -> fpackH
  float* v_ds = ws + 4*Nq;     // fpackV
  size_t off = 5*Nq;
  float* hcum  = ws + off; off += (size_t)Bq*7*HWq;
  float* vcum  = ws + off; off += (size_t)Bq*7*HWq;
  float* wEffH = ws + off; off += 64*19;
  float* bEffH = ws + off; off += 64;
  float* wEffV = ws + off; off += 64*19;
  float* bEffV = ws + off; off += 64;
  float* wtH   = ws + off; off += 64*64*7;   // holds wtpH f16 pack
  float* wtV   = ws + off; off += 64*64*7;   // holds wtpV f16 pack
  float* wOffH = ws + off; off += 9*64*8;
  float* bOffH = ws + off; off += 8;
  float* wOffV = ws + off; off += 9*64*8;
  float* bOffV = ws + off; off += 8;
  float* lwT   = ws + off; off += 64*64;
  float* lbO   = ws + off; off += 64;
  float* stats = ws + off; off += 512;
  float* gnAB  = ws + off; off += 512;
  float* wB    = ws + off; off += 2*64*18*20;
  unsigned short* wpack = (unsigned short*)(ws + off); off += 2*49*2*64*32/2 + 16;
  unsigned short* xpack  = (unsigned short*)h_ds;
  unsigned short* fpackH = (unsigned short*)h_ds;
  unsigned short* fpackV = (unsigned short*)v_ds;
  unsigned short* wtpH = (unsigned short*)wtH;
  unsigned short* wtpV = (unsigned short*)wtV;

  prep_small_kernel<<<dim3(1), dim3(256), 0, stream>>>(
      (const float*)d_in[2],  (const float*)d_in[3],  (const float*)d_in[4],  (const float*)d_in[5],
      (const float*)d_in[6],  (const float*)d_in[7],
      (const float*)d_in[8],  (const float*)d_in[9],  (const float*)d_in[10], (const float*)d_in[11],
      (const float*)d_in[12], (const float*)d_in[13],
      (const float*)d_in[14], (const float*)d_in[15], (const float*)d_in[16], (const float*)d_in[17],
      (const float*)d_in[18], (const float*)d_in[19],
      (const float*)d_in[24], (const float*)d_in[25], (const float*)d_in[26], (const float*)d_in[27],
      (const float*)d_in[28], (const float*)d_in[29],
      (const float*)d_in[34], (const float*)d_in[35], (const float*)d_in[36], (const float*)d_in[37],
      (const float*)d_in[38],
      wEffH, bEffH, wEffV, bEffV, wOffH, bOffH, wOffV, bOffV, lwT, lbO);

  prep_border_kernel<<<dim3(9), dim3(256), 0, stream>>>(
      (const float*)d_in[2],  (const float*)d_in[3],  (const float*)d_in[4],  (const float*)d_in[5],
      (const float*)d_in[6],  (const float*)d_in[7],
      (const float*)d_in[8],  (const float*)d_in[9],  (const float*)d_in[10], (const float*)d_in[11],
      (const float*)d_in[12], (const float*)d_in[13], wB);

  prep_big_kernel<<<dim3(64), dim3(256), 0, stream>>>(
      w_first, (const float*)d_in[20], (const float*)d_in[30], wtpH, wtpV, wpack);

  tof16_pack_kernel<<<dim3(Hq, Bq), dim3(192), 0, stream>>>(x, xpack);
  conv7_mfma_kernel<<<dim3(4, 96, 2), dim3(128), 0, stream>>>(xpack, wpack, bufA);

  pool_fused_kernel<<<dim3(6, 128), dim3(256), 0, stream>>>(bufA, x1);

  dwf_h_kernel<<<dim3(144, 8, 2), dim3(256), 0, stream>>>(x1, wEffH, bEffH, wB, fpackH);
  dwf_v_kernel<<<dim3(144, 8, 2), dim3(256), 0, stream>>>(x1, wEffV, bEffV, wB + 64*18*20, fpackV);

  off_cum_kernel<<<dim3(144, 2), dim3(256), 0, stream>>>(fpackH, wOffH, bOffH, hcum);
  off_cum_kernel<<<dim3(144, 2), dim3(256), 0, stream>>>(fpackV, wOffV, bOffV, vcum);

  einsum_mfma_kernel<0><<<dim3(576), dim3(128), 0, stream>>>(fpackH, hcum, wtpH, (const float*)d_in[21], bufA);
  einsum_mfma_kernel<1><<<dim3(576), dim3(128), 0, stream>>>(fpackV, vcum, wtpV, (const float*)d_in[31], bufB);

  gnstats_kernel<<<dim3(256), dim3(256), 0, stream>>>(bufA, bufB, stats);
  gnfinal_kernel<<<dim3(1), dim3(256), 0, stream>>>(stats,
      (const float*)d_in[22], (const float*)d_in[23],
      (const float*)d_in[32], (const float*)d_in[33], gnAB);

  final2_kernel<<<dim3(144, 2), dim3(256), 0, stream>>>(bufA, bufB, x1, gnAB, lwT, lbO, (float*)d_out);
}

// Round 17
// 429.541 us; speedup vs baseline: 1.4502x; 1.0685x over previous
//
#include <hip/hip_runtime.h>
#include <hip/hip_bf16.h>
#include <hip/hip_fp16.h>
#include <math.h>

#define Bq 2
#define Cq 64
#define Hq 192
#define Wq 192
#define HWq (Hq*Wq)            // 36864
#define Nq ((size_t)Bq*Cq*HWq) // 4718592

typedef __attribute__((ext_vector_type(8))) _Float16 f16x8;
typedef __attribute__((ext_vector_type(4))) float f32x4;

__device__ inline unsigned short h2us(__half h) {
  union { __half h; unsigned short u; } v; v.h = h; return v.u;
}

// ---------------------------------------------------------------------------
// Small prep (1 block) — register-unrolled composition
// ---------------------------------------------------------------------------
__global__ __launch_bounds__(256) void prep_small_kernel(
    const float* hc1_w, const float* hc1_b, const float* hc2_w, const float* hc2_b,
    const float* hc3_w, const float* hc3_b,
    const float* vc1_w, const float* vc1_b, const float* vc2_w, const float* vc2_b,
    const float* vc3_w, const float* vc3_b,
    const float* h_off_w, const float* h_off_b, const float* h_bn_g, const float* h_bn_b,
    const float* h_bn_m, const float* h_bn_v,
    const float* v_off_w, const float* v_off_b, const float* v_bn_g, const float* v_bn_b,
    const float* v_bn_m, const float* v_bn_v,
    const float* last_w, const float* last_g, const float* last_b, const float* last_m,
    const float* last_v,
    float* wEffH, float* bEffH, float* wEffV, float* bEffV,
    float* wOffH, float* bOffH, float* wOffV, float* bOffV,
    float* lwT, float* lbO)
{
  int t = threadIdx.x;
  if (t < 128) {
    int ch = t & 63;
    bool ish = t < 64;
    const float* w1p = (ish ? hc1_w : vc1_w) + ch*9;
    const float* w2p = (ish ? hc2_w : vc2_w) + ch*7;
    const float* w3p = (ish ? hc3_w : vc3_w) + ch*5;
    float w1r[9], w2r[7], w3r[5];
#pragma unroll
    for (int j = 0; j < 9; j++) w1r[j] = w1p[j];
#pragma unroll
    for (int k = 0; k < 7; k++) w2r[k] = w2p[k];
#pragma unroll
    for (int m = 0; m < 5; m++) w3r[m] = w3p[m];
    float t15[15];
#pragma unroll
    for (int s = 0; s < 15; s++) {
      float a = 0.f;
#pragma unroll
      for (int j = 0; j < 9; j++) { int k2 = s - j; if (k2 >= 0 && k2 < 7) a += w1r[j]*w2r[k2]; }
      t15[s] = a;
    }
    float* we = (ish ? wEffH : wEffV) + ch*19;
#pragma unroll
    for (int s = 0; s < 19; s++) {
      float a = 0.f;
#pragma unroll
      for (int j = 0; j < 15; j++) { int k3 = s - j; if (k3 >= 0 && k3 < 5) a += t15[j]*w3r[k3]; }
      we[s] = a;
    }
    float S2 = 0.f, S3 = 0.f;
#pragma unroll
    for (int j = 0; j < 7; j++) S2 += w2r[j];
#pragma unroll
    for (int j = 0; j < 5; j++) S3 += w3r[j];
    float b1 = (ish ? hc1_b : vc1_b)[ch];
    float b2 = (ish ? hc2_b : vc2_b)[ch];
    float b3 = (ish ? hc3_b : vc3_b)[ch];
    (ish ? bEffH : bEffV)[ch] = b1*S2*S3 + b2*S3 + b3;
  }
  for (int idx = t; idx < 9*64*7; idx += 256) {
    int tap = idx / 448; int rem = idx % 448; int i = rem / 7; int m = rem % 7;
    float invh = h_bn_g[m] / sqrtf(h_bn_v[m] + 1e-5f);
    wOffH[(tap*64 + i)*8 + m] = h_off_w[(m*64 + i)*9 + tap] * invh;
    float invv = v_bn_g[7+m] / sqrtf(v_bn_v[7+m] + 1e-5f);
    wOffV[(tap*64 + i)*8 + m] = v_off_w[((7+m)*64 + i)*9 + tap] * invv;
  }
  if (t < 7) {
    float invh = h_bn_g[t] / sqrtf(h_bn_v[t] + 1e-5f);
    bOffH[t] = h_off_b[t]*invh + h_bn_b[t] - h_bn_m[t]*invh;
    float invv = v_bn_g[7+t] / sqrtf(v_bn_v[7+t] + 1e-5f);
    bOffV[t] = v_off_b[7+t]*invv + v_bn_b[7+t] - v_bn_m[7+t]*invv;
  }
  for (int idx = t; idx < 4096; idx += 256) {
    int o = idx % 64; int i = idx / 64;
    float inv = last_g[o] / sqrtf(last_v[o] + 1e-3f);
    lwT[i*64 + o] = last_w[o*64 + i] * inv;
  }
  if (t < 64) {
    float inv = last_g[t] / sqrtf(last_v[t] + 1e-3f);
    lbO[t] = last_b[t] - last_m[t]*inv;
  }
}

// ---------------------------------------------------------------------------
// Border prep — fully unrolled, registers only
// ---------------------------------------------------------------------------
__global__ __launch_bounds__(256) void prep_border_kernel(
    const float* hc1_w, const float* hc1_b, const float* hc2_w, const float* hc2_b,
    const float* hc3_w, const float* hc3_b,
    const float* vc1_w, const float* vc1_b, const float* vc2_w, const float* vc2_b,
    const float* vc3_w, const float* vc3_b,
    float* wB)
{
  int tid = blockIdx.x*256 + threadIdx.x;
  if (tid >= 2*64*18) return;
  int cls = tid % 18;
  int ch  = (tid / 18) % 64;
  int br  = tid / (18*64);
  int c = (cls < 9) ? cls : cls + 174;
  const float* w1p = (br==0 ? hc1_w : vc1_w) + ch*9;
  const float* w2p = (br==0 ? hc2_w : vc2_w) + ch*7;
  const float* w3p = (br==0 ? hc3_w : vc3_w) + ch*5;
  float b1 = (br==0 ? hc1_b : vc1_b)[ch];
  float b2 = (br==0 ? hc2_b : vc2_b)[ch];
  float b3 = (br==0 ? hc3_b : vc3_b)[ch];
  float w1r[9], w2r[7], w3r[5];
#pragma unroll
  for (int j = 0; j < 9; j++) w1r[j] = w1p[j];
#pragma unroll
  for (int k = 0; k < 7; k++) w2r[k] = w2p[k];
#pragma unroll
  for (int m = 0; m < 5; m++) w3r[m] = w3p[m];

  float acc[19];
#pragma unroll
  for (int s = 0; s < 19; s++) acc[s] = 0.f;
  float bacc = b3;
#pragma unroll
  for (int m = 0; m < 5; m++) {
    int d = c + m - 2;
    bool dok = (d >= 0 && d < Wq);
    float s2b = b2;
#pragma unroll
    for (int k = 0; k < 7; k++) {
      int e = d + k - 3;
      bool eok = (e >= 0 && e < Wq);
      if (eok) s2b += w2r[k] * b1;
      float wmk = w3r[m] * w2r[k];
#pragma unroll
      for (int j = 0; j < 9; j++) {
        int fd = e + j - 4;
        bool fok = (fd >= 0 && fd < Wq);
        float contrib = (dok && eok && fok) ? wmk * w1r[j] : 0.f;
        acc[m + k + j] += contrib;
      }
    }
    if (dok) bacc += w3r[m] * s2b;
  }
  float* dst = wB + ((size_t)(br*64 + ch)*18 + cls)*20;
#pragma unroll
  for (int s = 0; s < 19; s++) dst[s] = acc[s];
  dst[19] = bacc;
}

// ---------------------------------------------------------------------------
// Big prep: dsc weights -> f16 hi/lo MFMA pack [tap][kc][hl][oc][32]
//           + w_first f16 hi/lo pack for conv7 [h][tap][hl][oc][32].
// ---------------------------------------------------------------------------
__global__ __launch_bounds__(256) void prep_big_kernel(
    const float* __restrict__ w_first,
    const float* __restrict__ h_dsc_w, const float* __restrict__ v_dsc_w,
    unsigned short* __restrict__ wtpH, unsigned short* __restrict__ wtpV,
    unsigned short* __restrict__ wpack)
{
  int tid = blockIdx.x*256 + threadIdx.x;
  int nthr = gridDim.x*256;
  for (int idx = tid; idx < 7*2*2*64*32; idx += nthr) {
    int ch32 = idx & 31;
    int oc   = (idx >> 5) & 63;
    int hl   = (idx >> 11) & 1;
    int kc   = (idx >> 12) & 1;
    int tap  = idx >> 13;
    int i = kc*32 + ch32;
    float vh = h_dsc_w[oc*448 + i*7 + tap];
    float vv = v_dsc_w[oc*448 + i*7 + tap];
    _Float16 hh = (_Float16)vh;
    _Float16 hv = (_Float16)vv;
    unsigned short uh, uv;
    if (!hl) { uh = *(unsigned short*)&hh; uv = *(unsigned short*)&hv; }
    else {
      _Float16 lh = (_Float16)(vh - (float)hh);
      _Float16 lv = (_Float16)(vv - (float)hv);
      uh = *(unsigned short*)&lh; uv = *(unsigned short*)&lv;
    }
    wtpH[idx] = uh; wtpV[idx] = uv;
  }
  for (int e = tid; e < 2*49*2*64*32; e += nthr) {
    int ch  = e & 31;
    int oc  = (e >> 5) & 63;
    int hl  = (e >> 11) & 1;
    int rest = e >> 12;
    int tap = rest % 49;
    int h   = rest / 49;
    float wv = w_first[((size_t)oc*64 + h*32 + ch)*49 + tap];
    __half hh = __float2half(wv);
    unsigned short us;
    if (!hl) us = h2us(hh);
    else { float rr = wv - __half2float(hh); us = h2us(__float2half(rr)); }
    wpack[e] = us;
  }
}

// ---------------------------------------------------------------------------
// x (NCHW f32) -> xpack single f16: [b][r][c][64]
// ---------------------------------------------------------------------------
__global__ __launch_bounds__(192) void tof16_pack_kernel(const float* __restrict__ x,
                                                         unsigned short* __restrict__ xpack)
{
  __shared__ unsigned int s[192*64];
  int r = blockIdx.x, b = blockIdx.y;
  int t = threadIdx.x;
  for (int ch = 0; ch < 64; ch++) {
    float v = x[((size_t)(b*64+ch)*Hq + r)*Wq + t];
    _Float16 hh = (_Float16)v;
    s[t*64 + (ch ^ (t & 31))] = (unsigned int)*(unsigned short*)&hh;
  }
  __syncthreads();
  unsigned short* dst = xpack + ((size_t)b*Hq + r)*Wq*64;
  for (int i = 0; i < 8; i++) {
    int gidx = i*192 + t;
    int c = gidx >> 3, g = gidx & 7;
    unsigned short tmp[8];
#pragma unroll
    for (int j = 0; j < 8; j++) {
      int ch = g*8 + j;
      tmp[j] = (unsigned short)s[c*64 + (ch ^ (c & 31))];
    }
    uint4 v;
    v.x = (unsigned int)tmp[0] | ((unsigned int)tmp[1] << 16);
    v.y = (unsigned int)tmp[2] | ((unsigned int)tmp[3] << 16);
    v.z = (unsigned int)tmp[4] | ((unsigned int)tmp[5] << 16);
    v.w = (unsigned int)tmp[6] | ((unsigned int)tmp[7] << 16);
    *(uint4*)(dst + (size_t)gidx*8) = v;
  }
}

// ---------------------------------------------------------------------------
// 7x7 conv via MFMA, 2-pass (x single f16, w hi/lo exact).
// Block = 4 waves split by OC-QUARTER (wave w owns oc w*16..w*16+15):
// per-wave B-fetch 2KB/tap, 12 MFMA/tap, acc 24 VGPR.
// Grid 4x96x2 = 768 blocks -> 3 blocks/CU x 4 waves = 12 waves/CU.
// A-tile in LDS shared by all 4 waves (same-address reads broadcast).
// ---------------------------------------------------------------------------
__global__ __launch_bounds__(256) void conv7_mfma_kernel(
    const unsigned short* __restrict__ xpack,   // [b][r][c][64] f16
    const unsigned short* __restrict__ wpack,   // [h][tap][hl][oc][32] f16
    float* __restrict__ out)
{
  __shared__ __align__(16) unsigned short sA[8*54*32];   // 27648 B
  int ct = blockIdx.x;          // 0..3
  int rt = blockIdx.y;          // 0..95
  int b  = blockIdx.z;
  int r0 = rt*2, c0 = ct*48;
  int t = threadIdx.x;
  int wv = t >> 6;              // wave -> oc quarter
  int l  = t & 63;
  int l15 = l & 15, lg = l >> 4;
  int oc = wv*16 + l15;         // this lane's output channel

  f32x4 acc[2][3];
#pragma unroll
  for (int i = 0; i < 2; i++)
#pragma unroll
    for (int j = 0; j < 3; j++) acc[i][j] = (f32x4){0.f,0.f,0.f,0.f};

  for (int h = 0; h < 2; h++) {
    __syncthreads();
    for (int idx = t; idx < 8*54*4; idx += 256) {
      int g = idx & 3, pix = idx >> 2;
      int row = pix / 54, col = pix % 54;
      int gr = r0 - 3 + row, gc = c0 - 3 + col;
      uint4 v = {0u,0u,0u,0u};
      if (gr >= 0 && gr < Hq && gc >= 0 && gc < Wq)
        v = *(const uint4*)(xpack + (((size_t)b*Hq + gr)*Wq + gc)*64 + (h*4 + g)*8);
      ((uint4*)sA)[(row*54 + col)*4 + (g ^ ((col >> 1) & 3))] = v;
    }
    __syncthreads();
    const unsigned short* wb = wpack + (size_t)h*49*4096;
#pragma unroll 7
    for (int tap = 0; tap < 49; tap++) {
      int dy = tap / 7, dx = tap % 7;
      f16x8 bh = *(const f16x8*)(wb + (size_t)tap*4096 +        oc*32 + lg*8);
      f16x8 bl = *(const f16x8*)(wb + (size_t)tap*4096 + 2048 + oc*32 + lg*8);
#pragma unroll
      for (int rw = 0; rw < 2; rw++) {
        int arow = rw + dy;
        f16x8 a[3];
#pragma unroll
        for (int tc = 0; tc < 3; tc++) {
          int col = tc*16 + l15 + dx;
          a[tc] = *(const f16x8*)((const uint4*)sA + (arow*54 + col)*4 + (lg ^ ((col >> 1) & 3)));
        }
#pragma unroll
        for (int tc = 0; tc < 3; tc++) {
          acc[rw][tc] = __builtin_amdgcn_mfma_f32_16x16x32_f16(a[tc], bh, acc[rw][tc], 0, 0, 0);
          acc[rw][tc] = __builtin_amdgcn_mfma_f32_16x16x32_f16(a[tc], bl, acc[rw][tc], 0, 0, 0);
        }
      }
    }
  }
#pragma unroll
  for (int rw = 0; rw < 2; rw++) {
    float* dst = out + ((size_t)(b*64 + oc)*Hq + (r0 + rw))*Wq + c0;
#pragma unroll
    for (int tc = 0; tc < 3; tc++) {
      f32x4 v = acc[rw][tc];
      *(float4*)(dst + tc*16 + lg*4) = make_float4(v[0], v[1], v[2], v[3]);
    }
  }
}

// ---------------------------------------------------------------------------
// FUSED separable 7x7 avg pool: one kernel, LDS-staged.
// ---------------------------------------------------------------------------
__global__ __launch_bounds__(256) void pool_fused_kernel(const float* __restrict__ in,
                                                         float* __restrict__ out)
{
  __shared__ float raw[38][192];
  __shared__ float cs[32][192];
  int rt = blockIdx.x;
  int plane = blockIdx.y;
  int r0 = rt*32;
  int t = threadIdx.x;
  const float* src = in + (size_t)plane*HWq;
  for (int idx = t; idx < 38*192; idx += 256) {
    int lr = idx / 192, c = idx % 192;
    int gr = r0 - 3 + lr;
    raw[lr][c] = (gr >= 0 && gr < Hq) ? src[gr*Wq + c] : 0.f;
  }
  __syncthreads();
  for (int idx = t; idx < 32*192; idx += 256) {
    int lr = idx / 192, c = idx % 192;
    float s = 0.f;
#pragma unroll
    for (int dr = 0; dr < 7; dr++) s += raw[lr + dr][c];
    cs[lr][c] = s;
  }
  __syncthreads();
  float* dst = out + (size_t)plane*HWq + r0*Wq;
  for (int idx = t; idx < 32*192; idx += 256) {
    int lr = idx / 192, c = idx % 192;
    float s = 0.f;
#pragma unroll
    for (int dc = -3; dc <= 3; dc++) {
      int cc = c + dc;
      if (cc >= 0 && cc < Wq) s += cs[lr][cc];
    }
    dst[idx] = s * (1.f/49.f);
  }
}

// ---------------------------------------------------------------------------
// FUSED depthwise 19-tap + f16 hi/lo plane-major pack.
// ---------------------------------------------------------------------------
__global__ __launch_bounds__(256) void dwf_h_kernel(const float* __restrict__ x1,
                                                    const float* __restrict__ wEff,
                                                    const float* __restrict__ bEff,
                                                    const float* __restrict__ wB,
                                                    unsigned short* __restrict__ pack)
{
  __shared__ float sW[8][19][20];
  int b = blockIdx.z, g8 = blockIdx.y;
  int t = threadIdx.x;
  int chb = g8*8;
  for (int i = t; i < 8*380; i += 256) {
    int ch8 = i / 380; int rem = i % 380;
    int row = rem / 20, jj = rem % 20;
    int ch = chb + ch8;
    float v;
    if (row < 18) v = wB[((size_t)ch*18 + row)*20 + jj];
    else v = (jj < 19) ? wEff[ch*19 + jj] : bEff[ch];
    sW[ch8][row][jj] = v;
  }
  __syncthreads();
  int p = blockIdx.x*256 + t;
  int r = p / Wq, c = p % Wq;
  int row = (c < 9) ? c : ((c >= Wq-9) ? (c - 174) : 18);
  float vals[8];
#pragma unroll
  for (int ch8 = 0; ch8 < 8; ch8++) {
    const float* src = x1 + (size_t)(b*Cq + chb + ch8)*HWq + r*Wq;
    float s = sW[ch8][row][19];
#pragma unroll
    for (int j = 0; j < 19; j++) {
      int idx = min(max(c + j - 9, 0), Wq-1);
      s += src[idx] * sW[ch8][row][j];
    }
    vals[ch8] = s;
  }
  unsigned int hi[4], lo[4];
#pragma unroll
  for (int q = 0; q < 4; q++) {
    __half h0 = __float2half(vals[2*q]);
    __half h1 = __float2half(vals[2*q+1]);
    __half l0 = __float2half(vals[2*q]   - __half2float(h0));
    __half l1 = __float2half(vals[2*q+1] - __half2float(h1));
    hi[q] = (unsigned int)h2us(h0) | ((unsigned int)h2us(h1) << 16);
    lo[q] = (unsigned int)h2us(l0) | ((unsigned int)h2us(l1) << 16);
  }
  *(uint4*)(pack + (((size_t)b*16 + g8)*HWq + p)*8)     = make_uint4(hi[0], hi[1], hi[2], hi[3]);
  *(uint4*)(pack + (((size_t)b*16 + 8 + g8)*HWq + p)*8) = make_uint4(lo[0], lo[1], lo[2], lo[3]);
}

__global__ __launch_bounds__(256) void dwf_v_kernel(const float* __restrict__ x1,
                                                    const float* __restrict__ wEff,
                                                    const float* __restrict__ bEff,
                                                    const float* __restrict__ wB,
                                                    unsigned short* __restrict__ pack)
{
  __shared__ float sW[8][19][20];
  int b = blockIdx.z, g8 = blockIdx.y;
  int t = threadIdx.x;
  int chb = g8*8;
  for (int i = t; i < 8*380; i += 256) {
    int ch8 = i / 380; int rem = i % 380;
    int row = rem / 20, jj = rem % 20;
    int ch = chb + ch8;
    float v;
    if (row < 18) v = wB[((size_t)ch*18 + row)*20 + jj];
    else v = (jj < 19) ? wEff[ch*19 + jj] : bEff[ch];
    sW[ch8][row][jj] = v;
  }
  __syncthreads();
  int p = blockIdx.x*256 + t;
  int r = p / Wq, c = p % Wq;
  int row = (r < 9) ? r : ((r >= Hq-9) ? (r - 174) : 18);
  float vals[8];
#pragma unroll
  for (int ch8 = 0; ch8 < 8; ch8++) {
    const float* src = x1 + (size_t)(b*Cq + chb + ch8)*HWq + c;
    float s = sW[ch8][row][19];
#pragma unroll
    for (int j = 0; j < 19; j++) {
      int idx = min(max(r + j - 9, 0), Hq-1);
      s += src[idx*Wq] * sW[ch8][row][j];
    }
    vals[ch8] = s;
  }
  unsigned int hi[4], lo[4];
#pragma unroll
  for (int q = 0; q < 4; q++) {
    __half h0 = __float2half(vals[2*q]);
    __half h1 = __float2half(vals[2*q+1]);
    __half l0 = __float2half(vals[2*q]   - __half2float(h0));
    __half l1 = __float2half(vals[2*q+1] - __half2float(h1));
    hi[q] = (unsigned int)h2us(h0) | ((unsigned int)h2us(h1) << 16);
    lo[q] = (unsigned int)h2us(l0) | ((unsigned int)h2us(l1) << 16);
  }
  *(uint4*)(pack + (((size_t)b*16 + g8)*HWq + p)*8)     = make_uint4(hi[0], hi[1], hi[2], hi[3]);
  *(uint4*)(pack + (((size_t)b*16 + 8 + g8)*HWq + p)*8) = make_uint4(lo[0], lo[1], lo[2], lo[3]);
}

// ---------------------------------------------------------------------------
// Offset conv + tanh + cum, reading plane-major fpack (coalesced)
// ---------------------------------------------------------------------------
__global__ __launch_bounds__(256) void off_cum_kernel(const unsigned short* __restrict__ fp,
                                                      const float* __restrict__ wOff,
                                                      const float* __restrict__ bOff,
                                                      float* __restrict__ cum)
{
  const size_t HW8 = (size_t)HWq*8;
  int b = blockIdx.y;
  int p = blockIdx.x*256 + threadIdx.x;
  int r = p / Wq, c = p % Wq;
  float tv[7];
#pragma unroll
  for (int m = 0; m < 7; m++) tv[m] = bOff[m];
  const unsigned short* fb = fp + (size_t)b*HWq*128;
  for (int tap = 0; tap < 9; tap++) {
    int dy = tap/3 - 1, dx = tap%3 - 1;
    int rr = r + dy, cc = c + dx;
    if (rr < 0 || rr >= Hq || cc < 0 || cc >= Wq) continue;
    const unsigned short* p0 = fb + ((size_t)rr*Wq + cc)*8;
    const float* wp = wOff + tap*512;
    for (int g = 0; g < 8; g++) {
      f16x8 hv = *(const f16x8*)(p0 + (size_t)g*HW8);
      f16x8 lv = *(const f16x8*)(p0 + (size_t)(8 + g)*HW8);
#pragma unroll
      for (int e = 0; e < 8; e++) {
        float fv = (float)hv[e] + (float)lv[e];
        const float* wr = wp + (g*8 + e)*8;
#pragma unroll
        for (int m = 0; m < 7; m++) tv[m] += fv * wr[m];
      }
    }
  }
#pragma unroll
  for (int m = 0; m < 7; m++) tv[m] = tanhf(tv[m]);
  float c0 = tv[0], c1 = tv[1] + tv[2], c2 = tv[2], c3 = 0.f;
  float c4 = tv[4], c5 = tv[4] + tv[5], c6 = tv[6];
  size_t bb = (size_t)b*7*HWq + p;
  cum[bb + 0*HWq] = c0; cum[bb + 1*HWq] = c1; cum[bb + 2*HWq] = c2;
  cum[bb + 3*HWq] = c3; cum[bb + 4*HWq] = c4; cum[bb + 5*HWq] = c5;
  cum[bb + 6*HWq] = c6;
}

// ---------------------------------------------------------------------------
// Deformable sample + einsum via MFMA (f16 hi/lo 3-pass) — validated.
// ---------------------------------------------------------------------------
template<int MORPH>
__global__ __launch_bounds__(128) void einsum_mfma_kernel(
    const unsigned short* __restrict__ fp,   // fpack [b][sub16][px][8]
    const float* __restrict__ cum,
    const unsigned short* __restrict__ wtp,  // [tap][kc][hl][oc][32] f16
    const float* __restrict__ dsc_b,
    float* __restrict__ out)                 // NCHW f32
{
  __shared__ __align__(16) unsigned short sA[2*64*128];  // 32 KB
  const size_t HW8 = (size_t)HWq*8;
  int bid = blockIdx.x;
  int swz = (bid & 7)*72 + (bid >> 3);
  int b   = swz / 288;
  int blk = swz % 288;
  int t = threadIdx.x;
  int w = t >> 6, l = t & 63;
  int l15 = l & 15, lg = l >> 4;
  int p = blk*128 + w*64 + l;
  int r = p / Wq, c = p % Wq;

  f32x4 acc[4][4];
#pragma unroll
  for (int i = 0; i < 4; i++)
#pragma unroll
    for (int j = 0; j < 4; j++) acc[i][j] = (f32x4){0.f,0.f,0.f,0.f};

  const unsigned short* fb = fp + (size_t)b*HWq*128;
  unsigned short* myrow = sA + (size_t)(w*64 + l)*128;

  for (int k = 0; k < 7; k++) {
    bool oob;
    const unsigned short *p0, *p1;
    float w0, w1;
    if (MORPH == 0) {
      int xi = c + k - 3;
      oob = (xi < 0 || xi >= Wq);
      if (!oob) {
        float y = (float)r + cum[((size_t)(b*7 + k))*HWq + p];
        float y0 = floorf(y);
        int y0q = (int)y0;
        int y0i = min(max(y0q, 0), Hq-1);
        int y1i = min(max(y0q + 1, 0), Hq-1);
        float y0f = fminf(fmaxf(y0, 0.f), (float)Hq);
        float y1f = fminf(fmaxf(y0 + 1.f, 0.f), (float)Hq);
        w0 = y1f - y; w1 = y - y0f;
        p0 = fb + ((size_t)y0i*Wq + xi)*8;
        p1 = fb + ((size_t)y1i*Wq + xi)*8;
      }
    } else {
      int yi = r + k - 3;
      oob = (yi < 0 || yi >= Hq);
      if (!oob) {
        float xf = (float)c + cum[((size_t)(b*7 + k))*HWq + p];
        float x0 = floorf(xf);
        int x0q = (int)x0;
        int x0i = min(max(x0q, 0), Wq-1);
        int x1i = min(max(x0q + 1, 0), Wq-1);
        float x0f = fminf(fmaxf(x0, 0.f), (float)Wq);
        float x1f = fminf(fmaxf(x0 + 1.f, 0.f), (float)Wq);
        w0 = x1f - xf; w1 = xf - x0f;
        p0 = fb + ((size_t)yi*Wq + x0i)*8;
        p1 = fb + ((size_t)yi*Wq + x1i)*8;
      }
    }
    if (oob) {
      uint4 z = {0u,0u,0u,0u};
#pragma unroll
      for (int j = 0; j < 16; j++) ((uint4*)myrow)[j] = z;
    } else {
#pragma unroll
      for (int g = 0; g < 8; g++) {
        f16x8 a0h = *(const f16x8*)(p0 + (size_t)g*HW8);
        f16x8 a0l = *(const f16x8*)(p0 + (size_t)(8 + g)*HW8);
        f16x8 a1h = *(const f16x8*)(p1 + (size_t)g*HW8);
        f16x8 a1l = *(const f16x8*)(p1 + (size_t)(8 + g)*HW8);
        f16x8 sh, sl;
#pragma unroll
        for (int e = 0; e < 8; e++) {
          float v = w0*((float)a0h[e] + (float)a0l[e]) + w1*((float)a1h[e] + (float)a1l[e]);
          _Float16 vh = (_Float16)v;
          sh[e] = vh;
          sl[e] = (_Float16)(v - (float)vh);
        }
        *(f16x8*)(myrow + (size_t)(g ^ l15)*8)       = sh;
        *(f16x8*)(myrow + (size_t)((8 + g) ^ l15)*8) = sl;
      }
    }
    __syncthreads();
#pragma unroll
    for (int kc = 0; kc < 2; kc++) {
      const unsigned short* wbase = wtp + (size_t)((k*2 + kc)*2)*2048;
      f16x8 bh[4], bl[4];
#pragma unroll
      for (int tb = 0; tb < 4; tb++) {
        bh[tb] = *(const f16x8*)(wbase + (tb*16 + l15)*32 + lg*8);
        bl[tb] = *(const f16x8*)(wbase + 2048 + (tb*16 + l15)*32 + lg*8);
      }
      f16x8 ah[4], al[4];
#pragma unroll
      for (int ta = 0; ta < 4; ta++) {
        const unsigned short* rbase = sA + (size_t)(w*64 + ta*16 + l15)*128;
        ah[ta] = *(const f16x8*)(rbase + (size_t)((kc*4 + lg) ^ l15)*8);
        al[ta] = *(const f16x8*)(rbase + (size_t)((8 + kc*4 + lg) ^ l15)*8);
      }
#pragma unroll
      for (int ta = 0; ta < 4; ta++)
#pragma unroll
        for (int tb = 0; tb < 4; tb++) {
          acc[ta][tb] = __builtin_amdgcn_mfma_f32_16x16x32_f16(ah[ta], bh[tb], acc[ta][tb], 0, 0, 0);
          acc[ta][tb] = __builtin_amdgcn_mfma_f32_16x16x32_f16(ah[ta], bl[tb], acc[ta][tb], 0, 0, 0);
          acc[ta][tb] = __builtin_amdgcn_mfma_f32_16x16x32_f16(al[ta], bh[tb], acc[ta][tb], 0, 0, 0);
        }
    }
    __syncthreads();
  }
  int pbase = blk*128 + w*64;
#pragma unroll
  for (int tb = 0; tb < 4; tb++) {
    int oc = tb*16 + l15;
    float bias = dsc_b[oc];
    float* dst = out + (size_t)(b*64 + oc)*HWq + pbase;
#pragma unroll
    for (int ta = 0; ta < 4; ta++) {
      f32x4 v = acc[ta][tb];
      *(float4*)(dst + ta*16 + lg*4) = make_float4(v[0]+bias, v[1]+bias, v[2]+bias, v[3]+bias);
    }
  }
}

// ---------------------------------------------------------------------------
// GroupNorm stats + finalize
// ---------------------------------------------------------------------------
__global__ __launch_bounds__(256) void gnstats_kernel(const float* __restrict__ h_ds,
                                                      const float* __restrict__ v_ds,
                                                      float* __restrict__ stats)
{
  int plane = blockIdx.x;
  int buf = plane >> 7;
  int rem = plane & 127;
  const float* src = (buf ? v_ds : h_ds) + (size_t)rem*HWq;
  float s = 0.f, s2 = 0.f;
  for (int i = threadIdx.x; i < HWq; i += 256) {
    float v = src[i];
    s += v; s2 += v*v;
  }
  __shared__ float red[2][4];
  for (int off = 32; off; off >>= 1) {
    s  += __shfl_down(s, off);
    s2 += __shfl_down(s2, off);
  }
  if ((threadIdx.x & 63) == 0) { red[0][threadIdx.x >> 6] = s; red[1][threadIdx.x >> 6] = s2; }
  __syncthreads();
  if (threadIdx.x == 0) {
    s  = red[0][0] + red[0][1] + red[0][2] + red[0][3];
    s2 = red[1][0] + red[1][1] + red[1][2] + red[1][3];
    stats[plane*2 + 0] = s;
    stats[plane*2 + 1] = s2;
  }
}

__global__ __launch_bounds__(256) void gnfinal_kernel(const float* __restrict__ stats,
                                                      const float* __restrict__ h_gn_g, const float* __restrict__ h_gn_b,
                                                      const float* __restrict__ v_gn_g, const float* __restrict__ v_gn_b,
                                                      float* __restrict__ gnAB)
{
  int t = threadIdx.x;
  int buf = t >> 7, ch = t & 63;
  int base = t & ~3;
  float sum = 0.f, ss = 0.f;
#pragma unroll
  for (int q = 0; q < 4; q++) { sum += stats[(base+q)*2]; ss += stats[(base+q)*2 + 1]; }
  const float n = 4.f * HWq;
  float mean = sum / n;
  float var = ss / n - mean*mean;
  float gg = (buf ? v_gn_g : h_gn_g)[ch];
  float bb = (buf ? v_gn_b : h_gn_b)[ch];
  float A = gg / sqrtf(var + 1e-5f);
  gnAB[t*2 + 0] = A;
  gnAB[t*2 + 1] = bb - mean*A;
}

// ---------------------------------------------------------------------------
// FUSED: comb = relu(GN(h)) + relu(GN(v)) + x1 inline, then 1x1 conv + SiLU
// ---------------------------------------------------------------------------
__global__ __launch_bounds__(256) void final2_kernel(const float* __restrict__ hbuf,
                                                     const float* __restrict__ vbuf,
                                                     const float* __restrict__ x1,
                                                     const float* __restrict__ gnAB,
                                                     const float* __restrict__ lwT,
                                                     const float* __restrict__ lbO,
                                                     float* __restrict__ out)
{
  int b = blockIdx.y;
  int p = blockIdx.x*256 + threadIdx.x;
  float acc[64];
#pragma unroll
  for (int o = 0; o < 64; o++) acc[o] = 0.f;
  for (int i = 0; i < 64; i++) {
    size_t off = (size_t)(b*64 + i)*HWq + p;
    int plane = b*64 + i;
    int ih = plane*2;
    int iv = (128 + plane)*2;
    float hv = fmaxf(hbuf[off]*gnAB[ih] + gnAB[ih+1], 0.f);
    float vv = fmaxf(vbuf[off]*gnAB[iv] + gnAB[iv+1], 0.f);
    float cv = hv + vv + x1[off];
    const float* wr = lwT + i*64;
#pragma unroll
    for (int o = 0; o < 64; o++) acc[o] += cv * wr[o];
  }
  float* dst = out + (size_t)b*Cq*HWq + p;
#pragma unroll
  for (int o = 0; o < 64; o++) {
    float yv = acc[o] + lbO[o];
    dst[(size_t)o*HWq] = yv / (1.f + expf(-yv));
  }
}

// ---------------------------------------------------------------------------
extern "C" void kernel_launch(void* const* d_in, const int* in_sizes, int n_in,
                              void* d_out, int out_size, void* d_ws, size_t ws_size,
                              hipStream_t stream)
{
  const float* x       = (const float*)d_in[0];
  const float* w_first = (const float*)d_in[1];
  float* ws = (float*)d_ws;

  float* bufA = ws;            // conv7 out -> h-einsum-out
  float* bufB = ws + Nq;       // v-einsum-out
  float* x1   = ws + 2*Nq;
  float* h_ds = ws + 3*Nq;     // xpack -> fpackH
  float* v_ds = ws + 4*Nq;     // fpackV
  size_t off = 5*Nq;
  float* hcum  = ws + off; off += (size_t)Bq*7*HWq;
  float* vcum  = ws + off; off += (size_t)Bq*7*HWq;
  float* wEffH = ws + off; off += 64*19;
  float* bEffH = ws + off; off += 64;
  float* wEffV = ws + off; off += 64*19;
  float* bEffV = ws + off; off += 64;
  float* wtH   = ws + off; off += 64*64*7;   // holds wtpH f16 pack
  float* wtV   = ws + off; off += 64*64*7;   // holds wtpV f16 pack
  float* wOffH = ws + off; off += 9*64*8;
  float* bOffH = ws + off; off += 8;
  float* wOffV = ws + off; off += 9*64*8;
  float* bOffV = ws + off; off += 8;
  float* lwT   = ws + off; off += 64*64;
  float* lbO   = ws + off; off += 64;
  float* stats = ws + off; off += 512;
  float* gnAB  = ws + off; off += 512;
  float* wB    = ws + off; off += 2*64*18*20;
  unsigned short* wpack = (unsigned short*)(ws + off); off += 2*49*2*64*32/2 + 16;
  unsigned short* xpack  = (unsigned short*)h_ds;
  unsigned short* fpackH = (unsigned short*)h_ds;
  unsigned short* fpackV = (unsigned short*)v_ds;
  unsigned short* wtpH = (unsigned short*)wtH;
  unsigned short* wtpV = (unsigned short*)wtV;

  prep_small_kernel<<<dim3(1), dim3(256), 0, stream>>>(
      (const float*)d_in[2],  (const float*)d_in[3],  (const float*)d_in[4],  (const float*)d_in[5],
      (const float*)d_in[6],  (const float*)d_in[7],
      (const float*)d_in[8],  (const float*)d_in[9],  (const float*)d_in[10], (const float*)d_in[11],
      (const float*)d_in[12], (const float*)d_in[13],
      (const float*)d_in[14], (const float*)d_in[15], (const float*)d_in[16], (const float*)d_in[17],
      (const float*)d_in[18], (const float*)d_in[19],
      (const float*)d_in[24], (const float*)d_in[25], (const float*)d_in[26], (const float*)d_in[27],
      (const float*)d_in[28], (const float*)d_in[29],
      (const float*)d_in[34], (const float*)d_in[35], (const float*)d_in[36], (const float*)d_in[37],
      (const float*)d_in[38],
      wEffH, bEffH, wEffV, bEffV, wOffH, bOffH, wOffV, bOffV, lwT, lbO);

  prep_border_kernel<<<dim3(9), dim3(256), 0, stream>>>(
      (const float*)d_in[2],  (const float*)d_in[3],  (const float*)d_in[4],  (const float*)d_in[5],
      (const float*)d_in[6],  (const float*)d_in[7],
      (const float*)d_in[8],  (const float*)d_in[9],  (const float*)d_in[10], (const float*)d_in[11],
      (const float*)d_in[12], (const float*)d_in[13], wB);

  prep_big_kernel<<<dim3(64), dim3(256), 0, stream>>>(
      w_first, (const float*)d_in[20], (const float*)d_in[30], wtpH, wtpV, wpack);

  tof16_pack_kernel<<<dim3(Hq, Bq), dim3(192), 0, stream>>>(x, xpack);
  conv7_mfma_kernel<<<dim3(4, 96, 2), dim3(256), 0, stream>>>(xpack, wpack, bufA);

  pool_fused_kernel<<<dim3(6, 128), dim3(256), 0, stream>>>(bufA, x1);

  dwf_h_kernel<<<dim3(144, 8, 2), dim3(256), 0, stream>>>(x1, wEffH, bEffH, wB, fpackH);
  dwf_v_kernel<<<dim3(144, 8, 2), dim3(256), 0, stream>>>(x1, wEffV, bEffV, wB + 64*18*20, fpackV);

  off_cum_kernel<<<dim3(144, 2), dim3(256), 0, stream>>>(fpackH, wOffH, bOffH, hcum);
  off_cum_kernel<<<dim3(144, 2), dim3(256), 0, stream>>>(fpackV, wOffV, bOffV, vcum);

  einsum_mfma_kernel<0><<<dim3(576), dim3(128), 0, stream>>>(fpackH, hcum, wtpH, (const float*)d_in[21], bufA);
  einsum_mfma_kernel<1><<<dim3(576), dim3(128), 0, stream>>>(fpackV, vcum, wtpV, (const float*)d_in[31], bufB);

  gnstats_kernel<<<dim3(256), dim3(256), 0, stream>>>(bufA, bufB, stats);
  gnfinal_kernel<<<dim3(1), dim3(256), 0, stream>>>(stats,
      (const float*)d_in[22], (const float*)d_in[23],
      (const float*)d_in[32], (const float*)d_in[33], gnAB);

  final2_kernel<<<dim3(144, 2), dim3(256), 0, stream>>>(bufA, bufB, x1, gnAB, lwT, lbO, (float*)d_out);
}

// Round 18
// 375.679 us; speedup vs baseline: 1.6581x; 1.1434x over previous
//
#include <hip/hip_runtime.h>
#include <hip/hip_bf16.h>
#include <hip/hip_fp16.h>
#include <math.h>

#define Bq 2
#define Cq 64
#define Hq 192
#define Wq 192
#define HWq (Hq*Wq)            // 36864
#define Nq ((size_t)Bq*Cq*HWq) // 4718592

typedef __attribute__((ext_vector_type(8))) _Float16 f16x8;
typedef __attribute__((ext_vector_type(4))) float f32x4;

__device__ inline unsigned short h2us(__half h) {
  union { __half h; unsigned short u; } v; v.h = h; return v.u;
}

// ---------------------------------------------------------------------------
// Small prep (1 block) — register-unrolled composition
// ---------------------------------------------------------------------------
__global__ __launch_bounds__(256) void prep_small_kernel(
    const float* hc1_w, const float* hc1_b, const float* hc2_w, const float* hc2_b,
    const float* hc3_w, const float* hc3_b,
    const float* vc1_w, const float* vc1_b, const float* vc2_w, const float* vc2_b,
    const float* vc3_w, const float* vc3_b,
    const float* h_off_w, const float* h_off_b, const float* h_bn_g, const float* h_bn_b,
    const float* h_bn_m, const float* h_bn_v,
    const float* v_off_w, const float* v_off_b, const float* v_bn_g, const float* v_bn_b,
    const float* v_bn_m, const float* v_bn_v,
    const float* last_w, const float* last_g, const float* last_b, const float* last_m,
    const float* last_v,
    float* wEffH, float* bEffH, float* wEffV, float* bEffV,
    float* wOffH, float* bOffH, float* wOffV, float* bOffV,
    float* lwT, float* lbO)
{
  int t = threadIdx.x;
  if (t < 128) {
    int ch = t & 63;
    bool ish = t < 64;
    const float* w1p = (ish ? hc1_w : vc1_w) + ch*9;
    const float* w2p = (ish ? hc2_w : vc2_w) + ch*7;
    const float* w3p = (ish ? hc3_w : vc3_w) + ch*5;
    float w1r[9], w2r[7], w3r[5];
#pragma unroll
    for (int j = 0; j < 9; j++) w1r[j] = w1p[j];
#pragma unroll
    for (int k = 0; k < 7; k++) w2r[k] = w2p[k];
#pragma unroll
    for (int m = 0; m < 5; m++) w3r[m] = w3p[m];
    float t15[15];
#pragma unroll
    for (int s = 0; s < 15; s++) {
      float a = 0.f;
#pragma unroll
      for (int j = 0; j < 9; j++) { int k2 = s - j; if (k2 >= 0 && k2 < 7) a += w1r[j]*w2r[k2]; }
      t15[s] = a;
    }
    float* we = (ish ? wEffH : wEffV) + ch*19;
#pragma unroll
    for (int s = 0; s < 19; s++) {
      float a = 0.f;
#pragma unroll
      for (int j = 0; j < 15; j++) { int k3 = s - j; if (k3 >= 0 && k3 < 5) a += t15[j]*w3r[k3]; }
      we[s] = a;
    }
    float S2 = 0.f, S3 = 0.f;
#pragma unroll
    for (int j = 0; j < 7; j++) S2 += w2r[j];
#pragma unroll
    for (int j = 0; j < 5; j++) S3 += w3r[j];
    float b1 = (ish ? hc1_b : vc1_b)[ch];
    float b2 = (ish ? hc2_b : vc2_b)[ch];
    float b3 = (ish ? hc3_b : vc3_b)[ch];
    (ish ? bEffH : bEffV)[ch] = b1*S2*S3 + b2*S3 + b3;
  }
  for (int idx = t; idx < 9*64*7; idx += 256) {
    int tap = idx / 448; int rem = idx % 448; int i = rem / 7; int m = rem % 7;
    float invh = h_bn_g[m] / sqrtf(h_bn_v[m] + 1e-5f);
    wOffH[(tap*64 + i)*8 + m] = h_off_w[(m*64 + i)*9 + tap] * invh;
    float invv = v_bn_g[7+m] / sqrtf(v_bn_v[7+m] + 1e-5f);
    wOffV[(tap*64 + i)*8 + m] = v_off_w[((7+m)*64 + i)*9 + tap] * invv;
  }
  if (t < 7) {
    float invh = h_bn_g[t] / sqrtf(h_bn_v[t] + 1e-5f);
    bOffH[t] = h_off_b[t]*invh + h_bn_b[t] - h_bn_m[t]*invh;
    float invv = v_bn_g[7+t] / sqrtf(v_bn_v[7+t] + 1e-5f);
    bOffV[t] = v_off_b[7+t]*invv + v_bn_b[7+t] - v_bn_m[7+t]*invv;
  }
  for (int idx = t; idx < 4096; idx += 256) {
    int o = idx % 64; int i = idx / 64;
    float inv = last_g[o] / sqrtf(last_v[o] + 1e-3f);
    lwT[i*64 + o] = last_w[o*64 + i] * inv;
  }
  if (t < 64) {
    float inv = last_g[t] / sqrtf(last_v[t] + 1e-3f);
    lbO[t] = last_b[t] - last_m[t]*inv;
  }
}

// ---------------------------------------------------------------------------
// Border prep — fully unrolled, registers only
// ---------------------------------------------------------------------------
__global__ __launch_bounds__(256) void prep_border_kernel(
    const float* hc1_w, const float* hc1_b, const float* hc2_w, const float* hc2_b,
    const float* hc3_w, const float* hc3_b,
    const float* vc1_w, const float* vc1_b, const float* vc2_w, const float* vc2_b,
    const float* vc3_w, const float* vc3_b,
    float* wB)
{
  int tid = blockIdx.x*256 + threadIdx.x;
  if (tid >= 2*64*18) return;
  int cls = tid % 18;
  int ch  = (tid / 18) % 64;
  int br  = tid / (18*64);
  int c = (cls < 9) ? cls : cls + 174;
  const float* w1p = (br==0 ? hc1_w : vc1_w) + ch*9;
  const float* w2p = (br==0 ? hc2_w : vc2_w) + ch*7;
  const float* w3p = (br==0 ? hc3_w : vc3_w) + ch*5;
  float b1 = (br==0 ? hc1_b : vc1_b)[ch];
  float b2 = (br==0 ? hc2_b : vc2_b)[ch];
  float b3 = (br==0 ? hc3_b : vc3_b)[ch];
  float w1r[9], w2r[7], w3r[5];
#pragma unroll
  for (int j = 0; j < 9; j++) w1r[j] = w1p[j];
#pragma unroll
  for (int k = 0; k < 7; k++) w2r[k] = w2p[k];
#pragma unroll
  for (int m = 0; m < 5; m++) w3r[m] = w3p[m];

  float acc[19];
#pragma unroll
  for (int s = 0; s < 19; s++) acc[s] = 0.f;
  float bacc = b3;
#pragma unroll
  for (int m = 0; m < 5; m++) {
    int d = c + m - 2;
    bool dok = (d >= 0 && d < Wq);
    float s2b = b2;
#pragma unroll
    for (int k = 0; k < 7; k++) {
      int e = d + k - 3;
      bool eok = (e >= 0 && e < Wq);
      if (eok) s2b += w2r[k] * b1;
      float wmk = w3r[m] * w2r[k];
#pragma unroll
      for (int j = 0; j < 9; j++) {
        int fd = e + j - 4;
        bool fok = (fd >= 0 && fd < Wq);
        float contrib = (dok && eok && fok) ? wmk * w1r[j] : 0.f;
        acc[m + k + j] += contrib;
      }
    }
    if (dok) bacc += w3r[m] * s2b;
  }
  float* dst = wB + ((size_t)(br*64 + ch)*18 + cls)*20;
#pragma unroll
  for (int s = 0; s < 19; s++) dst[s] = acc[s];
  dst[19] = bacc;
}

// ---------------------------------------------------------------------------
// Big prep: dsc weights -> f16 hi/lo MFMA pack [tap][kc][hl][oc][32]
//           + w_first f16 hi/lo pack for conv7 [h][tap][hl][oc][32].
// ---------------------------------------------------------------------------
__global__ __launch_bounds__(256) void prep_big_kernel(
    const float* __restrict__ w_first,
    const float* __restrict__ h_dsc_w, const float* __restrict__ v_dsc_w,
    unsigned short* __restrict__ wtpH, unsigned short* __restrict__ wtpV,
    unsigned short* __restrict__ wpack)
{
  int tid = blockIdx.x*256 + threadIdx.x;
  int nthr = gridDim.x*256;
  for (int idx = tid; idx < 7*2*2*64*32; idx += nthr) {
    int ch32 = idx & 31;
    int oc   = (idx >> 5) & 63;
    int hl   = (idx >> 11) & 1;
    int kc   = (idx >> 12) & 1;
    int tap  = idx >> 13;
    int i = kc*32 + ch32;
    float vh = h_dsc_w[oc*448 + i*7 + tap];
    float vv = v_dsc_w[oc*448 + i*7 + tap];
    _Float16 hh = (_Float16)vh;
    _Float16 hv = (_Float16)vv;
    unsigned short uh, uv;
    if (!hl) { uh = *(unsigned short*)&hh; uv = *(unsigned short*)&hv; }
    else {
      _Float16 lh = (_Float16)(vh - (float)hh);
      _Float16 lv = (_Float16)(vv - (float)hv);
      uh = *(unsigned short*)&lh; uv = *(unsigned short*)&lv;
    }
    wtpH[idx] = uh; wtpV[idx] = uv;
  }
  for (int e = tid; e < 2*49*2*64*32; e += nthr) {
    int ch  = e & 31;
    int oc  = (e >> 5) & 63;
    int hl  = (e >> 11) & 1;
    int rest = e >> 12;
    int tap = rest % 49;
    int h   = rest / 49;
    float wv = w_first[((size_t)oc*64 + h*32 + ch)*49 + tap];
    __half hh = __float2half(wv);
    unsigned short us;
    if (!hl) us = h2us(hh);
    else { float rr = wv - __half2float(hh); us = h2us(__float2half(rr)); }
    wpack[e] = us;
  }
}

// ---------------------------------------------------------------------------
// x (NCHW f32) -> xpack single f16: [b][r][c][64]
// ---------------------------------------------------------------------------
__global__ __launch_bounds__(192) void tof16_pack_kernel(const float* __restrict__ x,
                                                         unsigned short* __restrict__ xpack)
{
  __shared__ unsigned int s[192*64];
  int r = blockIdx.x, b = blockIdx.y;
  int t = threadIdx.x;
  for (int ch = 0; ch < 64; ch++) {
    float v = x[((size_t)(b*64+ch)*Hq + r)*Wq + t];
    _Float16 hh = (_Float16)v;
    s[t*64 + (ch ^ (t & 31))] = (unsigned int)*(unsigned short*)&hh;
  }
  __syncthreads();
  unsigned short* dst = xpack + ((size_t)b*Hq + r)*Wq*64;
  for (int i = 0; i < 8; i++) {
    int gidx = i*192 + t;
    int c = gidx >> 3, g = gidx & 7;
    unsigned short tmp[8];
#pragma unroll
    for (int j = 0; j < 8; j++) {
      int ch = g*8 + j;
      tmp[j] = (unsigned short)s[c*64 + (ch ^ (c & 31))];
    }
    uint4 v;
    v.x = (unsigned int)tmp[0] | ((unsigned int)tmp[1] << 16);
    v.y = (unsigned int)tmp[2] | ((unsigned int)tmp[3] << 16);
    v.z = (unsigned int)tmp[4] | ((unsigned int)tmp[5] << 16);
    v.w = (unsigned int)tmp[6] | ((unsigned int)tmp[7] << 16);
    *(uint4*)(dst + (size_t)gidx*8) = v;
  }
}

// ---------------------------------------------------------------------------
// 7x7 conv via MFMA, 2-pass (x single f16, w hi/lo exact) — R17 validated.
// 4 waves by oc-quarter, 12 waves/CU.
// ---------------------------------------------------------------------------
__global__ __launch_bounds__(256) void conv7_mfma_kernel(
    const unsigned short* __restrict__ xpack,   // [b][r][c][64] f16
    const unsigned short* __restrict__ wpack,   // [h][tap][hl][oc][32] f16
    float* __restrict__ out)
{
  __shared__ __align__(16) unsigned short sA[8*54*32];   // 27648 B
  int ct = blockIdx.x;          // 0..3
  int rt = blockIdx.y;          // 0..95
  int b  = blockIdx.z;
  int r0 = rt*2, c0 = ct*48;
  int t = threadIdx.x;
  int wv = t >> 6;              // wave -> oc quarter
  int l  = t & 63;
  int l15 = l & 15, lg = l >> 4;
  int oc = wv*16 + l15;

  f32x4 acc[2][3];
#pragma unroll
  for (int i = 0; i < 2; i++)
#pragma unroll
    for (int j = 0; j < 3; j++) acc[i][j] = (f32x4){0.f,0.f,0.f,0.f};

  for (int h = 0; h < 2; h++) {
    __syncthreads();
    for (int idx = t; idx < 8*54*4; idx += 256) {
      int g = idx & 3, pix = idx >> 2;
      int row = pix / 54, col = pix % 54;
      int gr = r0 - 3 + row, gc = c0 - 3 + col;
      uint4 v = {0u,0u,0u,0u};
      if (gr >= 0 && gr < Hq && gc >= 0 && gc < Wq)
        v = *(const uint4*)(xpack + (((size_t)b*Hq + gr)*Wq + gc)*64 + (h*4 + g)*8);
      ((uint4*)sA)[(row*54 + col)*4 + (g ^ ((col >> 1) & 3))] = v;
    }
    __syncthreads();
    const unsigned short* wb = wpack + (size_t)h*49*4096;
#pragma unroll 7
    for (int tap = 0; tap < 49; tap++) {
      int dy = tap / 7, dx = tap % 7;
      f16x8 bh = *(const f16x8*)(wb + (size_t)tap*4096 +        oc*32 + lg*8);
      f16x8 bl = *(const f16x8*)(wb + (size_t)tap*4096 + 2048 + oc*32 + lg*8);
#pragma unroll
      for (int rw = 0; rw < 2; rw++) {
        int arow = rw + dy;
        f16x8 a[3];
#pragma unroll
        for (int tc = 0; tc < 3; tc++) {
          int col = tc*16 + l15 + dx;
          a[tc] = *(const f16x8*)((const uint4*)sA + (arow*54 + col)*4 + (lg ^ ((col >> 1) & 3)));
        }
#pragma unroll
        for (int tc = 0; tc < 3; tc++) {
          acc[rw][tc] = __builtin_amdgcn_mfma_f32_16x16x32_f16(a[tc], bh, acc[rw][tc], 0, 0, 0);
          acc[rw][tc] = __builtin_amdgcn_mfma_f32_16x16x32_f16(a[tc], bl, acc[rw][tc], 0, 0, 0);
        }
      }
    }
  }
#pragma unroll
  for (int rw = 0; rw < 2; rw++) {
    float* dst = out + ((size_t)(b*64 + oc)*Hq + (r0 + rw))*Wq + c0;
#pragma unroll
    for (int tc = 0; tc < 3; tc++) {
      f32x4 v = acc[rw][tc];
      *(float4*)(dst + tc*16 + lg*4) = make_float4(v[0], v[1], v[2], v[3]);
    }
  }
}

// ---------------------------------------------------------------------------
// FUSED separable 7x7 avg pool: one kernel, LDS-staged.
// ---------------------------------------------------------------------------
__global__ __launch_bounds__(256) void pool_fused_kernel(const float* __restrict__ in,
                                                         float* __restrict__ out)
{
  __shared__ float raw[38][192];
  __shared__ float cs[32][192];
  int rt = blockIdx.x;
  int plane = blockIdx.y;
  int r0 = rt*32;
  int t = threadIdx.x;
  const float* src = in + (size_t)plane*HWq;
  for (int idx = t; idx < 38*192; idx += 256) {
    int lr = idx / 192, c = idx % 192;
    int gr = r0 - 3 + lr;
    raw[lr][c] = (gr >= 0 && gr < Hq) ? src[gr*Wq + c] : 0.f;
  }
  __syncthreads();
  for (int idx = t; idx < 32*192; idx += 256) {
    int lr = idx / 192, c = idx % 192;
    float s = 0.f;
#pragma unroll
    for (int dr = 0; dr < 7; dr++) s += raw[lr + dr][c];
    cs[lr][c] = s;
  }
  __syncthreads();
  float* dst = out + (size_t)plane*HWq + r0*Wq;
  for (int idx = t; idx < 32*192; idx += 256) {
    int lr = idx / 192, c = idx % 192;
    float s = 0.f;
#pragma unroll
    for (int dc = -3; dc <= 3; dc++) {
      int cc = c + dc;
      if (cc >= 0 && cc < Wq) s += cs[lr][cc];
    }
    dst[idx] = s * (1.f/49.f);
  }
}

// ---------------------------------------------------------------------------
// MERGED fused depthwise 19-tap + f16 hi/lo plane-major pack.
// Grid (144, 8, 4): z = branch*2 + b.
// ---------------------------------------------------------------------------
__global__ __launch_bounds__(256) void dwf_kernel(const float* __restrict__ x1,
                                                  const float* __restrict__ wEffH,
                                                  const float* __restrict__ bEffH,
                                                  const float* __restrict__ wBH,
                                                  const float* __restrict__ wEffV,
                                                  const float* __restrict__ bEffV,
                                                  const float* __restrict__ wBV,
                                                  unsigned short* __restrict__ packH,
                                                  unsigned short* __restrict__ packV)
{
  __shared__ float sW[8][19][20];
  int z = blockIdx.z;
  int br = z >> 1, b = z & 1;
  const float* wEff = br ? wEffV : wEffH;
  const float* bEff = br ? bEffV : bEffH;
  const float* wB   = br ? wBV   : wBH;
  unsigned short* pack = br ? packV : packH;
  int g8 = blockIdx.y;
  int t = threadIdx.x;
  int chb = g8*8;
  for (int i = t; i < 8*380; i += 256) {
    int ch8 = i / 380; int rem = i % 380;
    int row = rem / 20, jj = rem % 20;
    int ch = chb + ch8;
    float v;
    if (row < 18) v = wB[((size_t)ch*18 + row)*20 + jj];
    else v = (jj < 19) ? wEff[ch*19 + jj] : bEff[ch];
    sW[ch8][row][jj] = v;
  }
  __syncthreads();
  int p = blockIdx.x*256 + t;
  int r = p / Wq, c = p % Wq;
  float vals[8];
  if (br == 0) {
    int row = (c < 9) ? c : ((c >= Wq-9) ? (c - 174) : 18);
#pragma unroll
    for (int ch8 = 0; ch8 < 8; ch8++) {
      const float* src = x1 + (size_t)(b*Cq + chb + ch8)*HWq + r*Wq;
      float s = sW[ch8][row][19];
#pragma unroll
      for (int j = 0; j < 19; j++) {
        int idx = min(max(c + j - 9, 0), Wq-1);
        s += src[idx] * sW[ch8][row][j];
      }
      vals[ch8] = s;
    }
  } else {
    int row = (r < 9) ? r : ((r >= Hq-9) ? (r - 174) : 18);
#pragma unroll
    for (int ch8 = 0; ch8 < 8; ch8++) {
      const float* src = x1 + (size_t)(b*Cq + chb + ch8)*HWq + c;
      float s = sW[ch8][row][19];
#pragma unroll
      for (int j = 0; j < 19; j++) {
        int idx = min(max(r + j - 9, 0), Hq-1);
        s += src[idx*Wq] * sW[ch8][row][j];
      }
      vals[ch8] = s;
    }
  }
  unsigned int hi[4], lo[4];
#pragma unroll
  for (int q = 0; q < 4; q++) {
    __half h0 = __float2half(vals[2*q]);
    __half h1 = __float2half(vals[2*q+1]);
    __half l0 = __float2half(vals[2*q]   - __half2float(h0));
    __half l1 = __float2half(vals[2*q+1] - __half2float(h1));
    hi[q] = (unsigned int)h2us(h0) | ((unsigned int)h2us(h1) << 16);
    lo[q] = (unsigned int)h2us(l0) | ((unsigned int)h2us(l1) << 16);
  }
  *(uint4*)(pack + (((size_t)b*16 + g8)*HWq + p)*8)     = make_uint4(hi[0], hi[1], hi[2], hi[3]);
  *(uint4*)(pack + (((size_t)b*16 + 8 + g8)*HWq + p)*8) = make_uint4(lo[0], lo[1], lo[2], lo[3]);
}

// ---------------------------------------------------------------------------
// MERGED offset conv + tanh + cum. Grid (144, 2, 2): z = branch.
// ---------------------------------------------------------------------------
__global__ __launch_bounds__(256) void off_cum_kernel(const unsigned short* __restrict__ fpH,
                                                      const unsigned short* __restrict__ fpV,
                                                      const float* __restrict__ wOffH,
                                                      const float* __restrict__ bOffH,
                                                      const float* __restrict__ wOffV,
                                                      const float* __restrict__ bOffV,
                                                      float* __restrict__ hcum,
                                                      float* __restrict__ vcum)
{
  const size_t HW8 = (size_t)HWq*8;
  int br = blockIdx.z;
  const unsigned short* fp = br ? fpV : fpH;
  const float* wOff = br ? wOffV : wOffH;
  const float* bOff = br ? bOffV : bOffH;
  float* cum = br ? vcum : hcum;
  int b = blockIdx.y;
  int p = blockIdx.x*256 + threadIdx.x;
  int r = p / Wq, c = p % Wq;
  float tv[7];
#pragma unroll
  for (int m = 0; m < 7; m++) tv[m] = bOff[m];
  const unsigned short* fb = fp + (size_t)b*HWq*128;
  for (int tap = 0; tap < 9; tap++) {
    int dy = tap/3 - 1, dx = tap%3 - 1;
    int rr = r + dy, cc = c + dx;
    if (rr < 0 || rr >= Hq || cc < 0 || cc >= Wq) continue;
    const unsigned short* p0 = fb + ((size_t)rr*Wq + cc)*8;
    const float* wp = wOff + tap*512;
    for (int g = 0; g < 8; g++) {
      f16x8 hv = *(const f16x8*)(p0 + (size_t)g*HW8);
      f16x8 lv = *(const f16x8*)(p0 + (size_t)(8 + g)*HW8);
#pragma unroll
      for (int e = 0; e < 8; e++) {
        float fv = (float)hv[e] + (float)lv[e];
        const float* wr = wp + (g*8 + e)*8;
#pragma unroll
        for (int m = 0; m < 7; m++) tv[m] += fv * wr[m];
      }
    }
  }
#pragma unroll
  for (int m = 0; m < 7; m++) tv[m] = tanhf(tv[m]);
  float c0 = tv[0], c1 = tv[1] + tv[2], c2 = tv[2], c3 = 0.f;
  float c4 = tv[4], c5 = tv[4] + tv[5], c6 = tv[6];
  size_t bb = (size_t)b*7*HWq + p;
  cum[bb + 0*HWq] = c0; cum[bb + 1*HWq] = c1; cum[bb + 2*HWq] = c2;
  cum[bb + 3*HWq] = c3; cum[bb + 4*HWq] = c4; cum[bb + 5*HWq] = c5;
  cum[bb + 6*HWq] = c6;
}

// ---------------------------------------------------------------------------
// MERGED deformable sample + einsum via MFMA (f16 hi/lo 3-pass).
// Grid (576, 2): y = morph. XCD-banded swizzle per morph slice.
// ---------------------------------------------------------------------------
__global__ __launch_bounds__(128) void einsum_mfma_kernel(
    const unsigned short* __restrict__ fpH, const unsigned short* __restrict__ fpV,
    const float* __restrict__ cumH, const float* __restrict__ cumV,
    const unsigned short* __restrict__ wtpHp, const unsigned short* __restrict__ wtpVp,
    const float* __restrict__ dscbH, const float* __restrict__ dscbV,
    float* __restrict__ outH, float* __restrict__ outV)
{
  __shared__ __align__(16) unsigned short sA[2*64*128];  // 32 KB
  const size_t HW8 = (size_t)HWq*8;
  int morph = blockIdx.y;
  const unsigned short* fp  = morph ? fpV   : fpH;
  const float* cum          = morph ? cumV  : cumH;
  const unsigned short* wtp = morph ? wtpVp : wtpHp;
  const float* dsc_b        = morph ? dscbV : dscbH;
  float* out                = morph ? outV  : outH;
  int bid = blockIdx.x;
  int swz = (bid & 7)*72 + (bid >> 3);
  int b   = swz / 288;
  int blk = swz % 288;
  int t = threadIdx.x;
  int w = t >> 6, l = t & 63;
  int l15 = l & 15, lg = l >> 4;
  int p = blk*128 + w*64 + l;
  int r = p / Wq, c = p % Wq;

  f32x4 acc[4][4];
#pragma unroll
  for (int i = 0; i < 4; i++)
#pragma unroll
    for (int j = 0; j < 4; j++) acc[i][j] = (f32x4){0.f,0.f,0.f,0.f};

  const unsigned short* fb = fp + (size_t)b*HWq*128;
  unsigned short* myrow = sA + (size_t)(w*64 + l)*128;

  for (int k = 0; k < 7; k++) {
    bool oob;
    const unsigned short *p0, *p1;
    float w0, w1;
    if (morph == 0) {
      int xi = c + k - 3;
      oob = (xi < 0 || xi >= Wq);
      if (!oob) {
        float y = (float)r + cum[((size_t)(b*7 + k))*HWq + p];
        float y0 = floorf(y);
        int y0q = (int)y0;
        int y0i = min(max(y0q, 0), Hq-1);
        int y1i = min(max(y0q + 1, 0), Hq-1);
        float y0f = fminf(fmaxf(y0, 0.f), (float)Hq);
        float y1f = fminf(fmaxf(y0 + 1.f, 0.f), (float)Hq);
        w0 = y1f - y; w1 = y - y0f;
        p0 = fb + ((size_t)y0i*Wq + xi)*8;
        p1 = fb + ((size_t)y1i*Wq + xi)*8;
      }
    } else {
      int yi = r + k - 3;
      oob = (yi < 0 || yi >= Hq);
      if (!oob) {
        float xf = (float)c + cum[((size_t)(b*7 + k))*HWq + p];
        float x0 = floorf(xf);
        int x0q = (int)x0;
        int x0i = min(max(x0q, 0), Wq-1);
        int x1i = min(max(x0q + 1, 0), Wq-1);
        float x0f = fminf(fmaxf(x0, 0.f), (float)Wq);
        float x1f = fminf(fmaxf(x0 + 1.f, 0.f), (float)Wq);
        w0 = x1f - xf; w1 = xf - x0f;
        p0 = fb + ((size_t)yi*Wq + x0i)*8;
        p1 = fb + ((size_t)yi*Wq + x1i)*8;
      }
    }
    if (oob) {
      uint4 z = {0u,0u,0u,0u};
#pragma unroll
      for (int j = 0; j < 16; j++) ((uint4*)myrow)[j] = z;
    } else {
#pragma unroll
      for (int g = 0; g < 8; g++) {
        f16x8 a0h = *(const f16x8*)(p0 + (size_t)g*HW8);
        f16x8 a0l = *(const f16x8*)(p0 + (size_t)(8 + g)*HW8);
        f16x8 a1h = *(const f16x8*)(p1 + (size_t)g*HW8);
        f16x8 a1l = *(const f16x8*)(p1 + (size_t)(8 + g)*HW8);
        f16x8 sh, sl;
#pragma unroll
        for (int e = 0; e < 8; e++) {
          float v = w0*((float)a0h[e] + (float)a0l[e]) + w1*((float)a1h[e] + (float)a1l[e]);
          _Float16 vh = (_Float16)v;
          sh[e] = vh;
          sl[e] = (_Float16)(v - (float)vh);
        }
        *(f16x8*)(myrow + (size_t)(g ^ l15)*8)       = sh;
        *(f16x8*)(myrow + (size_t)((8 + g) ^ l15)*8) = sl;
      }
    }
    __syncthreads();
#pragma unroll
    for (int kc = 0; kc < 2; kc++) {
      const unsigned short* wbase = wtp + (size_t)((k*2 + kc)*2)*2048;
      f16x8 bh[4], bl[4];
#pragma unroll
      for (int tb = 0; tb < 4; tb++) {
        bh[tb] = *(const f16x8*)(wbase + (tb*16 + l15)*32 + lg*8);
        bl[tb] = *(const f16x8*)(wbase + 2048 + (tb*16 + l15)*32 + lg*8);
      }
      f16x8 ah[4], al[4];
#pragma unroll
      for (int ta = 0; ta < 4; ta++) {
        const unsigned short* rbase = sA + (size_t)(w*64 + ta*16 + l15)*128;
        ah[ta] = *(const f16x8*)(rbase + (size_t)((kc*4 + lg) ^ l15)*8);
        al[ta] = *(const f16x8*)(rbase + (size_t)((8 + kc*4 + lg) ^ l15)*8);
      }
#pragma unroll
      for (int ta = 0; ta < 4; ta++)
#pragma unroll
        for (int tb = 0; tb < 4; tb++) {
          acc[ta][tb] = __builtin_amdgcn_mfma_f32_16x16x32_f16(ah[ta], bh[tb], acc[ta][tb], 0, 0, 0);
          acc[ta][tb] = __builtin_amdgcn_mfma_f32_16x16x32_f16(ah[ta], bl[tb], acc[ta][tb], 0, 0, 0);
          acc[ta][tb] = __builtin_amdgcn_mfma_f32_16x16x32_f16(al[ta], bh[tb], acc[ta][tb], 0, 0, 0);
        }
    }
    __syncthreads();
  }
  int pbase = blk*128 + w*64;
#pragma unroll
  for (int tb = 0; tb < 4; tb++) {
    int oc = tb*16 + l15;
    float bias = dsc_b[oc];
    float* dst = out + (size_t)(b*64 + oc)*HWq + pbase;
#pragma unroll
    for (int ta = 0; ta < 4; ta++) {
      f32x4 v = acc[ta][tb];
      *(float4*)(dst + ta*16 + lg*4) = make_float4(v[0]+bias, v[1]+bias, v[2]+bias, v[3]+bias);
    }
  }
}

// ---------------------------------------------------------------------------
// GroupNorm stats + finalize
// ---------------------------------------------------------------------------
__global__ __launch_bounds__(256) void gnstats_kernel(const float* __restrict__ h_ds,
                                                      const float* __restrict__ v_ds,
                                                      float* __restrict__ stats)
{
  int plane = blockIdx.x;
  int buf = plane >> 7;
  int rem = plane & 127;
  const float* src = (buf ? v_ds : h_ds) + (size_t)rem*HWq;
  float s = 0.f, s2 = 0.f;
  for (int i = threadIdx.x; i < HWq; i += 256) {
    float v = src[i];
    s += v; s2 += v*v;
  }
  __shared__ float red[2][4];
  for (int off = 32; off; off >>= 1) {
    s  += __shfl_down(s, off);
    s2 += __shfl_down(s2, off);
  }
  if ((threadIdx.x & 63) == 0) { red[0][threadIdx.x >> 6] = s; red[1][threadIdx.x >> 6] = s2; }
  __syncthreads();
  if (threadIdx.x == 0) {
    s  = red[0][0] + red[0][1] + red[0][2] + red[0][3];
    s2 = red[1][0] + red[1][1] + red[1][2] + red[1][3];
    stats[plane*2 + 0] = s;
    stats[plane*2 + 1] = s2;
  }
}

__global__ __launch_bounds__(256) void gnfinal_kernel(const float* __restrict__ stats,
                                                      const float* __restrict__ h_gn_g, const float* __restrict__ h_gn_b,
                                                      const float* __restrict__ v_gn_g, const float* __restrict__ v_gn_b,
                                                      float* __restrict__ gnAB)
{
  int t = threadIdx.x;
  int buf = t >> 7, ch = t & 63;
  int base = t & ~3;
  float sum = 0.f, ss = 0.f;
#pragma unroll
  for (int q = 0; q < 4; q++) { sum += stats[(base+q)*2]; ss += stats[(base+q)*2 + 1]; }
  const float n = 4.f * HWq;
  float mean = sum / n;
  float var = ss / n - mean*mean;
  float gg = (buf ? v_gn_g : h_gn_g)[ch];
  float bb = (buf ? v_gn_b : h_gn_b)[ch];
  float A = gg / sqrtf(var + 1e-5f);
  gnAB[t*2 + 0] = A;
  gnAB[t*2 + 1] = bb - mean*A;
}

// ---------------------------------------------------------------------------
// FUSED: comb = relu(GN(h)) + relu(GN(v)) + x1 inline, then 1x1 conv + SiLU
// ---------------------------------------------------------------------------
__global__ __launch_bounds__(256) void final2_kernel(const float* __restrict__ hbuf,
                                                     const float* __restrict__ vbuf,
                                                     const float* __restrict__ x1,
                                                     const float* __restrict__ gnAB,
                                                     const float* __restrict__ lwT,
                                                     const float* __restrict__ lbO,
                                                     float* __restrict__ out)
{
  int b = blockIdx.y;
  int p = blockIdx.x*256 + threadIdx.x;
  float acc[64];
#pragma unroll
  for (int o = 0; o < 64; o++) acc[o] = 0.f;
  for (int i = 0; i < 64; i++) {
    size_t off = (size_t)(b*64 + i)*HWq + p;
    int plane = b*64 + i;
    int ih = plane*2;
    int iv = (128 + plane)*2;
    float hv = fmaxf(hbuf[off]*gnAB[ih] + gnAB[ih+1], 0.f);
    float vv = fmaxf(vbuf[off]*gnAB[iv] + gnAB[iv+1], 0.f);
    float cv = hv + vv + x1[off];
    const float* wr = lwT + i*64;
#pragma unroll
    for (int o = 0; o < 64; o++) acc[o] += cv * wr[o];
  }
  float* dst = out + (size_t)b*Cq*HWq + p;
#pragma unroll
  for (int o = 0; o < 64; o++) {
    float yv = acc[o] + lbO[o];
    dst[(size_t)o*HWq] = yv / (1.f + expf(-yv));
  }
}

// ---------------------------------------------------------------------------
extern "C" void kernel_launch(void* const* d_in, const int* in_sizes, int n_in,
                              void* d_out, int out_size, void* d_ws, size_t ws_size,
                              hipStream_t stream)
{
  const float* x       = (const float*)d_in[0];
  const float* w_first = (const float*)d_in[1];
  float* ws = (float*)d_ws;

  float* bufA = ws;            // conv7 out -> h-einsum-out
  float* bufB = ws + Nq;       // v-einsum-out
  float* x1   = ws + 2*Nq;
  float* h_ds = ws + 3*Nq;     // xpack -> fpackH
  float* v_ds = ws + 4*Nq;     // fpackV
  size_t off = 5*Nq;
  float* hcum  = ws + off; off += (size_t)Bq*7*HWq;
  float* vcum  = ws + off; off += (size_t)Bq*7*HWq;
  float* wEffH = ws + off; off += 64*19;
  float* bEffH = ws + off; off += 64;
  float* wEffV = ws + off; off += 64*19;
  float* bEffV = ws + off; off += 64;
  float* wtH   = ws + off; off += 64*64*7;   // holds wtpH f16 pack
  float* wtV   = ws + off; off += 64*64*7;   // holds wtpV f16 pack
  float* wOffH = ws + off; off += 9*64*8;
  float* bOffH = ws + off; off += 8;
  float* wOffV = ws + off; off += 9*64*8;
  float* bOffV = ws + off; off += 8;
  float* lwT   = ws + off; off += 64*64;
  float* lbO   = ws + off; off += 64;
  float* stats = ws + off; off += 512;
  float* gnAB  = ws + off; off += 512;
  float* wB    = ws + off; off += 2*64*18*20;
  unsigned short* wpack = (unsigned short*)(ws + off); off += 2*49*2*64*32/2 + 16;
  unsigned short* xpack  = (unsigned short*)h_ds;
  unsigned short* fpackH = (unsigned short*)h_ds;
  unsigned short* fpackV = (unsigned short*)v_ds;
  unsigned short* wtpH = (unsigned short*)wtH;
  unsigned short* wtpV = (unsigned short*)wtV;

  prep_small_kernel<<<dim3(1), dim3(256), 0, stream>>>(
      (const float*)d_in[2],  (const float*)d_in[3],  (const float*)d_in[4],  (const float*)d_in[5],
      (const float*)d_in[6],  (const float*)d_in[7],
      (const float*)d_in[8],  (const float*)d_in[9],  (const float*)d_in[10], (const float*)d_in[11],
      (const float*)d_in[12], (const float*)d_in[13],
      (const float*)d_in[14], (const float*)d_in[15], (const float*)d_in[16], (const float*)d_in[17],
      (const float*)d_in[18], (const float*)d_in[19],
      (const float*)d_in[24], (const float*)d_in[25], (const float*)d_in[26], (const float*)d_in[27],
      (const float*)d_in[28], (const float*)d_in[29],
      (const float*)d_in[34], (const float*)d_in[35], (const float*)d_in[36], (const float*)d_in[37],
      (const float*)d_in[38],
      wEffH, bEffH, wEffV, bEffV, wOffH, bOffH, wOffV, bOffV, lwT, lbO);

  prep_border_kernel<<<dim3(9), dim3(256), 0, stream>>>(
      (const float*)d_in[2],  (const float*)d_in[3],  (const float*)d_in[4],  (const float*)d_in[5],
      (const float*)d_in[6],  (const float*)d_in[7],
      (const float*)d_in[8],  (const float*)d_in[9],  (const float*)d_in[10], (const float*)d_in[11],
      (const float*)d_in[12], (const float*)d_in[13], wB);

  prep_big_kernel<<<dim3(64), dim3(256), 0, stream>>>(
      w_first, (const float*)d_in[20], (const float*)d_in[30], wtpH, wtpV, wpack);

  tof16_pack_kernel<<<dim3(Hq, Bq), dim3(192), 0, stream>>>(x, xpack);
  conv7_mfma_kernel<<<dim3(4, 96, 2), dim3(256), 0, stream>>>(xpack, wpack, bufA);

  pool_fused_kernel<<<dim3(6, 128), dim3(256), 0, stream>>>(bufA, x1);

  dwf_kernel<<<dim3(144, 8, 4), dim3(256), 0, stream>>>(x1, wEffH, bEffH, wB,
      wEffV, bEffV, wB + 64*18*20, fpackH, fpackV);

  off_cum_kernel<<<dim3(144, 2, 2), dim3(256), 0, stream>>>(fpackH, fpackV,
      wOffH, bOffH, wOffV, bOffV, hcum, vcum);

  einsum_mfma_kernel<<<dim3(576, 2), dim3(128), 0, stream>>>(fpackH, fpackV,
      hcum, vcum, wtpH, wtpV, (const float*)d_in[21], (const float*)d_in[31], bufA, bufB);

  gnstats_kernel<<<dim3(256), dim3(256), 0, stream>>>(bufA, bufB, stats);
  gnfinal_kernel<<<dim3(1), dim3(256), 0, stream>>>(stats,
      (const float*)d_in[22], (const float*)d_in[23],
      (const float*)d_in[32], (const float*)d_in[33], gnAB);

  final2_kernel<<<dim3(144, 2), dim3(256), 0, stream>>>(bufA, bufB, x1, gnAB, lwT, lbO, (float*)d_out);
}

// Round 19
// 364.409 us; speedup vs baseline: 1.7094x; 1.0309x over previous
//
#include <hip/hip_runtime.h>
#include <hip/hip_bf16.h>
#include <hip/hip_fp16.h>
#include <math.h>

#define Bq 2
#define Cq 64
#define Hq 192
#define Wq 192
#define HWq (Hq*Wq)            // 36864
#define Nq ((size_t)Bq*Cq*HWq) // 4718592

typedef __attribute__((ext_vector_type(8))) _Float16 f16x8;
typedef __attribute__((ext_vector_type(4))) float f32x4;

__device__ inline unsigned short h2us(__half h) {
  union { __half h; unsigned short u; } v; v.h = h; return v.u;
}

// ---------------------------------------------------------------------------
// Small prep (1 block) — register-unrolled composition
// ---------------------------------------------------------------------------
__global__ __launch_bounds__(256) void prep_small_kernel(
    const float* hc1_w, const float* hc1_b, const float* hc2_w, const float* hc2_b,
    const float* hc3_w, const float* hc3_b,
    const float* vc1_w, const float* vc1_b, const float* vc2_w, const float* vc2_b,
    const float* vc3_w, const float* vc3_b,
    const float* h_off_w, const float* h_off_b, const float* h_bn_g, const float* h_bn_b,
    const float* h_bn_m, const float* h_bn_v,
    const float* v_off_w, const float* v_off_b, const float* v_bn_g, const float* v_bn_b,
    const float* v_bn_m, const float* v_bn_v,
    const float* last_w, const float* last_g, const float* last_b, const float* last_m,
    const float* last_v,
    float* wEffH, float* bEffH, float* wEffV, float* bEffV,
    float* wOffH, float* bOffH, float* wOffV, float* bOffV,
    float* lwT, float* lbO)
{
  int t = threadIdx.x;
  if (t < 128) {
    int ch = t & 63;
    bool ish = t < 64;
    const float* w1p = (ish ? hc1_w : vc1_w) + ch*9;
    const float* w2p = (ish ? hc2_w : vc2_w) + ch*7;
    const float* w3p = (ish ? hc3_w : vc3_w) + ch*5;
    float w1r[9], w2r[7], w3r[5];
#pragma unroll
    for (int j = 0; j < 9; j++) w1r[j] = w1p[j];
#pragma unroll
    for (int k = 0; k < 7; k++) w2r[k] = w2p[k];
#pragma unroll
    for (int m = 0; m < 5; m++) w3r[m] = w3p[m];
    float t15[15];
#pragma unroll
    for (int s = 0; s < 15; s++) {
      float a = 0.f;
#pragma unroll
      for (int j = 0; j < 9; j++) { int k2 = s - j; if (k2 >= 0 && k2 < 7) a += w1r[j]*w2r[k2]; }
      t15[s] = a;
    }
    float* we = (ish ? wEffH : wEffV) + ch*19;
#pragma unroll
    for (int s = 0; s < 19; s++) {
      float a = 0.f;
#pragma unroll
      for (int j = 0; j < 15; j++) { int k3 = s - j; if (k3 >= 0 && k3 < 5) a += t15[j]*w3r[k3]; }
      we[s] = a;
    }
    float S2 = 0.f, S3 = 0.f;
#pragma unroll
    for (int j = 0; j < 7; j++) S2 += w2r[j];
#pragma unroll
    for (int j = 0; j < 5; j++) S3 += w3r[j];
    float b1 = (ish ? hc1_b : vc1_b)[ch];
    float b2 = (ish ? hc2_b : vc2_b)[ch];
    float b3 = (ish ? hc3_b : vc3_b)[ch];
    (ish ? bEffH : bEffV)[ch] = b1*S2*S3 + b2*S3 + b3;
  }
  for (int idx = t; idx < 9*64*7; idx += 256) {
    int tap = idx / 448; int rem = idx % 448; int i = rem / 7; int m = rem % 7;
    float invh = h_bn_g[m] / sqrtf(h_bn_v[m] + 1e-5f);
    wOffH[(tap*64 + i)*8 + m] = h_off_w[(m*64 + i)*9 + tap] * invh;
    float invv = v_bn_g[7+m] / sqrtf(v_bn_v[7+m] + 1e-5f);
    wOffV[(tap*64 + i)*8 + m] = v_off_w[((7+m)*64 + i)*9 + tap] * invv;
  }
  if (t < 7) {
    float invh = h_bn_g[t] / sqrtf(h_bn_v[t] + 1e-5f);
    bOffH[t] = h_off_b[t]*invh + h_bn_b[t] - h_bn_m[t]*invh;
    float invv = v_bn_g[7+t] / sqrtf(v_bn_v[7+t] + 1e-5f);
    bOffV[t] = v_off_b[7+t]*invv + v_bn_b[7+t] - v_bn_m[7+t]*invv;
  }
  for (int idx = t; idx < 4096; idx += 256) {
    int o = idx % 64; int i = idx / 64;
    float inv = last_g[o] / sqrtf(last_v[o] + 1e-3f);
    lwT[i*64 + o] = last_w[o*64 + i] * inv;
  }
  if (t < 64) {
    float inv = last_g[t] / sqrtf(last_v[t] + 1e-3f);
    lbO[t] = last_b[t] - last_m[t]*inv;
  }
}

// ---------------------------------------------------------------------------
// Border prep — fully unrolled, registers only
// ---------------------------------------------------------------------------
__global__ __launch_bounds__(256) void prep_border_kernel(
    const float* hc1_w, const float* hc1_b, const float* hc2_w, const float* hc2_b,
    const float* hc3_w, const float* hc3_b,
    const float* vc1_w, const float* vc1_b, const float* vc2_w, const float* vc2_b,
    const float* vc3_w, const float* vc3_b,
    float* wB)
{
  int tid = blockIdx.x*256 + threadIdx.x;
  if (tid >= 2*64*18) return;
  int cls = tid % 18;
  int ch  = (tid / 18) % 64;
  int br  = tid / (18*64);
  int c = (cls < 9) ? cls : cls + 174;
  const float* w1p = (br==0 ? hc1_w : vc1_w) + ch*9;
  const float* w2p = (br==0 ? hc2_w : vc2_w) + ch*7;
  const float* w3p = (br==0 ? hc3_w : vc3_w) + ch*5;
  float b1 = (br==0 ? hc1_b : vc1_b)[ch];
  float b2 = (br==0 ? hc2_b : vc2_b)[ch];
  float b3 = (br==0 ? hc3_b : vc3_b)[ch];
  float w1r[9], w2r[7], w3r[5];
#pragma unroll
  for (int j = 0; j < 9; j++) w1r[j] = w1p[j];
#pragma unroll
  for (int k = 0; k < 7; k++) w2r[k] = w2p[k];
#pragma unroll
  for (int m = 0; m < 5; m++) w3r[m] = w3p[m];

  float acc[19];
#pragma unroll
  for (int s = 0; s < 19; s++) acc[s] = 0.f;
  float bacc = b3;
#pragma unroll
  for (int m = 0; m < 5; m++) {
    int d = c + m - 2;
    bool dok = (d >= 0 && d < Wq);
    float s2b = b2;
#pragma unroll
    for (int k = 0; k < 7; k++) {
      int e = d + k - 3;
      bool eok = (e >= 0 && e < Wq);
      if (eok) s2b += w2r[k] * b1;
      float wmk = w3r[m] * w2r[k];
#pragma unroll
      for (int j = 0; j < 9; j++) {
        int fd = e + j - 4;
        bool fok = (fd >= 0 && fd < Wq);
        float contrib = (dok && eok && fok) ? wmk * w1r[j] : 0.f;
        acc[m + k + j] += contrib;
      }
    }
    if (dok) bacc += w3r[m] * s2b;
  }
  float* dst = wB + ((size_t)(br*64 + ch)*18 + cls)*20;
#pragma unroll
  for (int s = 0; s < 19; s++) dst[s] = acc[s];
  dst[19] = bacc;
}

// ---------------------------------------------------------------------------
// Big prep: dsc weights -> f16 hi/lo MFMA pack [tap][kc][hl][oc][32]
//           + w_first f16 hi/lo pack for conv7 [h][tap][hl][oc][32].
// ---------------------------------------------------------------------------
__global__ __launch_bounds__(256) void prep_big_kernel(
    const float* __restrict__ w_first,
    const float* __restrict__ h_dsc_w, const float* __restrict__ v_dsc_w,
    unsigned short* __restrict__ wtpH, unsigned short* __restrict__ wtpV,
    unsigned short* __restrict__ wpack)
{
  int tid = blockIdx.x*256 + threadIdx.x;
  int nthr = gridDim.x*256;
  for (int idx = tid; idx < 7*2*2*64*32; idx += nthr) {
    int ch32 = idx & 31;
    int oc   = (idx >> 5) & 63;
    int hl   = (idx >> 11) & 1;
    int kc   = (idx >> 12) & 1;
    int tap  = idx >> 13;
    int i = kc*32 + ch32;
    float vh = h_dsc_w[oc*448 + i*7 + tap];
    float vv = v_dsc_w[oc*448 + i*7 + tap];
    _Float16 hh = (_Float16)vh;
    _Float16 hv = (_Float16)vv;
    unsigned short uh, uv;
    if (!hl) { uh = *(unsigned short*)&hh; uv = *(unsigned short*)&hv; }
    else {
      _Float16 lh = (_Float16)(vh - (float)hh);
      _Float16 lv = (_Float16)(vv - (float)hv);
      uh = *(unsigned short*)&lh; uv = *(unsigned short*)&lv;
    }
    wtpH[idx] = uh; wtpV[idx] = uv;
  }
  for (int e = tid; e < 2*49*2*64*32; e += nthr) {
    int ch  = e & 31;
    int oc  = (e >> 5) & 63;
    int hl  = (e >> 11) & 1;
    int rest = e >> 12;
    int tap = rest % 49;
    int h   = rest / 49;
    float wv = w_first[((size_t)oc*64 + h*32 + ch)*49 + tap];
    __half hh = __float2half(wv);
    unsigned short us;
    if (!hl) us = h2us(hh);
    else { float rr = wv - __half2float(hh); us = h2us(__float2half(rr)); }
    wpack[e] = us;
  }
}

// ---------------------------------------------------------------------------
// x (NCHW f32) -> xpack single f16: [b][r][c][64]
// ---------------------------------------------------------------------------
__global__ __launch_bounds__(192) void tof16_pack_kernel(const float* __restrict__ x,
                                                         unsigned short* __restrict__ xpack)
{
  __shared__ unsigned int s[192*64];
  int r = blockIdx.x, b = blockIdx.y;
  int t = threadIdx.x;
  for (int ch = 0; ch < 64; ch++) {
    float v = x[((size_t)(b*64+ch)*Hq + r)*Wq + t];
    _Float16 hh = (_Float16)v;
    s[t*64 + (ch ^ (t & 31))] = (unsigned int)*(unsigned short*)&hh;
  }
  __syncthreads();
  unsigned short* dst = xpack + ((size_t)b*Hq + r)*Wq*64;
  for (int i = 0; i < 8; i++) {
    int gidx = i*192 + t;
    int c = gidx >> 3, g = gidx & 7;
    unsigned short tmp[8];
#pragma unroll
    for (int j = 0; j < 8; j++) {
      int ch = g*8 + j;
      tmp[j] = (unsigned short)s[c*64 + (ch ^ (c & 31))];
    }
    uint4 v;
    v.x = (unsigned int)tmp[0] | ((unsigned int)tmp[1] << 16);
    v.y = (unsigned int)tmp[2] | ((unsigned int)tmp[3] << 16);
    v.z = (unsigned int)tmp[4] | ((unsigned int)tmp[5] << 16);
    v.w = (unsigned int)tmp[6] | ((unsigned int)tmp[7] << 16);
    *(uint4*)(dst + (size_t)gidx*8) = v;
  }
}

// ---------------------------------------------------------------------------
// 7x7 conv via MFMA, 2-pass (x single f16, w hi/lo exact) — R17 validated.
// ---------------------------------------------------------------------------
__global__ __launch_bounds__(256) void conv7_mfma_kernel(
    const unsigned short* __restrict__ xpack,   // [b][r][c][64] f16
    const unsigned short* __restrict__ wpack,   // [h][tap][hl][oc][32] f16
    float* __restrict__ out)
{
  __shared__ __align__(16) unsigned short sA[8*54*32];   // 27648 B
  int ct = blockIdx.x;          // 0..3
  int rt = blockIdx.y;          // 0..95
  int b  = blockIdx.z;
  int r0 = rt*2, c0 = ct*48;
  int t = threadIdx.x;
  int wv = t >> 6;              // wave -> oc quarter
  int l  = t & 63;
  int l15 = l & 15, lg = l >> 4;
  int oc = wv*16 + l15;

  f32x4 acc[2][3];
#pragma unroll
  for (int i = 0; i < 2; i++)
#pragma unroll
    for (int j = 0; j < 3; j++) acc[i][j] = (f32x4){0.f,0.f,0.f,0.f};

  for (int h = 0; h < 2; h++) {
    __syncthreads();
    for (int idx = t; idx < 8*54*4; idx += 256) {
      int g = idx & 3, pix = idx >> 2;
      int row = pix / 54, col = pix % 54;
      int gr = r0 - 3 + row, gc = c0 - 3 + col;
      uint4 v = {0u,0u,0u,0u};
      if (gr >= 0 && gr < Hq && gc >= 0 && gc < Wq)
        v = *(const uint4*)(xpack + (((size_t)b*Hq + gr)*Wq + gc)*64 + (h*4 + g)*8);
      ((uint4*)sA)[(row*54 + col)*4 + (g ^ ((col >> 1) & 3))] = v;
    }
    __syncthreads();
    const unsigned short* wb = wpack + (size_t)h*49*4096;
#pragma unroll 7
    for (int tap = 0; tap < 49; tap++) {
      int dy = tap / 7, dx = tap % 7;
      f16x8 bh = *(const f16x8*)(wb + (size_t)tap*4096 +        oc*32 + lg*8);
      f16x8 bl = *(const f16x8*)(wb + (size_t)tap*4096 + 2048 + oc*32 + lg*8);
#pragma unroll
      for (int rw = 0; rw < 2; rw++) {
        int arow = rw + dy;
        f16x8 a[3];
#pragma unroll
        for (int tc = 0; tc < 3; tc++) {
          int col = tc*16 + l15 + dx;
          a[tc] = *(const f16x8*)((const uint4*)sA + (arow*54 + col)*4 + (lg ^ ((col >> 1) & 3)));
        }
#pragma unroll
        for (int tc = 0; tc < 3; tc++) {
          acc[rw][tc] = __builtin_amdgcn_mfma_f32_16x16x32_f16(a[tc], bh, acc[rw][tc], 0, 0, 0);
          acc[rw][tc] = __builtin_amdgcn_mfma_f32_16x16x32_f16(a[tc], bl, acc[rw][tc], 0, 0, 0);
        }
      }
    }
  }
#pragma unroll
  for (int rw = 0; rw < 2; rw++) {
    float* dst = out + ((size_t)(b*64 + oc)*Hq + (r0 + rw))*Wq + c0;
#pragma unroll
    for (int tc = 0; tc < 3; tc++) {
      f32x4 v = acc[rw][tc];
      *(float4*)(dst + tc*16 + lg*4) = make_float4(v[0], v[1], v[2], v[3]);
    }
  }
}

// ---------------------------------------------------------------------------
// FUSED separable 7x7 avg pool: one kernel, LDS-staged.
// ---------------------------------------------------------------------------
__global__ __launch_bounds__(256) void pool_fused_kernel(const float* __restrict__ in,
                                                         float* __restrict__ out)
{
  __shared__ float raw[38][192];
  __shared__ float cs[32][192];
  int rt = blockIdx.x;
  int plane = blockIdx.y;
  int r0 = rt*32;
  int t = threadIdx.x;
  const float* src = in + (size_t)plane*HWq;
  for (int idx = t; idx < 38*192; idx += 256) {
    int lr = idx / 192, c = idx % 192;
    int gr = r0 - 3 + lr;
    raw[lr][c] = (gr >= 0 && gr < Hq) ? src[gr*Wq + c] : 0.f;
  }
  __syncthreads();
  for (int idx = t; idx < 32*192; idx += 256) {
    int lr = idx / 192, c = idx % 192;
    float s = 0.f;
#pragma unroll
    for (int dr = 0; dr < 7; dr++) s += raw[lr + dr][c];
    cs[lr][c] = s;
  }
  __syncthreads();
  float* dst = out + (size_t)plane*HWq + r0*Wq;
  for (int idx = t; idx < 32*192; idx += 256) {
    int lr = idx / 192, c = idx % 192;
    float s = 0.f;
#pragma unroll
    for (int dc = -3; dc <= 3; dc++) {
      int cc = c + dc;
      if (cc >= 0 && cc < Wq) s += cs[lr][cc];
    }
    dst[idx] = s * (1.f/49.f);
  }
}

// ---------------------------------------------------------------------------
// MERGED fused depthwise 19-tap + f16 hi/lo plane-major pack.
// Grid (144, 8, 4): z = branch*2 + b.
// ---------------------------------------------------------------------------
__global__ __launch_bounds__(256) void dwf_kernel(const float* __restrict__ x1,
                                                  const float* __restrict__ wEffH,
                                                  const float* __restrict__ bEffH,
                                                  const float* __restrict__ wBH,
                                                  const float* __restrict__ wEffV,
                                                  const float* __restrict__ bEffV,
                                                  const float* __restrict__ wBV,
                                                  unsigned short* __restrict__ packH,
                                                  unsigned short* __restrict__ packV)
{
  __shared__ float sW[8][19][20];
  int z = blockIdx.z;
  int br = z >> 1, b = z & 1;
  const float* wEff = br ? wEffV : wEffH;
  const float* bEff = br ? bEffV : bEffH;
  const float* wB   = br ? wBV   : wBH;
  unsigned short* pack = br ? packV : packH;
  int g8 = blockIdx.y;
  int t = threadIdx.x;
  int chb = g8*8;
  for (int i = t; i < 8*380; i += 256) {
    int ch8 = i / 380; int rem = i % 380;
    int row = rem / 20, jj = rem % 20;
    int ch = chb + ch8;
    float v;
    if (row < 18) v = wB[((size_t)ch*18 + row)*20 + jj];
    else v = (jj < 19) ? wEff[ch*19 + jj] : bEff[ch];
    sW[ch8][row][jj] = v;
  }
  __syncthreads();
  int p = blockIdx.x*256 + t;
  int r = p / Wq, c = p % Wq;
  float vals[8];
  if (br == 0) {
    int row = (c < 9) ? c : ((c >= Wq-9) ? (c - 174) : 18);
#pragma unroll
    for (int ch8 = 0; ch8 < 8; ch8++) {
      const float* src = x1 + (size_t)(b*Cq + chb + ch8)*HWq + r*Wq;
      float s = sW[ch8][row][19];
#pragma unroll
      for (int j = 0; j < 19; j++) {
        int idx = min(max(c + j - 9, 0), Wq-1);
        s += src[idx] * sW[ch8][row][j];
      }
      vals[ch8] = s;
    }
  } else {
    int row = (r < 9) ? r : ((r >= Hq-9) ? (r - 174) : 18);
#pragma unroll
    for (int ch8 = 0; ch8 < 8; ch8++) {
      const float* src = x1 + (size_t)(b*Cq + chb + ch8)*HWq + c;
      float s = sW[ch8][row][19];
#pragma unroll
      for (int j = 0; j < 19; j++) {
        int idx = min(max(r + j - 9, 0), Hq-1);
        s += src[idx*Wq] * sW[ch8][row][j];
      }
      vals[ch8] = s;
    }
  }
  unsigned int hi[4], lo[4];
#pragma unroll
  for (int q = 0; q < 4; q++) {
    __half h0 = __float2half(vals[2*q]);
    __half h1 = __float2half(vals[2*q+1]);
    __half l0 = __float2half(vals[2*q]   - __half2float(h0));
    __half l1 = __float2half(vals[2*q+1] - __half2float(h1));
    hi[q] = (unsigned int)h2us(h0) | ((unsigned int)h2us(h1) << 16);
    lo[q] = (unsigned int)h2us(l0) | ((unsigned int)h2us(l1) << 16);
  }
  *(uint4*)(pack + (((size_t)b*16 + g8)*HWq + p)*8)     = make_uint4(hi[0], hi[1], hi[2], hi[3]);
  *(uint4*)(pack + (((size_t)b*16 + 8 + g8)*HWq + p)*8) = make_uint4(lo[0], lo[1], lo[2], lo[3]);
}

// ---------------------------------------------------------------------------
// MERGED offset conv + tanh + cum. Grid (144, 2, 2): z = branch.
// ---------------------------------------------------------------------------
__global__ __launch_bounds__(256) void off_cum_kernel(const unsigned short* __restrict__ fpH,
                                                      const unsigned short* __restrict__ fpV,
                                                      const float* __restrict__ wOffH,
                                                      const float* __restrict__ bOffH,
                                                      const float* __restrict__ wOffV,
                                                      const float* __restrict__ bOffV,
                                                      float* __restrict__ hcum,
                                                      float* __restrict__ vcum)
{
  const size_t HW8 = (size_t)HWq*8;
  int br = blockIdx.z;
  const unsigned short* fp = br ? fpV : fpH;
  const float* wOff = br ? wOffV : wOffH;
  const float* bOff = br ? bOffV : bOffH;
  float* cum = br ? vcum : hcum;
  int b = blockIdx.y;
  int p = blockIdx.x*256 + threadIdx.x;
  int r = p / Wq, c = p % Wq;
  float tv[7];
#pragma unroll
  for (int m = 0; m < 7; m++) tv[m] = bOff[m];
  const unsigned short* fb = fp + (size_t)b*HWq*128;
  for (int tap = 0; tap < 9; tap++) {
    int dy = tap/3 - 1, dx = tap%3 - 1;
    int rr = r + dy, cc = c + dx;
    if (rr < 0 || rr >= Hq || cc < 0 || cc >= Wq) continue;
    const unsigned short* p0 = fb + ((size_t)rr*Wq + cc)*8;
    const float* wp = wOff + tap*512;
    for (int g = 0; g < 8; g++) {
      f16x8 hv = *(const f16x8*)(p0 + (size_t)g*HW8);
      f16x8 lv = *(const f16x8*)(p0 + (size_t)(8 + g)*HW8);
#pragma unroll
      for (int e = 0; e < 8; e++) {
        float fv = (float)hv[e] + (float)lv[e];
        const float* wr = wp + (g*8 + e)*8;
#pragma unroll
        for (int m = 0; m < 7; m++) tv[m] += fv * wr[m];
      }
    }
  }
#pragma unroll
  for (int m = 0; m < 7; m++) tv[m] = tanhf(tv[m]);
  float c0 = tv[0], c1 = tv[1] + tv[2], c2 = tv[2], c3 = 0.f;
  float c4 = tv[4], c5 = tv[4] + tv[5], c6 = tv[6];
  size_t bb = (size_t)b*7*HWq + p;
  cum[bb + 0*HWq] = c0; cum[bb + 1*HWq] = c1; cum[bb + 2*HWq] = c2;
  cum[bb + 3*HWq] = c3; cum[bb + 4*HWq] = c4; cum[bb + 5*HWq] = c5;
  cum[bb + 6*HWq] = c6;
}

// ---------------------------------------------------------------------------
// MERGED deformable sample + einsum via MFMA, 2-PASS (A single f16, W hi/lo).
// 2 k-taps staged per barrier phase: LDS [2][128px][64] f16 = 32 KB.
// Grid (576, 2): y = morph. XCD-banded swizzle per morph slice.
// ---------------------------------------------------------------------------
__global__ __launch_bounds__(128) void einsum_mfma_kernel(
    const unsigned short* __restrict__ fpH, const unsigned short* __restrict__ fpV,
    const float* __restrict__ cumH, const float* __restrict__ cumV,
    const unsigned short* __restrict__ wtpHp, const unsigned short* __restrict__ wtpVp,
    const float* __restrict__ dscbH, const float* __restrict__ dscbV,
    float* __restrict__ outH, float* __restrict__ outV)
{
  __shared__ __align__(16) unsigned short sA[2*128*64];  // 32 KB
  const size_t HW8 = (size_t)HWq*8;
  int morph = blockIdx.y;
  const unsigned short* fp  = morph ? fpV   : fpH;
  const float* cum          = morph ? cumV  : cumH;
  const unsigned short* wtp = morph ? wtpVp : wtpHp;
  const float* dsc_b        = morph ? dscbV : dscbH;
  float* out                = morph ? outV  : outH;
  int bid = blockIdx.x;
  int swz = (bid & 7)*72 + (bid >> 3);
  int b   = swz / 288;
  int blk = swz % 288;
  int t = threadIdx.x;
  int w = t >> 6, l = t & 63;
  int l15 = l & 15, lg = l >> 4;
  int l7 = l15 & 7;
  int p = blk*128 + w*64 + l;
  int r = p / Wq, c = p % Wq;

  f32x4 acc[4][4];
#pragma unroll
  for (int i = 0; i < 4; i++)
#pragma unroll
    for (int j = 0; j < 4; j++) acc[i][j] = (f32x4){0.f,0.f,0.f,0.f};

  const unsigned short* fb = fp + (size_t)b*HWq*128;

  for (int kp = 0; kp < 4; kp++) {
    int k0 = kp*2;
    int nk = (kp < 3) ? 2 : 1;
    // ---- stage nk taps: sample + lerp -> single f16 rows -----------------
    for (int kk = 0; kk < nk; kk++) {
      int k = k0 + kk;
      unsigned short* myrow = sA + (size_t)(kk*128 + w*64 + l)*64;
      bool oob;
      const unsigned short *p0, *p1;
      float w0, w1;
      if (morph == 0) {
        int xi = c + k - 3;
        oob = (xi < 0 || xi >= Wq);
        if (!oob) {
          float y = (float)r + cum[((size_t)(b*7 + k))*HWq + p];
          float y0 = floorf(y);
          int y0q = (int)y0;
          int y0i = min(max(y0q, 0), Hq-1);
          int y1i = min(max(y0q + 1, 0), Hq-1);
          float y0f = fminf(fmaxf(y0, 0.f), (float)Hq);
          float y1f = fminf(fmaxf(y0 + 1.f, 0.f), (float)Hq);
          w0 = y1f - y; w1 = y - y0f;
          p0 = fb + ((size_t)y0i*Wq + xi)*8;
          p1 = fb + ((size_t)y1i*Wq + xi)*8;
        }
      } else {
        int yi = r + k - 3;
        oob = (yi < 0 || yi >= Hq);
        if (!oob) {
          float xf = (float)c + cum[((size_t)(b*7 + k))*HWq + p];
          float x0 = floorf(xf);
          int x0q = (int)x0;
          int x0i = min(max(x0q, 0), Wq-1);
          int x1i = min(max(x0q + 1, 0), Wq-1);
          float x0f = fminf(fmaxf(x0, 0.f), (float)Wq);
          float x1f = fminf(fmaxf(x0 + 1.f, 0.f), (float)Wq);
          w0 = x1f - xf; w1 = xf - x0f;
          p0 = fb + ((size_t)yi*Wq + x0i)*8;
          p1 = fb + ((size_t)yi*Wq + x1i)*8;
        }
      }
      if (oob) {
        uint4 z = {0u,0u,0u,0u};
#pragma unroll
        for (int j = 0; j < 8; j++) ((uint4*)myrow)[j] = z;
      } else {
#pragma unroll
        for (int g = 0; g < 8; g++) {
          f16x8 a0h = *(const f16x8*)(p0 + (size_t)g*HW8);
          f16x8 a0l = *(const f16x8*)(p0 + (size_t)(8 + g)*HW8);
          f16x8 a1h = *(const f16x8*)(p1 + (size_t)g*HW8);
          f16x8 a1l = *(const f16x8*)(p1 + (size_t)(8 + g)*HW8);
          f16x8 sh;
#pragma unroll
          for (int e = 0; e < 8; e++) {
            float v = w0*((float)a0h[e] + (float)a0l[e]) + w1*((float)a1h[e] + (float)a1l[e]);
            sh[e] = (_Float16)v;
          }
          *(f16x8*)(myrow + (size_t)(g ^ l7)*8) = sh;
        }
      }
    }
    __syncthreads();
    // ---- MFMA over staged taps -------------------------------------------
    for (int kk = 0; kk < nk; kk++) {
      int k = k0 + kk;
#pragma unroll
      for (int kc = 0; kc < 2; kc++) {
        const unsigned short* wbase = wtp + (size_t)((k*2 + kc)*2)*2048;
        f16x8 bh[4], bl[4];
#pragma unroll
        for (int tb = 0; tb < 4; tb++) {
          bh[tb] = *(const f16x8*)(wbase + (tb*16 + l15)*32 + lg*8);
          bl[tb] = *(const f16x8*)(wbase + 2048 + (tb*16 + l15)*32 + lg*8);
        }
        f16x8 ah[4];
#pragma unroll
        for (int ta = 0; ta < 4; ta++) {
          const unsigned short* rbase = sA + (size_t)(kk*128 + w*64 + ta*16 + l15)*64;
          ah[ta] = *(const f16x8*)(rbase + (size_t)((kc*4 + lg) ^ l7)*8);
        }
#pragma unroll
        for (int ta = 0; ta < 4; ta++)
#pragma unroll
          for (int tb = 0; tb < 4; tb++) {
            acc[ta][tb] = __builtin_amdgcn_mfma_f32_16x16x32_f16(ah[ta], bh[tb], acc[ta][tb], 0, 0, 0);
            acc[ta][tb] = __builtin_amdgcn_mfma_f32_16x16x32_f16(ah[ta], bl[tb], acc[ta][tb], 0, 0, 0);
          }
      }
    }
    __syncthreads();
  }
  int pbase = blk*128 + w*64;
#pragma unroll
  for (int tb = 0; tb < 4; tb++) {
    int oc = tb*16 + l15;
    float bias = dsc_b[oc];
    float* dst = out + (size_t)(b*64 + oc)*HWq + pbase;
#pragma unroll
    for (int ta = 0; ta < 4; ta++) {
      f32x4 v = acc[ta][tb];
      *(float4*)(dst + ta*16 + lg*4) = make_float4(v[0]+bias, v[1]+bias, v[2]+bias, v[3]+bias);
    }
  }
}

// ---------------------------------------------------------------------------
// GroupNorm stats + finalize
// ---------------------------------------------------------------------------
__global__ __launch_bounds__(256) void gnstats_kernel(const float* __restrict__ h_ds,
                                                      const float* __restrict__ v_ds,
                                                      float* __restrict__ stats)
{
  int plane = blockIdx.x;
  int buf = plane >> 7;
  int rem = plane & 127;
  const float* src = (buf ? v_ds : h_ds) + (size_t)rem*HWq;
  float s = 0.f, s2 = 0.f;
  for (int i = threadIdx.x; i < HWq; i += 256) {
    float v = src[i];
    s += v; s2 += v*v;
  }
  __shared__ float red[2][4];
  for (int off = 32; off; off >>= 1) {
    s  += __shfl_down(s, off);
    s2 += __shfl_down(s2, off);
  }
  if ((threadIdx.x & 63) == 0) { red[0][threadIdx.x >> 6] = s; red[1][threadIdx.x >> 6] = s2; }
  __syncthreads();
  if (threadIdx.x == 0) {
    s  = red[0][0] + red[0][1] + red[0][2] + red[0][3];
    s2 = red[1][0] + red[1][1] + red[1][2] + red[1][3];
    stats[plane*2 + 0] = s;
    stats[plane*2 + 1] = s2;
  }
}

__global__ __launch_bounds__(256) void gnfinal_kernel(const float* __restrict__ stats,
                                                      const float* __restrict__ h_gn_g, const float* __restrict__ h_gn_b,
                                                      const float* __restrict__ v_gn_g, const float* __restrict__ v_gn_b,
                                                      float* __restrict__ gnAB)
{
  int t = threadIdx.x;
  int buf = t >> 7, ch = t & 63;
  int base = t & ~3;
  float sum = 0.f, ss = 0.f;
#pragma unroll
  for (int q = 0; q < 4; q++) { sum += stats[(base+q)*2]; ss += stats[(base+q)*2 + 1]; }
  const float n = 4.f * HWq;
  float mean = sum / n;
  float var = ss / n - mean*mean;
  float gg = (buf ? v_gn_g : h_gn_g)[ch];
  float bb = (buf ? v_gn_b : h_gn_b)[ch];
  float A = gg / sqrtf(var + 1e-5f);
  gnAB[t*2 + 0] = A;
  gnAB[t*2 + 1] = bb - mean*A;
}

// ---------------------------------------------------------------------------
// FUSED: comb = relu(GN(h)) + relu(GN(v)) + x1 inline, then 1x1 conv + SiLU
// ---------------------------------------------------------------------------
__global__ __launch_bounds__(256) void final2_kernel(const float* __restrict__ hbuf,
                                                     const float* __restrict__ vbuf,
                                                     const float* __restrict__ x1,
                                                     const float* __restrict__ gnAB,
                                                     const float* __restrict__ lwT,
                                                     const float* __restrict__ lbO,
                                                     float* __restrict__ out)
{
  int b = blockIdx.y;
  int p = blockIdx.x*256 + threadIdx.x;
  float acc[64];
#pragma unroll
  for (int o = 0; o < 64; o++) acc[o] = 0.f;
  for (int i = 0; i < 64; i++) {
    size_t off = (size_t)(b*64 + i)*HWq + p;
    int plane = b*64 + i;
    int ih = plane*2;
    int iv = (128 + plane)*2;
    float hv = fmaxf(hbuf[off]*gnAB[ih] + gnAB[ih+1], 0.f);
    float vv = fmaxf(vbuf[off]*gnAB[iv] + gnAB[iv+1], 0.f);
    float cv = hv + vv + x1[off];
    const float* wr = lwT + i*64;
#pragma unroll
    for (int o = 0; o < 64; o++) acc[o] += cv * wr[o];
  }
  float* dst = out + (size_t)b*Cq*HWq + p;
#pragma unroll
  for (int o = 0; o < 64; o++) {
    float yv = acc[o] + lbO[o];
    dst[(size_t)o*HWq] = yv / (1.f + expf(-yv));
  }
}

// ---------------------------------------------------------------------------
extern "C" void kernel_launch(void* const* d_in, const int* in_sizes, int n_in,
                              void* d_out, int out_size, void* d_ws, size_t ws_size,
                              hipStream_t stream)
{
  const float* x       = (const float*)d_in[0];
  const float* w_first = (const float*)d_in[1];
  float* ws = (float*)d_ws;

  float* bufA = ws;            // conv7 out -> h-einsum-out
  float* bufB = ws + Nq;       // v-einsum-out
  float* x1   = ws + 2*Nq;
  float* h_ds = ws + 3*Nq;     // xpack -> fpackH
  float* v_ds = ws + 4*Nq;     // fpackV
  size_t off = 5*Nq;
  float* hcum  = ws + off; off += (size_t)Bq*7*HWq;
  float* vcum  = ws + off; off += (size_t)Bq*7*HWq;
  float* wEffH = ws + off; off += 64*19;
  float* bEffH = ws + off; off += 64;
  float* wEffV = ws + off; off += 64*19;
  float* bEffV = ws + off; off += 64;
  float* wtH   = ws + off; off += 64*64*7;   // holds wtpH f16 pack
  float* wtV   = ws + off; off += 64*64*7;   // holds wtpV f16 pack
  float* wOffH = ws + off; off += 9*64*8;
  float* bOffH = ws + off; off += 8;
  float* wOffV = ws + off; off += 9*64*8;
  float* bOffV = ws + off; off += 8;
  float* lwT   = ws + off; off += 64*64;
  float* lbO   = ws + off; off += 64;
  float* stats = ws + off; off += 512;
  float* gnAB  = ws + off; off += 512;
  float* wB    = ws + off; off += 2*64*18*20;
  unsigned short* wpack = (unsigned short*)(ws + off); off += 2*49*2*64*32/2 + 16;
  unsigned short* xpack  = (unsigned short*)h_ds;
  unsigned short* fpackH = (unsigned short*)h_ds;
  unsigned short* fpackV = (unsigned short*)v_ds;
  unsigned short* wtpH = (unsigned short*)wtH;
  unsigned short* wtpV = (unsigned short*)wtV;

  prep_small_kernel<<<dim3(1), dim3(256), 0, stream>>>(
      (const float*)d_in[2],  (const float*)d_in[3],  (const float*)d_in[4],  (const float*)d_in[5],
      (const float*)d_in[6],  (const float*)d_in[7],
      (const float*)d_in[8],  (const float*)d_in[9],  (const float*)d_in[10], (const float*)d_in[11],
      (const float*)d_in[12], (const float*)d_in[13],
      (const float*)d_in[14], (const float*)d_in[15], (const float*)d_in[16], (const float*)d_in[17],
      (const float*)d_in[18], (const float*)d_in[19],
      (const float*)d_in[24], (const float*)d_in[25], (const float*)d_in[26], (const float*)d_in[27],
      (const float*)d_in[28], (const float*)d_in[29],
      (const float*)d_in[34], (const float*)d_in[35], (const float*)d_in[36], (const float*)d_in[37],
      (const float*)d_in[38],
      wEffH, bEffH, wEffV, bEffV, wOffH, bOffH, wOffV, bOffV, lwT, lbO);

  prep_border_kernel<<<dim3(9), dim3(256), 0, stream>>>(
      (const float*)d_in[2],  (const float*)d_in[3],  (const float*)d_in[4],  (const float*)d_in[5],
      (const float*)d_in[6],  (const float*)d_in[7],
      (const float*)d_in[8],  (const float*)d_in[9],  (const float*)d_in[10], (const float*)d_in[11],
      (const float*)d_in[12], (const float*)d_in[13], wB);

  prep_big_kernel<<<dim3(64), dim3(256), 0, stream>>>(
      w_first, (const float*)d_in[20], (const float*)d_in[30], wtpH, wtpV, wpack);

  tof16_pack_kernel<<<dim3(Hq, Bq), dim3(192), 0, stream>>>(x, xpack);
  conv7_mfma_kernel<<<dim3(4, 96, 2), dim3(256), 0, stream>>>(xpack, wpack, bufA);

  pool_fused_kernel<<<dim3(6, 128), dim3(256), 0, stream>>>(bufA, x1);

  dwf_kernel<<<dim3(144, 8, 4), dim3(256), 0, stream>>>(x1, wEffH, bEffH, wB,
      wEffV, bEffV, wB + 64*18*20, fpackH, fpackV);

  off_cum_kernel<<<dim3(144, 2, 2), dim3(256), 0, stream>>>(fpackH, fpackV,
      wOffH, bOffH, wOffV, bOffV, hcum, vcum);

  einsum_mfma_kernel<<<dim3(576, 2), dim3(128), 0, stream>>>(fpackH, fpackV,
      hcum, vcum, wtpH, wtpV, (const float*)d_in[21], (const float*)d_in[31], bufA, bufB);

  gnstats_kernel<<<dim3(256), dim3(256), 0, stream>>>(bufA, bufB, stats);
  gnfinal_kernel<<<dim3(1), dim3(256), 0, stream>>>(stats,
      (const float*)d_in[22], (const float*)d_in[23],
      (const float*)d_in[32], (const float*)d_in[33], gnAB);

  final2_kernel<<<dim3(144, 2), dim3(256), 0, stream>>>(bufA, bufB, x1, gnAB, lwT, lbO, (float*)d_out);
}

// Round 21
// 348.611 us; speedup vs baseline: 1.7869x; 1.0453x over previous
//
#include <hip/hip_runtime.h>
#include <hip/hip_bf16.h>
#include <hip/hip_fp16.h>
#include <math.h>

#define Bq 2
#define Cq 64
#define Hq 192
#define Wq 192
#define HWq (Hq*Wq)            // 36864
#define Nq ((size_t)Bq*Cq*HWq) // 4718592

typedef __attribute__((ext_vector_type(8))) _Float16 f16x8;
typedef __attribute__((ext_vector_type(4))) float f32x4;

__device__ inline unsigned short h2us(__half h) {
  union { __half h; unsigned short u; } v; v.h = h; return v.u;
}

// ---------------------------------------------------------------------------
// Small prep (1 block) — register-unrolled composition
// ---------------------------------------------------------------------------
__global__ __launch_bounds__(256) void prep_small_kernel(
    const float* hc1_w, const float* hc1_b, const float* hc2_w, const float* hc2_b,
    const float* hc3_w, const float* hc3_b,
    const float* vc1_w, const float* vc1_b, const float* vc2_w, const float* vc2_b,
    const float* vc3_w, const float* vc3_b,
    const float* h_off_w, const float* h_off_b, const float* h_bn_g, const float* h_bn_b,
    const float* h_bn_m, const float* h_bn_v,
    const float* v_off_w, const float* v_off_b, const float* v_bn_g, const float* v_bn_b,
    const float* v_bn_m, const float* v_bn_v,
    const float* last_w, const float* last_g, const float* last_b, const float* last_m,
    const float* last_v,
    float* wEffH, float* bEffH, float* wEffV, float* bEffV,
    float* wOffH, float* bOffH, float* wOffV, float* bOffV,
    float* lwT, float* lbO)
{
  int t = threadIdx.x;
  if (t < 128) {
    int ch = t & 63;
    bool ish = t < 64;
    const float* w1p = (ish ? hc1_w : vc1_w) + ch*9;
    const float* w2p = (ish ? hc2_w : vc2_w) + ch*7;
    const float* w3p = (ish ? hc3_w : vc3_w) + ch*5;
    float w1r[9], w2r[7], w3r[5];
#pragma unroll
    for (int j = 0; j < 9; j++) w1r[j] = w1p[j];
#pragma unroll
    for (int k = 0; k < 7; k++) w2r[k] = w2p[k];
#pragma unroll
    for (int m = 0; m < 5; m++) w3r[m] = w3p[m];
    float t15[15];
#pragma unroll
    for (int s = 0; s < 15; s++) {
      float a = 0.f;
#pragma unroll
      for (int j = 0; j < 9; j++) { int k2 = s - j; if (k2 >= 0 && k2 < 7) a += w1r[j]*w2r[k2]; }
      t15[s] = a;
    }
    float* we = (ish ? wEffH : wEffV) + ch*19;
#pragma unroll
    for (int s = 0; s < 19; s++) {
      float a = 0.f;
#pragma unroll
      for (int j = 0; j < 15; j++) { int k3 = s - j; if (k3 >= 0 && k3 < 5) a += t15[j]*w3r[k3]; }
      we[s] = a;
    }
    float S2 = 0.f, S3 = 0.f;
#pragma unroll
    for (int j = 0; j < 7; j++) S2 += w2r[j];
#pragma unroll
    for (int j = 0; j < 5; j++) S3 += w3r[j];
    float b1 = (ish ? hc1_b : vc1_b)[ch];
    float b2 = (ish ? hc2_b : vc2_b)[ch];
    float b3 = (ish ? hc3_b : vc3_b)[ch];
    (ish ? bEffH : bEffV)[ch] = b1*S2*S3 + b2*S3 + b3;
  }
  for (int idx = t; idx < 9*64*7; idx += 256) {
    int tap = idx / 448; int rem = idx % 448; int i = rem / 7; int m = rem % 7;
    float invh = h_bn_g[m] / sqrtf(h_bn_v[m] + 1e-5f);
    wOffH[(tap*64 + i)*8 + m] = h_off_w[(m*64 + i)*9 + tap] * invh;
    float invv = v_bn_g[7+m] / sqrtf(v_bn_v[7+m] + 1e-5f);
    wOffV[(tap*64 + i)*8 + m] = v_off_w[((7+m)*64 + i)*9 + tap] * invv;
  }
  if (t < 7) {
    float invh = h_bn_g[t] / sqrtf(h_bn_v[t] + 1e-5f);
    bOffH[t] = h_off_b[t]*invh + h_bn_b[t] - h_bn_m[t]*invh;
    float invv = v_bn_g[7+t] / sqrtf(v_bn_v[7+t] + 1e-5f);
    bOffV[t] = v_off_b[7+t]*invv + v_bn_b[7+t] - v_bn_m[7+t]*invv;
  }
  for (int idx = t; idx < 4096; idx += 256) {
    int o = idx % 64; int i = idx / 64;
    float inv = last_g[o] / sqrtf(last_v[o] + 1e-3f);
    lwT[i*64 + o] = last_w[o*64 + i] * inv;
  }
  if (t < 64) {
    float inv = last_g[t] / sqrtf(last_v[t] + 1e-3f);
    lbO[t] = last_b[t] - last_m[t]*inv;
  }
}

// ---------------------------------------------------------------------------
// Border prep — fully unrolled, registers only
// ---------------------------------------------------------------------------
__global__ __launch_bounds__(256) void prep_border_kernel(
    const float* hc1_w, const float* hc1_b, const float* hc2_w, const float* hc2_b,
    const float* hc3_w, const float* hc3_b,
    const float* vc1_w, const float* vc1_b, const float* vc2_w, const float* vc2_b,
    const float* vc3_w, const float* vc3_b,
    float* wB)
{
  int tid = blockIdx.x*256 + threadIdx.x;
  if (tid >= 2*64*18) return;
  int cls = tid % 18;
  int ch  = (tid / 18) % 64;
  int br  = tid / (18*64);
  int c = (cls < 9) ? cls : cls + 174;
  const float* w1p = (br==0 ? hc1_w : vc1_w) + ch*9;
  const float* w2p = (br==0 ? hc2_w : vc2_w) + ch*7;
  const float* w3p = (br==0 ? hc3_w : vc3_w) + ch*5;
  float b1 = (br==0 ? hc1_b : vc1_b)[ch];
  float b2 = (br==0 ? hc2_b : vc2_b)[ch];
  float b3 = (br==0 ? hc3_b : vc3_b)[ch];
  float w1r[9], w2r[7], w3r[5];
#pragma unroll
  for (int j = 0; j < 9; j++) w1r[j] = w1p[j];
#pragma unroll
  for (int k = 0; k < 7; k++) w2r[k] = w2p[k];
#pragma unroll
  for (int m = 0; m < 5; m++) w3r[m] = w3p[m];

  float acc[19];
#pragma unroll
  for (int s = 0; s < 19; s++) acc[s] = 0.f;
  float bacc = b3;
#pragma unroll
  for (int m = 0; m < 5; m++) {
    int d = c + m - 2;
    bool dok = (d >= 0 && d < Wq);
    float s2b = b2;
#pragma unroll
    for (int k = 0; k < 7; k++) {
      int e = d + k - 3;
      bool eok = (e >= 0 && e < Wq);
      if (eok) s2b += w2r[k] * b1;
      float wmk = w3r[m] * w2r[k];
#pragma unroll
      for (int j = 0; j < 9; j++) {
        int fd = e + j - 4;
        bool fok = (fd >= 0 && fd < Wq);
        float contrib = (dok && eok && fok) ? wmk * w1r[j] : 0.f;
        acc[m + k + j] += contrib;
      }
    }
    if (dok) bacc += w3r[m] * s2b;
  }
  float* dst = wB + ((size_t)(br*64 + ch)*18 + cls)*20;
#pragma unroll
  for (int s = 0; s < 19; s++) dst[s] = acc[s];
  dst[19] = bacc;
}

// ---------------------------------------------------------------------------
// Big prep: dsc weights -> f16 hi/lo MFMA pack [tap][kc][hl][oc][32]
//           + w_first f16 hi/lo pack for conv7 [h][tap][hl][oc][32].
// ---------------------------------------------------------------------------
__global__ __launch_bounds__(256) void prep_big_kernel(
    const float* __restrict__ w_first,
    const float* __restrict__ h_dsc_w, const float* __restrict__ v_dsc_w,
    unsigned short* __restrict__ wtpH, unsigned short* __restrict__ wtpV,
    unsigned short* __restrict__ wpack)
{
  int tid = blockIdx.x*256 + threadIdx.x;
  int nthr = gridDim.x*256;
  for (int idx = tid; idx < 7*2*2*64*32; idx += nthr) {
    int ch32 = idx & 31;
    int oc   = (idx >> 5) & 63;
    int hl   = (idx >> 11) & 1;
    int kc   = (idx >> 12) & 1;
    int tap  = idx >> 13;
    int i = kc*32 + ch32;
    float vh = h_dsc_w[oc*448 + i*7 + tap];
    float vv = v_dsc_w[oc*448 + i*7 + tap];
    _Float16 hh = (_Float16)vh;
    _Float16 hv = (_Float16)vv;
    unsigned short uh, uv;
    if (!hl) { uh = *(unsigned short*)&hh; uv = *(unsigned short*)&hv; }
    else {
      _Float16 lh = (_Float16)(vh - (float)hh);
      _Float16 lv = (_Float16)(vv - (float)hv);
      uh = *(unsigned short*)&lh; uv = *(unsigned short*)&lv;
    }
    wtpH[idx] = uh; wtpV[idx] = uv;
  }
  for (int e = tid; e < 2*49*2*64*32; e += nthr) {
    int ch  = e & 31;
    int oc  = (e >> 5) & 63;
    int hl  = (e >> 11) & 1;
    int rest = e >> 12;
    int tap = rest % 49;
    int h   = rest / 49;
    float wv = w_first[((size_t)oc*64 + h*32 + ch)*49 + tap];
    __half hh = __float2half(wv);
    unsigned short us;
    if (!hl) us = h2us(hh);
    else { float rr = wv - __half2float(hh); us = h2us(__float2half(rr)); }
    wpack[e] = us;
  }
}

// ---------------------------------------------------------------------------
// x (NCHW f32) -> xpack single f16: [b][r][c][64]
// ---------------------------------------------------------------------------
__global__ __launch_bounds__(192) void tof16_pack_kernel(const float* __restrict__ x,
                                                         unsigned short* __restrict__ xpack)
{
  __shared__ unsigned int s[192*64];
  int r = blockIdx.x, b = blockIdx.y;
  int t = threadIdx.x;
  for (int ch = 0; ch < 64; ch++) {
    float v = x[((size_t)(b*64+ch)*Hq + r)*Wq + t];
    _Float16 hh = (_Float16)v;
    s[t*64 + (ch ^ (t & 31))] = (unsigned int)*(unsigned short*)&hh;
  }
  __syncthreads();
  unsigned short* dst = xpack + ((size_t)b*Hq + r)*Wq*64;
  for (int i = 0; i < 8; i++) {
    int gidx = i*192 + t;
    int c = gidx >> 3, g = gidx & 7;
    unsigned short tmp[8];
#pragma unroll
    for (int j = 0; j < 8; j++) {
      int ch = g*8 + j;
      tmp[j] = (unsigned short)s[c*64 + (ch ^ (c & 31))];
    }
    uint4 v;
    v.x = (unsigned int)tmp[0] | ((unsigned int)tmp[1] << 16);
    v.y = (unsigned int)tmp[2] | ((unsigned int)tmp[3] << 16);
    v.z = (unsigned int)tmp[4] | ((unsigned int)tmp[5] << 16);
    v.w = (unsigned int)tmp[6] | ((unsigned int)tmp[7] << 16);
    *(uint4*)(dst + (size_t)gidx*8) = v;
  }
}

// ---------------------------------------------------------------------------
// 7x7 conv via MFMA, 2-pass (x single f16, w hi/lo exact) — R17 validated.
// ---------------------------------------------------------------------------
__global__ __launch_bounds__(256) void conv7_mfma_kernel(
    const unsigned short* __restrict__ xpack,   // [b][r][c][64] f16
    const unsigned short* __restrict__ wpack,   // [h][tap][hl][oc][32] f16
    float* __restrict__ out)
{
  __shared__ __align__(16) unsigned short sA[8*54*32];   // 27648 B
  int ct = blockIdx.x;          // 0..3
  int rt = blockIdx.y;          // 0..95
  int b  = blockIdx.z;
  int r0 = rt*2, c0 = ct*48;
  int t = threadIdx.x;
  int wv = t >> 6;              // wave -> oc quarter
  int l  = t & 63;
  int l15 = l & 15, lg = l >> 4;
  int oc = wv*16 + l15;

  f32x4 acc[2][3];
#pragma unroll
  for (int i = 0; i < 2; i++)
#pragma unroll
    for (int j = 0; j < 3; j++) acc[i][j] = (f32x4){0.f,0.f,0.f,0.f};

  for (int h = 0; h < 2; h++) {
    __syncthreads();
    for (int idx = t; idx < 8*54*4; idx += 256) {
      int g = idx & 3, pix = idx >> 2;
      int row = pix / 54, col = pix % 54;
      int gr = r0 - 3 + row, gc = c0 - 3 + col;
      uint4 v = {0u,0u,0u,0u};
      if (gr >= 0 && gr < Hq && gc >= 0 && gc < Wq)
        v = *(const uint4*)(xpack + (((size_t)b*Hq + gr)*Wq + gc)*64 + (h*4 + g)*8);
      ((uint4*)sA)[(row*54 + col)*4 + (g ^ ((col >> 1) & 3))] = v;
    }
    __syncthreads();
    const unsigned short* wb = wpack + (size_t)h*49*4096;
#pragma unroll 7
    for (int tap = 0; tap < 49; tap++) {
      int dy = tap / 7, dx = tap % 7;
      f16x8 bh = *(const f16x8*)(wb + (size_t)tap*4096 +        oc*32 + lg*8);
      f16x8 bl = *(const f16x8*)(wb + (size_t)tap*4096 + 2048 + oc*32 + lg*8);
#pragma unroll
      for (int rw = 0; rw < 2; rw++) {
        int arow = rw + dy;
        f16x8 a[3];
#pragma unroll
        for (int tc = 0; tc < 3; tc++) {
          int col = tc*16 + l15 + dx;
          a[tc] = *(const f16x8*)((const uint4*)sA + (arow*54 + col)*4 + (lg ^ ((col >> 1) & 3)));
        }
#pragma unroll
        for (int tc = 0; tc < 3; tc++) {
          acc[rw][tc] = __builtin_amdgcn_mfma_f32_16x16x32_f16(a[tc], bh, acc[rw][tc], 0, 0, 0);
          acc[rw][tc] = __builtin_amdgcn_mfma_f32_16x16x32_f16(a[tc], bl, acc[rw][tc], 0, 0, 0);
        }
      }
    }
  }
#pragma unroll
  for (int rw = 0; rw < 2; rw++) {
    float* dst = out + ((size_t)(b*64 + oc)*Hq + (r0 + rw))*Wq + c0;
#pragma unroll
    for (int tc = 0; tc < 3; tc++) {
      f32x4 v = acc[rw][tc];
      *(float4*)(dst + tc*16 + lg*4) = make_float4(v[0], v[1], v[2], v[3]);
    }
  }
}

// ---------------------------------------------------------------------------
// FUSED separable 7x7 avg pool: one kernel, LDS-staged.
// ---------------------------------------------------------------------------
__global__ __launch_bounds__(256) void pool_fused_kernel(const float* __restrict__ in,
                                                         float* __restrict__ out)
{
  __shared__ float raw[38][192];
  __shared__ float cs[32][192];
  int rt = blockIdx.x;
  int plane = blockIdx.y;
  int r0 = rt*32;
  int t = threadIdx.x;
  const float* src = in + (size_t)plane*HWq;
  for (int idx = t; idx < 38*192; idx += 256) {
    int lr = idx / 192, c = idx % 192;
    int gr = r0 - 3 + lr;
    raw[lr][c] = (gr >= 0 && gr < Hq) ? src[gr*Wq + c] : 0.f;
  }
  __syncthreads();
  for (int idx = t; idx < 32*192; idx += 256) {
    int lr = idx / 192, c = idx % 192;
    float s = 0.f;
#pragma unroll
    for (int dr = 0; dr < 7; dr++) s += raw[lr + dr][c];
    cs[lr][c] = s;
  }
  __syncthreads();
  float* dst = out + (size_t)plane*HWq + r0*Wq;
  for (int idx = t; idx < 32*192; idx += 256) {
    int lr = idx / 192, c = idx % 192;
    float s = 0.f;
#pragma unroll
    for (int dc = -3; dc <= 3; dc++) {
      int cc = c + dc;
      if (cc >= 0 && cc < Wq) s += cs[lr][cc];
    }
    dst[idx] = s * (1.f/49.f);
  }
}

// ---------------------------------------------------------------------------
// MERGED fused depthwise 19-tap + f16 HI/LO plane-major pack [b][sub16][px][8].
// Grid (144, 8, 4): z = branch*2 + b.
// ---------------------------------------------------------------------------
__global__ __launch_bounds__(256) void dwf_kernel(const float* __restrict__ x1,
                                                  const float* __restrict__ wEffH,
                                                  const float* __restrict__ bEffH,
                                                  const float* __restrict__ wBH,
                                                  const float* __restrict__ wEffV,
                                                  const float* __restrict__ bEffV,
                                                  const float* __restrict__ wBV,
                                                  unsigned short* __restrict__ packH,
                                                  unsigned short* __restrict__ packV)
{
  __shared__ float sW[8][19][20];
  int z = blockIdx.z;
  int br = z >> 1, b = z & 1;
  const float* wEff = br ? wEffV : wEffH;
  const float* bEff = br ? bEffV : bEffH;
  const float* wB   = br ? wBV   : wBH;
  unsigned short* pack = br ? packV : packH;
  int g8 = blockIdx.y;
  int t = threadIdx.x;
  int chb = g8*8;
  for (int i = t; i < 8*380; i += 256) {
    int ch8 = i / 380; int rem = i % 380;
    int row = rem / 20, jj = rem % 20;
    int ch = chb + ch8;
    float v;
    if (row < 18) v = wB[((size_t)ch*18 + row)*20 + jj];
    else v = (jj < 19) ? wEff[ch*19 + jj] : bEff[ch];
    sW[ch8][row][jj] = v;
  }
  __syncthreads();
  int p = blockIdx.x*256 + t;
  int r = p / Wq, c = p % Wq;
  float vals[8];
  if (br == 0) {
    int row = (c < 9) ? c : ((c >= Wq-9) ? (c - 174) : 18);
#pragma unroll
    for (int ch8 = 0; ch8 < 8; ch8++) {
      const float* src = x1 + (size_t)(b*Cq + chb + ch8)*HWq + r*Wq;
      float s = sW[ch8][row][19];
#pragma unroll
      for (int j = 0; j < 19; j++) {
        int idx = min(max(c + j - 9, 0), Wq-1);
        s += src[idx] * sW[ch8][row][j];
      }
      vals[ch8] = s;
    }
  } else {
    int row = (r < 9) ? r : ((r >= Hq-9) ? (r - 174) : 18);
#pragma unroll
    for (int ch8 = 0; ch8 < 8; ch8++) {
      const float* src = x1 + (size_t)(b*Cq + chb + ch8)*HWq + c;
      float s = sW[ch8][row][19];
#pragma unroll
      for (int j = 0; j < 19; j++) {
        int idx = min(max(r + j - 9, 0), Hq-1);
        s += src[idx*Wq] * sW[ch8][row][j];
      }
      vals[ch8] = s;
    }
  }
  unsigned int hi[4], lo[4];
#pragma unroll
  for (int q = 0; q < 4; q++) {
    __half h0 = __float2half(vals[2*q]);
    __half h1 = __float2half(vals[2*q+1]);
    __half l0 = __float2half(vals[2*q]   - __half2float(h0));
    __half l1 = __float2half(vals[2*q+1] - __half2float(h1));
    hi[q] = (unsigned int)h2us(h0) | ((unsigned int)h2us(h1) << 16);
    lo[q] = (unsigned int)h2us(l0) | ((unsigned int)h2us(l1) << 16);
  }
  *(uint4*)(pack + (((size_t)b*16 + g8)*HWq + p)*8)     = make_uint4(hi[0], hi[1], hi[2], hi[3]);
  *(uint4*)(pack + (((size_t)b*16 + 8 + g8)*HWq + p)*8) = make_uint4(lo[0], lo[1], lo[2], lo[3]);
}

// ---------------------------------------------------------------------------
// MERGED offset conv + tanh + cum (reads HI+LO -> near-f32 offsets; the
// bilinear boundary discontinuity makes offsets precision-critical).
// Grid (144, 2, 2).
// ---------------------------------------------------------------------------
__global__ __launch_bounds__(256) void off_cum_kernel(const unsigned short* __restrict__ fpH,
                                                      const unsigned short* __restrict__ fpV,
                                                      const float* __restrict__ wOffH,
                                                      const float* __restrict__ bOffH,
                                                      const float* __restrict__ wOffV,
                                                      const float* __restrict__ bOffV,
                                                      float* __restrict__ hcum,
                                                      float* __restrict__ vcum)
{
  const size_t HW8 = (size_t)HWq*8;
  int br = blockIdx.z;
  const unsigned short* fp = br ? fpV : fpH;
  const float* wOff = br ? wOffV : wOffH;
  const float* bOff = br ? bOffV : bOffH;
  float* cum = br ? vcum : hcum;
  int b = blockIdx.y;
  int p = blockIdx.x*256 + threadIdx.x;
  int r = p / Wq, c = p % Wq;
  float tv[7];
#pragma unroll
  for (int m = 0; m < 7; m++) tv[m] = bOff[m];
  const unsigned short* fb = fp + (size_t)b*HWq*128;
  for (int tap = 0; tap < 9; tap++) {
    int dy = tap/3 - 1, dx = tap%3 - 1;
    int rr = r + dy, cc = c + dx;
    if (rr < 0 || rr >= Hq || cc < 0 || cc >= Wq) continue;
    const unsigned short* p0 = fb + ((size_t)rr*Wq + cc)*8;
    const float* wp = wOff + tap*512;
    for (int g = 0; g < 8; g++) {
      f16x8 hv = *(const f16x8*)(p0 + (size_t)g*HW8);
      f16x8 lv = *(const f16x8*)(p0 + (size_t)(8 + g)*HW8);
#pragma unroll
      for (int e = 0; e < 8; e++) {
        float fv = (float)hv[e] + (float)lv[e];
        const float* wr = wp + (g*8 + e)*8;
#pragma unroll
        for (int m = 0; m < 7; m++) tv[m] += fv * wr[m];
      }
    }
  }
#pragma unroll
  for (int m = 0; m < 7; m++) tv[m] = tanhf(tv[m]);
  float c0 = tv[0], c1 = tv[1] + tv[2], c2 = tv[2], c3 = 0.f;
  float c4 = tv[4], c5 = tv[4] + tv[5], c6 = tv[6];
  size_t bb = (size_t)b*7*HWq + p;
  cum[bb + 0*HWq] = c0; cum[bb + 1*HWq] = c1; cum[bb + 2*HWq] = c2;
  cum[bb + 3*HWq] = c3; cum[bb + 4*HWq] = c4; cum[bb + 5*HWq] = c5;
  cum[bb + 6*HWq] = c6;
}

// ---------------------------------------------------------------------------
// MERGED deformable sample + einsum via MFMA, 2-PASS (A single f16, W hi/lo).
// A staged from HI granules only (16 scattered loads/tap/thread).
// 2 taps staged per barrier phase: LDS [2][128px][64] f16 = 32 KB.
// Grid (576, 2): y = morph. XCD-banded swizzle per morph slice.
// ---------------------------------------------------------------------------
__global__ __launch_bounds__(128) void einsum_mfma_kernel(
    const unsigned short* __restrict__ fpH, const unsigned short* __restrict__ fpV,
    const float* __restrict__ cumH, const float* __restrict__ cumV,
    const unsigned short* __restrict__ wtpHp, const unsigned short* __restrict__ wtpVp,
    const float* __restrict__ dscbH, const float* __restrict__ dscbV,
    float* __restrict__ outH, float* __restrict__ outV)
{
  __shared__ __align__(16) unsigned short sA[2*128*64];  // 32 KB
  const size_t HW8 = (size_t)HWq*8;
  int morph = blockIdx.y;
  const unsigned short* fp  = morph ? fpV   : fpH;
  const float* cum          = morph ? cumV  : cumH;
  const unsigned short* wtp = morph ? wtpVp : wtpHp;
  const float* dsc_b        = morph ? dscbV : dscbH;
  float* out                = morph ? outV  : outH;
  int bid = blockIdx.x;
  int swz = (bid & 7)*72 + (bid >> 3);
  int b   = swz / 288;
  int blk = swz % 288;
  int t = threadIdx.x;
  int w = t >> 6, l = t & 63;
  int l15 = l & 15, lg = l >> 4;
  int l7 = l15 & 7;
  int p = blk*128 + w*64 + l;
  int r = p / Wq, c = p % Wq;

  f32x4 acc[4][4];
#pragma unroll
  for (int i = 0; i < 4; i++)
#pragma unroll
    for (int j = 0; j < 4; j++) acc[i][j] = (f32x4){0.f,0.f,0.f,0.f};

  const unsigned short* fb = fp + (size_t)b*HWq*128;

  for (int kp = 0; kp < 4; kp++) {
    int k0 = kp*2;
    int nk = (kp < 3) ? 2 : 1;
    // ---- stage nk taps: sample hi granules + lerp -> f16 rows -------------
    for (int kk = 0; kk < nk; kk++) {
      int k = k0 + kk;
      unsigned short* myrow = sA + (size_t)(kk*128 + w*64 + l)*64;
      bool oob;
      const unsigned short *p0, *p1;
      float w0, w1;
      if (morph == 0) {
        int xi = c + k - 3;
        oob = (xi < 0 || xi >= Wq);
        if (!oob) {
          float y = (float)r + cum[((size_t)(b*7 + k))*HWq + p];
          float y0 = floorf(y);
          int y0q = (int)y0;
          int y0i = min(max(y0q, 0), Hq-1);
          int y1i = min(max(y0q + 1, 0), Hq-1);
          float y0f = fminf(fmaxf(y0, 0.f), (float)Hq);
          float y1f = fminf(fmaxf(y0 + 1.f, 0.f), (float)Hq);
          w0 = y1f - y; w1 = y - y0f;
          p0 = fb + ((size_t)y0i*Wq + xi)*8;
          p1 = fb + ((size_t)y1i*Wq + xi)*8;
        }
      } else {
        int yi = r + k - 3;
        oob = (yi < 0 || yi >= Hq);
        if (!oob) {
          float xf = (float)c + cum[((size_t)(b*7 + k))*HWq + p];
          float x0 = floorf(xf);
          int x0q = (int)x0;
          int x0i = min(max(x0q, 0), Wq-1);
          int x1i = min(max(x0q + 1, 0), Wq-1);
          float x0f = fminf(fmaxf(x0, 0.f), (float)Wq);
          float x1f = fminf(fmaxf(x0 + 1.f, 0.f), (float)Wq);
          w0 = x1f - xf; w1 = xf - x0f;
          p0 = fb + ((size_t)yi*Wq + x0i)*8;
          p1 = fb + ((size_t)yi*Wq + x1i)*8;
        }
      }
      if (oob) {
        uint4 z = {0u,0u,0u,0u};
#pragma unroll
        for (int j = 0; j < 8; j++) ((uint4*)myrow)[j] = z;
      } else {
#pragma unroll
        for (int g = 0; g < 8; g++) {
          f16x8 a0h = *(const f16x8*)(p0 + (size_t)g*HW8);
          f16x8 a1h = *(const f16x8*)(p1 + (size_t)g*HW8);
          f16x8 sh;
#pragma unroll
          for (int e = 0; e < 8; e++) {
            float v = w0*(float)a0h[e] + w1*(float)a1h[e];
            sh[e] = (_Float16)v;
          }
          *(f16x8*)(myrow + (size_t)(g ^ l7)*8) = sh;
        }
      }
    }
    __syncthreads();
    // ---- MFMA over staged taps -------------------------------------------
    for (int kk = 0; kk < nk; kk++) {
      int k = k0 + kk;
#pragma unroll
      for (int kc = 0; kc < 2; kc++) {
        const unsigned short* wbase = wtp + (size_t)((k*2 + kc)*2)*2048;
        f16x8 bh[4], bl[4];
#pragma unroll
        for (int tb = 0; tb < 4; tb++) {
          bh[tb] = *(const f16x8*)(wbase + (tb*16 + l15)*32 + lg*8);
          bl[tb] = *(const f16x8*)(wbase + 2048 + (tb*16 + l15)*32 + lg*8);
        }
        f16x8 ah[4];
#pragma unroll
        for (int ta = 0; ta < 4; ta++) {
          const unsigned short* rbase = sA + (size_t)(kk*128 + w*64 + ta*16 + l15)*64;
          ah[ta] = *(const f16x8*)(rbase + (size_t)((kc*4 + lg) ^ l7)*8);
        }
#pragma unroll
        for (int ta = 0; ta < 4; ta++)
#pragma unroll
          for (int tb = 0; tb < 4; tb++) {
            acc[ta][tb] = __builtin_amdgcn_mfma_f32_16x16x32_f16(ah[ta], bh[tb], acc[ta][tb], 0, 0, 0);
            acc[ta][tb] = __builtin_amdgcn_mfma_f32_16x16x32_f16(ah[ta], bl[tb], acc[ta][tb], 0, 0, 0);
          }
      }
    }
    __syncthreads();
  }
  int pbase = blk*128 + w*64;
#pragma unroll
  for (int tb = 0; tb < 4; tb++) {
    int oc = tb*16 + l15;
    float bias = dsc_b[oc];
    float* dst = out + (size_t)(b*64 + oc)*HWq + pbase;
#pragma unroll
    for (int ta = 0; ta < 4; ta++) {
      f32x4 v = acc[ta][tb];
      *(float4*)(dst + ta*16 + lg*4) = make_float4(v[0]+bias, v[1]+bias, v[2]+bias, v[3]+bias);
    }
  }
}

// ---------------------------------------------------------------------------
// GroupNorm stats + finalize
// ---------------------------------------------------------------------------
__global__ __launch_bounds__(256) void gnstats_kernel(const float* __restrict__ h_ds,
                                                      const float* __restrict__ v_ds,
                                                      float* __restrict__ stats)
{
  int plane = blockIdx.x;
  int buf = plane >> 7;
  int rem = plane & 127;
  const float* src = (buf ? v_ds : h_ds) + (size_t)rem*HWq;
  float s = 0.f, s2 = 0.f;
  for (int i = threadIdx.x; i < HWq; i += 256) {
    float v = src[i];
    s += v; s2 += v*v;
  }
  __shared__ float red[2][4];
  for (int off = 32; off; off >>= 1) {
    s  += __shfl_down(s, off);
    s2 += __shfl_down(s2, off);
  }
  if ((threadIdx.x & 63) == 0) { red[0][threadIdx.x >> 6] = s; red[1][threadIdx.x >> 6] = s2; }
  __syncthreads();
  if (threadIdx.x == 0) {
    s  = red[0][0] + red[0][1] + red[0][2] + red[0][3];
    s2 = red[1][0] + red[1][1] + red[1][2] + red[1][3];
    stats[plane*2 + 0] = s;
    stats[plane*2 + 1] = s2;
  }
}

__global__ __launch_bounds__(256) void gnfinal_kernel(const float* __restrict__ stats,
                                                      const float* __restrict__ h_gn_g, const float* __restrict__ h_gn_b,
                                                      const float* __restrict__ v_gn_g, const float* __restrict__ v_gn_b,
                                                      float* __restrict__ gnAB)
{
  int t = threadIdx.x;
  int buf = t >> 7, ch = t & 63;
  int base = t & ~3;
  float sum = 0.f, ss = 0.f;
#pragma unroll
  for (int q = 0; q < 4; q++) { sum += stats[(base+q)*2]; ss += stats[(base+q)*2 + 1]; }
  const float n = 4.f * HWq;
  float mean = sum / n;
  float var = ss / n - mean*mean;
  float gg = (buf ? v_gn_g : h_gn_g)[ch];
  float bb = (buf ? v_gn_b : h_gn_b)[ch];
  float A = gg / sqrtf(var + 1e-5f);
  gnAB[t*2 + 0] = A;
  gnAB[t*2 + 1] = bb - mean*A;
}

// ---------------------------------------------------------------------------
// FUSED: comb = relu(GN(h)) + relu(GN(v)) + x1 inline, then 1x1 conv + SiLU
// ---------------------------------------------------------------------------
__global__ __launch_bounds__(256) void final2_kernel(const float* __restrict__ hbuf,
                                                     const float* __restrict__ vbuf,
                                                     const float* __restrict__ x1,
                                                     const float* __restrict__ gnAB,
                                                     const float* __restrict__ lwT,
                                                     const float* __restrict__ lbO,
                                                     float* __restrict__ out)
{
  int b = blockIdx.y;
  int p = blockIdx.x*256 + threadIdx.x;
  float acc[64];
#pragma unroll
  for (int o = 0; o < 64; o++) acc[o] = 0.f;
  for (int i = 0; i < 64; i++) {
    size_t off = (size_t)(b*64 + i)*HWq + p;
    int plane = b*64 + i;
    int ih = plane*2;
    int iv = (128 + plane)*2;
    float hv = fmaxf(hbuf[off]*gnAB[ih] + gnAB[ih+1], 0.f);
    float vv = fmaxf(vbuf[off]*gnAB[iv] + gnAB[iv+1], 0.f);
    float cv = hv + vv + x1[off];
    const float* wr = lwT + i*64;
#pragma unroll
    for (int o = 0; o < 64; o++) acc[o] += cv * wr[o];
  }
  float* dst = out + (size_t)b*Cq*HWq + p;
#pragma unroll
  for (int o = 0; o < 64; o++) {
    float yv = acc[o] + lbO[o];
    dst[(size_t)o*HWq] = yv / (1.f + expf(-yv));
  }
}

// ---------------------------------------------------------------------------
extern "C" void kernel_launch(void* const* d_in, const int* in_sizes, int n_in,
                              void* d_out, int out_size, void* d_ws, size_t ws_size,
                              hipStream_t stream)
{
  const float* x       = (const float*)d_in[0];
  const float* w_first = (const float*)d_in[1];
  float* ws = (float*)d_ws;

  float* bufA = ws;            // conv7 out -> h-einsum-out
  float* bufB = ws + Nq;       // v-einsum-out
  float* x1   = ws + 2*Nq;
  float* h_ds = ws + 3*Nq;     // xpack -> fpackH
  float* v_ds = ws + 4*Nq;     // fpackV
  size_t off = 5*Nq;
  float* hcum  = ws + off; off += (size_t)Bq*7*HWq;
  float* vcum  = ws + off; off += (size_t)Bq*7*HWq;
  float* wEffH = ws + off; off += 64*19;
  float* bEffH = ws + off; off += 64;
  float* wEffV = ws + off; off += 64*19;
  float* bEffV = ws + off; off += 64;
  float* wtH   = ws + off; off += 64*64*7;   // holds wtpH f16 pack
  float* wtV   = ws + off; off += 64*64*7;   // holds wtpV f16 pack
  float* wOffH = ws + off; off += 9*64*8;
  float* bOffH = ws + off; off += 8;
  float* wOffV = ws + off; off += 9*64*8;
  float* bOffV = ws + off; off += 8;
  float* lwT   = ws + off; off += 64*64;
  float* lbO   = ws + off; off += 64;
  float* stats = ws + off; off += 512;
  float* gnAB  = ws + off; off += 512;
  float* wB    = ws + off; off += 2*64*18*20;
  unsigned short* wpack = (unsigned short*)(ws + off); off += 2*49*2*64*32/2 + 16;
  unsigned short* xpack  = (unsigned short*)h_ds;
  unsigned short* fpackH = (unsigned short*)h_ds;
  unsigned short* fpackV = (unsigned short*)v_ds;
  unsigned short* wtpH = (unsigned short*)wtH;
  unsigned short* wtpV = (unsigned short*)wtV;

  prep_small_kernel<<<dim3(1), dim3(256), 0, stream>>>(
      (const float*)d_in[2],  (const float*)d_in[3],  (const float*)d_in[4],  (const float*)d_in[5],
      (const float*)d_in[6],  (const float*)d_in[7],
      (const float*)d_in[8],  (const float*)d_in[9],  (const float*)d_in[10], (const float*)d_in[11],
      (const float*)d_in[12], (const float*)d_in[13],
      (const float*)d_in[14], (const float*)d_in[15], (const float*)d_in[16], (const float*)d_in[17],
      (const float*)d_in[18], (const float*)d_in[19],
      (const float*)d_in[24], (const float*)d_in[25], (const float*)d_in[26], (const float*)d_in[27],
      (const float*)d_in[28], (const float*)d_in[29],
      (const float*)d_in[34], (const float*)d_in[35], (const float*)d_in[36], (const float*)d_in[37],
      (const float*)d_in[38],
      wEffH, bEffH, wEffV, bEffV, wOffH, bOffH, wOffV, bOffV, lwT, lbO);

  prep_border_kernel<<<dim3(9), dim3(256), 0, stream>>>(
      (const float*)d_in[2],  (const float*)d_in[3],  (const float*)d_in[4],  (const float*)d_in[5],
      (const float*)d_in[6],  (const float*)d_in[7],
      (const float*)d_in[8],  (const float*)d_in[9],  (const float*)d_in[10], (const float*)d_in[11],
      (const float*)d_in[12], (const float*)d_in[13], wB);

  prep_big_kernel<<<dim3(64), dim3(256), 0, stream>>>(
      w_first, (const float*)d_in[20], (const float*)d_in[30], wtpH, wtpV, wpack);

  tof16_pack_kernel<<<dim3(Hq, Bq), dim3(192), 0, stream>>>(x, xpack);
  conv7_mfma_kernel<<<dim3(4, 96, 2), dim3(256), 0, stream>>>(xpack, wpack, bufA);

  pool_fused_kernel<<<dim3(6, 128), dim3(256), 0, stream>>>(bufA, x1);

  dwf_kernel<<<dim3(144, 8, 4), dim3(256), 0, stream>>>(x1, wEffH, bEffH, wB,
      wEffV, bEffV, wB + 64*18*20, fpackH, fpackV);

  off_cum_kernel<<<dim3(144, 2, 2), dim3(256), 0, stream>>>(fpackH, fpackV,
      wOffH, bOffH, wOffV, bOffV, hcum, vcum);

  einsum_mfma_kernel<<<dim3(576, 2), dim3(128), 0, stream>>>(fpackH, fpackV,
      hcum, vcum, wtpH, wtpV, (const float*)d_in[21], (const float*)d_in[31], bufA, bufB);

  gnstats_kernel<<<dim3(256), dim3(256), 0, stream>>>(bufA, bufB, stats);
  gnfinal_kernel<<<dim3(1), dim3(256), 0, stream>>>(stats,
      (const float*)d_in[22], (const float*)d_in[23],
      (const float*)d_in[32], (const float*)d_in[33], gnAB);

  final2_kernel<<<dim3(144, 2), dim3(256), 0, stream>>>(bufA, bufB, x1, gnAB, lwT, lbO, (float*)d_out);
}

// Round 22
// 344.528 us; speedup vs baseline: 1.8081x; 1.0119x over previous
//
#include <hip/hip_runtime.h>
#include <hip/hip_bf16.h>
#include <hip/hip_fp16.h>
#include <math.h>

#define Bq 2
#define Cq 64
#define Hq 192
#define Wq 192
#define HWq (Hq*Wq)            // 36864
#define Nq ((size_t)Bq*Cq*HWq) // 4718592

typedef __attribute__((ext_vector_type(8))) _Float16 f16x8;
typedef __attribute__((ext_vector_type(4))) float f32x4;

__device__ inline unsigned short h2us(__half h) {
  union { __half h; unsigned short u; } v; v.h = h; return v.u;
}

// ---------------------------------------------------------------------------
// Small prep (1 block) — register-unrolled composition
// ---------------------------------------------------------------------------
__global__ __launch_bounds__(256) void prep_small_kernel(
    const float* hc1_w, const float* hc1_b, const float* hc2_w, const float* hc2_b,
    const float* hc3_w, const float* hc3_b,
    const float* vc1_w, const float* vc1_b, const float* vc2_w, const float* vc2_b,
    const float* vc3_w, const float* vc3_b,
    const float* h_off_w, const float* h_off_b, const float* h_bn_g, const float* h_bn_b,
    const float* h_bn_m, const float* h_bn_v,
    const float* v_off_w, const float* v_off_b, const float* v_bn_g, const float* v_bn_b,
    const float* v_bn_m, const float* v_bn_v,
    const float* last_w, const float* last_g, const float* last_b, const float* last_m,
    const float* last_v,
    float* wEffH, float* bEffH, float* wEffV, float* bEffV,
    float* wOffH, float* bOffH, float* wOffV, float* bOffV,
    float* lwT, float* lbO)
{
  int t = threadIdx.x;
  if (t < 128) {
    int ch = t & 63;
    bool ish = t < 64;
    const float* w1p = (ish ? hc1_w : vc1_w) + ch*9;
    const float* w2p = (ish ? hc2_w : vc2_w) + ch*7;
    const float* w3p = (ish ? hc3_w : vc3_w) + ch*5;
    float w1r[9], w2r[7], w3r[5];
#pragma unroll
    for (int j = 0; j < 9; j++) w1r[j] = w1p[j];
#pragma unroll
    for (int k = 0; k < 7; k++) w2r[k] = w2p[k];
#pragma unroll
    for (int m = 0; m < 5; m++) w3r[m] = w3p[m];
    float t15[15];
#pragma unroll
    for (int s = 0; s < 15; s++) {
      float a = 0.f;
#pragma unroll
      for (int j = 0; j < 9; j++) { int k2 = s - j; if (k2 >= 0 && k2 < 7) a += w1r[j]*w2r[k2]; }
      t15[s] = a;
    }
    float* we = (ish ? wEffH : wEffV) + ch*19;
#pragma unroll
    for (int s = 0; s < 19; s++) {
      float a = 0.f;
#pragma unroll
      for (int j = 0; j < 15; j++) { int k3 = s - j; if (k3 >= 0 && k3 < 5) a += t15[j]*w3r[k3]; }
      we[s] = a;
    }
    float S2 = 0.f, S3 = 0.f;
#pragma unroll
    for (int j = 0; j < 7; j++) S2 += w2r[j];
#pragma unroll
    for (int j = 0; j < 5; j++) S3 += w3r[j];
    float b1 = (ish ? hc1_b : vc1_b)[ch];
    float b2 = (ish ? hc2_b : vc2_b)[ch];
    float b3 = (ish ? hc3_b : vc3_b)[ch];
    (ish ? bEffH : bEffV)[ch] = b1*S2*S3 + b2*S3 + b3;
  }
  for (int idx = t; idx < 9*64*7; idx += 256) {
    int tap = idx / 448; int rem = idx % 448; int i = rem / 7; int m = rem % 7;
    float invh = h_bn_g[m] / sqrtf(h_bn_v[m] + 1e-5f);
    wOffH[(tap*64 + i)*8 + m] = h_off_w[(m*64 + i)*9 + tap] * invh;
    float invv = v_bn_g[7+m] / sqrtf(v_bn_v[7+m] + 1e-5f);
    wOffV[(tap*64 + i)*8 + m] = v_off_w[((7+m)*64 + i)*9 + tap] * invv;
  }
  if (t < 7) {
    float invh = h_bn_g[t] / sqrtf(h_bn_v[t] + 1e-5f);
    bOffH[t] = h_off_b[t]*invh + h_bn_b[t] - h_bn_m[t]*invh;
    float invv = v_bn_g[7+t] / sqrtf(v_bn_v[7+t] + 1e-5f);
    bOffV[t] = v_off_b[7+t]*invv + v_bn_b[7+t] - v_bn_m[7+t]*invv;
  }
  for (int idx = t; idx < 4096; idx += 256) {
    int o = idx % 64; int i = idx / 64;
    float inv = last_g[o] / sqrtf(last_v[o] + 1e-3f);
    lwT[i*64 + o] = last_w[o*64 + i] * inv;
  }
  if (t < 64) {
    float inv = last_g[t] / sqrtf(last_v[t] + 1e-3f);
    lbO[t] = last_b[t] - last_m[t]*inv;
  }
}

// ---------------------------------------------------------------------------
// Border prep — fully unrolled, registers only
// ---------------------------------------------------------------------------
__global__ __launch_bounds__(256) void prep_border_kernel(
    const float* hc1_w, const float* hc1_b, const float* hc2_w, const float* hc2_b,
    const float* hc3_w, const float* hc3_b,
    const float* vc1_w, const float* vc1_b, const float* vc2_w, const float* vc2_b,
    const float* vc3_w, const float* vc3_b,
    float* wB)
{
  int tid = blockIdx.x*256 + threadIdx.x;
  if (tid >= 2*64*18) return;
  int cls = tid % 18;
  int ch  = (tid / 18) % 64;
  int br  = tid / (18*64);
  int c = (cls < 9) ? cls : cls + 174;
  const float* w1p = (br==0 ? hc1_w : vc1_w) + ch*9;
  const float* w2p = (br==0 ? hc2_w : vc2_w) + ch*7;
  const float* w3p = (br==0 ? hc3_w : vc3_w) + ch*5;
  float b1 = (br==0 ? hc1_b : vc1_b)[ch];
  float b2 = (br==0 ? hc2_b : vc2_b)[ch];
  float b3 = (br==0 ? hc3_b : vc3_b)[ch];
  float w1r[9], w2r[7], w3r[5];
#pragma unroll
  for (int j = 0; j < 9; j++) w1r[j] = w1p[j];
#pragma unroll
  for (int k = 0; k < 7; k++) w2r[k] = w2p[k];
#pragma unroll
  for (int m = 0; m < 5; m++) w3r[m] = w3p[m];

  float acc[19];
#pragma unroll
  for (int s = 0; s < 19; s++) acc[s] = 0.f;
  float bacc = b3;
#pragma unroll
  for (int m = 0; m < 5; m++) {
    int d = c + m - 2;
    bool dok = (d >= 0 && d < Wq);
    float s2b = b2;
#pragma unroll
    for (int k = 0; k < 7; k++) {
      int e = d + k - 3;
      bool eok = (e >= 0 && e < Wq);
      if (eok) s2b += w2r[k] * b1;
      float wmk = w3r[m] * w2r[k];
#pragma unroll
      for (int j = 0; j < 9; j++) {
        int fd = e + j - 4;
        bool fok = (fd >= 0 && fd < Wq);
        float contrib = (dok && eok && fok) ? wmk * w1r[j] : 0.f;
        acc[m + k + j] += contrib;
      }
    }
    if (dok) bacc += w3r[m] * s2b;
  }
  float* dst = wB + ((size_t)(br*64 + ch)*18 + cls)*20;
#pragma unroll
  for (int s = 0; s < 19; s++) dst[s] = acc[s];
  dst[19] = bacc;
}

// ---------------------------------------------------------------------------
// Big prep: dsc weights -> f16 hi/lo MFMA pack [tap][kc][hl][oc][32]
//           + w_first f16 hi/lo pack for conv7 [h][tap][hl][oc][32].
// ---------------------------------------------------------------------------
__global__ __launch_bounds__(256) void prep_big_kernel(
    const float* __restrict__ w_first,
    const float* __restrict__ h_dsc_w, const float* __restrict__ v_dsc_w,
    unsigned short* __restrict__ wtpH, unsigned short* __restrict__ wtpV,
    unsigned short* __restrict__ wpack)
{
  int tid = blockIdx.x*256 + threadIdx.x;
  int nthr = gridDim.x*256;
  for (int idx = tid; idx < 7*2*2*64*32; idx += nthr) {
    int ch32 = idx & 31;
    int oc   = (idx >> 5) & 63;
    int hl   = (idx >> 11) & 1;
    int kc   = (idx >> 12) & 1;
    int tap  = idx >> 13;
    int i = kc*32 + ch32;
    float vh = h_dsc_w[oc*448 + i*7 + tap];
    float vv = v_dsc_w[oc*448 + i*7 + tap];
    _Float16 hh = (_Float16)vh;
    _Float16 hv = (_Float16)vv;
    unsigned short uh, uv;
    if (!hl) { uh = *(unsigned short*)&hh; uv = *(unsigned short*)&hv; }
    else {
      _Float16 lh = (_Float16)(vh - (float)hh);
      _Float16 lv = (_Float16)(vv - (float)hv);
      uh = *(unsigned short*)&lh; uv = *(unsigned short*)&lv;
    }
    wtpH[idx] = uh; wtpV[idx] = uv;
  }
  for (int e = tid; e < 2*49*2*64*32; e += nthr) {
    int ch  = e & 31;
    int oc  = (e >> 5) & 63;
    int hl  = (e >> 11) & 1;
    int rest = e >> 12;
    int tap = rest % 49;
    int h   = rest / 49;
    float wv = w_first[((size_t)oc*64 + h*32 + ch)*49 + tap];
    __half hh = __float2half(wv);
    unsigned short us;
    if (!hl) us = h2us(hh);
    else { float rr = wv - __half2float(hh); us = h2us(__float2half(rr)); }
    wpack[e] = us;
  }
}

// ---------------------------------------------------------------------------
// x (NCHW f32) -> xpack single f16: [b][r][c][64]
// ---------------------------------------------------------------------------
__global__ __launch_bounds__(192) void tof16_pack_kernel(const float* __restrict__ x,
                                                         unsigned short* __restrict__ xpack)
{
  __shared__ unsigned int s[192*64];
  int r = blockIdx.x, b = blockIdx.y;
  int t = threadIdx.x;
  for (int ch = 0; ch < 64; ch++) {
    float v = x[((size_t)(b*64+ch)*Hq + r)*Wq + t];
    _Float16 hh = (_Float16)v;
    s[t*64 + (ch ^ (t & 31))] = (unsigned int)*(unsigned short*)&hh;
  }
  __syncthreads();
  unsigned short* dst = xpack + ((size_t)b*Hq + r)*Wq*64;
  for (int i = 0; i < 8; i++) {
    int gidx = i*192 + t;
    int c = gidx >> 3, g = gidx & 7;
    unsigned short tmp[8];
#pragma unroll
    for (int j = 0; j < 8; j++) {
      int ch = g*8 + j;
      tmp[j] = (unsigned short)s[c*64 + (ch ^ (c & 31))];
    }
    uint4 v;
    v.x = (unsigned int)tmp[0] | ((unsigned int)tmp[1] << 16);
    v.y = (unsigned int)tmp[2] | ((unsigned int)tmp[3] << 16);
    v.z = (unsigned int)tmp[4] | ((unsigned int)tmp[5] << 16);
    v.w = (unsigned int)tmp[6] | ((unsigned int)tmp[7] << 16);
    *(uint4*)(dst + (size_t)gidx*8) = v;
  }
}

// ---------------------------------------------------------------------------
// 7x7 conv via MFMA, 2-pass (x single f16, w hi/lo exact) — R17 validated.
// ---------------------------------------------------------------------------
__global__ __launch_bounds__(256) void conv7_mfma_kernel(
    const unsigned short* __restrict__ xpack,   // [b][r][c][64] f16
    const unsigned short* __restrict__ wpack,   // [h][tap][hl][oc][32] f16
    float* __restrict__ out)
{
  __shared__ __align__(16) unsigned short sA[8*54*32];   // 27648 B
  int ct = blockIdx.x;          // 0..3
  int rt = blockIdx.y;          // 0..95
  int b  = blockIdx.z;
  int r0 = rt*2, c0 = ct*48;
  int t = threadIdx.x;
  int wv = t >> 6;              // wave -> oc quarter
  int l  = t & 63;
  int l15 = l & 15, lg = l >> 4;
  int oc = wv*16 + l15;

  f32x4 acc[2][3];
#pragma unroll
  for (int i = 0; i < 2; i++)
#pragma unroll
    for (int j = 0; j < 3; j++) acc[i][j] = (f32x4){0.f,0.f,0.f,0.f};

  for (int h = 0; h < 2; h++) {
    __syncthreads();
    for (int idx = t; idx < 8*54*4; idx += 256) {
      int g = idx & 3, pix = idx >> 2;
      int row = pix / 54, col = pix % 54;
      int gr = r0 - 3 + row, gc = c0 - 3 + col;
      uint4 v = {0u,0u,0u,0u};
      if (gr >= 0 && gr < Hq && gc >= 0 && gc < Wq)
        v = *(const uint4*)(xpack + (((size_t)b*Hq + gr)*Wq + gc)*64 + (h*4 + g)*8);
      ((uint4*)sA)[(row*54 + col)*4 + (g ^ ((col >> 1) & 3))] = v;
    }
    __syncthreads();
    const unsigned short* wb = wpack + (size_t)h*49*4096;
#pragma unroll 7
    for (int tap = 0; tap < 49; tap++) {
      int dy = tap / 7, dx = tap % 7;
      f16x8 bh = *(const f16x8*)(wb + (size_t)tap*4096 +        oc*32 + lg*8);
      f16x8 bl = *(const f16x8*)(wb + (size_t)tap*4096 + 2048 + oc*32 + lg*8);
#pragma unroll
      for (int rw = 0; rw < 2; rw++) {
        int arow = rw + dy;
        f16x8 a[3];
#pragma unroll
        for (int tc = 0; tc < 3; tc++) {
          int col = tc*16 + l15 + dx;
          a[tc] = *(const f16x8*)((const uint4*)sA + (arow*54 + col)*4 + (lg ^ ((col >> 1) & 3)));
        }
#pragma unroll
        for (int tc = 0; tc < 3; tc++) {
          acc[rw][tc] = __builtin_amdgcn_mfma_f32_16x16x32_f16(a[tc], bh, acc[rw][tc], 0, 0, 0);
          acc[rw][tc] = __builtin_amdgcn_mfma_f32_16x16x32_f16(a[tc], bl, acc[rw][tc], 0, 0, 0);
        }
      }
    }
  }
#pragma unroll
  for (int rw = 0; rw < 2; rw++) {
    float* dst = out + ((size_t)(b*64 + oc)*Hq + (r0 + rw))*Wq + c0;
#pragma unroll
    for (int tc = 0; tc < 3; tc++) {
      f32x4 v = acc[rw][tc];
      *(float4*)(dst + tc*16 + lg*4) = make_float4(v[0], v[1], v[2], v[3]);
    }
  }
}

// ---------------------------------------------------------------------------
// FUSED separable 7x7 avg pool: one kernel, LDS-staged.
// ---------------------------------------------------------------------------
__global__ __launch_bounds__(256) void pool_fused_kernel(const float* __restrict__ in,
                                                         float* __restrict__ out)
{
  __shared__ float raw[38][192];
  __shared__ float cs[32][192];
  int rt = blockIdx.x;
  int plane = blockIdx.y;
  int r0 = rt*32;
  int t = threadIdx.x;
  const float* src = in + (size_t)plane*HWq;
  for (int idx = t; idx < 38*192; idx += 256) {
    int lr = idx / 192, c = idx % 192;
    int gr = r0 - 3 + lr;
    raw[lr][c] = (gr >= 0 && gr < Hq) ? src[gr*Wq + c] : 0.f;
  }
  __syncthreads();
  for (int idx = t; idx < 32*192; idx += 256) {
    int lr = idx / 192, c = idx % 192;
    float s = 0.f;
#pragma unroll
    for (int dr = 0; dr < 7; dr++) s += raw[lr + dr][c];
    cs[lr][c] = s;
  }
  __syncthreads();
  float* dst = out + (size_t)plane*HWq + r0*Wq;
  for (int idx = t; idx < 32*192; idx += 256) {
    int lr = idx / 192, c = idx % 192;
    float s = 0.f;
#pragma unroll
    for (int dc = -3; dc <= 3; dc++) {
      int cc = c + dc;
      if (cc >= 0 && cc < Wq) s += cs[lr][cc];
    }
    dst[idx] = s * (1.f/49.f);
  }
}

// ---------------------------------------------------------------------------
// MERGED fused depthwise 19-tap + f16 HI/LO plane-major pack [b][sub16][px][8].
// Grid (144, 8, 4): z = branch*2 + b.
// ---------------------------------------------------------------------------
__global__ __launch_bounds__(256) void dwf_kernel(const float* __restrict__ x1,
                                                  const float* __restrict__ wEffH,
                                                  const float* __restrict__ bEffH,
                                                  const float* __restrict__ wBH,
                                                  const float* __restrict__ wEffV,
                                                  const float* __restrict__ bEffV,
                                                  const float* __restrict__ wBV,
                                                  unsigned short* __restrict__ packH,
                                                  unsigned short* __restrict__ packV)
{
  __shared__ float sW[8][19][20];
  int z = blockIdx.z;
  int br = z >> 1, b = z & 1;
  const float* wEff = br ? wEffV : wEffH;
  const float* bEff = br ? bEffV : bEffH;
  const float* wB   = br ? wBV   : wBH;
  unsigned short* pack = br ? packV : packH;
  int g8 = blockIdx.y;
  int t = threadIdx.x;
  int chb = g8*8;
  for (int i = t; i < 8*380; i += 256) {
    int ch8 = i / 380; int rem = i % 380;
    int row = rem / 20, jj = rem % 20;
    int ch = chb + ch8;
    float v;
    if (row < 18) v = wB[((size_t)ch*18 + row)*20 + jj];
    else v = (jj < 19) ? wEff[ch*19 + jj] : bEff[ch];
    sW[ch8][row][jj] = v;
  }
  __syncthreads();
  int p = blockIdx.x*256 + t;
  int r = p / Wq, c = p % Wq;
  float vals[8];
  if (br == 0) {
    int row = (c < 9) ? c : ((c >= Wq-9) ? (c - 174) : 18);
#pragma unroll
    for (int ch8 = 0; ch8 < 8; ch8++) {
      const float* src = x1 + (size_t)(b*Cq + chb + ch8)*HWq + r*Wq;
      float s = sW[ch8][row][19];
#pragma unroll
      for (int j = 0; j < 19; j++) {
        int idx = min(max(c + j - 9, 0), Wq-1);
        s += src[idx] * sW[ch8][row][j];
      }
      vals[ch8] = s;
    }
  } else {
    int row = (r < 9) ? r : ((r >= Hq-9) ? (r - 174) : 18);
#pragma unroll
    for (int ch8 = 0; ch8 < 8; ch8++) {
      const float* src = x1 + (size_t)(b*Cq + chb + ch8)*HWq + c;
      float s = sW[ch8][row][19];
#pragma unroll
      for (int j = 0; j < 19; j++) {
        int idx = min(max(r + j - 9, 0), Hq-1);
        s += src[idx*Wq] * sW[ch8][row][j];
      }
      vals[ch8] = s;
    }
  }
  unsigned int hi[4], lo[4];
#pragma unroll
  for (int q = 0; q < 4; q++) {
    __half h0 = __float2half(vals[2*q]);
    __half h1 = __float2half(vals[2*q+1]);
    __half l0 = __float2half(vals[2*q]   - __half2float(h0));
    __half l1 = __float2half(vals[2*q+1] - __half2float(h1));
    hi[q] = (unsigned int)h2us(h0) | ((unsigned int)h2us(h1) << 16);
    lo[q] = (unsigned int)h2us(l0) | ((unsigned int)h2us(l1) << 16);
  }
  *(uint4*)(pack + (((size_t)b*16 + g8)*HWq + p)*8)     = make_uint4(hi[0], hi[1], hi[2], hi[3]);
  *(uint4*)(pack + (((size_t)b*16 + 8 + g8)*HWq + p)*8) = make_uint4(lo[0], lo[1], lo[2], lo[3]);
}

// ---------------------------------------------------------------------------
// MERGED offset conv + tanh + cum (reads HI+LO -> near-f32 offsets).
// 1D grid 576, XCD-PARTITIONED: xcd = bid&7 owns 72 consecutive px-blocks of
// ONE (b,branch) combo -> per-XCD working set ~4.8 MB, tap re-reads hit L2.
// ---------------------------------------------------------------------------
__global__ __launch_bounds__(256) void off_cum_kernel(const unsigned short* __restrict__ fpH,
                                                      const unsigned short* __restrict__ fpV,
                                                      const float* __restrict__ wOffH,
                                                      const float* __restrict__ bOffH,
                                                      const float* __restrict__ wOffV,
                                                      const float* __restrict__ bOffV,
                                                      float* __restrict__ hcum,
                                                      float* __restrict__ vcum)
{
  const size_t HW8 = (size_t)HWq*8;
  int bid = blockIdx.x;                 // 0..575
  int xcd = bid & 7, lid = bid >> 3;    // lid 0..71
  int combo = xcd >> 1;                 // 0..3
  int br = combo >> 1, b = combo & 1;
  int pxblk = (xcd & 1)*72 + lid;       // 0..143
  const unsigned short* fp = br ? fpV : fpH;
  const float* wOff = br ? wOffV : wOffH;
  const float* bOff = br ? bOffV : bOffH;
  float* cum = br ? vcum : hcum;
  int p = pxblk*256 + threadIdx.x;
  int r = p / Wq, c = p % Wq;
  float tv[7];
#pragma unroll
  for (int m = 0; m < 7; m++) tv[m] = bOff[m];
  const unsigned short* fb = fp + (size_t)b*HWq*128;
  for (int tap = 0; tap < 9; tap++) {
    int dy = tap/3 - 1, dx = tap%3 - 1;
    int rr = r + dy, cc = c + dx;
    if (rr < 0 || rr >= Hq || cc < 0 || cc >= Wq) continue;
    const unsigned short* p0 = fb + ((size_t)rr*Wq + cc)*8;
    const float* wp = wOff + tap*512;
    for (int g = 0; g < 8; g++) {
      f16x8 hv = *(const f16x8*)(p0 + (size_t)g*HW8);
      f16x8 lv = *(const f16x8*)(p0 + (size_t)(8 + g)*HW8);
#pragma unroll
      for (int e = 0; e < 8; e++) {
        float fv = (float)hv[e] + (float)lv[e];
        const float* wr = wp + (g*8 + e)*8;
#pragma unroll
        for (int m = 0; m < 7; m++) tv[m] += fv * wr[m];
      }
    }
  }
#pragma unroll
  for (int m = 0; m < 7; m++) tv[m] = tanhf(tv[m]);
  float c0 = tv[0], c1 = tv[1] + tv[2], c2 = tv[2], c3 = 0.f;
  float c4 = tv[4], c5 = tv[4] + tv[5], c6 = tv[6];
  size_t bb = (size_t)b*7*HWq + p;
  cum[bb + 0*HWq] = c0; cum[bb + 1*HWq] = c1; cum[bb + 2*HWq] = c2;
  cum[bb + 3*HWq] = c3; cum[bb + 4*HWq] = c4; cum[bb + 5*HWq] = c5;
  cum[bb + 6*HWq] = c6;
}

// ---------------------------------------------------------------------------
// MERGED deformable sample + einsum via MFMA, 2-PASS (A single f16, W hi/lo).
// A staged from HI granules only (16 scattered loads/tap/thread).
// 2 taps staged per barrier phase: LDS [2][128px][64] f16 = 32 KB.
// Grid (576, 2): y = morph. XCD-banded swizzle per morph slice.
// ---------------------------------------------------------------------------
__global__ __launch_bounds__(128) void einsum_mfma_kernel(
    const unsigned short* __restrict__ fpH, const unsigned short* __restrict__ fpV,
    const float* __restrict__ cumH, const float* __restrict__ cumV,
    const unsigned short* __restrict__ wtpHp, const unsigned short* __restrict__ wtpVp,
    const float* __restrict__ dscbH, const float* __restrict__ dscbV,
    float* __restrict__ outH, float* __restrict__ outV)
{
  __shared__ __align__(16) unsigned short sA[2*128*64];  // 32 KB
  const size_t HW8 = (size_t)HWq*8;
  int morph = blockIdx.y;
  const unsigned short* fp  = morph ? fpV   : fpH;
  const float* cum          = morph ? cumV  : cumH;
  const unsigned short* wtp = morph ? wtpVp : wtpHp;
  const float* dsc_b        = morph ? dscbV : dscbH;
  float* out                = morph ? outV  : outH;
  int bid = blockIdx.x;
  int swz = (bid & 7)*72 + (bid >> 3);
  int b   = swz / 288;
  int blk = swz % 288;
  int t = threadIdx.x;
  int w = t >> 6, l = t & 63;
  int l15 = l & 15, lg = l >> 4;
  int l7 = l15 & 7;
  int p = blk*128 + w*64 + l;
  int r = p / Wq, c = p % Wq;

  f32x4 acc[4][4];
#pragma unroll
  for (int i = 0; i < 4; i++)
#pragma unroll
    for (int j = 0; j < 4; j++) acc[i][j] = (f32x4){0.f,0.f,0.f,0.f};

  const unsigned short* fb = fp + (size_t)b*HWq*128;

  for (int kp = 0; kp < 4; kp++) {
    int k0 = kp*2;
    int nk = (kp < 3) ? 2 : 1;
    for (int kk = 0; kk < nk; kk++) {
      int k = k0 + kk;
      unsigned short* myrow = sA + (size_t)(kk*128 + w*64 + l)*64;
      bool oob;
      const unsigned short *p0, *p1;
      float w0, w1;
      if (morph == 0) {
        int xi = c + k - 3;
        oob = (xi < 0 || xi >= Wq);
        if (!oob) {
          float y = (float)r + cum[((size_t)(b*7 + k))*HWq + p];
          float y0 = floorf(y);
          int y0q = (int)y0;
          int y0i = min(max(y0q, 0), Hq-1);
          int y1i = min(max(y0q + 1, 0), Hq-1);
          float y0f = fminf(fmaxf(y0, 0.f), (float)Hq);
          float y1f = fminf(fmaxf(y0 + 1.f, 0.f), (float)Hq);
          w0 = y1f - y; w1 = y - y0f;
          p0 = fb + ((size_t)y0i*Wq + xi)*8;
          p1 = fb + ((size_t)y1i*Wq + xi)*8;
        }
      } else {
        int yi = r + k - 3;
        oob = (yi < 0 || yi >= Hq);
        if (!oob) {
          float xf = (float)c + cum[((size_t)(b*7 + k))*HWq + p];
          float x0 = floorf(xf);
          int x0q = (int)x0;
          int x0i = min(max(x0q, 0), Wq-1);
          int x1i = min(max(x0q + 1, 0), Wq-1);
          float x0f = fminf(fmaxf(x0, 0.f), (float)Wq);
          float x1f = fminf(fmaxf(x0 + 1.f, 0.f), (float)Wq);
          w0 = x1f - xf; w1 = xf - x0f;
          p0 = fb + ((size_t)yi*Wq + x0i)*8;
          p1 = fb + ((size_t)yi*Wq + x1i)*8;
        }
      }
      if (oob) {
        uint4 z = {0u,0u,0u,0u};
#pragma unroll
        for (int j = 0; j < 8; j++) ((uint4*)myrow)[j] = z;
      } else {
#pragma unroll
        for (int g = 0; g < 8; g++) {
          f16x8 a0h = *(const f16x8*)(p0 + (size_t)g*HW8);
          f16x8 a1h = *(const f16x8*)(p1 + (size_t)g*HW8);
          f16x8 sh;
#pragma unroll
          for (int e = 0; e < 8; e++) {
            float v = w0*(float)a0h[e] + w1*(float)a1h[e];
            sh[e] = (_Float16)v;
          }
          *(f16x8*)(myrow + (size_t)(g ^ l7)*8) = sh;
        }
      }
    }
    __syncthreads();
    for (int kk = 0; kk < nk; kk++) {
      int k = k0 + kk;
#pragma unroll
      for (int kc = 0; kc < 2; kc++) {
        const unsigned short* wbase = wtp + (size_t)((k*2 + kc)*2)*2048;
        f16x8 bh[4], bl[4];
#pragma unroll
        for (int tb = 0; tb < 4; tb++) {
          bh[tb] = *(const f16x8*)(wbase + (tb*16 + l15)*32 + lg*8);
          bl[tb] = *(const f16x8*)(wbase + 2048 + (tb*16 + l15)*32 + lg*8);
        }
        f16x8 ah[4];
#pragma unroll
        for (int ta = 0; ta < 4; ta++) {
          const unsigned short* rbase = sA + (size_t)(kk*128 + w*64 + ta*16 + l15)*64;
          ah[ta] = *(const f16x8*)(rbase + (size_t)((kc*4 + lg) ^ l7)*8);
        }
#pragma unroll
        for (int ta = 0; ta < 4; ta++)
#pragma unroll
          for (int tb = 0; tb < 4; tb++) {
            acc[ta][tb] = __builtin_amdgcn_mfma_f32_16x16x32_f16(ah[ta], bh[tb], acc[ta][tb], 0, 0, 0);
            acc[ta][tb] = __builtin_amdgcn_mfma_f32_16x16x32_f16(ah[ta], bl[tb], acc[ta][tb], 0, 0, 0);
          }
      }
    }
    __syncthreads();
  }
  int pbase = blk*128 + w*64;
#pragma unroll
  for (int tb = 0; tb < 4; tb++) {
    int oc = tb*16 + l15;
    float bias = dsc_b[oc];
    float* dst = out + (size_t)(b*64 + oc)*HWq + pbase;
#pragma unroll
    for (int ta = 0; ta < 4; ta++) {
      f32x4 v = acc[ta][tb];
      *(float4*)(dst + ta*16 + lg*4) = make_float4(v[0]+bias, v[1]+bias, v[2]+bias, v[3]+bias);
    }
  }
}

// ---------------------------------------------------------------------------
// GroupNorm stats + finalize
// ---------------------------------------------------------------------------
__global__ __launch_bounds__(256) void gnstats_kernel(const float* __restrict__ h_ds,
                                                      const float* __restrict__ v_ds,
                                                      float* __restrict__ stats)
{
  int plane = blockIdx.x;
  int buf = plane >> 7;
  int rem = plane & 127;
  const float* src = (buf ? v_ds : h_ds) + (size_t)rem*HWq;
  float s = 0.f, s2 = 0.f;
  for (int i = threadIdx.x; i < HWq; i += 256) {
    float v = src[i];
    s += v; s2 += v*v;
  }
  __shared__ float red[2][4];
  for (int off = 32; off; off >>= 1) {
    s  += __shfl_down(s, off);
    s2 += __shfl_down(s2, off);
  }
  if ((threadIdx.x & 63) == 0) { red[0][threadIdx.x >> 6] = s; red[1][threadIdx.x >> 6] = s2; }
  __syncthreads();
  if (threadIdx.x == 0) {
    s  = red[0][0] + red[0][1] + red[0][2] + red[0][3];
    s2 = red[1][0] + red[1][1] + red[1][2] + red[1][3];
    stats[plane*2 + 0] = s;
    stats[plane*2 + 1] = s2;
  }
}

__global__ __launch_bounds__(256) void gnfinal_kernel(const float* __restrict__ stats,
                                                      const float* __restrict__ h_gn_g, const float* __restrict__ h_gn_b,
                                                      const float* __restrict__ v_gn_g, const float* __restrict__ v_gn_b,
                                                      float* __restrict__ gnAB)
{
  int t = threadIdx.x;
  int buf = t >> 7, ch = t & 63;
  int base = t & ~3;
  float sum = 0.f, ss = 0.f;
#pragma unroll
  for (int q = 0; q < 4; q++) { sum += stats[(base+q)*2]; ss += stats[(base+q)*2 + 1]; }
  const float n = 4.f * HWq;
  float mean = sum / n;
  float var = ss / n - mean*mean;
  float gg = (buf ? v_gn_g : h_gn_g)[ch];
  float bb = (buf ? v_gn_b : h_gn_b)[ch];
  float A = gg / sqrtf(var + 1e-5f);
  gnAB[t*2 + 0] = A;
  gnAB[t*2 + 1] = bb - mean*A;
}

// ---------------------------------------------------------------------------
// FUSED: comb = relu(GN(h)) + relu(GN(v)) + x1 inline, then 1x1 conv + SiLU
// ---------------------------------------------------------------------------
__global__ __launch_bounds__(256) void final2_kernel(const float* __restrict__ hbuf,
                                                     const float* __restrict__ vbuf,
                                                     const float* __restrict__ x1,
                                                     const float* __restrict__ gnAB,
                                                     const float* __restrict__ lwT,
                                                     const float* __restrict__ lbO,
                                                     float* __restrict__ out)
{
  int b = blockIdx.y;
  int p = blockIdx.x*256 + threadIdx.x;
  float acc[64];
#pragma unroll
  for (int o = 0; o < 64; o++) acc[o] = 0.f;
  for (int i = 0; i < 64; i++) {
    size_t off = (size_t)(b*64 + i)*HWq + p;
    int plane = b*64 + i;
    int ih = plane*2;
    int iv = (128 + plane)*2;
    float hv = fmaxf(hbuf[off]*gnAB[ih] + gnAB[ih+1], 0.f);
    float vv = fmaxf(vbuf[off]*gnAB[iv] + gnAB[iv+1], 0.f);
    float cv = hv + vv + x1[off];
    const float* wr = lwT + i*64;
#pragma unroll
    for (int o = 0; o < 64; o++) acc[o] += cv * wr[o];
  }
  float* dst = out + (size_t)b*Cq*HWq + p;
#pragma unroll
  for (int o = 0; o < 64; o++) {
    float yv = acc[o] + lbO[o];
    dst[(size_t)o*HWq] = yv / (1.f + expf(-yv));
  }
}

// ---------------------------------------------------------------------------
extern "C" void kernel_launch(void* const* d_in, const int* in_sizes, int n_in,
                              void* d_out, int out_size, void* d_ws, size_t ws_size,
                              hipStream_t stream)
{
  const float* x       = (const float*)d_in[0];
  const float* w_first = (const float*)d_in[1];
  float* ws = (float*)d_ws;

  float* bufA = ws;            // conv7 out -> h-einsum-out
  float* bufB = ws + Nq;       // v-einsum-out
  float* x1   = ws + 2*Nq;
  float* h_ds = ws + 3*Nq;     // xpack -> fpackH
  float* v_ds = ws + 4*Nq;     // fpackV
  size_t off = 5*Nq;
  float* hcum  = ws + off; off += (size_t)Bq*7*HWq;
  float* vcum  = ws + off; off += (size_t)Bq*7*HWq;
  float* wEffH = ws + off; off += 64*19;
  float* bEffH = ws + off; off += 64;
  float* wEffV = ws + off; off += 64*19;
  float* bEffV = ws + off; off += 64;
  float* wtH   = ws + off; off += 64*64*7;   // holds wtpH f16 pack
  float* wtV   = ws + off; off += 64*64*7;   // holds wtpV f16 pack
  float* wOffH = ws + off; off += 9*64*8;
  float* bOffH = ws + off; off += 8;
  float* wOffV = ws + off; off += 9*64*8;
  float* bOffV = ws + off; off += 8;
  float* lwT   = ws + off; off += 64*64;
  float* lbO   = ws + off; off += 64;
  float* stats = ws + off; off += 512;
  float* gnAB  = ws + off; off += 512;
  float* wB    = ws + off; off += 2*64*18*20;
  unsigned short* wpack = (unsigned short*)(ws + off); off += 2*49*2*64*32/2 + 16;
  unsigned short* xpack  = (unsigned short*)h_ds;
  unsigned short* fpackH = (unsigned short*)h_ds;
  unsigned short* fpackV = (unsigned short*)v_ds;
  unsigned short* wtpH = (unsigned short*)wtH;
  unsigned short* wtpV = (unsigned short*)wtV;

  prep_small_kernel<<<dim3(1), dim3(256), 0, stream>>>(
      (const float*)d_in[2],  (const float*)d_in[3],  (const float*)d_in[4],  (const float*)d_in[5],
      (const float*)d_in[6],  (const float*)d_in[7],
      (const float*)d_in[8],  (const float*)d_in[9],  (const float*)d_in[10], (const float*)d_in[11],
      (const float*)d_in[12], (const float*)d_in[13],
      (const float*)d_in[14], (const float*)d_in[15], (const float*)d_in[16], (const float*)d_in[17],
      (const float*)d_in[18], (const float*)d_in[19],
      (const float*)d_in[24], (const float*)d_in[25], (const float*)d_in[26], (const float*)d_in[27],
      (const float*)d_in[28], (const float*)d_in[29],
      (const float*)d_in[34], (const float*)d_in[35], (const float*)d_in[36], (const float*)d_in[37],
      (const float*)d_in[38],
      wEffH, bEffH, wEffV, bEffV, wOffH, bOffH, wOffV, bOffV, lwT, lbO);

  prep_border_kernel<<<dim3(9), dim3(256), 0, stream>>>(
      (const float*)d_in[2],  (const float*)d_in[3],  (const float*)d_in[4],  (const float*)d_in[5],
      (const float*)d_in[6],  (const float*)d_in[7],
      (const float*)d_in[8],  (const float*)d_in[9],  (const float*)d_in[10], (const float*)d_in[11],
      (const float*)d_in[12], (const float*)d_in[13], wB);

  prep_big_kernel<<<dim3(64), dim3(256), 0, stream>>>(
      w_first, (const float*)d_in[20], (const float*)d_in[30], wtpH, wtpV, wpack);

  tof16_pack_kernel<<<dim3(Hq, Bq), dim3(192), 0, stream>>>(x, xpack);
  conv7_mfma_kernel<<<dim3(4, 96, 2), dim3(256), 0, stream>>>(xpack, wpack, bufA);

  pool_fused_kernel<<<dim3(6, 128), dim3(256), 0, stream>>>(bufA, x1);

  dwf_kernel<<<dim3(144, 8, 4), dim3(256), 0, stream>>>(x1, wEffH, bEffH, wB,
      wEffV, bEffV, wB + 64*18*20, fpackH, fpackV);

  off_cum_kernel<<<dim3(576), dim3(256), 0, stream>>>(fpackH, fpackV,
      wOffH, bOffH, wOffV, bOffV, hcum, vcum);

  einsum_mfma_kernel<<<dim3(576, 2), dim3(128), 0, stream>>>(fpackH, fpackV,
      hcum, vcum, wtpH, wtpV, (const float*)d_in[21], (const float*)d_in[31], bufA, bufB);

  gnstats_kernel<<<dim3(256), dim3(256), 0, stream>>>(bufA, bufB, stats);
  gnfinal_kernel<<<dim3(1), dim3(256), 0, stream>>>(stats,
      (const float*)d_in[22], (const float*)d_in[23],
      (const float*)d_in[32], (const float*)d_in[33], gnAB);

  final2_kernel<<<dim3(144, 2), dim3(256), 0, stream>>>(bufA, bufB, x1, gnAB, lwT, lbO, (float*)d_out);
}

// Round 23
// 302.075 us; speedup vs baseline: 2.0622x; 1.1405x over previous
//
#include <hip/hip_runtime.h>
#include <hip/hip_bf16.h>
#include <hip/hip_fp16.h>
#include <math.h>

#define Bq 2
#define Cq 64
#define Hq 192
#define Wq 192
#define HWq (Hq*Wq)            // 36864
#define Nq ((size_t)Bq*Cq*HWq) // 4718592

typedef __attribute__((ext_vector_type(8))) _Float16 f16x8;
typedef __attribute__((ext_vector_type(4))) float f32x4;

__device__ inline unsigned short h2us(__half h) {
  union { __half h; unsigned short u; } v; v.h = h; return v.u;
}

// ---------------------------------------------------------------------------
// MERGED prep: block 0 = small folds; blocks 1-9 = border; blocks 10-73 = big.
// ---------------------------------------------------------------------------
__global__ __launch_bounds__(256) void prep_all_kernel(
    const float* hc1_w, const float* hc1_b, const float* hc2_w, const float* hc2_b,
    const float* hc3_w, const float* hc3_b,
    const float* vc1_w, const float* vc1_b, const float* vc2_w, const float* vc2_b,
    const float* vc3_w, const float* vc3_b,
    const float* h_off_w, const float* h_off_b, const float* h_bn_g, const float* h_bn_b,
    const float* h_bn_m, const float* h_bn_v,
    const float* v_off_w, const float* v_off_b, const float* v_bn_g, const float* v_bn_b,
    const float* v_bn_m, const float* v_bn_v,
    const float* last_w, const float* last_g, const float* last_b, const float* last_m,
    const float* last_v,
    const float* __restrict__ w_first,
    const float* __restrict__ h_dsc_w, const float* __restrict__ v_dsc_w,
    float* wEffH, float* bEffH, float* wEffV, float* bEffV,
    float* wOffH, float* bOffH, float* wOffV, float* bOffV,
    float* lwT, float* lbO, float* wB,
    unsigned short* __restrict__ wtpH, unsigned short* __restrict__ wtpV,
    unsigned short* __restrict__ wpack)
{
  int bid = blockIdx.x;
  int t = threadIdx.x;
  if (bid == 0) {
    // ---- small folds ------------------------------------------------------
    if (t < 128) {
      int ch = t & 63;
      bool ish = t < 64;
      const float* w1p = (ish ? hc1_w : vc1_w) + ch*9;
      const float* w2p = (ish ? hc2_w : vc2_w) + ch*7;
      const float* w3p = (ish ? hc3_w : vc3_w) + ch*5;
      float w1r[9], w2r[7], w3r[5];
#pragma unroll
      for (int j = 0; j < 9; j++) w1r[j] = w1p[j];
#pragma unroll
      for (int k = 0; k < 7; k++) w2r[k] = w2p[k];
#pragma unroll
      for (int m = 0; m < 5; m++) w3r[m] = w3p[m];
      float t15[15];
#pragma unroll
      for (int s = 0; s < 15; s++) {
        float a = 0.f;
#pragma unroll
        for (int j = 0; j < 9; j++) { int k2 = s - j; if (k2 >= 0 && k2 < 7) a += w1r[j]*w2r[k2]; }
        t15[s] = a;
      }
      float* we = (ish ? wEffH : wEffV) + ch*19;
#pragma unroll
      for (int s = 0; s < 19; s++) {
        float a = 0.f;
#pragma unroll
        for (int j = 0; j < 15; j++) { int k3 = s - j; if (k3 >= 0 && k3 < 5) a += t15[j]*w3r[k3]; }
        we[s] = a;
      }
      float S2 = 0.f, S3 = 0.f;
#pragma unroll
      for (int j = 0; j < 7; j++) S2 += w2r[j];
#pragma unroll
      for (int j = 0; j < 5; j++) S3 += w3r[j];
      float b1 = (ish ? hc1_b : vc1_b)[ch];
      float b2 = (ish ? hc2_b : vc2_b)[ch];
      float b3 = (ish ? hc3_b : vc3_b)[ch];
      (ish ? bEffH : bEffV)[ch] = b1*S2*S3 + b2*S3 + b3;
    }
    for (int idx = t; idx < 9*64*7; idx += 256) {
      int tap = idx / 448; int rem = idx % 448; int i = rem / 7; int m = rem % 7;
      float invh = h_bn_g[m] / sqrtf(h_bn_v[m] + 1e-5f);
      wOffH[(tap*64 + i)*8 + m] = h_off_w[(m*64 + i)*9 + tap] * invh;
      float invv = v_bn_g[7+m] / sqrtf(v_bn_v[7+m] + 1e-5f);
      wOffV[(tap*64 + i)*8 + m] = v_off_w[((7+m)*64 + i)*9 + tap] * invv;
    }
    if (t < 7) {
      float invh = h_bn_g[t] / sqrtf(h_bn_v[t] + 1e-5f);
      bOffH[t] = h_off_b[t]*invh + h_bn_b[t] - h_bn_m[t]*invh;
      float invv = v_bn_g[7+t] / sqrtf(v_bn_v[7+t] + 1e-5f);
      bOffV[t] = v_off_b[7+t]*invv + v_bn_b[7+t] - v_bn_m[7+t]*invv;
    }
    for (int idx = t; idx < 4096; idx += 256) {
      int o = idx % 64; int i = idx / 64;
      float inv = last_g[o] / sqrtf(last_v[o] + 1e-3f);
      lwT[i*64 + o] = last_w[o*64 + i] * inv;
    }
    if (t < 64) {
      float inv = last_g[t] / sqrtf(last_v[t] + 1e-3f);
      lbO[t] = last_b[t] - last_m[t]*inv;
    }
  } else if (bid <= 9) {
    // ---- border composed weights ------------------------------------------
    int tid = (bid - 1)*256 + t;
    if (tid >= 2*64*18) return;
    int cls = tid % 18;
    int ch  = (tid / 18) % 64;
    int br  = tid / (18*64);
    int c = (cls < 9) ? cls : cls + 174;
    const float* w1p = (br==0 ? hc1_w : vc1_w) + ch*9;
    const float* w2p = (br==0 ? hc2_w : vc2_w) + ch*7;
    const float* w3p = (br==0 ? hc3_w : vc3_w) + ch*5;
    float b1 = (br==0 ? hc1_b : vc1_b)[ch];
    float b2 = (br==0 ? hc2_b : vc2_b)[ch];
    float b3 = (br==0 ? hc3_b : vc3_b)[ch];
    float w1r[9], w2r[7], w3r[5];
#pragma unroll
    for (int j = 0; j < 9; j++) w1r[j] = w1p[j];
#pragma unroll
    for (int k = 0; k < 7; k++) w2r[k] = w2p[k];
#pragma unroll
    for (int m = 0; m < 5; m++) w3r[m] = w3p[m];
    float acc[19];
#pragma unroll
    for (int s = 0; s < 19; s++) acc[s] = 0.f;
    float bacc = b3;
#pragma unroll
    for (int m = 0; m < 5; m++) {
      int d = c + m - 2;
      bool dok = (d >= 0 && d < Wq);
      float s2b = b2;
#pragma unroll
      for (int k = 0; k < 7; k++) {
        int e = d + k - 3;
        bool eok = (e >= 0 && e < Wq);
        if (eok) s2b += w2r[k] * b1;
        float wmk = w3r[m] * w2r[k];
#pragma unroll
        for (int j = 0; j < 9; j++) {
          int fd = e + j - 4;
          bool fok = (fd >= 0 && fd < Wq);
          float contrib = (dok && eok && fok) ? wmk * w1r[j] : 0.f;
          acc[m + k + j] += contrib;
        }
      }
      if (dok) bacc += w3r[m] * s2b;
    }
    float* dst = wB + ((size_t)(br*64 + ch)*18 + cls)*20;
#pragma unroll
    for (int s = 0; s < 19; s++) dst[s] = acc[s];
    dst[19] = bacc;
  } else {
    // ---- big packs --------------------------------------------------------
    int tid = (bid - 10)*256 + t;
    int nthr = 64*256;
    for (int idx = tid; idx < 7*2*2*64*32; idx += nthr) {
      int ch32 = idx & 31;
      int oc   = (idx >> 5) & 63;
      int hl   = (idx >> 11) & 1;
      int kc   = (idx >> 12) & 1;
      int tap  = idx >> 13;
      int i = kc*32 + ch32;
      float vh = h_dsc_w[oc*448 + i*7 + tap];
      float vv = v_dsc_w[oc*448 + i*7 + tap];
      _Float16 hh = (_Float16)vh;
      _Float16 hv = (_Float16)vv;
      unsigned short uh, uv;
      if (!hl) { uh = *(unsigned short*)&hh; uv = *(unsigned short*)&hv; }
      else {
        _Float16 lh = (_Float16)(vh - (float)hh);
        _Float16 lv = (_Float16)(vv - (float)hv);
        uh = *(unsigned short*)&lh; uv = *(unsigned short*)&lv;
      }
      wtpH[idx] = uh; wtpV[idx] = uv;
    }
    for (int e = tid; e < 2*49*2*64*32; e += nthr) {
      int ch  = e & 31;
      int oc  = (e >> 5) & 63;
      int hl  = (e >> 11) & 1;
      int rest = e >> 12;
      int tap = rest % 49;
      int h   = rest / 49;
      float wv = w_first[((size_t)oc*64 + h*32 + ch)*49 + tap];
      __half hh = __float2half(wv);
      unsigned short us;
      if (!hl) us = h2us(hh);
      else { float rr = wv - __half2float(hh); us = h2us(__float2half(rr)); }
      wpack[e] = us;
    }
  }
}

// ---------------------------------------------------------------------------
// x (NCHW f32) -> xpack single f16: [b][r][c][64]
// ---------------------------------------------------------------------------
__global__ __launch_bounds__(192) void tof16_pack_kernel(const float* __restrict__ x,
                                                         unsigned short* __restrict__ xpack)
{
  __shared__ unsigned int s[192*64];
  int r = blockIdx.x, b = blockIdx.y;
  int t = threadIdx.x;
  for (int ch = 0; ch < 64; ch++) {
    float v = x[((size_t)(b*64+ch)*Hq + r)*Wq + t];
    _Float16 hh = (_Float16)v;
    s[t*64 + (ch ^ (t & 31))] = (unsigned int)*(unsigned short*)&hh;
  }
  __syncthreads();
  unsigned short* dst = xpack + ((size_t)b*Hq + r)*Wq*64;
  for (int i = 0; i < 8; i++) {
    int gidx = i*192 + t;
    int c = gidx >> 3, g = gidx & 7;
    unsigned short tmp[8];
#pragma unroll
    for (int j = 0; j < 8; j++) {
      int ch = g*8 + j;
      tmp[j] = (unsigned short)s[c*64 + (ch ^ (c & 31))];
    }
    uint4 v;
    v.x = (unsigned int)tmp[0] | ((unsigned int)tmp[1] << 16);
    v.y = (unsigned int)tmp[2] | ((unsigned int)tmp[3] << 16);
    v.z = (unsigned int)tmp[4] | ((unsigned int)tmp[5] << 16);
    v.w = (unsigned int)tmp[6] | ((unsigned int)tmp[7] << 16);
    *(uint4*)(dst + (size_t)gidx*8) = v;
  }
}

// ---------------------------------------------------------------------------
// 7x7 conv via MFMA, 2-pass (x single f16, w hi/lo exact) — R17 validated.
// ---------------------------------------------------------------------------
__global__ __launch_bounds__(256) void conv7_mfma_kernel(
    const unsigned short* __restrict__ xpack,   // [b][r][c][64] f16
    const unsigned short* __restrict__ wpack,   // [h][tap][hl][oc][32] f16
    float* __restrict__ out)
{
  __shared__ __align__(16) unsigned short sA[8*54*32];   // 27648 B
  int ct = blockIdx.x;          // 0..3
  int rt = blockIdx.y;          // 0..95
  int b  = blockIdx.z;
  int r0 = rt*2, c0 = ct*48;
  int t = threadIdx.x;
  int wv = t >> 6;              // wave -> oc quarter
  int l  = t & 63;
  int l15 = l & 15, lg = l >> 4;
  int oc = wv*16 + l15;

  f32x4 acc[2][3];
#pragma unroll
  for (int i = 0; i < 2; i++)
#pragma unroll
    for (int j = 0; j < 3; j++) acc[i][j] = (f32x4){0.f,0.f,0.f,0.f};

  for (int h = 0; h < 2; h++) {
    __syncthreads();
    for (int idx = t; idx < 8*54*4; idx += 256) {
      int g = idx & 3, pix = idx >> 2;
      int row = pix / 54, col = pix % 54;
      int gr = r0 - 3 + row, gc = c0 - 3 + col;
      uint4 v = {0u,0u,0u,0u};
      if (gr >= 0 && gr < Hq && gc >= 0 && gc < Wq)
        v = *(const uint4*)(xpack + (((size_t)b*Hq + gr)*Wq + gc)*64 + (h*4 + g)*8);
      ((uint4*)sA)[(row*54 + col)*4 + (g ^ ((col >> 1) & 3))] = v;
    }
    __syncthreads();
    const unsigned short* wb = wpack + (size_t)h*49*4096;
#pragma unroll 7
    for (int tap = 0; tap < 49; tap++) {
      int dy = tap / 7, dx = tap % 7;
      f16x8 bh = *(const f16x8*)(wb + (size_t)tap*4096 +        oc*32 + lg*8);
      f16x8 bl = *(const f16x8*)(wb + (size_t)tap*4096 + 2048 + oc*32 + lg*8);
#pragma unroll
      for (int rw = 0; rw < 2; rw++) {
        int arow = rw + dy;
        f16x8 a[3];
#pragma unroll
        for (int tc = 0; tc < 3; tc++) {
          int col = tc*16 + l15 + dx;
          a[tc] = *(const f16x8*)((const uint4*)sA + (arow*54 + col)*4 + (lg ^ ((col >> 1) & 3)));
        }
#pragma unroll
        for (int tc = 0; tc < 3; tc++) {
          acc[rw][tc] = __builtin_amdgcn_mfma_f32_16x16x32_f16(a[tc], bh, acc[rw][tc], 0, 0, 0);
          acc[rw][tc] = __builtin_amdgcn_mfma_f32_16x16x32_f16(a[tc], bl, acc[rw][tc], 0, 0, 0);
        }
      }
    }
  }
#pragma unroll
  for (int rw = 0; rw < 2; rw++) {
    float* dst = out + ((size_t)(b*64 + oc)*Hq + (r0 + rw))*Wq + c0;
#pragma unroll
    for (int tc = 0; tc < 3; tc++) {
      f32x4 v = acc[rw][tc];
      *(float4*)(dst + tc*16 + lg*4) = make_float4(v[0], v[1], v[2], v[3]);
    }
  }
}

// ---------------------------------------------------------------------------
// FUSED separable 7x7 avg pool: one kernel, LDS-staged.
// ---------------------------------------------------------------------------
__global__ __launch_bounds__(256) void pool_fused_kernel(const float* __restrict__ in,
                                                         float* __restrict__ out)
{
  __shared__ float raw[38][192];
  __shared__ float cs[32][192];
  int rt = blockIdx.x;
  int plane = blockIdx.y;
  int r0 = rt*32;
  int t = threadIdx.x;
  const float* src = in + (size_t)plane*HWq;
  for (int idx = t; idx < 38*192; idx += 256) {
    int lr = idx / 192, c = idx % 192;
    int gr = r0 - 3 + lr;
    raw[lr][c] = (gr >= 0 && gr < Hq) ? src[gr*Wq + c] : 0.f;
  }
  __syncthreads();
  for (int idx = t; idx < 32*192; idx += 256) {
    int lr = idx / 192, c = idx % 192;
    float s = 0.f;
#pragma unroll
    for (int dr = 0; dr < 7; dr++) s += raw[lr + dr][c];
    cs[lr][c] = s;
  }
  __syncthreads();
  float* dst = out + (size_t)plane*HWq + r0*Wq;
  for (int idx = t; idx < 32*192; idx += 256) {
    int lr = idx / 192, c = idx % 192;
    float s = 0.f;
#pragma unroll
    for (int dc = -3; dc <= 3; dc++) {
      int cc = c + dc;
      if (cc >= 0 && cc < Wq) s += cs[lr][cc];
    }
    dst[idx] = s * (1.f/49.f);
  }
}

// ---------------------------------------------------------------------------
// MERGED fused depthwise 19-tap + f16 HI/LO plane-major pack [b][sub16][px][8].
// Grid (144, 8, 4): z = branch*2 + b.
// ---------------------------------------------------------------------------
__global__ __launch_bounds__(256) void dwf_kernel(const float* __restrict__ x1,
                                                  const float* __restrict__ wEffH,
                                                  const float* __restrict__ bEffH,
                                                  const float* __restrict__ wBH,
                                                  const float* __restrict__ wEffV,
                                                  const float* __restrict__ bEffV,
                                                  const float* __restrict__ wBV,
                                                  unsigned short* __restrict__ packH,
                                                  unsigned short* __restrict__ packV)
{
  __shared__ float sW[8][19][20];
  int z = blockIdx.z;
  int br = z >> 1, b = z & 1;
  const float* wEff = br ? wEffV : wEffH;
  const float* bEff = br ? bEffV : bEffH;
  const float* wB   = br ? wBV   : wBH;
  unsigned short* pack = br ? packV : packH;
  int g8 = blockIdx.y;
  int t = threadIdx.x;
  int chb = g8*8;
  for (int i = t; i < 8*380; i += 256) {
    int ch8 = i / 380; int rem = i % 380;
    int row = rem / 20, jj = rem % 20;
    int ch = chb + ch8;
    float v;
    if (row < 18) v = wB[((size_t)ch*18 + row)*20 + jj];
    else v = (jj < 19) ? wEff[ch*19 + jj] : bEff[ch];
    sW[ch8][row][jj] = v;
  }
  __syncthreads();
  int p = blockIdx.x*256 + t;
  int r = p / Wq, c = p % Wq;
  float vals[8];
  if (br == 0) {
    int row = (c < 9) ? c : ((c >= Wq-9) ? (c - 174) : 18);
#pragma unroll
    for (int ch8 = 0; ch8 < 8; ch8++) {
      const float* src = x1 + (size_t)(b*Cq + chb + ch8)*HWq + r*Wq;
      float s = sW[ch8][row][19];
#pragma unroll
      for (int j = 0; j < 19; j++) {
        int idx = min(max(c + j - 9, 0), Wq-1);
        s += src[idx] * sW[ch8][row][j];
      }
      vals[ch8] = s;
    }
  } else {
    int row = (r < 9) ? r : ((r >= Hq-9) ? (r - 174) : 18);
#pragma unroll
    for (int ch8 = 0; ch8 < 8; ch8++) {
      const float* src = x1 + (size_t)(b*Cq + chb + ch8)*HWq + c;
      float s = sW[ch8][row][19];
#pragma unroll
      for (int j = 0; j < 19; j++) {
        int idx = min(max(r + j - 9, 0), Hq-1);
        s += src[idx*Wq] * sW[ch8][row][j];
      }
      vals[ch8] = s;
    }
  }
  unsigned int hi[4], lo[4];
#pragma unroll
  for (int q = 0; q < 4; q++) {
    __half h0 = __float2half(vals[2*q]);
    __half h1 = __float2half(vals[2*q+1]);
    __half l0 = __float2half(vals[2*q]   - __half2float(h0));
    __half l1 = __float2half(vals[2*q+1] - __half2float(h1));
    hi[q] = (unsigned int)h2us(h0) | ((unsigned int)h2us(h1) << 16);
    lo[q] = (unsigned int)h2us(l0) | ((unsigned int)h2us(l1) << 16);
  }
  *(uint4*)(pack + (((size_t)b*16 + g8)*HWq + p)*8)     = make_uint4(hi[0], hi[1], hi[2], hi[3]);
  *(uint4*)(pack + (((size_t)b*16 + 8 + g8)*HWq + p)*8) = make_uint4(lo[0], lo[1], lo[2], lo[3]);
}

// ---------------------------------------------------------------------------
// MERGED offset conv + tanh + cum (reads HI+LO -> near-f32 offsets).
// 1D grid 576, XCD-PARTITIONED.
// ---------------------------------------------------------------------------
__global__ __launch_bounds__(256) void off_cum_kernel(const unsigned short* __restrict__ fpH,
                                                      const unsigned short* __restrict__ fpV,
                                                      const float* __restrict__ wOffH,
                                                      const float* __restrict__ bOffH,
                                                      const float* __restrict__ wOffV,
                                                      const float* __restrict__ bOffV,
                                                      float* __restrict__ hcum,
                                                      float* __restrict__ vcum)
{
  const size_t HW8 = (size_t)HWq*8;
  int bid = blockIdx.x;                 // 0..575
  int xcd = bid & 7, lid = bid >> 3;    // lid 0..71
  int combo = xcd >> 1;                 // 0..3
  int br = combo >> 1, b = combo & 1;
  int pxblk = (xcd & 1)*72 + lid;       // 0..143
  const unsigned short* fp = br ? fpV : fpH;
  const float* wOff = br ? wOffV : wOffH;
  const float* bOff = br ? bOffV : bOffH;
  float* cum = br ? vcum : hcum;
  int p = pxblk*256 + threadIdx.x;
  int r = p / Wq, c = p % Wq;
  float tv[7];
#pragma unroll
  for (int m = 0; m < 7; m++) tv[m] = bOff[m];
  const unsigned short* fb = fp + (size_t)b*HWq*128;
  for (int tap = 0; tap < 9; tap++) {
    int dy = tap/3 - 1, dx = tap%3 - 1;
    int rr = r + dy, cc = c + dx;
    if (rr < 0 || rr >= Hq || cc < 0 || cc >= Wq) continue;
    const unsigned short* p0 = fb + ((size_t)rr*Wq + cc)*8;
    const float* wp = wOff + tap*512;
    for (int g = 0; g < 8; g++) {
      f16x8 hv = *(const f16x8*)(p0 + (size_t)g*HW8);
      f16x8 lv = *(const f16x8*)(p0 + (size_t)(8 + g)*HW8);
#pragma unroll
      for (int e = 0; e < 8; e++) {
        float fv = (float)hv[e] + (float)lv[e];
        const float* wr = wp + (g*8 + e)*8;
#pragma unroll
        for (int m = 0; m < 7; m++) tv[m] += fv * wr[m];
      }
    }
  }
#pragma unroll
  for (int m = 0; m < 7; m++) tv[m] = tanhf(tv[m]);
  float c0 = tv[0], c1 = tv[1] + tv[2], c2 = tv[2], c3 = 0.f;
  float c4 = tv[4], c5 = tv[4] + tv[5], c6 = tv[6];
  size_t bb = (size_t)b*7*HWq + p;
  cum[bb + 0*HWq] = c0; cum[bb + 1*HWq] = c1; cum[bb + 2*HWq] = c2;
  cum[bb + 3*HWq] = c3; cum[bb + 4*HWq] = c4; cum[bb + 5*HWq] = c5;
  cum[bb + 6*HWq] = c6;
}

// ---------------------------------------------------------------------------
// MERGED deformable sample + einsum via MFMA, 2-PASS (A single f16, W hi/lo).
// BARRIER-FREE: LDS exchange is intra-wave only (writer/reader rows both in
// wave's own 64-row band; per-wave in-order DS pipe guarantees RAW/WAR).
// Epilogue emits per-(block,wave) GN partial sums (deterministic).
// ---------------------------------------------------------------------------
__global__ __launch_bounds__(128) void einsum_mfma_kernel(
    const unsigned short* __restrict__ fpH, const unsigned short* __restrict__ fpV,
    const float* __restrict__ cumH, const float* __restrict__ cumV,
    const unsigned short* __restrict__ wtpHp, const unsigned short* __restrict__ wtpVp,
    const float* __restrict__ dscbH, const float* __restrict__ dscbV,
    float* __restrict__ outH, float* __restrict__ outV,
    float* __restrict__ pstat)
{
  __shared__ __align__(16) unsigned short sA[2*128*64];  // 32 KB
  const size_t HW8 = (size_t)HWq*8;
  int morph = blockIdx.y;
  const unsigned short* fp  = morph ? fpV   : fpH;
  const float* cum          = morph ? cumV  : cumH;
  const unsigned short* wtp = morph ? wtpVp : wtpHp;
  const float* dsc_b        = morph ? dscbV : dscbH;
  float* out                = morph ? outV  : outH;
  int bid = blockIdx.x;
  int swz = (bid & 7)*72 + (bid >> 3);
  int b   = swz / 288;
  int blk = swz % 288;
  int t = threadIdx.x;
  int w = t >> 6, l = t & 63;
  int l15 = l & 15, lg = l >> 4;
  int l7 = l15 & 7;
  int p = blk*128 + w*64 + l;
  int r = p / Wq, c = p % Wq;

  f32x4 acc[4][4];
#pragma unroll
  for (int i = 0; i < 4; i++)
#pragma unroll
    for (int j = 0; j < 4; j++) acc[i][j] = (f32x4){0.f,0.f,0.f,0.f};

  const unsigned short* fb = fp + (size_t)b*HWq*128;

  for (int kp = 0; kp < 4; kp++) {
    int k0 = kp*2;
    int nk = (kp < 3) ? 2 : 1;
    for (int kk = 0; kk < nk; kk++) {
      int k = k0 + kk;
      unsigned short* myrow = sA + (size_t)(kk*128 + w*64 + l)*64;
      bool oob;
      const unsigned short *p0, *p1;
      float w0, w1;
      if (morph == 0) {
        int xi = c + k - 3;
        oob = (xi < 0 || xi >= Wq);
        if (!oob) {
          float y = (float)r + cum[((size_t)(b*7 + k))*HWq + p];
          float y0 = floorf(y);
          int y0q = (int)y0;
          int y0i = min(max(y0q, 0), Hq-1);
          int y1i = min(max(y0q + 1, 0), Hq-1);
          float y0f = fminf(fmaxf(y0, 0.f), (float)Hq);
          float y1f = fminf(fmaxf(y0 + 1.f, 0.f), (float)Hq);
          w0 = y1f - y; w1 = y - y0f;
          p0 = fb + ((size_t)y0i*Wq + xi)*8;
          p1 = fb + ((size_t)y1i*Wq + xi)*8;
        }
      } else {
        int yi = r + k - 3;
        oob = (yi < 0 || yi >= Hq);
        if (!oob) {
          float xf = (float)c + cum[((size_t)(b*7 + k))*HWq + p];
          float x0 = floorf(xf);
          int x0q = (int)x0;
          int x0i = min(max(x0q, 0), Wq-1);
          int x1i = min(max(x0q + 1, 0), Wq-1);
          float x0f = fminf(fmaxf(x0, 0.f), (float)Wq);
          float x1f = fminf(fmaxf(x0 + 1.f, 0.f), (float)Wq);
          w0 = x1f - xf; w1 = xf - x0f;
          p0 = fb + ((size_t)yi*Wq + x0i)*8;
          p1 = fb + ((size_t)yi*Wq + x1i)*8;
        }
      }
      if (oob) {
        uint4 z = {0u,0u,0u,0u};
#pragma unroll
        for (int j = 0; j < 8; j++) ((uint4*)myrow)[j] = z;
      } else {
#pragma unroll
        for (int g = 0; g < 8; g++) {
          f16x8 a0h = *(const f16x8*)(p0 + (size_t)g*HW8);
          f16x8 a1h = *(const f16x8*)(p1 + (size_t)g*HW8);
          f16x8 sh;
#pragma unroll
          for (int e = 0; e < 8; e++) {
            float v = w0*(float)a0h[e] + w1*(float)a1h[e];
            sh[e] = (_Float16)v;
          }
          *(f16x8*)(myrow + (size_t)(g ^ l7)*8) = sh;
        }
      }
    }
    for (int kk = 0; kk < nk; kk++) {
      int k = k0 + kk;
#pragma unroll
      for (int kc = 0; kc < 2; kc++) {
        const unsigned short* wbase = wtp + (size_t)((k*2 + kc)*2)*2048;
        f16x8 bh[4], bl[4];
#pragma unroll
        for (int tb = 0; tb < 4; tb++) {
          bh[tb] = *(const f16x8*)(wbase + (tb*16 + l15)*32 + lg*8);
          bl[tb] = *(const f16x8*)(wbase + 2048 + (tb*16 + l15)*32 + lg*8);
        }
        f16x8 ah[4];
#pragma unroll
        for (int ta = 0; ta < 4; ta++) {
          const unsigned short* rbase = sA + (size_t)(kk*128 + w*64 + ta*16 + l15)*64;
          ah[ta] = *(const f16x8*)(rbase + (size_t)((kc*4 + lg) ^ l7)*8);
        }
#pragma unroll
        for (int ta = 0; ta < 4; ta++)
#pragma unroll
          for (int tb = 0; tb < 4; tb++) {
            acc[ta][tb] = __builtin_amdgcn_mfma_f32_16x16x32_f16(ah[ta], bh[tb], acc[ta][tb], 0, 0, 0);
            acc[ta][tb] = __builtin_amdgcn_mfma_f32_16x16x32_f16(ah[ta], bl[tb], acc[ta][tb], 0, 0, 0);
          }
      }
    }
  }
  int pbase = blk*128 + w*64;
#pragma unroll
  for (int tb = 0; tb < 4; tb++) {
    int oc = tb*16 + l15;
    float bias = dsc_b[oc];
    float* dst = out + (size_t)(b*64 + oc)*HWq + pbase;
    float s = 0.f, ss = 0.f;
#pragma unroll
    for (int ta = 0; ta < 4; ta++) {
      f32x4 v = acc[ta][tb];
      float v0 = v[0]+bias, v1 = v[1]+bias, v2 = v[2]+bias, v3 = v[3]+bias;
      *(float4*)(dst + ta*16 + lg*4) = make_float4(v0, v1, v2, v3);
      s  += v0 + v1 + v2 + v3;
      ss += v0*v0 + v1*v1 + v2*v2 + v3*v3;
    }
    s  += __shfl_xor(s, 16);
    s  += __shfl_xor(s, 32);
    ss += __shfl_xor(ss, 16);
    ss += __shfl_xor(ss, 32);
    if (lg == 0) {
      float* pp = pstat + ((size_t)(morph*576 + swz)*2 + w)*128 + oc*2;
      pp[0] = s; pp[1] = ss;
    }
  }
}

// ---------------------------------------------------------------------------
// GN partial reduce: grid 256 (one block per (buf,b,ch)), reads pstat.
// ---------------------------------------------------------------------------
__global__ __launch_bounds__(256) void gnred_kernel(const float* __restrict__ pstat,
                                                    float* __restrict__ stats)
{
  int combo = blockIdx.x;           // buf*128 + b*64 + ch
  int buf = combo >> 7;
  int rem = combo & 127;
  int b = rem >> 6, ch = rem & 63;
  int t = threadIdx.x;
  float s = 0.f, ss = 0.f;
  for (int q = t; q < 576; q += 256) {
    int blk = q >> 1, w = q & 1;
    const float* pp = pstat + ((size_t)(buf*576 + b*288 + blk)*2 + w)*128 + ch*2;
    s += pp[0]; ss += pp[1];
  }
  __shared__ float red[2][4];
  for (int off = 32; off; off >>= 1) {
    s  += __shfl_down(s, off);
    ss += __shfl_down(ss, off);
  }
  if ((t & 63) == 0) { red[0][t >> 6] = s; red[1][t >> 6] = ss; }
  __syncthreads();
  if (t == 0) {
    s  = red[0][0] + red[0][1] + red[0][2] + red[0][3];
    ss = red[1][0] + red[1][1] + red[1][2] + red[1][3];
    stats[combo*2 + 0] = s;
    stats[combo*2 + 1] = ss;
  }
}

__global__ __launch_bounds__(256) void gnfinal_kernel(const float* __restrict__ stats,
                                                      const float* __restrict__ h_gn_g, const float* __restrict__ h_gn_b,
                                                      const float* __restrict__ v_gn_g, const float* __restrict__ v_gn_b,
                                                      float* __restrict__ gnAB)
{
  int t = threadIdx.x;
  int buf = t >> 7, ch = t & 63;
  int base = t & ~3;
  float sum = 0.f, ss = 0.f;
#pragma unroll
  for (int q = 0; q < 4; q++) { sum += stats[(base+q)*2]; ss += stats[(base+q)*2 + 1]; }
  const float n = 4.f * HWq;
  float mean = sum / n;
  float var = ss / n - mean*mean;
  float gg = (buf ? v_gn_g : h_gn_g)[ch];
  float bb = (buf ? v_gn_b : h_gn_b)[ch];
  float A = gg / sqrtf(var + 1e-5f);
  gnAB[t*2 + 0] = A;
  gnAB[t*2 + 1] = bb - mean*A;
}

// ---------------------------------------------------------------------------
// FUSED: comb = relu(GN(h)) + relu(GN(v)) + x1 inline, then 1x1 conv + SiLU
// ---------------------------------------------------------------------------
__global__ __launch_bounds__(256) void final2_kernel(const float* __restrict__ hbuf,
                                                     const float* __restrict__ vbuf,
                                                     const float* __restrict__ x1,
                                                     const float* __restrict__ gnAB,
                                                     const float* __restrict__ lwT,
                                                     const float* __restrict__ lbO,
                                                     float* __restrict__ out)
{
  int b = blockIdx.y;
  int p = blockIdx.x*256 + threadIdx.x;
  float acc[64];
#pragma unroll
  for (int o = 0; o < 64; o++) acc[o] = 0.f;
  for (int i = 0; i < 64; i++) {
    size_t off = (size_t)(b*64 + i)*HWq + p;
    int plane = b*64 + i;
    int ih = plane*2;
    int iv = (128 + plane)*2;
    float hv = fmaxf(hbuf[off]*gnAB[ih] + gnAB[ih+1], 0.f);
    float vv = fmaxf(vbuf[off]*gnAB[iv] + gnAB[iv+1], 0.f);
    float cv = hv + vv + x1[off];
    const float* wr = lwT + i*64;
#pragma unroll
    for (int o = 0; o < 64; o++) acc[o] += cv * wr[o];
  }
  float* dst = out + (size_t)b*Cq*HWq + p;
#pragma unroll
  for (int o = 0; o < 64; o++) {
    float yv = acc[o] + lbO[o];
    dst[(size_t)o*HWq] = yv / (1.f + expf(-yv));
  }
}

// ---------------------------------------------------------------------------
extern "C" void kernel_launch(void* const* d_in, const int* in_sizes, int n_in,
                              void* d_out, int out_size, void* d_ws, size_t ws_size,
                              hipStream_t stream)
{
  const float* x       = (const float*)d_in[0];
  const float* w_first = (const float*)d_in[1];
  float* ws = (float*)d_ws;

  float* bufA = ws;            // conv7 out -> h-einsum-out
  float* bufB = ws + Nq;       // v-einsum-out
  float* x1   = ws + 2*Nq;
  float* h_ds = ws + 3*Nq;     // xpack -> fpackH
  float* v_ds = ws + 4*Nq;     // fpackV
  size_t off = 5*Nq;
  float* hcum  = ws + off; off += (size_t)Bq*7*HWq;
  float* vcum  = ws + off; off += (size_t)Bq*7*HWq;
  float* wEffH = ws + off; off += 64*19;
  float* bEffH = ws + off; off += 64;
  float* wEffV = ws + off; off += 64*19;
  float* bEffV = ws + off; off += 64;
  float* wtH   = ws + off; off += 64*64*7;   // holds wtpH f16 pack
  float* wtV   = ws + off; off += 64*64*7;   // holds wtpV f16 pack
  float* wOffH = ws + off; off += 9*64*8;
  float* bOffH = ws + off; off += 8;
  float* wOffV = ws + off; off += 9*64*8;
  float* bOffV = ws + off; off += 8;
  float* lwT   = ws + off; off += 64*64;
  float* lbO   = ws + off; off += 64;
  float* stats = ws + off; off += 512;
  float* gnAB  = ws + off; off += 512;
  float* wB    = ws + off; off += 2*64*18*20;
  float* pstat = ws + off; off += (size_t)2*576*2*128;
  unsigned short* wpack = (unsigned short*)(ws + off); off += 2*49*2*64*32/2 + 16;
  unsigned short* xpack  = (unsigned short*)h_ds;
  unsigned short* fpackH = (unsigned short*)h_ds;
  unsigned short* fpackV = (unsigned short*)v_ds;
  unsigned short* wtpH = (unsigned short*)wtH;
  unsigned short* wtpV = (unsigned short*)wtV;

  prep_all_kernel<<<dim3(74), dim3(256), 0, stream>>>(
      (const float*)d_in[2],  (const float*)d_in[3],  (const float*)d_in[4],  (const float*)d_in[5],
      (const float*)d_in[6],  (const float*)d_in[7],
      (const float*)d_in[8],  (const float*)d_in[9],  (const float*)d_in[10], (const float*)d_in[11],
      (const float*)d_in[12], (const float*)d_in[13],
      (const float*)d_in[14], (const float*)d_in[15], (const float*)d_in[16], (const float*)d_in[17],
      (const float*)d_in[18], (const float*)d_in[19],
      (const float*)d_in[24], (const float*)d_in[25], (const float*)d_in[26], (const float*)d_in[27],
      (const float*)d_in[28], (const float*)d_in[29],
      (const float*)d_in[34], (const float*)d_in[35], (const float*)d_in[36], (const float*)d_in[37],
      (const float*)d_in[38],
      w_first, (const float*)d_in[20], (const float*)d_in[30],
      wEffH, bEffH, wEffV, bEffV, wOffH, bOffH, wOffV, bOffV, lwT, lbO, wB,
      wtpH, wtpV, wpack);

  tof16_pack_kernel<<<dim3(Hq, Bq), dim3(192), 0, stream>>>(x, xpack);
  conv7_mfma_kernel<<<dim3(4, 96, 2), dim3(256), 0, stream>>>(xpack, wpack, bufA);

  pool_fused_kernel<<<dim3(6, 128), dim3(256), 0, stream>>>(bufA, x1);

  dwf_kernel<<<dim3(144, 8, 4), dim3(256), 0, stream>>>(x1, wEffH, bEffH, wB,
      wEffV, bEffV, wB + 64*18*20, fpackH, fpackV);

  off_cum_kernel<<<dim3(576), dim3(256), 0, stream>>>(fpackH, fpackV,
      wOffH, bOffH, wOffV, bOffV, hcum, vcum);

  einsum_mfma_kernel<<<dim3(576, 2), dim3(128), 0, stream>>>(fpackH, fpackV,
      hcum, vcum, wtpH, wtpV, (const float*)d_in[21], (const float*)d_in[31], bufA, bufB, pstat);

  gnred_kernel<<<dim3(256), dim3(256), 0, stream>>>(pstat, stats);
  gnfinal_kernel<<<dim3(1), dim3(256), 0, stream>>>(stats,
      (const float*)d_in[22], (const float*)d_in[23],
      (const float*)d_in[32], (const float*)d_in[33], gnAB);

  final2_kernel<<<dim3(144, 2), dim3(256), 0, stream>>>(bufA, bufB, x1, gnAB, lwT, lbO, (float*)d_out);
}